// Round 2
// baseline (1458.419 us; speedup 1.0000x reference)
//
#include <hip/hip_runtime.h>
#include <cfloat>
#include <cmath>

// ---------------------------------------------------------------------------
// Round 19: inline-asm load pipeline for the decoder convT kernels.
// R18 post-mortem: C-level double-buffer + sched_barrier did NOT stick --
// VGPR stayed at 56 (two stages need ~96 live), so the compiler re-rolled
// the staging into load->wait->use chains at IR level. Counters confirm
// zero memory ILP: 36 cy per load-instr per CU == 1 outstanding load/wave
// at ~435cy latency.
// Fix: asm volatile global_load_dwordx2/dwordx4/ushort (cannot be
// reordered/serialized by the compiler; outputs forced live) + counted
// "s_waitcnt vmcnt(12)" (one full stage of 12 loads stays in flight, never
// drained to 0 in-loop) + sched_barrier(0) after each waitcnt (guide rule:
// MFMAs otherwise hoist past inline-asm waits). launch_bounds(256,3) gives
// a 170-VGPR cap so the ~130-reg live set cannot spill (scratch VMEM would
// corrupt the vmcnt counting). Per-accumulator MFMA order unchanged =>
// bit-identical results. Applied to convt_mfma_v2 (dec2/dec3) and
// convt_mfma (dec1). Everything else unchanged from R18.
// ---------------------------------------------------------------------------

using f32x4  = __attribute__((ext_vector_type(4))) float;
using bf16x8 = __attribute__((ext_vector_type(8))) short;
typedef float f32x4u __attribute__((ext_vector_type(4), aligned(4)));
typedef unsigned short u16x4u __attribute__((ext_vector_type(4), aligned(4)));

__device__ __forceinline__ unsigned short f32_to_bf16(float f) {
    unsigned int u = __float_as_uint(f);
    u += 0x7fffu + ((u >> 16) & 1u);          // round-to-nearest-even
    return (unsigned short)(u >> 16);
}
__device__ __forceinline__ void split_bf16(float v, unsigned short& h, unsigned short& l) {
    h = f32_to_bf16(v);
    float hf = __uint_as_float((unsigned)h << 16);
    l = f32_to_bf16(v - hf);
}
__device__ __forceinline__ void store_act(float* p, float v) { *p = v; }
__device__ __forceinline__ void store_act(unsigned short* p, float v) { *p = f32_to_bf16(v); }

template <typename V>
__device__ __forceinline__ bf16x8 pack_b(V r0, V r1) {
    bf16x8 b;
    b[0] = (short)r0[0]; b[1] = (short)r0[1]; b[2] = (short)r0[2]; b[3] = (short)r0[3];
    b[4] = (short)r1[0]; b[5] = (short)r1[1]; b[6] = (short)r1[2]; b[7] = (short)r1[3];
    return b;
}

// ---------------- prep: weight hi/lo split ----------------
__global__ __launch_bounds__(256)
void prep_split_w(const float* __restrict__ w, short* __restrict__ whi,
                  short* __restrict__ wlo, long total)
{
    long idx = (long)blockIdx.x * blockDim.x + threadIdx.x;
    if (idx >= total) return;
    unsigned short h, l;
    split_bf16(w[idx], h, l);
    whi[idx] = (short)h; wlo[idx] = (short)l;
}

// ---------------- pad input -> hi/lo bf16 pitched planes --------------------
__global__ __launch_bounds__(256)
void pad_input_split(const float* __restrict__ x, unsigned short* __restrict__ xhi,
                     unsigned short* __restrict__ xlo)
{
    const int D = 64, PD = 66, PRX = 68, BC = 6;
    long total = (long)BC * PD * PD * PRX;
    long idx = (long)blockIdx.x * blockDim.x + threadIdx.x;
    if (idx >= total) return;
    int px = (int)(idx % PRX); long t = idx / PRX;
    int py = (int)(t % PD); t /= PD;
    int pz = (int)(t % PD); int c = (int)(t / PD);
    int ix = px - 1, iy = py - 1, iz = pz - 1;
    float v = 0.0f;
    if ((unsigned)ix < (unsigned)D && (unsigned)iy < (unsigned)D && (unsigned)iz < (unsigned)D)
        v = x[(((long)c * D + iz) * D + iy) * D + ix];
    unsigned short h, l;
    split_bf16(v, h, l);
    xhi[idx] = h; xlo[idx] = l;
}

__global__ __launch_bounds__(256)
void zero_halo_ps(unsigned short* __restrict__ p, int C, int PD, int PRX)
{
    long total = (long)C * PD * PD * PRX;
    long idx = (long)blockIdx.x * blockDim.x + threadIdx.x;
    if (idx >= total) return;
    int px = (int)(idx % PRX); long t = idx / PRX;
    int py = (int)(t % PD); t /= PD;
    int pz = (int)(t % PD);
    if (px == 0 || px >= PD - 1 || py == 0 || py == PD - 1 || pz == 0 || pz == PD - 1)
        p[idx] = 0;
}

template <typename T>
__global__ __launch_bounds__(256) void zero_halo_t(T* __restrict__ p, int C, int PD)
{
    long total = (long)C * PD * PD * PD;
    long idx = (long)blockIdx.x * blockDim.x + threadIdx.x;
    if (idx >= total) return;
    int px = (int)(idx % PD); long t = idx / PD;
    int py = (int)(t % PD); t /= PD;
    int pz = (int)(t % PD);
    if (px == 0 || px == PD - 1 || py == 0 || py == PD - 1 || pz == 0 || pz == PD - 1)
        p[idx] = (T)0;
}

// ---------------------------------------------------------------------------
// Conv3d k4 s2 p1 as MFMA implicit GEMM, bf16 hi/lo pair inputs (unchanged)
// ---------------------------------------------------------------------------
template <int CIN, int COUT, int DOUT, int PD, int PRX, int MTW, int OWT,
          int OWHALF, int KSPLIT, int OUTSPLIT>
__global__ __launch_bounds__(256)
void conv_s2_mfma(const unsigned short* __restrict__ xhi,
                  const unsigned short* __restrict__ xlo,
                  const short* __restrict__ Whi, const short* __restrict__ Wlo,
                  const float* __restrict__ bias,
                  unsigned short* __restrict__ yhi, unsigned short* __restrict__ ylo,
                  float* __restrict__ yf,
                  int OPD, int OPRX, int po, long sstride)
{
    constexpr int K = CIN * 64;
    constexpr int MWAVES = COUT / (16 * MTW);
    constexpr int RPB = 4 / MWAVES;
    constexpr int KN = (CIN * 2) / KSPLIT;

    int bx = blockIdx.x;
    const int ks = (KSPLIT > 1) ? (bx % KSPLIT) : 0;
    const int rowblk = (KSPLIT > 1) ? (bx / KSPLIT) : bx;
    const int lane = (int)threadIdx.x & 63, w = (int)threadIdx.x >> 6;
    const int mi = (MWAVES == 4) ? w : 0;
    const int ri = (MWAVES == 4) ? 0 : w;
    const int rowid = rowblk * RPB + ri;
    const int n16 = lane & 15, quad = lane >> 4;

    int b, od, oh, ow;
    if (OWHALF) {
        constexpr int NOH = DOUT / 2;
        const int ohb = rowid % NOH; int t = rowid / NOH;
        od = t % DOUT; b = t / DOUT;
        oh = ohb * 2 + (n16 >> 3);
        ow = n16 & 7;
    } else {
        const int owt = rowid % OWT; int t = rowid / OWT;
        oh = t % DOUT; t /= DOUT;
        od = t % DOUT; b = t / DOUT;
        ow = owt * 16 + n16;
    }

    const int co0 = mi * (MTW * 16);

    f32x4 acc[MTW];
    #pragma unroll
    for (int mt = 0; mt < MTW; ++mt)
        #pragma unroll
        for (int r = 0; r < 4; ++r) {
            int co = co0 + mt * 16 + quad * 4 + r;
            acc[mt][r] = (ks == 0) ? bias[co] : 0.0f;
        }

    const int sg0 = ks * KN;
    const long chs = (long)PD * PD * PRX;
    long off = ((long)(b * CIN + (sg0 >> 1)) * PD + (2 * od + (quad >> 1))) * PD * PRX
             + (long)(2 * oh + (quad & 1) * 2) * PRX + 2 * ow;
    const unsigned short* phi = xhi + off;
    const unsigned short* plo = xlo + off;
    const long incA = 2L * PD * PRX;
    const long incB = chs - 2L * PD * PRX;

    const short* a0h = Whi + (long)(co0 + n16) * K + sg0 * 32 + quad * 8;
    const short* a0l = Wlo + (long)(co0 + n16) * K + sg0 * 32 + quad * 8;

    #pragma unroll 2
    for (int s = 0; s < KN; ++s) {
        u16x4u h0 = *(const u16x4u*)phi;
        u16x4u h1 = *(const u16x4u*)(phi + PRX);
        u16x4u l0 = *(const u16x4u*)plo;
        u16x4u l1 = *(const u16x4u*)(plo + PRX);
        bf16x8 bhi = pack_b(h0, h1);
        bf16x8 blo = pack_b(l0, l1);
        #pragma unroll
        for (int mt = 0; mt < MTW; ++mt) {
            bf16x8 ah = *(const bf16x8*)(a0h + (long)mt * 16 * K + s * 32);
            bf16x8 al = *(const bf16x8*)(a0l + (long)mt * 16 * K + s * 32);
            acc[mt] = __builtin_amdgcn_mfma_f32_16x16x32_bf16(ah, bhi, acc[mt], 0, 0, 0);
            acc[mt] = __builtin_amdgcn_mfma_f32_16x16x32_bf16(ah, blo, acc[mt], 0, 0, 0);
            acc[mt] = __builtin_amdgcn_mfma_f32_16x16x32_bf16(al, bhi, acc[mt], 0, 0, 0);
        }
        long inc = (s & 1) ? incB : incA;
        phi += inc; plo += inc;
    }

    if (OUTSPLIT) {
        #pragma unroll
        for (int mt = 0; mt < MTW; ++mt)
            #pragma unroll
            for (int r = 0; r < 4; ++r) {
                int co = co0 + mt * 16 + quad * 4 + r;
                float v = fmaxf(acc[mt][r], 0.0f);
                unsigned short h, l;
                split_bf16(v, h, l);
                long o = (((long)(b * COUT + co) * OPD + od + po) * OPD + oh + po) * OPRX
                       + ow + po;
                yhi[o] = h; ylo[o] = l;
            }
    } else {
        #pragma unroll
        for (int mt = 0; mt < MTW; ++mt)
            #pragma unroll
            for (int r = 0; r < 4; ++r) {
                int co = co0 + mt * 16 + quad * 4 + r;
                long o = (long)ks * sstride
                       + (((long)(b * COUT + co) * OPD + od) * OPD + oh) * OPRX + ow;
                yf[o] = acc[mt][r];
            }
    }
}

__global__ __launch_bounds__(256)
void combine4_relu(const float* __restrict__ p, float* __restrict__ y, long N, long ss)
{
    long idx = (long)blockIdx.x * blockDim.x + threadIdx.x;
    if (idx >= N) return;
    float v = p[idx] + p[idx + ss] + p[idx + 2 * ss] + p[idx + 3 * ss];
    y[idx] = fmaxf(v, 0.0f);
}

// ---------------- 1x1 conv (fp32 exact) ----------------
__global__ __launch_bounds__(128)
void conv1x1_b(const float* __restrict__ x, const float* __restrict__ w,
               const float* __restrict__ bias, float* __restrict__ y)
{
    const int co = blockIdx.x & 255, b = blockIdx.x >> 8;
    const int s4 = (int)threadIdx.x * 4;
    const float* xb = x + (long)b * 256 * 512 + s4;
    const float* wr = w + (long)co * 256;      // uniform -> s_load
    float bv = bias[co];
    float4 acc = {bv, bv, bv, bv};
    for (int ci = 0; ci < 256; ++ci) {
        float wv = wr[ci];
        float4 xv = *(const float4*)(xb + (long)ci * 512);
        acc.x = fmaf(xv.x, wv, acc.x); acc.y = fmaf(xv.y, wv, acc.y);
        acc.z = fmaf(xv.z, wv, acc.z); acc.w = fmaf(xv.w, wv, acc.w);
    }
    *(float4*)(y + (long)(b * 256 + co) * 512 + s4) = acc;
}

// ---------------- VQ (fp32 exact; unchanged) ----------------
__global__ void codenorm_kernel(const float* __restrict__ cb, float* __restrict__ norms)
{
    int k = blockIdx.x;
    int lane = threadIdx.x;
    float s = 0.0f;
    const float* row = cb + (long)k * 256;
    for (int d = lane; d < 256; d += 64) { float v = row[d]; s = fmaf(v, v, s); }
    for (int off = 32; off > 0; off >>= 1) s += __shfl_down(s, off);
    if (lane == 0) norms[k] = s;
}

__global__ __launch_bounds__(256)
void vq_kernel(const float* __restrict__ lat, const float* __restrict__ cb,
               const float* __restrict__ norms, unsigned short* __restrict__ q,
               float* __restrict__ idx_out)
{
    __shared__ __align__(16) float row[256];
    __shared__ float s_best[256];
    __shared__ int   s_bidx[256];
    int r = blockIdx.x;
    int t = threadIdx.x;
    row[t] = lat[(long)r * 256 + t];
    __syncthreads();

    const float4* rowv = (const float4*)row;
    float latn = 0.0f;
    #pragma unroll 4
    for (int d = 0; d < 64; ++d) {
        float4 rv = rowv[d];
        latn = fmaf(rv.x, rv.x, latn); latn = fmaf(rv.y, rv.y, latn);
        latn = fmaf(rv.z, rv.z, latn); latn = fmaf(rv.w, rv.w, latn);
    }

    float best = FLT_MAX;
    int bidx = 0x7fffffff;
    for (int j = 0; j < 4; ++j) {
        int k = t + 256 * j;
        const float4* cr = (const float4*)(cb + (long)k * 256);
        float dot = 0.0f;
        #pragma unroll 4
        for (int d = 0; d < 64; ++d) {
            float4 c = cr[d]; float4 rv = rowv[d];
            dot = fmaf(rv.x, c.x, dot); dot = fmaf(rv.y, c.y, dot);
            dot = fmaf(rv.z, c.z, dot); dot = fmaf(rv.w, c.w, dot);
        }
        float sc = latn - 2.0f * dot + norms[k];
        if (sc < best || (sc == best && k < bidx)) { best = sc; bidx = k; }
    }
    s_best[t] = best; s_bidx[t] = bidx;
    __syncthreads();
    for (int off = 128; off > 0; off >>= 1) {
        if (t < off) {
            float o = s_best[t + off]; int oi = s_bidx[t + off];
            if (o < s_best[t] || (o == s_best[t] && oi < s_bidx[t])) {
                s_best[t] = o; s_bidx[t] = oi;
            }
        }
        __syncthreads();
    }
    int bk = s_bidx[0];
    int b = r >> 9, n = r & 511;
    int zz = n >> 6, yy = (n >> 3) & 7, xx = n & 7;
    q[(long)(b * 256 + t) * 1000 + ((long)(zz + 1) * 10 + (yy + 1)) * 10 + (xx + 1)]
        = f32_to_bf16(cb[(long)bk * 256 + t]);
    if (t == 0) idx_out[r] = (float)bk;
}

// ---------------- decoder: MFMA implicit-GEMM ConvTranspose ----------------
// xflip=0: B slot a <-> x offset (1-ax), kw=(1-px)+2*ax (old cube kernel).
// xflip=1: B slot a <-> x offset ax,     kw=(1-px)+2*(1-ax) (dword-pair kernel).
__global__ __launch_bounds__(256)
void prep_convt_w(const float* __restrict__ w, short* __restrict__ Ap,
                  int Cin, int Cout, int xflip)
{
    const int K = Cin * 8;
    long total = 8L * Cout * K;
    long idx = (long)blockIdx.x * blockDim.x + threadIdx.x;
    if (idx >= total) return;
    int k = (int)(idx % K);
    int co = (int)((idx / K) % Cout);
    int p = (int)(idx / ((long)K * Cout));
    int ci = k >> 3, a = k & 7;
    int az = (a >> 2) & 1, ay = (a >> 1) & 1, ax = a & 1;
    int pz = p >> 2, py = (p >> 1) & 1, px = p & 1;
    int axw = xflip ? (1 - ax) : ax;
    int kd = (1 - pz) + 2 * az, kh = (1 - py) + 2 * ay, kw = (1 - px) + 2 * axw;
    float v = w[((long)ci * Cout + co) * 64 + kd * 16 + kh * 4 + kw];
    Ap[idx] = (short)f32_to_bf16(v);
}

// Old cube-N layout (kept for dec1, DIN=8): nt-slab XCD swizzle + px inner.
// R19: inline-asm load pipeline, counted vmcnt(12), 2-stage double buffer.
template <int CIN, int COUT, int DIN, int OPAD, typename OutT>
__global__ __launch_bounds__(256, 2)
void convt_mfma(const unsigned short* __restrict__ Xp, const short* __restrict__ Ap,
                const float* __restrict__ bias, OutT* __restrict__ Y)
{
    constexpr int PD = DIN + 2;
    constexpr int PD3 = PD * PD * PD;
    constexpr int T = DIN >> 2;
    constexpr int NT = T * T * T;
    constexpr int SLAB = NT / 8;
    constexpr int OPD = 2 * DIN + 2 * OPAD;
    constexpr int K = CIN * 8;
    constexpr int MG = COUT >> 6;
    constexpr int nsteps = K >> 5;
    static_assert((nsteps & 1) == 0 && nsteps >= 4, "pipeline needs even nsteps >= 4");

    int bx = blockIdx.x;
    const int xcd = bx & 7;
    int local = bx >> 3;
    const int px = local & 1; local >>= 1;
    const int mg = local % MG; local /= MG;
    const int ntin = local % SLAB;
    const int pzy = local / SLAB;            // 0..3
    const int pz = pzy >> 1, py = pzy & 1;
    const int p = pz * 4 + py * 2 + px;
    const int nt = xcd * SLAB + ntin;

    const int lane = threadIdx.x & 63, wave = threadIdx.x >> 6;
    const int n16 = lane & 15, quad = lane >> 4;

    const int tx = nt % T, ty = (nt / T) % T, tz = nt / (T * T);
    const int mz = tz * 4 + wave, my = ty * 4 + (n16 >> 2), mx = tx * 4 + (n16 & 3);
    const int sp = ((mz + pz) * PD + (my + py)) * PD + (mx + px);

    const unsigned short* xq = Xp + (long)quad * PD3 + sp;

    const int cobase = mg * 64;
    const short* ap0 = Ap + ((long)p * COUT + cobase + n16) * K + quad * 8;

    f32x4 acc[4];
    #pragma unroll
    for (int cb = 0; cb < 4; ++cb) {
        const float* bp = bias + cobase + cb * 16 + quad * 4;
        acc[cb][0] = bp[0]; acc[cb][1] = bp[1]; acc[cb][2] = bp[2]; acc[cb][3] = bp[3];
    }

    constexpr int xoffs[8] = { (PD + 1) * PD + 1, (PD + 1) * PD, PD * PD + 1, PD * PD,
                               PD + 1, PD, 1, 0 };

    struct Buf { unsigned x[8]; bf16x8 a[4]; };
    Buf b0, b1;

    auto issue = [&](int s, Buf& b) {
        const unsigned short* xs = xq + (long)s * 4 * PD3;
        #pragma unroll
        for (int k = 0; k < 8; ++k)
            asm volatile("global_load_ushort %0, %1, off"
                         : "=v"(b.x[k]) : "v"(xs + xoffs[k]));
        const short* as = ap0 + s * 32;
        #pragma unroll
        for (int cb = 0; cb < 4; ++cb)
            asm volatile("global_load_dwordx4 %0, %1, off"
                         : "=v"(b.a[cb]) : "v"(as + (long)cb * 16 * K));
    };
    auto consume = [&](Buf& b) {
        bf16x8 bf;
        #pragma unroll
        for (int k = 0; k < 8; ++k) bf[k] = (short)b.x[k];
        #pragma unroll
        for (int cb = 0; cb < 4; ++cb)
            acc[cb] = __builtin_amdgcn_mfma_f32_16x16x32_bf16(b.a[cb], bf, acc[cb], 0, 0, 0);
    };

    issue(0, b0);
    issue(1, b1);
    #pragma unroll 1
    for (int s = 0; s < nsteps - 2; s += 2) {
        asm volatile("s_waitcnt vmcnt(12)" ::: "memory");
        __builtin_amdgcn_sched_barrier(0);
        consume(b0);
        __builtin_amdgcn_sched_barrier(0);
        issue(s + 2, b0);
        asm volatile("s_waitcnt vmcnt(12)" ::: "memory");
        __builtin_amdgcn_sched_barrier(0);
        consume(b1);
        __builtin_amdgcn_sched_barrier(0);
        issue(s + 3, b1);
    }
    asm volatile("s_waitcnt vmcnt(12)" ::: "memory");
    __builtin_amdgcn_sched_barrier(0);
    consume(b0);
    __builtin_amdgcn_sched_barrier(0);
    asm volatile("s_waitcnt vmcnt(0)" ::: "memory");
    __builtin_amdgcn_sched_barrier(0);
    consume(b1);
    __builtin_amdgcn_sched_barrier(0);

    const int opz = 2 * mz + pz + OPAD, opy = 2 * my + py + OPAD, opx = 2 * mx + px + OPAD;
    const long spo = ((long)opz * OPD + opy) * OPD + opx;
    #pragma unroll
    for (int cb = 0; cb < 4; ++cb) {
        #pragma unroll
        for (int r = 0; r < 4; ++r) {
            int co = cobase + cb * 16 + quad * 4 + r;
            float v = fmaxf(acc[cb][r], 0.0f);
            store_act(Y + (long)co * OPD * OPD * OPD + spo, v);
        }
    }
}

// Dword-pair B-gather (dec2/dec3), R19 inline-asm pipeline:
//  - asm volatile global_load_dwordx2 (X) / dwordx4 (A): compiler cannot
//    serialize or re-roll them; 12 loads of the next stage stay in flight
//  - counted s_waitcnt vmcnt(12) (never 0 in-loop), sched_barrier(0) fences
//  - launch_bounds(256,3): 170-VGPR cap, ~130 live -> no scratch spills
//    (a spill inside the loop would break the vmcnt counting)
template <int CIN, int COUT, int DIN, int OPAD, int MXP, int MYP, typename OutT>
__global__ __launch_bounds__(256, 3)
void convt_mfma_v2(const unsigned short* __restrict__ Xp, const short* __restrict__ Ap,
                   const float* __restrict__ bias, OutT* __restrict__ Y)
{
    constexpr int PD = DIN + 2;
    constexpr int PD3 = PD * PD * PD;
    constexpr int OPD = 2 * DIN + 2 * OPAD;
    constexpr int K = CIN * 8;
    constexpr int MG = COUT >> 6;
    constexpr int nsteps = K >> 5;           // even for all our layers
    static_assert((nsteps & 1) == 0 && nsteps >= 4, "pipeline needs even nsteps >= 4");
    constexpr int MXT = DIN / (16 * MXP);
    constexpr int MYT = DIN / (4 * MYP);
    constexpr int MZS = DIN / 8;             // mz per XCD slab
    constexpr int TPE = MXP * MYP;           // tiles per wave (one of MXP/MYP is 1)

    int bx = blockIdx.x;
    const int xcd = bx & 7;
    int local = bx >> 3;
    const int px = local & 1; local >>= 1;
    const int py = local & 1; local >>= 1;
    const int mg = local % MG; local /= MG;
    const int mxt = local % MXT; local /= MXT;
    const int myt = local % MYT; local /= MYT;
    const int pz = local & 1; local >>= 1;
    const int mzin = local;                  // 0..MZS-1
    const int mz = xcd * MZS + mzin;
    const int p = pz * 4 + py * 2 + px;

    const int lane = threadIdx.x & 63, wave = threadIdx.x >> 6;
    const int n16 = lane & 15, quad = lane >> 4;

    const int mx0 = mxt * (16 * MXP) + n16;
    const int my0 = myt * (4 * MYP) + wave * MYP;
    const int baseX = mx0 & ~1;
    const int sh = 16 * ((n16 & 1) + px);    // 0, 16, or 32
    const long sp = ((long)(mz + pz) * PD + (my0 + py)) * PD + baseX;

    const unsigned short* xq = Xp + (long)quad * PD3 + sp;

    const int cobase = mg * 64;
    const short* ap0 = Ap + ((long)p * COUT + cobase + n16) * K + quad * 8;

    f32x4 acc[TPE][4];
    #pragma unroll
    for (int t = 0; t < TPE; ++t)
        #pragma unroll
        for (int cb = 0; cb < 4; ++cb) {
            const float* bp = bias + cobase + cb * 16 + quad * 4;
            acc[t][cb][0] = bp[0]; acc[t][cb][1] = bp[1];
            acc[t][cb][2] = bp[2]; acc[t][cb][3] = bp[3];
        }

    constexpr int rowoff[4] = { (PD + 1) * PD, PD * PD, PD, 0 };

    union Frag { unsigned u[4]; bf16x8 b; };

    struct Buf { unsigned long long x[TPE][4]; bf16x8 a[4]; };
    Buf b0, b1;

    auto issue = [&](int s, Buf& b) {
        const unsigned short* xs = xq + (long)s * 4 * PD3;
        #pragma unroll
        for (int t = 0; t < TPE; ++t) {
            const int toff = (MXP > 1) ? t * 16 : t * PD;
            #pragma unroll
            for (int j = 0; j < 4; ++j)
                asm volatile("global_load_dwordx2 %0, %1, off"
                             : "=v"(b.x[t][j]) : "v"(xs + toff + rowoff[j]));
        }
        const short* as = ap0 + s * 32;
        #pragma unroll
        for (int cb = 0; cb < 4; ++cb)
            asm volatile("global_load_dwordx4 %0, %1, off"
                         : "=v"(b.a[cb]) : "v"(as + (long)cb * 16 * K));
    };

    auto consume = [&](Buf& b) {
        #pragma unroll
        for (int t = 0; t < TPE; ++t) {
            Frag fr;
            #pragma unroll
            for (int j = 0; j < 4; ++j)
                fr.u[j] = (unsigned)(b.x[t][j] >> sh);
            #pragma unroll
            for (int cb = 0; cb < 4; ++cb)
                acc[t][cb] = __builtin_amdgcn_mfma_f32_16x16x32_bf16(b.a[cb], fr.b,
                                                                     acc[t][cb], 0, 0, 0);
        }
    };

    issue(0, b0);
    issue(1, b1);
    #pragma unroll 1
    for (int s = 0; s < nsteps - 2; s += 2) {
        asm volatile("s_waitcnt vmcnt(12)" ::: "memory");
        __builtin_amdgcn_sched_barrier(0);
        consume(b0);
        __builtin_amdgcn_sched_barrier(0);
        issue(s + 2, b0);
        asm volatile("s_waitcnt vmcnt(12)" ::: "memory");
        __builtin_amdgcn_sched_barrier(0);
        consume(b1);
        __builtin_amdgcn_sched_barrier(0);
        issue(s + 3, b1);
    }
    asm volatile("s_waitcnt vmcnt(12)" ::: "memory");
    __builtin_amdgcn_sched_barrier(0);
    consume(b0);
    __builtin_amdgcn_sched_barrier(0);
    asm volatile("s_waitcnt vmcnt(0)" ::: "memory");
    __builtin_amdgcn_sched_barrier(0);
    consume(b1);
    __builtin_amdgcn_sched_barrier(0);

    const int opz = 2 * mz + pz + OPAD;
    #pragma unroll
    for (int t = 0; t < TPE; ++t) {
        const int opx = 2 * (mx0 + ((MXP > 1) ? t * 16 : 0)) + px + OPAD;
        const int opy = 2 * (my0 + ((MYP > 1) ? t : 0)) + py + OPAD;
        const long spo = ((long)opz * OPD + opy) * OPD + opx;
        #pragma unroll
        for (int cb = 0; cb < 4; ++cb) {
            #pragma unroll
            for (int r = 0; r < 4; ++r) {
                int co = cobase + cb * 16 + quad * 4 + r;
                float v = fmaxf(acc[t][cb][r], 0.0f);
                store_act(Y + (long)co * OPD * OPD * OPD + spo, v);
            }
        }
    }
}

// ---------------- dec4 as MFMA GEMM: 4 oh rows per wave (unchanged) ---------
__global__ __launch_bounds__(256)
void prep_dec4A(const float* __restrict__ w, short* __restrict__ Aw)
{
    int idx = blockIdx.x * 256 + (int)threadIdx.x;    // 0..65535
    int m = idx >> 12, k = idx & 4095;
    float v = (m < 3) ? w[m * 4096 + k] : 0.0f;
    Aw[idx] = (short)f32_to_bf16(v);
}

__global__ __launch_bounds__(256)
void conv_dec4_mfma(const float* __restrict__ d3, const short* __restrict__ Aw,
                    const float* __restrict__ bias, float* __restrict__ y)
{
    constexpr int D = 64, Dout = 61;
    int bx = blockIdx.x;
    const int slab = bx & 7;
    const int i = bx >> 3;                 // 0..127
    const int od = slab * 8 + (i >> 4);
    const int oh0 = (i & 15) * 4;          // covers oh0..oh0+3 (guard < 61)
    if (od >= Dout) return;
    const int lane = (int)threadIdx.x & 63, wave = (int)threadIdx.x >> 6;
    const int n16 = lane & 15, quad = lane >> 4;
    const int ow = wave * 16 + n16;

    f32x4 acc[4];
    #pragma unroll
    for (int j = 0; j < 4; ++j)
        #pragma unroll
        for (int r = 0; r < 4; ++r) {
            int co = quad * 4 + r;
            acc[j][r] = (co < 3) ? bias[co] : 0.0f;
        }

    const short* ap = Aw + (long)n16 * 4096 + quad * 8;   // m = lane&15
    const int kd0 = quad >> 1;
    const int kh0 = (quad & 1) * 2;
    const float* basez = d3 + ((long)(od + kd0) * D) * D + ow;
    int yoff[5];
    #pragma unroll
    for (int r = 0; r < 5; ++r) yoff[r] = min(oh0 + kh0 + r, D - 1) * D;

    #pragma unroll 4
    for (int s = 0; s < 128; ++s) {
        const int ci = s >> 1;
        const float* plane = basez + ((long)ci * D + (s & 1) * 2) * D * D;
        unsigned p0[5], p1[5];
        #pragma unroll
        for (int r = 0; r < 5; ++r) {
            f32x4u v = *(const f32x4u*)(plane + yoff[r]);
            p0[r] = (__float_as_uint(v[0]) >> 16) | (__float_as_uint(v[1]) & 0xffff0000u);
            p1[r] = (__float_as_uint(v[2]) >> 16) | (__float_as_uint(v[3]) & 0xffff0000u);
        }
        bf16x8 af = *(const bf16x8*)(ap + s * 32);
        #pragma unroll
        for (int j = 0; j < 4; ++j) {
            union { unsigned u[4]; bf16x8 b; } fr;
            fr.u[0] = p0[j];     fr.u[1] = p1[j];
            fr.u[2] = p0[j + 1]; fr.u[3] = p1[j + 1];
            acc[j] = __builtin_amdgcn_mfma_f32_16x16x32_bf16(af, fr.b, acc[j], 0, 0, 0);
        }
    }

    if (ow < Dout && quad == 0) {
        #pragma unroll
        for (int j = 0; j < 4; ++j) {
            const int oh = oh0 + j;
            if (oh >= Dout) continue;
            #pragma unroll
            for (int r = 0; r < 3; ++r)
                y[((long)(r * Dout + od) * Dout + oh) * Dout + ow] = tanhf(acc[j][r]);
        }
    }
}

extern "C" void kernel_launch(void* const* d_in, const int* in_sizes, int n_in,
                              void* d_out, int out_size, void* d_ws, size_t ws_size,
                              hipStream_t stream)
{
    const float* x        = (const float*)d_in[0];
    const float* enc_w1   = (const float*)d_in[1];
    const float* enc_b1   = (const float*)d_in[2];
    const float* enc_w2   = (const float*)d_in[3];
    const float* enc_b2   = (const float*)d_in[4];
    const float* enc_w3   = (const float*)d_in[5];
    const float* enc_b3   = (const float*)d_in[6];
    const float* enc_w4   = (const float*)d_in[7];
    const float* enc_b4   = (const float*)d_in[8];
    const float* codebook = (const float*)d_in[9];
    const float* dec_w1   = (const float*)d_in[10];
    const float* dec_b1   = (const float*)d_in[11];
    const float* dec_w2   = (const float*)d_in[12];
    const float* dec_b2   = (const float*)d_in[13];
    const float* dec_w3   = (const float*)d_in[14];
    const float* dec_b3   = (const float*)d_in[15];
    const float* dec_w4   = (const float*)d_in[16];
    const float* dec_b4   = (const float*)d_in[17];

    float* out = (float*)d_out;
    float* idx_out = out + 2L * 3 * 61 * 61 * 61;

    // ---- workspace (byte offsets) ----
    char* wsb = (char*)d_ws;
    float*          cn   = (float*)wsb;                        //      4,096
    unsigned short* qp   = (unsigned short*)(wsb + 4096);      //  1,024,000
    short*          Ap1  = (short*)(wsb + 1028096);            //  8,388,608
    short*          Ap2  = (short*)(wsb + 9416704);            //  4,194,304
    short*          Ap3  = (short*)(wsb + 13611008);           //  1,048,576
    short*          Aw4  = (short*)(wsb + 14659584);           //    131,072
    short*          W1hi = (short*)(wsb + 14790656);           //     24,576
    short*          W1lo = (short*)(wsb + 14815232);           //     24,576
    short*          W2hi = (short*)(wsb + 14839808);           //  1,048,576
    short*          W2lo = (short*)(wsb + 15888384);           //  1,048,576
    short*          W3hi = (short*)(wsb + 16936960);           //  4,194,304
    short*          W3lo = (short*)(wsb + 21131264);           //  4,194,304
    char* arena = wsb + 25325568;
    // encoder phase:
    unsigned short* xphi = (unsigned short*)arena;                    // (2,3,66,66,68)
    unsigned short* xplo = (unsigned short*)(arena + 3554496);
    unsigned short* h1hi = (unsigned short*)(arena + 7108992);        // (2,64,34,34,36)
    unsigned short* h1lo = (unsigned short*)(arena + 17762688);
    unsigned short* h2hi = (unsigned short*)(arena + 28416384);       // (2,128,18,18,20)
    unsigned short* h2lo = (unsigned short*)(arena + 31734144);
    float*          pp3  = (float*)(arena + 35051904);                // 4x(2,256,8^3)
    float*          h3   = (float*)(arena + 39246208);                // (2,256,512)
    float*          lat  = (float*)(arena + 40294784);                // (2,256,512)
    // decoder phase (after VQ; overlaps encoder buffers):
    unsigned short* d1 = (unsigned short*)arena;                      // (256,18^3) bf16
    unsigned short* d2 = (unsigned short*)(arena + 2985984);          // (128,34^3) bf16
    float*          d3 = (float*)(arena + 13047808);                  // (64,64^3) fp32
    // arena peak 80.2 MB; total 105.5 MB (< 112.2 MB proven in R0)

    dim3 blk(256);
    auto nblk = [](long n) { return dim3((unsigned)((n + 255) / 256)); };

    // ---- weight prep ----
    prep_convt_w<<<nblk(8L * 256 * 2048), blk, 0, stream>>>(dec_w1, Ap1, 256, 256, 0);
    prep_convt_w<<<nblk(8L * 128 * 2048), blk, 0, stream>>>(dec_w2, Ap2, 256, 128, 1);
    prep_convt_w<<<nblk(8L * 64 * 1024), blk, 0, stream>>>(dec_w3, Ap3, 128, 64, 1);
    prep_dec4A<<<dim3(256), blk, 0, stream>>>(dec_w4, Aw4);
    prep_split_w<<<nblk(12288), blk, 0, stream>>>(enc_w1, W1hi, W1lo, 12288);
    prep_split_w<<<nblk(524288), blk, 0, stream>>>(enc_w2, W2hi, W2lo, 524288);
    prep_split_w<<<nblk(2097152), blk, 0, stream>>>(enc_w3, W3hi, W3lo, 2097152);

    // ---- encoder (MFMA, bf16-pair) ----
    pad_input_split<<<nblk(6L * 66 * 66 * 68), blk, 0, stream>>>(x, xphi, xplo);
    zero_halo_ps<<<nblk(128L * 34 * 34 * 36), blk, 0, stream>>>(h1hi, 128, 34, 36);
    zero_halo_ps<<<nblk(128L * 34 * 34 * 36), blk, 0, stream>>>(h1lo, 128, 34, 36);
    conv_s2_mfma<3, 64, 32, 66, 68, 4, 2, 0, 1, 1><<<dim3(1024), blk, 0, stream>>>(
        xphi, xplo, W1hi, W1lo, enc_b1, h1hi, h1lo, nullptr, 34, 36, 1, 0);
    zero_halo_ps<<<nblk(256L * 18 * 18 * 20), blk, 0, stream>>>(h2hi, 256, 18, 20);
    zero_halo_ps<<<nblk(256L * 18 * 18 * 20), blk, 0, stream>>>(h2lo, 256, 18, 20);
    conv_s2_mfma<64, 128, 16, 34, 36, 2, 1, 0, 1, 1><<<dim3(512), blk, 0, stream>>>(
        h1hi, h1lo, W2hi, W2lo, enc_b2, h2hi, h2lo, nullptr, 18, 20, 1, 0);
    conv_s2_mfma<128, 256, 8, 18, 20, 4, 1, 1, 4, 0><<<dim3(256), blk, 0, stream>>>(
        h2hi, h2lo, W3hi, W3lo, enc_b3, nullptr, nullptr, pp3, 8, 8, 0, 262144);
    combine4_relu<<<nblk(262144), blk, 0, stream>>>(pp3, h3, 262144, 262144);
    conv1x1_b<<<dim3(512), dim3(128), 0, stream>>>(h3, enc_w4, enc_b4, lat);

    // ---- VQ (fp32 exact) ----
    codenorm_kernel<<<dim3(1024), dim3(64), 0, stream>>>(codebook, cn);
    zero_halo_t<unsigned short><<<nblk(512L * 10 * 10 * 10), blk, 0, stream>>>(qp, 512, 10);
    vq_kernel<<<dim3(1024), blk, 0, stream>>>(lat, codebook, cn, qp, idx_out);

    // ---- decoder halos ----
    zero_halo_t<unsigned short><<<nblk(256L * 18 * 18 * 18), blk, 0, stream>>>(d1, 256, 18);
    zero_halo_t<unsigned short><<<nblk(128L * 34 * 34 * 34), blk, 0, stream>>>(d2, 128, 34);

    // ---- decoder (MFMA) per batch ----
    for (int b = 0; b < 2; ++b) {
        const unsigned short* qb = qp + (long)b * 256 * 1000;
        float* outb = out + (long)b * 3 * 226981;
        // dec1 (DIN=8, old layout): grid = 8*2*4*1*4 = 256
        convt_mfma<256, 256, 8, 1, unsigned short><<<dim3(256), blk, 0, stream>>>(
            qb, Ap1, dec_b1, d1);
        // dec2 (v2, MXP=1 MYP=2): grid = 8 * (2*2*2*1*2*2*2) = 512
        convt_mfma_v2<256, 128, 16, 1, 1, 2, unsigned short><<<dim3(512), blk, 0, stream>>>(
            d1, Ap2, dec_b2, d2);
        // dec3 (v2, MXP=2 MYP=1): grid = 8 * (2*2*1*1*8*2*4) = 2048
        convt_mfma_v2<128, 64, 32, 0, 2, 1, float><<<dim3(2048), blk, 0, stream>>>(
            d2, Ap3, dec_b3, d3);
        conv_dec4_mfma<<<dim3(8 * 8 * 16), blk, 0, stream>>>(d3, Aw4, dec_b4, outb);
    }
}

// Round 3
// 1185.823 us; speedup vs baseline: 1.2299x; 1.2299x over previous
//
#include <hip/hip_runtime.h>
#include <cfloat>
#include <cmath>

// ---------------------------------------------------------------------------
// Round 20: attack VMEM address-processing throughput (TA), not scheduling.
// R17/R18/R19 all land at 186-188us despite three different schedules and
// occupancies (47% vs 38%) -- refutes latency-serialization; fits a
// TA-throughput model: ~384 cache-line touches per block-step (A-loads are
// 16 scattered lines each and are issued redundantly by all 4 waves).
// Fix:
//   (a) fragment-major weight layout [p][mg][s][cb][lane][8] (new prep) so
//       the per-step A tile is one contiguous 4KB block;
//   (b) stage A via LDS once per block: each wave loads one contiguous 1KB
//       chunk (16 sequential lines), ds_write_b128, ds_read_b128 fragments.
//       A line-touches per block-step: 256 -> 64. One barrier per step.
//   (c) revert all inline-asm experiments; X loads are plain C again.
// Same fragment values in the same MFMA order => bit-identical results.
// dec1 (convt_mfma) restored to the round-0 body.
// ---------------------------------------------------------------------------

using f32x4  = __attribute__((ext_vector_type(4))) float;
using bf16x8 = __attribute__((ext_vector_type(8))) short;
typedef float f32x4u __attribute__((ext_vector_type(4), aligned(4)));
typedef unsigned short u16x4u __attribute__((ext_vector_type(4), aligned(4)));

__device__ __forceinline__ unsigned short f32_to_bf16(float f) {
    unsigned int u = __float_as_uint(f);
    u += 0x7fffu + ((u >> 16) & 1u);          // round-to-nearest-even
    return (unsigned short)(u >> 16);
}
__device__ __forceinline__ void split_bf16(float v, unsigned short& h, unsigned short& l) {
    h = f32_to_bf16(v);
    float hf = __uint_as_float((unsigned)h << 16);
    l = f32_to_bf16(v - hf);
}
__device__ __forceinline__ void store_act(float* p, float v) { *p = v; }
__device__ __forceinline__ void store_act(unsigned short* p, float v) { *p = f32_to_bf16(v); }

template <typename V>
__device__ __forceinline__ bf16x8 pack_b(V r0, V r1) {
    bf16x8 b;
    b[0] = (short)r0[0]; b[1] = (short)r0[1]; b[2] = (short)r0[2]; b[3] = (short)r0[3];
    b[4] = (short)r1[0]; b[5] = (short)r1[1]; b[6] = (short)r1[2]; b[7] = (short)r1[3];
    return b;
}

// ---------------- prep: weight hi/lo split ----------------
__global__ __launch_bounds__(256)
void prep_split_w(const float* __restrict__ w, short* __restrict__ whi,
                  short* __restrict__ wlo, long total)
{
    long idx = (long)blockIdx.x * blockDim.x + threadIdx.x;
    if (idx >= total) return;
    unsigned short h, l;
    split_bf16(w[idx], h, l);
    whi[idx] = (short)h; wlo[idx] = (short)l;
}

// ---------------- pad input -> hi/lo bf16 pitched planes --------------------
__global__ __launch_bounds__(256)
void pad_input_split(const float* __restrict__ x, unsigned short* __restrict__ xhi,
                     unsigned short* __restrict__ xlo)
{
    const int D = 64, PD = 66, PRX = 68, BC = 6;
    long total = (long)BC * PD * PD * PRX;
    long idx = (long)blockIdx.x * blockDim.x + threadIdx.x;
    if (idx >= total) return;
    int px = (int)(idx % PRX); long t = idx / PRX;
    int py = (int)(t % PD); t /= PD;
    int pz = (int)(t % PD); int c = (int)(t / PD);
    int ix = px - 1, iy = py - 1, iz = pz - 1;
    float v = 0.0f;
    if ((unsigned)ix < (unsigned)D && (unsigned)iy < (unsigned)D && (unsigned)iz < (unsigned)D)
        v = x[(((long)c * D + iz) * D + iy) * D + ix];
    unsigned short h, l;
    split_bf16(v, h, l);
    xhi[idx] = h; xlo[idx] = l;
}

__global__ __launch_bounds__(256)
void zero_halo_ps(unsigned short* __restrict__ p, int C, int PD, int PRX)
{
    long total = (long)C * PD * PD * PRX;
    long idx = (long)blockIdx.x * blockDim.x + threadIdx.x;
    if (idx >= total) return;
    int px = (int)(idx % PRX); long t = idx / PRX;
    int py = (int)(t % PD); t /= PD;
    int pz = (int)(t % PD);
    if (px == 0 || px >= PD - 1 || py == 0 || py == PD - 1 || pz == 0 || pz == PD - 1)
        p[idx] = 0;
}

template <typename T>
__global__ __launch_bounds__(256) void zero_halo_t(T* __restrict__ p, int C, int PD)
{
    long total = (long)C * PD * PD * PD;
    long idx = (long)blockIdx.x * blockDim.x + threadIdx.x;
    if (idx >= total) return;
    int px = (int)(idx % PD); long t = idx / PD;
    int py = (int)(t % PD); t /= PD;
    int pz = (int)(t % PD);
    if (px == 0 || px == PD - 1 || py == 0 || py == PD - 1 || pz == 0 || pz == PD - 1)
        p[idx] = (T)0;
}

// ---------------------------------------------------------------------------
// Conv3d k4 s2 p1 as MFMA implicit GEMM, bf16 hi/lo pair inputs (unchanged)
// ---------------------------------------------------------------------------
template <int CIN, int COUT, int DOUT, int PD, int PRX, int MTW, int OWT,
          int OWHALF, int KSPLIT, int OUTSPLIT>
__global__ __launch_bounds__(256)
void conv_s2_mfma(const unsigned short* __restrict__ xhi,
                  const unsigned short* __restrict__ xlo,
                  const short* __restrict__ Whi, const short* __restrict__ Wlo,
                  const float* __restrict__ bias,
                  unsigned short* __restrict__ yhi, unsigned short* __restrict__ ylo,
                  float* __restrict__ yf,
                  int OPD, int OPRX, int po, long sstride)
{
    constexpr int K = CIN * 64;
    constexpr int MWAVES = COUT / (16 * MTW);
    constexpr int RPB = 4 / MWAVES;
    constexpr int KN = (CIN * 2) / KSPLIT;

    int bx = blockIdx.x;
    const int ks = (KSPLIT > 1) ? (bx % KSPLIT) : 0;
    const int rowblk = (KSPLIT > 1) ? (bx / KSPLIT) : bx;
    const int lane = (int)threadIdx.x & 63, w = (int)threadIdx.x >> 6;
    const int mi = (MWAVES == 4) ? w : 0;
    const int ri = (MWAVES == 4) ? 0 : w;
    const int rowid = rowblk * RPB + ri;
    const int n16 = lane & 15, quad = lane >> 4;

    int b, od, oh, ow;
    if (OWHALF) {
        constexpr int NOH = DOUT / 2;
        const int ohb = rowid % NOH; int t = rowid / NOH;
        od = t % DOUT; b = t / DOUT;
        oh = ohb * 2 + (n16 >> 3);
        ow = n16 & 7;
    } else {
        const int owt = rowid % OWT; int t = rowid / OWT;
        oh = t % DOUT; t /= DOUT;
        od = t % DOUT; b = t / DOUT;
        ow = owt * 16 + n16;
    }

    const int co0 = mi * (MTW * 16);

    f32x4 acc[MTW];
    #pragma unroll
    for (int mt = 0; mt < MTW; ++mt)
        #pragma unroll
        for (int r = 0; r < 4; ++r) {
            int co = co0 + mt * 16 + quad * 4 + r;
            acc[mt][r] = (ks == 0) ? bias[co] : 0.0f;
        }

    const int sg0 = ks * KN;
    const long chs = (long)PD * PD * PRX;
    long off = ((long)(b * CIN + (sg0 >> 1)) * PD + (2 * od + (quad >> 1))) * PD * PRX
             + (long)(2 * oh + (quad & 1) * 2) * PRX + 2 * ow;
    const unsigned short* phi = xhi + off;
    const unsigned short* plo = xlo + off;
    const long incA = 2L * PD * PRX;
    const long incB = chs - 2L * PD * PRX;

    const short* a0h = Whi + (long)(co0 + n16) * K + sg0 * 32 + quad * 8;
    const short* a0l = Wlo + (long)(co0 + n16) * K + sg0 * 32 + quad * 8;

    #pragma unroll 2
    for (int s = 0; s < KN; ++s) {
        u16x4u h0 = *(const u16x4u*)phi;
        u16x4u h1 = *(const u16x4u*)(phi + PRX);
        u16x4u l0 = *(const u16x4u*)plo;
        u16x4u l1 = *(const u16x4u*)(plo + PRX);
        bf16x8 bhi = pack_b(h0, h1);
        bf16x8 blo = pack_b(l0, l1);
        #pragma unroll
        for (int mt = 0; mt < MTW; ++mt) {
            bf16x8 ah = *(const bf16x8*)(a0h + (long)mt * 16 * K + s * 32);
            bf16x8 al = *(const bf16x8*)(a0l + (long)mt * 16 * K + s * 32);
            acc[mt] = __builtin_amdgcn_mfma_f32_16x16x32_bf16(ah, bhi, acc[mt], 0, 0, 0);
            acc[mt] = __builtin_amdgcn_mfma_f32_16x16x32_bf16(ah, blo, acc[mt], 0, 0, 0);
            acc[mt] = __builtin_amdgcn_mfma_f32_16x16x32_bf16(al, bhi, acc[mt], 0, 0, 0);
        }
        long inc = (s & 1) ? incB : incA;
        phi += inc; plo += inc;
    }

    if (OUTSPLIT) {
        #pragma unroll
        for (int mt = 0; mt < MTW; ++mt)
            #pragma unroll
            for (int r = 0; r < 4; ++r) {
                int co = co0 + mt * 16 + quad * 4 + r;
                float v = fmaxf(acc[mt][r], 0.0f);
                unsigned short h, l;
                split_bf16(v, h, l);
                long o = (((long)(b * COUT + co) * OPD + od + po) * OPD + oh + po) * OPRX
                       + ow + po;
                yhi[o] = h; ylo[o] = l;
            }
    } else {
        #pragma unroll
        for (int mt = 0; mt < MTW; ++mt)
            #pragma unroll
            for (int r = 0; r < 4; ++r) {
                int co = co0 + mt * 16 + quad * 4 + r;
                long o = (long)ks * sstride
                       + (((long)(b * COUT + co) * OPD + od) * OPD + oh) * OPRX + ow;
                yf[o] = acc[mt][r];
            }
    }
}

__global__ __launch_bounds__(256)
void combine4_relu(const float* __restrict__ p, float* __restrict__ y, long N, long ss)
{
    long idx = (long)blockIdx.x * blockDim.x + threadIdx.x;
    if (idx >= N) return;
    float v = p[idx] + p[idx + ss] + p[idx + 2 * ss] + p[idx + 3 * ss];
    y[idx] = fmaxf(v, 0.0f);
}

// ---------------- 1x1 conv (fp32 exact) ----------------
__global__ __launch_bounds__(128)
void conv1x1_b(const float* __restrict__ x, const float* __restrict__ w,
               const float* __restrict__ bias, float* __restrict__ y)
{
    const int co = blockIdx.x & 255, b = blockIdx.x >> 8;
    const int s4 = (int)threadIdx.x * 4;
    const float* xb = x + (long)b * 256 * 512 + s4;
    const float* wr = w + (long)co * 256;      // uniform -> s_load
    float bv = bias[co];
    float4 acc = {bv, bv, bv, bv};
    for (int ci = 0; ci < 256; ++ci) {
        float wv = wr[ci];
        float4 xv = *(const float4*)(xb + (long)ci * 512);
        acc.x = fmaf(xv.x, wv, acc.x); acc.y = fmaf(xv.y, wv, acc.y);
        acc.z = fmaf(xv.z, wv, acc.z); acc.w = fmaf(xv.w, wv, acc.w);
    }
    *(float4*)(y + (long)(b * 256 + co) * 512 + s4) = acc;
}

// ---------------- VQ (fp32 exact; unchanged) ----------------
__global__ void codenorm_kernel(const float* __restrict__ cb, float* __restrict__ norms)
{
    int k = blockIdx.x;
    int lane = threadIdx.x;
    float s = 0.0f;
    const float* row = cb + (long)k * 256;
    for (int d = lane; d < 256; d += 64) { float v = row[d]; s = fmaf(v, v, s); }
    for (int off = 32; off > 0; off >>= 1) s += __shfl_down(s, off);
    if (lane == 0) norms[k] = s;
}

__global__ __launch_bounds__(256)
void vq_kernel(const float* __restrict__ lat, const float* __restrict__ cb,
               const float* __restrict__ norms, unsigned short* __restrict__ q,
               float* __restrict__ idx_out)
{
    __shared__ __align__(16) float row[256];
    __shared__ float s_best[256];
    __shared__ int   s_bidx[256];
    int r = blockIdx.x;
    int t = threadIdx.x;
    row[t] = lat[(long)r * 256 + t];
    __syncthreads();

    const float4* rowv = (const float4*)row;
    float latn = 0.0f;
    #pragma unroll 4
    for (int d = 0; d < 64; ++d) {
        float4 rv = rowv[d];
        latn = fmaf(rv.x, rv.x, latn); latn = fmaf(rv.y, rv.y, latn);
        latn = fmaf(rv.z, rv.z, latn); latn = fmaf(rv.w, rv.w, latn);
    }

    float best = FLT_MAX;
    int bidx = 0x7fffffff;
    for (int j = 0; j < 4; ++j) {
        int k = t + 256 * j;
        const float4* cr = (const float4*)(cb + (long)k * 256);
        float dot = 0.0f;
        #pragma unroll 4
        for (int d = 0; d < 64; ++d) {
            float4 c = cr[d]; float4 rv = rowv[d];
            dot = fmaf(rv.x, c.x, dot); dot = fmaf(rv.y, c.y, dot);
            dot = fmaf(rv.z, c.z, dot); dot = fmaf(rv.w, c.w, dot);
        }
        float sc = latn - 2.0f * dot + norms[k];
        if (sc < best || (sc == best && k < bidx)) { best = sc; bidx = k; }
    }
    s_best[t] = best; s_bidx[t] = bidx;
    __syncthreads();
    for (int off = 128; off > 0; off >>= 1) {
        if (t < off) {
            float o = s_best[t + off]; int oi = s_bidx[t + off];
            if (o < s_best[t] || (o == s_best[t] && oi < s_bidx[t])) {
                s_best[t] = o; s_bidx[t] = oi;
            }
        }
        __syncthreads();
    }
    int bk = s_bidx[0];
    int b = r >> 9, n = r & 511;
    int zz = n >> 6, yy = (n >> 3) & 7, xx = n & 7;
    q[(long)(b * 256 + t) * 1000 + ((long)(zz + 1) * 10 + (yy + 1)) * 10 + (xx + 1)]
        = f32_to_bf16(cb[(long)bk * 256 + t]);
    if (t == 0) idx_out[r] = (float)bk;
}

// ---------------- decoder: MFMA implicit-GEMM ConvTranspose ----------------
// xflip=0: B slot a <-> x offset (1-ax), kw=(1-px)+2*ax (old cube kernel).
// xflip=1: B slot a <-> x offset ax,     kw=(1-px)+2*(1-ax) (dword-pair kernel).
__global__ __launch_bounds__(256)
void prep_convt_w(const float* __restrict__ w, short* __restrict__ Ap,
                  int Cin, int Cout, int xflip)
{
    const int K = Cin * 8;
    long total = 8L * Cout * K;
    long idx = (long)blockIdx.x * blockDim.x + threadIdx.x;
    if (idx >= total) return;
    int k = (int)(idx % K);
    int co = (int)((idx / K) % Cout);
    int p = (int)(idx / ((long)K * Cout));
    int ci = k >> 3, a = k & 7;
    int az = (a >> 2) & 1, ay = (a >> 1) & 1, ax = a & 1;
    int pz = p >> 2, py = (p >> 1) & 1, px = p & 1;
    int axw = xflip ? (1 - ax) : ax;
    int kd = (1 - pz) + 2 * az, kh = (1 - py) + 2 * ay, kw = (1 - px) + 2 * axw;
    float v = w[((long)ci * Cout + co) * 64 + kd * 16 + kh * 4 + kw];
    Ap[idx] = (short)f32_to_bf16(v);
}

// Fragment-major layout for the LDS-staged v2 kernel:
//   ApN[((p*MG + mg)*nsteps + s)*2048 + cb*512 + l*8 + kk]
// where l = quad*16 + n16, korig = s*32 + quad*8 + kk, co = mg*64 + cb*16 + n16.
// Each (p,mg,s) tile is one contiguous 4KB block.
__global__ __launch_bounds__(256)
void prep_convt_w_frag(const float* __restrict__ w, short* __restrict__ Ap,
                       int Cin, int Cout, int xflip)
{
    const int MG = Cout >> 6;
    const int nsteps = Cin >> 2;             // (Cin*8)/32
    long total = 8L * MG * nsteps * 2048;
    long idx = (long)blockIdx.x * blockDim.x + threadIdx.x;
    if (idx >= total) return;
    int kk = (int)(idx & 7); long r = idx >> 3;
    int l  = (int)(r & 63);  r >>= 6;
    int cb = (int)(r & 3);   r >>= 2;
    int s  = (int)(r % nsteps); r /= nsteps;
    int mg = (int)(r % MG);
    int p  = (int)(r / MG);

    int n16 = l & 15, quad = l >> 4;
    int korig = s * 32 + quad * 8 + kk;
    int co = mg * 64 + cb * 16 + n16;
    int ci = korig >> 3, a = korig & 7;
    int az = (a >> 2) & 1, ay = (a >> 1) & 1, ax = a & 1;
    int pz = p >> 2, py = (p >> 1) & 1, px = p & 1;
    int axw = xflip ? (1 - ax) : ax;
    int kd = (1 - pz) + 2 * az, kh = (1 - py) + 2 * ay, kw = (1 - px) + 2 * axw;
    float v = w[((long)ci * Cout + co) * 64 + kd * 16 + kh * 4 + kw];
    Ap[idx] = (short)f32_to_bf16(v);
}

// Old cube-N layout (kept for dec1, DIN=8): round-0 body restored.
template <int CIN, int COUT, int DIN, int OPAD, typename OutT>
__global__ __launch_bounds__(256)
void convt_mfma(const unsigned short* __restrict__ Xp, const short* __restrict__ Ap,
                const float* __restrict__ bias, OutT* __restrict__ Y)
{
    constexpr int PD = DIN + 2;
    constexpr int PD3 = PD * PD * PD;
    constexpr int T = DIN >> 2;
    constexpr int NT = T * T * T;
    constexpr int SLAB = NT / 8;
    constexpr int OPD = 2 * DIN + 2 * OPAD;
    constexpr int K = CIN * 8;
    constexpr int MG = COUT >> 6;
    constexpr int nsteps = K >> 5;

    int bx = blockIdx.x;
    const int xcd = bx & 7;
    int local = bx >> 3;
    const int px = local & 1; local >>= 1;
    const int mg = local % MG; local /= MG;
    const int ntin = local % SLAB;
    const int pzy = local / SLAB;            // 0..3
    const int pz = pzy >> 1, py = pzy & 1;
    const int p = pz * 4 + py * 2 + px;
    const int nt = xcd * SLAB + ntin;

    const int lane = threadIdx.x & 63, wave = threadIdx.x >> 6;
    const int n16 = lane & 15, quad = lane >> 4;

    const int tx = nt % T, ty = (nt / T) % T, tz = nt / (T * T);
    const int mz = tz * 4 + wave, my = ty * 4 + (n16 >> 2), mx = tx * 4 + (n16 & 3);
    const int sp = ((mz + pz) * PD + (my + py)) * PD + (mx + px);

    const unsigned short* xq = Xp + (long)quad * PD3 + sp;

    const int cobase = mg * 64;
    const short* ap0 = Ap + ((long)p * COUT + cobase + n16) * K + quad * 8;

    f32x4 acc[4];
    #pragma unroll
    for (int cb = 0; cb < 4; ++cb) {
        const float* bp = bias + cobase + cb * 16 + quad * 4;
        acc[cb][0] = bp[0]; acc[cb][1] = bp[1]; acc[cb][2] = bp[2]; acc[cb][3] = bp[3];
    }

    #pragma unroll 4
    for (int s = 0; s < nsteps; ++s) {
        const unsigned short* xs = xq + (long)s * 4 * PD3;
        bf16x8 bf;
        bf[0] = (short)xs[(PD + 1) * PD + 1];
        bf[1] = (short)xs[(PD + 1) * PD];
        bf[2] = (short)xs[PD * PD + 1];
        bf[3] = (short)xs[PD * PD];
        bf[4] = (short)xs[PD + 1];
        bf[5] = (short)xs[PD];
        bf[6] = (short)xs[1];
        bf[7] = (short)xs[0];
        #pragma unroll
        for (int cb = 0; cb < 4; ++cb) {
            bf16x8 af = *(const bf16x8*)(ap0 + (long)cb * 16 * K + s * 32);
            acc[cb] = __builtin_amdgcn_mfma_f32_16x16x32_bf16(af, bf, acc[cb], 0, 0, 0);
        }
    }

    const int opz = 2 * mz + pz + OPAD, opy = 2 * my + py + OPAD, opx = 2 * mx + px + OPAD;
    const long spo = ((long)opz * OPD + opy) * OPD + opx;
    #pragma unroll
    for (int cb = 0; cb < 4; ++cb) {
        #pragma unroll
        for (int r = 0; r < 4; ++r) {
            int co = cobase + cb * 16 + quad * 4 + r;
            float v = fmaxf(acc[cb][r], 0.0f);
            store_act(Y + (long)co * OPD * OPD * OPD + spo, v);
        }
    }
}

// Dword-pair B-gather (dec2/dec3), R20: A staged through LDS.
//  - fragment-major ApN: per-step A tile = contiguous 4KB
//  - each wave loads 1KB chunk (1 dwordx4/lane, 16 sequential lines),
//    ds_write_b128; all waves ds_read_b128 their fragments (shared 4x)
//  - one __syncthreads per step; X loads stay per-lane plain C
template <int CIN, int COUT, int DIN, int OPAD, int MXP, int MYP, typename OutT>
__global__ __launch_bounds__(256)
void convt_mfma_v2(const unsigned short* __restrict__ Xp, const short* __restrict__ Ap,
                   const float* __restrict__ bias, OutT* __restrict__ Y)
{
    constexpr int PD = DIN + 2;
    constexpr int PD3 = PD * PD * PD;
    constexpr int OPD = 2 * DIN + 2 * OPAD;
    constexpr int K = CIN * 8;
    constexpr int MG = COUT >> 6;
    constexpr int nsteps = K >> 5;
    static_assert(nsteps >= 2, "need at least 2 K-steps");
    constexpr int MXT = DIN / (16 * MXP);
    constexpr int MYT = DIN / (4 * MYP);
    constexpr int MZS = DIN / 8;             // mz per XCD slab
    constexpr int TPE = MXP * MYP;           // tiles per wave (one of MXP/MYP is 1)

    int bx = blockIdx.x;
    const int xcd = bx & 7;
    int local = bx >> 3;
    const int px = local & 1; local >>= 1;
    const int py = local & 1; local >>= 1;
    const int mg = local % MG; local /= MG;
    const int mxt = local % MXT; local /= MXT;
    const int myt = local % MYT; local /= MYT;
    const int pz = local & 1; local >>= 1;
    const int mzin = local;                  // 0..MZS-1
    const int mz = xcd * MZS + mzin;
    const int p = pz * 4 + py * 2 + px;

    const int lane = threadIdx.x & 63, wave = threadIdx.x >> 6;
    const int n16 = lane & 15, quad = lane >> 4;

    const int mx0 = mxt * (16 * MXP) + n16;
    const int my0 = myt * (4 * MYP) + wave * MYP;
    const int baseX = mx0 & ~1;
    const int sh = 16 * ((n16 & 1) + px);    // 0, 16, or 32
    const long sp = ((long)(mz + pz) * PD + (my0 + py)) * PD + baseX;

    const unsigned short* xq = Xp + (long)quad * PD3 + sp;

    // fragment-major weight tiles: 2048 shorts (4KB) per (p,mg,s)
    const short* ApT = Ap + (((long)p * MG + mg) * nsteps) * 2048;

    __shared__ short Abuf[2][2048];          // 8KB double buffer

    f32x4 acc[TPE][4];
    #pragma unroll
    for (int t = 0; t < TPE; ++t)
        #pragma unroll
        for (int cb = 0; cb < 4; ++cb) {
            const float* bp = bias + (mg * 64) + cb * 16 + quad * 4;
            acc[t][cb][0] = bp[0]; acc[t][cb][1] = bp[1];
            acc[t][cb][2] = bp[2]; acc[t][cb][3] = bp[3];
        }

    constexpr int rowoff[4] = { (PD + 1) * PD, PD * PD, PD, 0 };
    union Frag { unsigned u[4]; bf16x8 b; };

    const int chunkoff = wave * 512 + lane * 8;   // this thread's 16B of the 4KB tile

    // prologue: stage step 0
    {
        bf16x8 a0 = *(const bf16x8*)(ApT + chunkoff);
        *(bf16x8*)(&Abuf[0][chunkoff]) = a0;
    }
    __syncthreads();

    #pragma unroll 1
    for (int s = 0; s < nsteps; ++s) {
        const int cur = s & 1;
        bf16x8 anext;
        const bool more = (s + 1 < nsteps);
        if (more)
            anext = *(const bf16x8*)(ApT + (long)(s + 1) * 2048 + chunkoff);

        // X loads (plain C, raw staging)
        const unsigned short* xs = xq + (long)s * 4 * PD3;
        unsigned long long xr[TPE][4];
        #pragma unroll
        for (int t = 0; t < TPE; ++t) {
            const int toff = (MXP > 1) ? t * 16 : t * PD;
            #pragma unroll
            for (int j = 0; j < 4; ++j) {
                union { u16x4u v; unsigned long long u; } ld;
                ld.v = *(const u16x4u*)(xs + toff + rowoff[j]);
                xr[t][j] = ld.u;
            }
        }

        // A fragments from LDS (l = quad*16 + n16 == lane)
        bf16x8 af[4];
        #pragma unroll
        for (int cb = 0; cb < 4; ++cb)
            af[cb] = *(const bf16x8*)(&Abuf[cur][cb * 512 + lane * 8]);

        #pragma unroll
        for (int t = 0; t < TPE; ++t) {
            Frag fr;
            #pragma unroll
            for (int j = 0; j < 4; ++j)
                fr.u[j] = (unsigned)(xr[t][j] >> sh);
            #pragma unroll
            for (int cb = 0; cb < 4; ++cb)
                acc[t][cb] = __builtin_amdgcn_mfma_f32_16x16x32_bf16(af[cb], fr.b,
                                                                     acc[t][cb], 0, 0, 0);
        }

        if (more)
            *(bf16x8*)(&Abuf[cur ^ 1][chunkoff]) = anext;
        __syncthreads();
    }

    const int opz = 2 * mz + pz + OPAD;
    #pragma unroll
    for (int t = 0; t < TPE; ++t) {
        const int opx = 2 * (mx0 + ((MXP > 1) ? t * 16 : 0)) + px + OPAD;
        const int opy = 2 * (my0 + ((MYP > 1) ? t : 0)) + py + OPAD;
        const long spo = ((long)opz * OPD + opy) * OPD + opx;
        #pragma unroll
        for (int cb = 0; cb < 4; ++cb) {
            #pragma unroll
            for (int r = 0; r < 4; ++r) {
                int co = (mg * 64) + cb * 16 + quad * 4 + r;
                float v = fmaxf(acc[t][cb][r], 0.0f);
                store_act(Y + (long)co * OPD * OPD * OPD + spo, v);
            }
        }
    }
}

// ---------------- dec4 as MFMA GEMM: 4 oh rows per wave (unchanged) ---------
__global__ __launch_bounds__(256)
void prep_dec4A(const float* __restrict__ w, short* __restrict__ Aw)
{
    int idx = blockIdx.x * 256 + (int)threadIdx.x;    // 0..65535
    int m = idx >> 12, k = idx & 4095;
    float v = (m < 3) ? w[m * 4096 + k] : 0.0f;
    Aw[idx] = (short)f32_to_bf16(v);
}

__global__ __launch_bounds__(256)
void conv_dec4_mfma(const float* __restrict__ d3, const short* __restrict__ Aw,
                    const float* __restrict__ bias, float* __restrict__ y)
{
    constexpr int D = 64, Dout = 61;
    int bx = blockIdx.x;
    const int slab = bx & 7;
    const int i = bx >> 3;                 // 0..127
    const int od = slab * 8 + (i >> 4);
    const int oh0 = (i & 15) * 4;          // covers oh0..oh0+3 (guard < 61)
    if (od >= Dout) return;
    const int lane = (int)threadIdx.x & 63, wave = (int)threadIdx.x >> 6;
    const int n16 = lane & 15, quad = lane >> 4;
    const int ow = wave * 16 + n16;

    f32x4 acc[4];
    #pragma unroll
    for (int j = 0; j < 4; ++j)
        #pragma unroll
        for (int r = 0; r < 4; ++r) {
            int co = quad * 4 + r;
            acc[j][r] = (co < 3) ? bias[co] : 0.0f;
        }

    const short* ap = Aw + (long)n16 * 4096 + quad * 8;   // m = lane&15
    const int kd0 = quad >> 1;
    const int kh0 = (quad & 1) * 2;
    const float* basez = d3 + ((long)(od + kd0) * D) * D + ow;
    int yoff[5];
    #pragma unroll
    for (int r = 0; r < 5; ++r) yoff[r] = min(oh0 + kh0 + r, D - 1) * D;

    #pragma unroll 4
    for (int s = 0; s < 128; ++s) {
        const int ci = s >> 1;
        const float* plane = basez + ((long)ci * D + (s & 1) * 2) * D * D;
        unsigned p0[5], p1[5];
        #pragma unroll
        for (int r = 0; r < 5; ++r) {
            f32x4u v = *(const f32x4u*)(plane + yoff[r]);
            p0[r] = (__float_as_uint(v[0]) >> 16) | (__float_as_uint(v[1]) & 0xffff0000u);
            p1[r] = (__float_as_uint(v[2]) >> 16) | (__float_as_uint(v[3]) & 0xffff0000u);
        }
        bf16x8 af = *(const bf16x8*)(ap + s * 32);
        #pragma unroll
        for (int j = 0; j < 4; ++j) {
            union { unsigned u[4]; bf16x8 b; } fr;
            fr.u[0] = p0[j];     fr.u[1] = p1[j];
            fr.u[2] = p0[j + 1]; fr.u[3] = p1[j + 1];
            acc[j] = __builtin_amdgcn_mfma_f32_16x16x32_bf16(af, fr.b, acc[j], 0, 0, 0);
        }
    }

    if (ow < Dout && quad == 0) {
        #pragma unroll
        for (int j = 0; j < 4; ++j) {
            const int oh = oh0 + j;
            if (oh >= Dout) continue;
            #pragma unroll
            for (int r = 0; r < 3; ++r)
                y[((long)(r * Dout + od) * Dout + oh) * Dout + ow] = tanhf(acc[j][r]);
        }
    }
}

extern "C" void kernel_launch(void* const* d_in, const int* in_sizes, int n_in,
                              void* d_out, int out_size, void* d_ws, size_t ws_size,
                              hipStream_t stream)
{
    const float* x        = (const float*)d_in[0];
    const float* enc_w1   = (const float*)d_in[1];
    const float* enc_b1   = (const float*)d_in[2];
    const float* enc_w2   = (const float*)d_in[3];
    const float* enc_b2   = (const float*)d_in[4];
    const float* enc_w3   = (const float*)d_in[5];
    const float* enc_b3   = (const float*)d_in[6];
    const float* enc_w4   = (const float*)d_in[7];
    const float* enc_b4   = (const float*)d_in[8];
    const float* codebook = (const float*)d_in[9];
    const float* dec_w1   = (const float*)d_in[10];
    const float* dec_b1   = (const float*)d_in[11];
    const float* dec_w2   = (const float*)d_in[12];
    const float* dec_b2   = (const float*)d_in[13];
    const float* dec_w3   = (const float*)d_in[14];
    const float* dec_b3   = (const float*)d_in[15];
    const float* dec_w4   = (const float*)d_in[16];
    const float* dec_b4   = (const float*)d_in[17];

    float* out = (float*)d_out;
    float* idx_out = out + 2L * 3 * 61 * 61 * 61;

    // ---- workspace (byte offsets) ----
    char* wsb = (char*)d_ws;
    float*          cn   = (float*)wsb;                        //      4,096
    unsigned short* qp   = (unsigned short*)(wsb + 4096);      //  1,024,000
    short*          Ap1  = (short*)(wsb + 1028096);            //  8,388,608
    short*          Ap2  = (short*)(wsb + 9416704);            //  4,194,304
    short*          Ap3  = (short*)(wsb + 13611008);           //  1,048,576
    short*          Aw4  = (short*)(wsb + 14659584);           //    131,072
    short*          W1hi = (short*)(wsb + 14790656);           //     24,576
    short*          W1lo = (short*)(wsb + 14815232);           //     24,576
    short*          W2hi = (short*)(wsb + 14839808);           //  1,048,576
    short*          W2lo = (short*)(wsb + 15888384);           //  1,048,576
    short*          W3hi = (short*)(wsb + 16936960);           //  4,194,304
    short*          W3lo = (short*)(wsb + 21131264);           //  4,194,304
    char* arena = wsb + 25325568;
    // encoder phase:
    unsigned short* xphi = (unsigned short*)arena;                    // (2,3,66,66,68)
    unsigned short* xplo = (unsigned short*)(arena + 3554496);
    unsigned short* h1hi = (unsigned short*)(arena + 7108992);        // (2,64,34,34,36)
    unsigned short* h1lo = (unsigned short*)(arena + 17762688);
    unsigned short* h2hi = (unsigned short*)(arena + 28416384);       // (2,128,18,18,20)
    unsigned short* h2lo = (unsigned short*)(arena + 31734144);
    float*          pp3  = (float*)(arena + 35051904);                // 4x(2,256,8^3)
    float*          h3   = (float*)(arena + 39246208);                // (2,256,512)
    float*          lat  = (float*)(arena + 40294784);                // (2,256,512)
    // decoder phase (after VQ; overlaps encoder buffers):
    unsigned short* d1 = (unsigned short*)arena;                      // (256,18^3) bf16
    unsigned short* d2 = (unsigned short*)(arena + 2985984);          // (128,34^3) bf16
    float*          d3 = (float*)(arena + 13047808);                  // (64,64^3) fp32
    // arena peak 80.2 MB; total 105.5 MB (< 112.2 MB proven in R0)

    dim3 blk(256);
    auto nblk = [](long n) { return dim3((unsigned)((n + 255) / 256)); };

    // ---- weight prep ----
    prep_convt_w<<<nblk(8L * 256 * 2048), blk, 0, stream>>>(dec_w1, Ap1, 256, 256, 0);
    prep_convt_w_frag<<<nblk(8L * 128 * 2048), blk, 0, stream>>>(dec_w2, Ap2, 256, 128, 1);
    prep_convt_w_frag<<<nblk(8L * 64 * 1024), blk, 0, stream>>>(dec_w3, Ap3, 128, 64, 1);
    prep_dec4A<<<dim3(256), blk, 0, stream>>>(dec_w4, Aw4);
    prep_split_w<<<nblk(12288), blk, 0, stream>>>(enc_w1, W1hi, W1lo, 12288);
    prep_split_w<<<nblk(524288), blk, 0, stream>>>(enc_w2, W2hi, W2lo, 524288);
    prep_split_w<<<nblk(2097152), blk, 0, stream>>>(enc_w3, W3hi, W3lo, 2097152);

    // ---- encoder (MFMA, bf16-pair) ----
    pad_input_split<<<nblk(6L * 66 * 66 * 68), blk, 0, stream>>>(x, xphi, xplo);
    zero_halo_ps<<<nblk(128L * 34 * 34 * 36), blk, 0, stream>>>(h1hi, 128, 34, 36);
    zero_halo_ps<<<nblk(128L * 34 * 34 * 36), blk, 0, stream>>>(h1lo, 128, 34, 36);
    conv_s2_mfma<3, 64, 32, 66, 68, 4, 2, 0, 1, 1><<<dim3(1024), blk, 0, stream>>>(
        xphi, xplo, W1hi, W1lo, enc_b1, h1hi, h1lo, nullptr, 34, 36, 1, 0);
    zero_halo_ps<<<nblk(256L * 18 * 18 * 20), blk, 0, stream>>>(h2hi, 256, 18, 20);
    zero_halo_ps<<<nblk(256L * 18 * 18 * 20), blk, 0, stream>>>(h2lo, 256, 18, 20);
    conv_s2_mfma<64, 128, 16, 34, 36, 2, 1, 0, 1, 1><<<dim3(512), blk, 0, stream>>>(
        h1hi, h1lo, W2hi, W2lo, enc_b2, h2hi, h2lo, nullptr, 18, 20, 1, 0);
    conv_s2_mfma<128, 256, 8, 18, 20, 4, 1, 1, 4, 0><<<dim3(256), blk, 0, stream>>>(
        h2hi, h2lo, W3hi, W3lo, enc_b3, nullptr, nullptr, pp3, 8, 8, 0, 262144);
    combine4_relu<<<nblk(262144), blk, 0, stream>>>(pp3, h3, 262144, 262144);
    conv1x1_b<<<dim3(512), dim3(128), 0, stream>>>(h3, enc_w4, enc_b4, lat);

    // ---- VQ (fp32 exact) ----
    codenorm_kernel<<<dim3(1024), dim3(64), 0, stream>>>(codebook, cn);
    zero_halo_t<unsigned short><<<nblk(512L * 10 * 10 * 10), blk, 0, stream>>>(qp, 512, 10);
    vq_kernel<<<dim3(1024), blk, 0, stream>>>(lat, codebook, cn, qp, idx_out);

    // ---- decoder halos ----
    zero_halo_t<unsigned short><<<nblk(256L * 18 * 18 * 18), blk, 0, stream>>>(d1, 256, 18);
    zero_halo_t<unsigned short><<<nblk(128L * 34 * 34 * 34), blk, 0, stream>>>(d2, 128, 34);

    // ---- decoder (MFMA) per batch ----
    for (int b = 0; b < 2; ++b) {
        const unsigned short* qb = qp + (long)b * 256 * 1000;
        float* outb = out + (long)b * 3 * 226981;
        // dec1 (DIN=8, old layout): grid = 8*2*4*1*4 = 256
        convt_mfma<256, 256, 8, 1, unsigned short><<<dim3(256), blk, 0, stream>>>(
            qb, Ap1, dec_b1, d1);
        // dec2 (v2, MXP=1 MYP=2): grid = 8 * (2*2*2*1*2*2*2) = 512
        convt_mfma_v2<256, 128, 16, 1, 1, 2, unsigned short><<<dim3(512), blk, 0, stream>>>(
            d1, Ap2, dec_b2, d2);
        // dec3 (v2, MXP=2 MYP=1): grid = 8 * (2*2*1*1*8*2*4) = 2048
        convt_mfma_v2<128, 64, 32, 0, 2, 1, float><<<dim3(2048), blk, 0, stream>>>(
            d2, Ap3, dec_b3, d3);
        conv_dec4_mfma<<<dim3(8 * 8 * 16), blk, 0, stream>>>(d3, Aw4, dec_b4, outb);
    }
}

// Round 5
// 1125.426 us; speedup vs baseline: 1.2959x; 1.0537x over previous
//
#include <hip/hip_runtime.h>
#include <cfloat>
#include <cmath>

// ---------------------------------------------------------------------------
// Round 22 (= R21 resubmit; R21 bench was an infra failure, container died
// before any kernel verdict -- no compile/pytest/counter evidence of a bug,
// and a source audit found no hang/fault candidate: LDS 64KB static is legal,
// barriers are block-uniform, staging addresses stay in-bounds).
//
// R21 theory (unchanged): port the R20 decoder fix (fragment-major weights +
// LDS staging) to encoder conv_s2 layers 2 and 3. enc2 was the new top-5
// (153us, MfmaUtil 6.5%, occupancy 22.6%): same scattered-A-line disease
// (256 scattered line-touches/block-step). prep_split_w_frag emits
// per-step-contiguous hi/lo tiles [s][m][lane][8]; conv_s2_mfma_lds stages
// each step tile through a double-buffered LDS pair with coalesced dwordx4
// bursts. X loads, MFMA order, epilogue unchanged => bit-identical.
// ---------------------------------------------------------------------------

using f32x4  = __attribute__((ext_vector_type(4))) float;
using bf16x8 = __attribute__((ext_vector_type(8))) short;
typedef float f32x4u __attribute__((ext_vector_type(4), aligned(4)));
typedef unsigned short u16x4u __attribute__((ext_vector_type(4), aligned(4)));

__device__ __forceinline__ unsigned short f32_to_bf16(float f) {
    unsigned int u = __float_as_uint(f);
    u += 0x7fffu + ((u >> 16) & 1u);          // round-to-nearest-even
    return (unsigned short)(u >> 16);
}
__device__ __forceinline__ void split_bf16(float v, unsigned short& h, unsigned short& l) {
    h = f32_to_bf16(v);
    float hf = __uint_as_float((unsigned)h << 16);
    l = f32_to_bf16(v - hf);
}
__device__ __forceinline__ void store_act(float* p, float v) { *p = v; }
__device__ __forceinline__ void store_act(unsigned short* p, float v) { *p = f32_to_bf16(v); }

template <typename V>
__device__ __forceinline__ bf16x8 pack_b(V r0, V r1) {
    bf16x8 b;
    b[0] = (short)r0[0]; b[1] = (short)r0[1]; b[2] = (short)r0[2]; b[3] = (short)r0[3];
    b[4] = (short)r1[0]; b[5] = (short)r1[1]; b[6] = (short)r1[2]; b[7] = (short)r1[3];
    return b;
}

// ---------------- prep: weight hi/lo split (linear; enc1) ----------------
__global__ __launch_bounds__(256)
void prep_split_w(const float* __restrict__ w, short* __restrict__ whi,
                  short* __restrict__ wlo, long total)
{
    long idx = (long)blockIdx.x * blockDim.x + threadIdx.x;
    if (idx >= total) return;
    unsigned short h, l;
    split_bf16(w[idx], h, l);
    whi[idx] = (short)h; wlo[idx] = (short)l;
}

// Fragment-major hi/lo split for the LDS-staged conv_s2 (enc2/enc3):
//   whi[((s*MT + m)*64 + l)*8 + kk] = hi(w[co*K + korig])
// with MT = COUT/16, co = m*16 + (l&15), korig = s*32 + (l>>4)*8 + kk.
// Each step tile (COUT*32 shorts) is contiguous.
__global__ __launch_bounds__(256)
void prep_split_w_frag(const float* __restrict__ w, short* __restrict__ whi,
                       short* __restrict__ wlo, int CIN, int COUT)
{
    const int K = CIN * 64;
    const int MT = COUT >> 4;
    long total = (long)COUT * K;
    long idx = (long)blockIdx.x * blockDim.x + threadIdx.x;
    if (idx >= total) return;
    int kk = (int)(idx & 7); long r = idx >> 3;
    int l  = (int)(r & 63);  r >>= 6;
    int m  = (int)(r % MT);
    int s  = (int)(r / MT);
    int n16 = l & 15, quad = l >> 4;
    int co = m * 16 + n16;
    int korig = s * 32 + quad * 8 + kk;
    unsigned short h, lo16;
    split_bf16(w[(long)co * K + korig], h, lo16);
    whi[idx] = (short)h; wlo[idx] = (short)lo16;
}

// ---------------- pad input -> hi/lo bf16 pitched planes --------------------
__global__ __launch_bounds__(256)
void pad_input_split(const float* __restrict__ x, unsigned short* __restrict__ xhi,
                     unsigned short* __restrict__ xlo)
{
    const int D = 64, PD = 66, PRX = 68, BC = 6;
    long total = (long)BC * PD * PD * PRX;
    long idx = (long)blockIdx.x * blockDim.x + threadIdx.x;
    if (idx >= total) return;
    int px = (int)(idx % PRX); long t = idx / PRX;
    int py = (int)(t % PD); t /= PD;
    int pz = (int)(t % PD); int c = (int)(t / PD);
    int ix = px - 1, iy = py - 1, iz = pz - 1;
    float v = 0.0f;
    if ((unsigned)ix < (unsigned)D && (unsigned)iy < (unsigned)D && (unsigned)iz < (unsigned)D)
        v = x[(((long)c * D + iz) * D + iy) * D + ix];
    unsigned short h, l;
    split_bf16(v, h, l);
    xhi[idx] = h; xlo[idx] = l;
}

__global__ __launch_bounds__(256)
void zero_halo_ps(unsigned short* __restrict__ p, int C, int PD, int PRX)
{
    long total = (long)C * PD * PD * PRX;
    long idx = (long)blockIdx.x * blockDim.x + threadIdx.x;
    if (idx >= total) return;
    int px = (int)(idx % PRX); long t = idx / PRX;
    int py = (int)(t % PD); t /= PD;
    int pz = (int)(t % PD);
    if (px == 0 || px >= PD - 1 || py == 0 || py == PD - 1 || pz == 0 || pz == PD - 1)
        p[idx] = 0;
}

template <typename T>
__global__ __launch_bounds__(256) void zero_halo_t(T* __restrict__ p, int C, int PD)
{
    long total = (long)C * PD * PD * PD;
    long idx = (long)blockIdx.x * blockDim.x + threadIdx.x;
    if (idx >= total) return;
    int px = (int)(idx % PD); long t = idx / PD;
    int py = (int)(t % PD); t /= PD;
    int pz = (int)(t % PD);
    if (px == 0 || px == PD - 1 || py == 0 || py == PD - 1 || pz == 0 || pz == PD - 1)
        p[idx] = (T)0;
}

// ---------------------------------------------------------------------------
// Conv3d k4 s2 p1 as MFMA implicit GEMM, bf16 hi/lo pair inputs (enc1 only)
// ---------------------------------------------------------------------------
template <int CIN, int COUT, int DOUT, int PD, int PRX, int MTW, int OWT,
          int OWHALF, int KSPLIT, int OUTSPLIT>
__global__ __launch_bounds__(256)
void conv_s2_mfma(const unsigned short* __restrict__ xhi,
                  const unsigned short* __restrict__ xlo,
                  const short* __restrict__ Whi, const short* __restrict__ Wlo,
                  const float* __restrict__ bias,
                  unsigned short* __restrict__ yhi, unsigned short* __restrict__ ylo,
                  float* __restrict__ yf,
                  int OPD, int OPRX, int po, long sstride)
{
    constexpr int K = CIN * 64;
    constexpr int MWAVES = COUT / (16 * MTW);
    constexpr int RPB = 4 / MWAVES;
    constexpr int KN = (CIN * 2) / KSPLIT;

    int bx = blockIdx.x;
    const int ks = (KSPLIT > 1) ? (bx % KSPLIT) : 0;
    const int rowblk = (KSPLIT > 1) ? (bx / KSPLIT) : bx;
    const int lane = (int)threadIdx.x & 63, w = (int)threadIdx.x >> 6;
    const int mi = (MWAVES == 4) ? w : 0;
    const int ri = (MWAVES == 4) ? 0 : w;
    const int rowid = rowblk * RPB + ri;
    const int n16 = lane & 15, quad = lane >> 4;

    int b, od, oh, ow;
    if (OWHALF) {
        constexpr int NOH = DOUT / 2;
        const int ohb = rowid % NOH; int t = rowid / NOH;
        od = t % DOUT; b = t / DOUT;
        oh = ohb * 2 + (n16 >> 3);
        ow = n16 & 7;
    } else {
        const int owt = rowid % OWT; int t = rowid / OWT;
        oh = t % DOUT; t /= DOUT;
        od = t % DOUT; b = t / DOUT;
        ow = owt * 16 + n16;
    }

    const int co0 = mi * (MTW * 16);

    f32x4 acc[MTW];
    #pragma unroll
    for (int mt = 0; mt < MTW; ++mt)
        #pragma unroll
        for (int r = 0; r < 4; ++r) {
            int co = co0 + mt * 16 + quad * 4 + r;
            acc[mt][r] = (ks == 0) ? bias[co] : 0.0f;
        }

    const int sg0 = ks * KN;
    const long chs = (long)PD * PD * PRX;
    long off = ((long)(b * CIN + (sg0 >> 1)) * PD + (2 * od + (quad >> 1))) * PD * PRX
             + (long)(2 * oh + (quad & 1) * 2) * PRX + 2 * ow;
    const unsigned short* phi = xhi + off;
    const unsigned short* plo = xlo + off;
    const long incA = 2L * PD * PRX;
    const long incB = chs - 2L * PD * PRX;

    const short* a0h = Whi + (long)(co0 + n16) * K + sg0 * 32 + quad * 8;
    const short* a0l = Wlo + (long)(co0 + n16) * K + sg0 * 32 + quad * 8;

    #pragma unroll 2
    for (int s = 0; s < KN; ++s) {
        u16x4u h0 = *(const u16x4u*)phi;
        u16x4u h1 = *(const u16x4u*)(phi + PRX);
        u16x4u l0 = *(const u16x4u*)plo;
        u16x4u l1 = *(const u16x4u*)(plo + PRX);
        bf16x8 bhi = pack_b(h0, h1);
        bf16x8 blo = pack_b(l0, l1);
        #pragma unroll
        for (int mt = 0; mt < MTW; ++mt) {
            bf16x8 ah = *(const bf16x8*)(a0h + (long)mt * 16 * K + s * 32);
            bf16x8 al = *(const bf16x8*)(a0l + (long)mt * 16 * K + s * 32);
            acc[mt] = __builtin_amdgcn_mfma_f32_16x16x32_bf16(ah, bhi, acc[mt], 0, 0, 0);
            acc[mt] = __builtin_amdgcn_mfma_f32_16x16x32_bf16(ah, blo, acc[mt], 0, 0, 0);
            acc[mt] = __builtin_amdgcn_mfma_f32_16x16x32_bf16(al, bhi, acc[mt], 0, 0, 0);
        }
        long inc = (s & 1) ? incB : incA;
        phi += inc; plo += inc;
    }

    if (OUTSPLIT) {
        #pragma unroll
        for (int mt = 0; mt < MTW; ++mt)
            #pragma unroll
            for (int r = 0; r < 4; ++r) {
                int co = co0 + mt * 16 + quad * 4 + r;
                float v = fmaxf(acc[mt][r], 0.0f);
                unsigned short h, l;
                split_bf16(v, h, l);
                long o = (((long)(b * COUT + co) * OPD + od + po) * OPD + oh + po) * OPRX
                       + ow + po;
                yhi[o] = h; ylo[o] = l;
            }
    } else {
        #pragma unroll
        for (int mt = 0; mt < MTW; ++mt)
            #pragma unroll
            for (int r = 0; r < 4; ++r) {
                int co = co0 + mt * 16 + quad * 4 + r;
                long o = (long)ks * sstride
                       + (((long)(b * COUT + co) * OPD + od) * OPD + oh) * OPRX + ow;
                yf[o] = acc[mt][r];
            }
    }
}

// LDS-staged variant (enc2/enc3): fragment-major Whi/Wlo, per-step tile
// staged cooperatively into a double-buffered LDS pair. Same MFMA order.
template <int CIN, int COUT, int DOUT, int PD, int PRX, int MTW, int OWT,
          int OWHALF, int KSPLIT, int OUTSPLIT>
__global__ __launch_bounds__(256)
void conv_s2_mfma_lds(const unsigned short* __restrict__ xhi,
                      const unsigned short* __restrict__ xlo,
                      const short* __restrict__ Whi, const short* __restrict__ Wlo,
                      const float* __restrict__ bias,
                      unsigned short* __restrict__ yhi, unsigned short* __restrict__ ylo,
                      float* __restrict__ yf,
                      int OPD, int OPRX, int po, long sstride)
{
    constexpr int K = CIN * 64;
    constexpr int MWAVES = COUT / (16 * MTW);
    constexpr int RPB = 4 / MWAVES;
    constexpr int KN = (CIN * 2) / KSPLIT;
    constexpr int TILE = COUT * 32;                 // shorts per step tile
    constexpr int PASSES = TILE / (256 * 8);        // dwordx4 passes/thread
    static_assert(PASSES >= 1, "tile too small for 256-thread staging");

    int bx = blockIdx.x;
    const int ks = (KSPLIT > 1) ? (bx % KSPLIT) : 0;
    const int rowblk = (KSPLIT > 1) ? (bx / KSPLIT) : bx;
    const int tid = (int)threadIdx.x;
    const int lane = tid & 63, w = tid >> 6;
    const int mi = (MWAVES == 4) ? w : 0;
    const int ri = (MWAVES == 4) ? 0 : w;
    const int rowid = rowblk * RPB + ri;
    const int n16 = lane & 15, quad = lane >> 4;

    int b, od, oh, ow;
    if (OWHALF) {
        constexpr int NOH = DOUT / 2;
        const int ohb = rowid % NOH; int t = rowid / NOH;
        od = t % DOUT; b = t / DOUT;
        oh = ohb * 2 + (n16 >> 3);
        ow = n16 & 7;
    } else {
        const int owt = rowid % OWT; int t = rowid / OWT;
        oh = t % DOUT; t /= DOUT;
        od = t % DOUT; b = t / DOUT;
        ow = owt * 16 + n16;
    }

    const int co0 = mi * (MTW * 16);

    f32x4 acc[MTW];
    #pragma unroll
    for (int mt = 0; mt < MTW; ++mt)
        #pragma unroll
        for (int r = 0; r < 4; ++r) {
            int co = co0 + mt * 16 + quad * 4 + r;
            acc[mt][r] = (ks == 0) ? bias[co] : 0.0f;
        }

    const int sg0 = ks * KN;
    const long chs = (long)PD * PD * PRX;
    long off = ((long)(b * CIN + (sg0 >> 1)) * PD + (2 * od + (quad >> 1))) * PD * PRX
             + (long)(2 * oh + (quad & 1) * 2) * PRX + 2 * ow;
    const unsigned short* phi = xhi + off;
    const unsigned short* plo = xlo + off;
    const long incA = 2L * PD * PRX;
    const long incB = chs - 2L * PD * PRX;

    __shared__ short AhiB[2][TILE];
    __shared__ short AloB[2][TILE];

    // prologue: stage step 0
    {
        const long tb = (long)sg0 * TILE;
        #pragma unroll
        for (int j = 0; j < PASSES; ++j) {
            const int o = tid * 8 + j * 2048;
            *(bf16x8*)(&AhiB[0][o]) = *(const bf16x8*)(Whi + tb + o);
            *(bf16x8*)(&AloB[0][o]) = *(const bf16x8*)(Wlo + tb + o);
        }
    }
    __syncthreads();

    #pragma unroll 1
    for (int s = 0; s < KN; ++s) {
        const int cur = s & 1;
        const bool more = (s + 1 < KN);
        bf16x8 nh[PASSES], nl[PASSES];
        if (more) {
            const long tb = (long)(sg0 + s + 1) * TILE;
            #pragma unroll
            for (int j = 0; j < PASSES; ++j) {
                const int o = tid * 8 + j * 2048;
                nh[j] = *(const bf16x8*)(Whi + tb + o);
                nl[j] = *(const bf16x8*)(Wlo + tb + o);
            }
        }

        u16x4u h0 = *(const u16x4u*)phi;
        u16x4u h1 = *(const u16x4u*)(phi + PRX);
        u16x4u l0 = *(const u16x4u*)plo;
        u16x4u l1 = *(const u16x4u*)(plo + PRX);
        bf16x8 bhi = pack_b(h0, h1);
        bf16x8 blo = pack_b(l0, l1);

        #pragma unroll
        for (int mt = 0; mt < MTW; ++mt) {
            const int m = mi * MTW + mt;
            bf16x8 ah = *(const bf16x8*)(&AhiB[cur][(m * 64 + lane) * 8]);
            bf16x8 al = *(const bf16x8*)(&AloB[cur][(m * 64 + lane) * 8]);
            acc[mt] = __builtin_amdgcn_mfma_f32_16x16x32_bf16(ah, bhi, acc[mt], 0, 0, 0);
            acc[mt] = __builtin_amdgcn_mfma_f32_16x16x32_bf16(ah, blo, acc[mt], 0, 0, 0);
            acc[mt] = __builtin_amdgcn_mfma_f32_16x16x32_bf16(al, bhi, acc[mt], 0, 0, 0);
        }

        long inc = (s & 1) ? incB : incA;
        phi += inc; plo += inc;

        if (more) {
            #pragma unroll
            for (int j = 0; j < PASSES; ++j) {
                const int o = tid * 8 + j * 2048;
                *(bf16x8*)(&AhiB[cur ^ 1][o]) = nh[j];
                *(bf16x8*)(&AloB[cur ^ 1][o]) = nl[j];
            }
        }
        __syncthreads();
    }

    if (OUTSPLIT) {
        #pragma unroll
        for (int mt = 0; mt < MTW; ++mt)
            #pragma unroll
            for (int r = 0; r < 4; ++r) {
                int co = co0 + mt * 16 + quad * 4 + r;
                float v = fmaxf(acc[mt][r], 0.0f);
                unsigned short h, l;
                split_bf16(v, h, l);
                long o = (((long)(b * COUT + co) * OPD + od + po) * OPD + oh + po) * OPRX
                       + ow + po;
                yhi[o] = h; ylo[o] = l;
            }
    } else {
        #pragma unroll
        for (int mt = 0; mt < MTW; ++mt)
            #pragma unroll
            for (int r = 0; r < 4; ++r) {
                int co = co0 + mt * 16 + quad * 4 + r;
                long o = (long)ks * sstride
                       + (((long)(b * COUT + co) * OPD + od) * OPD + oh) * OPRX + ow;
                yf[o] = acc[mt][r];
            }
    }
}

__global__ __launch_bounds__(256)
void combine4_relu(const float* __restrict__ p, float* __restrict__ y, long N, long ss)
{
    long idx = (long)blockIdx.x * blockDim.x + threadIdx.x;
    if (idx >= N) return;
    float v = p[idx] + p[idx + ss] + p[idx + 2 * ss] + p[idx + 3 * ss];
    y[idx] = fmaxf(v, 0.0f);
}

// ---------------- 1x1 conv (fp32 exact) ----------------
__global__ __launch_bounds__(128)
void conv1x1_b(const float* __restrict__ x, const float* __restrict__ w,
               const float* __restrict__ bias, float* __restrict__ y)
{
    const int co = blockIdx.x & 255, b = blockIdx.x >> 8;
    const int s4 = (int)threadIdx.x * 4;
    const float* xb = x + (long)b * 256 * 512 + s4;
    const float* wr = w + (long)co * 256;      // uniform -> s_load
    float bv = bias[co];
    float4 acc = {bv, bv, bv, bv};
    for (int ci = 0; ci < 256; ++ci) {
        float wv = wr[ci];
        float4 xv = *(const float4*)(xb + (long)ci * 512);
        acc.x = fmaf(xv.x, wv, acc.x); acc.y = fmaf(xv.y, wv, acc.y);
        acc.z = fmaf(xv.z, wv, acc.z); acc.w = fmaf(xv.w, wv, acc.w);
    }
    *(float4*)(y + (long)(b * 256 + co) * 512 + s4) = acc;
}

// ---------------- VQ (fp32 exact; unchanged) ----------------
__global__ void codenorm_kernel(const float* __restrict__ cb, float* __restrict__ norms)
{
    int k = blockIdx.x;
    int lane = threadIdx.x;
    float s = 0.0f;
    const float* row = cb + (long)k * 256;
    for (int d = lane; d < 256; d += 64) { float v = row[d]; s = fmaf(v, v, s); }
    for (int off = 32; off > 0; off >>= 1) s += __shfl_down(s, off);
    if (lane == 0) norms[k] = s;
}

__global__ __launch_bounds__(256)
void vq_kernel(const float* __restrict__ lat, const float* __restrict__ cb,
               const float* __restrict__ norms, unsigned short* __restrict__ q,
               float* __restrict__ idx_out)
{
    __shared__ __align__(16) float row[256];
    __shared__ float s_best[256];
    __shared__ int   s_bidx[256];
    int r = blockIdx.x;
    int t = threadIdx.x;
    row[t] = lat[(long)r * 256 + t];
    __syncthreads();

    const float4* rowv = (const float4*)row;
    float latn = 0.0f;
    #pragma unroll 4
    for (int d = 0; d < 64; ++d) {
        float4 rv = rowv[d];
        latn = fmaf(rv.x, rv.x, latn); latn = fmaf(rv.y, rv.y, latn);
        latn = fmaf(rv.z, rv.z, latn); latn = fmaf(rv.w, rv.w, latn);
    }

    float best = FLT_MAX;
    int bidx = 0x7fffffff;
    for (int j = 0; j < 4; ++j) {
        int k = t + 256 * j;
        const float4* cr = (const float4*)(cb + (long)k * 256);
        float dot = 0.0f;
        #pragma unroll 4
        for (int d = 0; d < 64; ++d) {
            float4 c = cr[d]; float4 rv = rowv[d];
            dot = fmaf(rv.x, c.x, dot); dot = fmaf(rv.y, c.y, dot);
            dot = fmaf(rv.z, c.z, dot); dot = fmaf(rv.w, c.w, dot);
        }
        float sc = latn - 2.0f * dot + norms[k];
        if (sc < best || (sc == best && k < bidx)) { best = sc; bidx = k; }
    }
    s_best[t] = best; s_bidx[t] = bidx;
    __syncthreads();
    for (int off = 128; off > 0; off >>= 1) {
        if (t < off) {
            float o = s_best[t + off]; int oi = s_bidx[t + off];
            if (o < s_best[t] || (o == s_best[t] && oi < s_bidx[t])) {
                s_best[t] = o; s_bidx[t] = oi;
            }
        }
        __syncthreads();
    }
    int bk = s_bidx[0];
    int b = r >> 9, n = r & 511;
    int zz = n >> 6, yy = (n >> 3) & 7, xx = n & 7;
    q[(long)(b * 256 + t) * 1000 + ((long)(zz + 1) * 10 + (yy + 1)) * 10 + (xx + 1)]
        = f32_to_bf16(cb[(long)bk * 256 + t]);
    if (t == 0) idx_out[r] = (float)bk;
}

// ---------------- decoder: MFMA implicit-GEMM ConvTranspose ----------------
// xflip=0: B slot a <-> x offset (1-ax), kw=(1-px)+2*ax (old cube kernel).
// xflip=1: B slot a <-> x offset ax,     kw=(1-px)+2*(1-ax) (dword-pair kernel).
__global__ __launch_bounds__(256)
void prep_convt_w(const float* __restrict__ w, short* __restrict__ Ap,
                  int Cin, int Cout, int xflip)
{
    const int K = Cin * 8;
    long total = 8L * Cout * K;
    long idx = (long)blockIdx.x * blockDim.x + threadIdx.x;
    if (idx >= total) return;
    int k = (int)(idx % K);
    int co = (int)((idx / K) % Cout);
    int p = (int)(idx / ((long)K * Cout));
    int ci = k >> 3, a = k & 7;
    int az = (a >> 2) & 1, ay = (a >> 1) & 1, ax = a & 1;
    int pz = p >> 2, py = (p >> 1) & 1, px = p & 1;
    int axw = xflip ? (1 - ax) : ax;
    int kd = (1 - pz) + 2 * az, kh = (1 - py) + 2 * ay, kw = (1 - px) + 2 * axw;
    float v = w[((long)ci * Cout + co) * 64 + kd * 16 + kh * 4 + kw];
    Ap[idx] = (short)f32_to_bf16(v);
}

// Fragment-major layout for the LDS-staged v2 kernel:
//   ApN[((p*MG + mg)*nsteps + s)*2048 + cb*512 + l*8 + kk]
// where l = quad*16 + n16, korig = s*32 + quad*8 + kk, co = mg*64 + cb*16 + n16.
// Each (p,mg,s) tile is one contiguous 4KB block.
__global__ __launch_bounds__(256)
void prep_convt_w_frag(const float* __restrict__ w, short* __restrict__ Ap,
                       int Cin, int Cout, int xflip)
{
    const int MG = Cout >> 6;
    const int nsteps = Cin >> 2;             // (Cin*8)/32
    long total = 8L * MG * nsteps * 2048;
    long idx = (long)blockIdx.x * blockDim.x + threadIdx.x;
    if (idx >= total) return;
    int kk = (int)(idx & 7); long r = idx >> 3;
    int l  = (int)(r & 63);  r >>= 6;
    int cb = (int)(r & 3);   r >>= 2;
    int s  = (int)(r % nsteps); r /= nsteps;
    int mg = (int)(r % MG);
    int p  = (int)(r / MG);

    int n16 = l & 15, quad = l >> 4;
    int korig = s * 32 + quad * 8 + kk;
    int co = mg * 64 + cb * 16 + n16;
    int ci = korig >> 3, a = korig & 7;
    int az = (a >> 2) & 1, ay = (a >> 1) & 1, ax = a & 1;
    int pz = p >> 2, py = (p >> 1) & 1, px = p & 1;
    int axw = xflip ? (1 - ax) : ax;
    int kd = (1 - pz) + 2 * az, kh = (1 - py) + 2 * ay, kw = (1 - px) + 2 * axw;
    float v = w[((long)ci * Cout + co) * 64 + kd * 16 + kh * 4 + kw];
    Ap[idx] = (short)f32_to_bf16(v);
}

// Old cube-N layout (kept for dec1, DIN=8): round-0 body.
template <int CIN, int COUT, int DIN, int OPAD, typename OutT>
__global__ __launch_bounds__(256)
void convt_mfma(const unsigned short* __restrict__ Xp, const short* __restrict__ Ap,
                const float* __restrict__ bias, OutT* __restrict__ Y)
{
    constexpr int PD = DIN + 2;
    constexpr int PD3 = PD * PD * PD;
    constexpr int T = DIN >> 2;
    constexpr int NT = T * T * T;
    constexpr int SLAB = NT / 8;
    constexpr int OPD = 2 * DIN + 2 * OPAD;
    constexpr int K = CIN * 8;
    constexpr int MG = COUT >> 6;
    constexpr int nsteps = K >> 5;

    int bx = blockIdx.x;
    const int xcd = bx & 7;
    int local = bx >> 3;
    const int px = local & 1; local >>= 1;
    const int mg = local % MG; local /= MG;
    const int ntin = local % SLAB;
    const int pzy = local / SLAB;            // 0..3
    const int pz = pzy >> 1, py = pzy & 1;
    const int p = pz * 4 + py * 2 + px;
    const int nt = xcd * SLAB + ntin;

    const int lane = threadIdx.x & 63, wave = threadIdx.x >> 6;
    const int n16 = lane & 15, quad = lane >> 4;

    const int tx = nt % T, ty = (nt / T) % T, tz = nt / (T * T);
    const int mz = tz * 4 + wave, my = ty * 4 + (n16 >> 2), mx = tx * 4 + (n16 & 3);
    const int sp = ((mz + pz) * PD + (my + py)) * PD + (mx + px);

    const unsigned short* xq = Xp + (long)quad * PD3 + sp;

    const int cobase = mg * 64;
    const short* ap0 = Ap + ((long)p * COUT + cobase + n16) * K + quad * 8;

    f32x4 acc[4];
    #pragma unroll
    for (int cb = 0; cb < 4; ++cb) {
        const float* bp = bias + cobase + cb * 16 + quad * 4;
        acc[cb][0] = bp[0]; acc[cb][1] = bp[1]; acc[cb][2] = bp[2]; acc[cb][3] = bp[3];
    }

    #pragma unroll 4
    for (int s = 0; s < nsteps; ++s) {
        const unsigned short* xs = xq + (long)s * 4 * PD3;
        bf16x8 bf;
        bf[0] = (short)xs[(PD + 1) * PD + 1];
        bf[1] = (short)xs[(PD + 1) * PD];
        bf[2] = (short)xs[PD * PD + 1];
        bf[3] = (short)xs[PD * PD];
        bf[4] = (short)xs[PD + 1];
        bf[5] = (short)xs[PD];
        bf[6] = (short)xs[1];
        bf[7] = (short)xs[0];
        #pragma unroll
        for (int cb = 0; cb < 4; ++cb) {
            bf16x8 af = *(const bf16x8*)(ap0 + (long)cb * 16 * K + s * 32);
            acc[cb] = __builtin_amdgcn_mfma_f32_16x16x32_bf16(af, bf, acc[cb], 0, 0, 0);
        }
    }

    const int opz = 2 * mz + pz + OPAD, opy = 2 * my + py + OPAD, opx = 2 * mx + px + OPAD;
    const long spo = ((long)opz * OPD + opy) * OPD + opx;
    #pragma unroll
    for (int cb = 0; cb < 4; ++cb) {
        #pragma unroll
        for (int r = 0; r < 4; ++r) {
            int co = cobase + cb * 16 + quad * 4 + r;
            float v = fmaxf(acc[cb][r], 0.0f);
            store_act(Y + (long)co * OPD * OPD * OPD + spo, v);
        }
    }
}

// Dword-pair B-gather (dec2/dec3), R20: A staged through LDS (unchanged).
template <int CIN, int COUT, int DIN, int OPAD, int MXP, int MYP, typename OutT>
__global__ __launch_bounds__(256)
void convt_mfma_v2(const unsigned short* __restrict__ Xp, const short* __restrict__ Ap,
                   const float* __restrict__ bias, OutT* __restrict__ Y)
{
    constexpr int PD = DIN + 2;
    constexpr int PD3 = PD * PD * PD;
    constexpr int OPD = 2 * DIN + 2 * OPAD;
    constexpr int K = CIN * 8;
    constexpr int MG = COUT >> 6;
    constexpr int nsteps = K >> 5;
    static_assert(nsteps >= 2, "need at least 2 K-steps");
    constexpr int MXT = DIN / (16 * MXP);
    constexpr int MYT = DIN / (4 * MYP);
    constexpr int MZS = DIN / 8;             // mz per XCD slab
    constexpr int TPE = MXP * MYP;           // tiles per wave (one of MXP/MYP is 1)

    int bx = blockIdx.x;
    const int xcd = bx & 7;
    int local = bx >> 3;
    const int px = local & 1; local >>= 1;
    const int py = local & 1; local >>= 1;
    const int mg = local % MG; local /= MG;
    const int mxt = local % MXT; local /= MXT;
    const int myt = local % MYT; local /= MYT;
    const int pz = local & 1; local >>= 1;
    const int mzin = local;                  // 0..MZS-1
    const int mz = xcd * MZS + mzin;
    const int p = pz * 4 + py * 2 + px;

    const int lane = threadIdx.x & 63, wave = threadIdx.x >> 6;
    const int n16 = lane & 15, quad = lane >> 4;

    const int mx0 = mxt * (16 * MXP) + n16;
    const int my0 = myt * (4 * MYP) + wave * MYP;
    const int baseX = mx0 & ~1;
    const int sh = 16 * ((n16 & 1) + px);    // 0, 16, or 32
    const long sp = ((long)(mz + pz) * PD + (my0 + py)) * PD + baseX;

    const unsigned short* xq = Xp + (long)quad * PD3 + sp;

    // fragment-major weight tiles: 2048 shorts (4KB) per (p,mg,s)
    const short* ApT = Ap + (((long)p * MG + mg) * nsteps) * 2048;

    __shared__ short Abuf[2][2048];          // 8KB double buffer

    f32x4 acc[TPE][4];
    #pragma unroll
    for (int t = 0; t < TPE; ++t)
        #pragma unroll
        for (int cb = 0; cb < 4; ++cb) {
            const float* bp = bias + (mg * 64) + cb * 16 + quad * 4;
            acc[t][cb][0] = bp[0]; acc[t][cb][1] = bp[1];
            acc[t][cb][2] = bp[2]; acc[t][cb][3] = bp[3];
        }

    constexpr int rowoff[4] = { (PD + 1) * PD, PD * PD, PD, 0 };
    union Frag { unsigned u[4]; bf16x8 b; };

    const int chunkoff = wave * 512 + lane * 8;   // this thread's 16B of the 4KB tile

    // prologue: stage step 0
    {
        bf16x8 a0 = *(const bf16x8*)(ApT + chunkoff);
        *(bf16x8*)(&Abuf[0][chunkoff]) = a0;
    }
    __syncthreads();

    #pragma unroll 1
    for (int s = 0; s < nsteps; ++s) {
        const int cur = s & 1;
        bf16x8 anext;
        const bool more = (s + 1 < nsteps);
        if (more)
            anext = *(const bf16x8*)(ApT + (long)(s + 1) * 2048 + chunkoff);

        // X loads (plain C, raw staging)
        const unsigned short* xs = xq + (long)s * 4 * PD3;
        unsigned long long xr[TPE][4];
        #pragma unroll
        for (int t = 0; t < TPE; ++t) {
            const int toff = (MXP > 1) ? t * 16 : t * PD;
            #pragma unroll
            for (int j = 0; j < 4; ++j) {
                union { u16x4u v; unsigned long long u; } ld;
                ld.v = *(const u16x4u*)(xs + toff + rowoff[j]);
                xr[t][j] = ld.u;
            }
        }

        // A fragments from LDS (l = quad*16 + n16 == lane)
        bf16x8 af[4];
        #pragma unroll
        for (int cb = 0; cb < 4; ++cb)
            af[cb] = *(const bf16x8*)(&Abuf[cur][cb * 512 + lane * 8]);

        #pragma unroll
        for (int t = 0; t < TPE; ++t) {
            Frag fr;
            #pragma unroll
            for (int j = 0; j < 4; ++j)
                fr.u[j] = (unsigned)(xr[t][j] >> sh);
            #pragma unroll
            for (int cb = 0; cb < 4; ++cb)
                acc[t][cb] = __builtin_amdgcn_mfma_f32_16x16x32_bf16(af[cb], fr.b,
                                                                     acc[t][cb], 0, 0, 0);
        }

        if (more)
            *(bf16x8*)(&Abuf[cur ^ 1][chunkoff]) = anext;
        __syncthreads();
    }

    const int opz = 2 * mz + pz + OPAD;
    #pragma unroll
    for (int t = 0; t < TPE; ++t) {
        const int opx = 2 * (mx0 + ((MXP > 1) ? t * 16 : 0)) + px + OPAD;
        const int opy = 2 * (my0 + ((MYP > 1) ? t : 0)) + py + OPAD;
        const long spo = ((long)opz * OPD + opy) * OPD + opx;
        #pragma unroll
        for (int cb = 0; cb < 4; ++cb) {
            #pragma unroll
            for (int r = 0; r < 4; ++r) {
                int co = (mg * 64) + cb * 16 + quad * 4 + r;
                float v = fmaxf(acc[t][cb][r], 0.0f);
                store_act(Y + (long)co * OPD * OPD * OPD + spo, v);
            }
        }
    }
}

// ---------------- dec4 as MFMA GEMM: 4 oh rows per wave (unchanged) ---------
__global__ __launch_bounds__(256)
void prep_dec4A(const float* __restrict__ w, short* __restrict__ Aw)
{
    int idx = blockIdx.x * 256 + (int)threadIdx.x;    // 0..65535
    int m = idx >> 12, k = idx & 4095;
    float v = (m < 3) ? w[m * 4096 + k] : 0.0f;
    Aw[idx] = (short)f32_to_bf16(v);
}

__global__ __launch_bounds__(256)
void conv_dec4_mfma(const float* __restrict__ d3, const short* __restrict__ Aw,
                    const float* __restrict__ bias, float* __restrict__ y)
{
    constexpr int D = 64, Dout = 61;
    int bx = blockIdx.x;
    const int slab = bx & 7;
    const int i = bx >> 3;                 // 0..127
    const int od = slab * 8 + (i >> 4);
    const int oh0 = (i & 15) * 4;          // covers oh0..oh0+3 (guard < 61)
    if (od >= Dout) return;
    const int lane = (int)threadIdx.x & 63, wave = (int)threadIdx.x >> 6;
    const int n16 = lane & 15, quad = lane >> 4;
    const int ow = wave * 16 + n16;

    f32x4 acc[4];
    #pragma unroll
    for (int j = 0; j < 4; ++j)
        #pragma unroll
        for (int r = 0; r < 4; ++r) {
            int co = quad * 4 + r;
            acc[j][r] = (co < 3) ? bias[co] : 0.0f;
        }

    const short* ap = Aw + (long)n16 * 4096 + quad * 8;   // m = lane&15
    const int kd0 = quad >> 1;
    const int kh0 = (quad & 1) * 2;
    const float* basez = d3 + ((long)(od + kd0) * D) * D + ow;
    int yoff[5];
    #pragma unroll
    for (int r = 0; r < 5; ++r) yoff[r] = min(oh0 + kh0 + r, D - 1) * D;

    #pragma unroll 4
    for (int s = 0; s < 128; ++s) {
        const int ci = s >> 1;
        const float* plane = basez + ((long)ci * D + (s & 1) * 2) * D * D;
        unsigned p0[5], p1[5];
        #pragma unroll
        for (int r = 0; r < 5; ++r) {
            f32x4u v = *(const f32x4u*)(plane + yoff[r]);
            p0[r] = (__float_as_uint(v[0]) >> 16) | (__float_as_uint(v[1]) & 0xffff0000u);
            p1[r] = (__float_as_uint(v[2]) >> 16) | (__float_as_uint(v[3]) & 0xffff0000u);
        }
        bf16x8 af = *(const bf16x8*)(ap + s * 32);
        #pragma unroll
        for (int j = 0; j < 4; ++j) {
            union { unsigned u[4]; bf16x8 b; } fr;
            fr.u[0] = p0[j];     fr.u[1] = p1[j];
            fr.u[2] = p0[j + 1]; fr.u[3] = p1[j + 1];
            acc[j] = __builtin_amdgcn_mfma_f32_16x16x32_bf16(af, fr.b, acc[j], 0, 0, 0);
        }
    }

    if (ow < Dout && quad == 0) {
        #pragma unroll
        for (int j = 0; j < 4; ++j) {
            const int oh = oh0 + j;
            if (oh >= Dout) continue;
            #pragma unroll
            for (int r = 0; r < 3; ++r)
                y[((long)(r * Dout + od) * Dout + oh) * Dout + ow] = tanhf(acc[j][r]);
        }
    }
}

extern "C" void kernel_launch(void* const* d_in, const int* in_sizes, int n_in,
                              void* d_out, int out_size, void* d_ws, size_t ws_size,
                              hipStream_t stream)
{
    const float* x        = (const float*)d_in[0];
    const float* enc_w1   = (const float*)d_in[1];
    const float* enc_b1   = (const float*)d_in[2];
    const float* enc_w2   = (const float*)d_in[3];
    const float* enc_b2   = (const float*)d_in[4];
    const float* enc_w3   = (const float*)d_in[5];
    const float* enc_b3   = (const float*)d_in[6];
    const float* enc_w4   = (const float*)d_in[7];
    const float* enc_b4   = (const float*)d_in[8];
    const float* codebook = (const float*)d_in[9];
    const float* dec_w1   = (const float*)d_in[10];
    const float* dec_b1   = (const float*)d_in[11];
    const float* dec_w2   = (const float*)d_in[12];
    const float* dec_b2   = (const float*)d_in[13];
    const float* dec_w3   = (const float*)d_in[14];
    const float* dec_b3   = (const float*)d_in[15];
    const float* dec_w4   = (const float*)d_in[16];
    const float* dec_b4   = (const float*)d_in[17];

    float* out = (float*)d_out;
    float* idx_out = out + 2L * 3 * 61 * 61 * 61;

    // ---- workspace (byte offsets) ----
    char* wsb = (char*)d_ws;
    float*          cn   = (float*)wsb;                        //      4,096
    unsigned short* qp   = (unsigned short*)(wsb + 4096);      //  1,024,000
    short*          Ap1  = (short*)(wsb + 1028096);            //  8,388,608
    short*          Ap2  = (short*)(wsb + 9416704);            //  4,194,304
    short*          Ap3  = (short*)(wsb + 13611008);           //  1,048,576
    short*          Aw4  = (short*)(wsb + 14659584);           //    131,072
    short*          W1hi = (short*)(wsb + 14790656);           //     24,576
    short*          W1lo = (short*)(wsb + 14815232);           //     24,576
    short*          W2hi = (short*)(wsb + 14839808);           //  1,048,576
    short*          W2lo = (short*)(wsb + 15888384);           //  1,048,576
    short*          W3hi = (short*)(wsb + 16936960);           //  4,194,304
    short*          W3lo = (short*)(wsb + 21131264);           //  4,194,304
    char* arena = wsb + 25325568;
    // encoder phase:
    unsigned short* xphi = (unsigned short*)arena;                    // (2,3,66,66,68)
    unsigned short* xplo = (unsigned short*)(arena + 3554496);
    unsigned short* h1hi = (unsigned short*)(arena + 7108992);        // (2,64,34,34,36)
    unsigned short* h1lo = (unsigned short*)(arena + 17762688);
    unsigned short* h2hi = (unsigned short*)(arena + 28416384);       // (2,128,18,18,20)
    unsigned short* h2lo = (unsigned short*)(arena + 31734144);
    float*          pp3  = (float*)(arena + 35051904);                // 4x(2,256,8^3)
    float*          h3   = (float*)(arena + 39246208);                // (2,256,512)
    float*          lat  = (float*)(arena + 40294784);                // (2,256,512)
    // decoder phase (after VQ; overlaps encoder buffers):
    unsigned short* d1 = (unsigned short*)arena;                      // (256,18^3) bf16
    unsigned short* d2 = (unsigned short*)(arena + 2985984);          // (128,34^3) bf16
    float*          d3 = (float*)(arena + 13047808);                  // (64,64^3) fp32
    // arena peak 80.2 MB; total 105.5 MB (< 112.2 MB proven in R0)

    dim3 blk(256);
    auto nblk = [](long n) { return dim3((unsigned)((n + 255) / 256)); };

    // ---- weight prep ----
    prep_convt_w<<<nblk(8L * 256 * 2048), blk, 0, stream>>>(dec_w1, Ap1, 256, 256, 0);
    prep_convt_w_frag<<<nblk(8L * 128 * 2048), blk, 0, stream>>>(dec_w2, Ap2, 256, 128, 1);
    prep_convt_w_frag<<<nblk(8L * 64 * 1024), blk, 0, stream>>>(dec_w3, Ap3, 128, 64, 1);
    prep_dec4A<<<dim3(256), blk, 0, stream>>>(dec_w4, Aw4);
    prep_split_w<<<nblk(12288), blk, 0, stream>>>(enc_w1, W1hi, W1lo, 12288);
    prep_split_w_frag<<<nblk(524288), blk, 0, stream>>>(enc_w2, W2hi, W2lo, 64, 128);
    prep_split_w_frag<<<nblk(2097152), blk, 0, stream>>>(enc_w3, W3hi, W3lo, 128, 256);

    // ---- encoder (MFMA, bf16-pair) ----
    pad_input_split<<<nblk(6L * 66 * 66 * 68), blk, 0, stream>>>(x, xphi, xplo);
    zero_halo_ps<<<nblk(128L * 34 * 34 * 36), blk, 0, stream>>>(h1hi, 128, 34, 36);
    zero_halo_ps<<<nblk(128L * 34 * 34 * 36), blk, 0, stream>>>(h1lo, 128, 34, 36);
    conv_s2_mfma<3, 64, 32, 66, 68, 4, 2, 0, 1, 1><<<dim3(1024), blk, 0, stream>>>(
        xphi, xplo, W1hi, W1lo, enc_b1, h1hi, h1lo, nullptr, 34, 36, 1, 0);
    zero_halo_ps<<<nblk(256L * 18 * 18 * 20), blk, 0, stream>>>(h2hi, 256, 18, 20);
    zero_halo_ps<<<nblk(256L * 18 * 18 * 20), blk, 0, stream>>>(h2lo, 256, 18, 20);
    conv_s2_mfma_lds<64, 128, 16, 34, 36, 2, 1, 0, 1, 1><<<dim3(512), blk, 0, stream>>>(
        h1hi, h1lo, W2hi, W2lo, enc_b2, h2hi, h2lo, nullptr, 18, 20, 1, 0);
    conv_s2_mfma_lds<128, 256, 8, 18, 20, 4, 1, 1, 4, 0><<<dim3(256), blk, 0, stream>>>(
        h2hi, h2lo, W3hi, W3lo, enc_b3, nullptr, nullptr, pp3, 8, 8, 0, 262144);
    combine4_relu<<<nblk(262144), blk, 0, stream>>>(pp3, h3, 262144, 262144);
    conv1x1_b<<<dim3(512), dim3(128), 0, stream>>>(h3, enc_w4, enc_b4, lat);

    // ---- VQ (fp32 exact) ----
    codenorm_kernel<<<dim3(1024), dim3(64), 0, stream>>>(codebook, cn);
    zero_halo_t<unsigned short><<<nblk(512L * 10 * 10 * 10), blk, 0, stream>>>(qp, 512, 10);
    vq_kernel<<<dim3(1024), blk, 0, stream>>>(lat, codebook, cn, qp, idx_out);

    // ---- decoder halos ----
    zero_halo_t<unsigned short><<<nblk(256L * 18 * 18 * 18), blk, 0, stream>>>(d1, 256, 18);
    zero_halo_t<unsigned short><<<nblk(128L * 34 * 34 * 34), blk, 0, stream>>>(d2, 128, 34);

    // ---- decoder (MFMA) per batch ----
    for (int b = 0; b < 2; ++b) {
        const unsigned short* qb = qp + (long)b * 256 * 1000;
        float* outb = out + (long)b * 3 * 226981;
        // dec1 (DIN=8, old layout): grid = 8*2*4*1*4 = 256
        convt_mfma<256, 256, 8, 1, unsigned short><<<dim3(256), blk, 0, stream>>>(
            qb, Ap1, dec_b1, d1);
        // dec2 (v2, MXP=1 MYP=2): grid = 8 * (2*2*2*1*2*2*2) = 512
        convt_mfma_v2<256, 128, 16, 1, 1, 2, unsigned short><<<dim3(512), blk, 0, stream>>>(
            d1, Ap2, dec_b2, d2);
        // dec3 (v2, MXP=2 MYP=1): grid = 8 * (2*2*1*1*8*2*4) = 2048
        convt_mfma_v2<128, 64, 32, 0, 2, 1, float><<<dim3(2048), blk, 0, stream>>>(
            d2, Ap3, dec_b3, d3);
        conv_dec4_mfma<<<dim3(8 * 8 * 16), blk, 0, stream>>>(d3, Aw4, dec_b4, outb);
    }
}

// Round 6
// 1062.431 us; speedup vs baseline: 1.3727x; 1.0593x over previous
//
#include <hip/hip_runtime.h>
#include <cfloat>
#include <cmath>

// ---------------------------------------------------------------------------
// Round 23: LDS-stage dec4's X rows + fragment-major dec4 weights.
// R22 post-mortem: enc2/enc3 LDS staging confirmed (total 1186 -> 1125us).
// New top-5: conv_dec4_mfma 139us x2, MfmaUtil 9%, HBM 6% -- TA line-touch
// bound again: 160 X-lines (4 waves x 5 loads x ~8 scattered lines) + 64
// A-lines (lane stride 8KB) per block-step. All 4 waves read the SAME 14
// rows (2z x 7y) per step, only the ow segment differs => stage the rows
// once per block into a double-buffered LDS tile (224 threads x 1 dwordx4 =
// 56 sequential lines) and make Aw fragment-major ([s][lane][8], 1KB/step
// contiguous). Truncation-pack expressions and MFMA order unchanged, d3
// stays fp32 => bit-identical output. Everything else unchanged from R22.
// ---------------------------------------------------------------------------

using f32x4  = __attribute__((ext_vector_type(4))) float;
using bf16x8 = __attribute__((ext_vector_type(8))) short;
typedef float f32x4u __attribute__((ext_vector_type(4), aligned(4)));
typedef unsigned short u16x4u __attribute__((ext_vector_type(4), aligned(4)));

__device__ __forceinline__ unsigned short f32_to_bf16(float f) {
    unsigned int u = __float_as_uint(f);
    u += 0x7fffu + ((u >> 16) & 1u);          // round-to-nearest-even
    return (unsigned short)(u >> 16);
}
__device__ __forceinline__ void split_bf16(float v, unsigned short& h, unsigned short& l) {
    h = f32_to_bf16(v);
    float hf = __uint_as_float((unsigned)h << 16);
    l = f32_to_bf16(v - hf);
}
__device__ __forceinline__ void store_act(float* p, float v) { *p = v; }
__device__ __forceinline__ void store_act(unsigned short* p, float v) { *p = f32_to_bf16(v); }

template <typename V>
__device__ __forceinline__ bf16x8 pack_b(V r0, V r1) {
    bf16x8 b;
    b[0] = (short)r0[0]; b[1] = (short)r0[1]; b[2] = (short)r0[2]; b[3] = (short)r0[3];
    b[4] = (short)r1[0]; b[5] = (short)r1[1]; b[6] = (short)r1[2]; b[7] = (short)r1[3];
    return b;
}

// ---------------- prep: weight hi/lo split (linear; enc1) ----------------
__global__ __launch_bounds__(256)
void prep_split_w(const float* __restrict__ w, short* __restrict__ whi,
                  short* __restrict__ wlo, long total)
{
    long idx = (long)blockIdx.x * blockDim.x + threadIdx.x;
    if (idx >= total) return;
    unsigned short h, l;
    split_bf16(w[idx], h, l);
    whi[idx] = (short)h; wlo[idx] = (short)l;
}

// Fragment-major hi/lo split for the LDS-staged conv_s2 (enc2/enc3):
//   whi[((s*MT + m)*64 + l)*8 + kk] = hi(w[co*K + korig])
// with MT = COUT/16, co = m*16 + (l&15), korig = s*32 + (l>>4)*8 + kk.
// Each step tile (COUT*32 shorts) is contiguous.
__global__ __launch_bounds__(256)
void prep_split_w_frag(const float* __restrict__ w, short* __restrict__ whi,
                       short* __restrict__ wlo, int CIN, int COUT)
{
    const int K = CIN * 64;
    const int MT = COUT >> 4;
    long total = (long)COUT * K;
    long idx = (long)blockIdx.x * blockDim.x + threadIdx.x;
    if (idx >= total) return;
    int kk = (int)(idx & 7); long r = idx >> 3;
    int l  = (int)(r & 63);  r >>= 6;
    int m  = (int)(r % MT);
    int s  = (int)(r / MT);
    int n16 = l & 15, quad = l >> 4;
    int co = m * 16 + n16;
    int korig = s * 32 + quad * 8 + kk;
    unsigned short h, lo16;
    split_bf16(w[(long)co * K + korig], h, lo16);
    whi[idx] = (short)h; wlo[idx] = (short)lo16;
}

// ---------------- pad input -> hi/lo bf16 pitched planes --------------------
__global__ __launch_bounds__(256)
void pad_input_split(const float* __restrict__ x, unsigned short* __restrict__ xhi,
                     unsigned short* __restrict__ xlo)
{
    const int D = 64, PD = 66, PRX = 68, BC = 6;
    long total = (long)BC * PD * PD * PRX;
    long idx = (long)blockIdx.x * blockDim.x + threadIdx.x;
    if (idx >= total) return;
    int px = (int)(idx % PRX); long t = idx / PRX;
    int py = (int)(t % PD); t /= PD;
    int pz = (int)(t % PD); int c = (int)(t / PD);
    int ix = px - 1, iy = py - 1, iz = pz - 1;
    float v = 0.0f;
    if ((unsigned)ix < (unsigned)D && (unsigned)iy < (unsigned)D && (unsigned)iz < (unsigned)D)
        v = x[(((long)c * D + iz) * D + iy) * D + ix];
    unsigned short h, l;
    split_bf16(v, h, l);
    xhi[idx] = h; xlo[idx] = l;
}

__global__ __launch_bounds__(256)
void zero_halo_ps(unsigned short* __restrict__ p, int C, int PD, int PRX)
{
    long total = (long)C * PD * PD * PRX;
    long idx = (long)blockIdx.x * blockDim.x + threadIdx.x;
    if (idx >= total) return;
    int px = (int)(idx % PRX); long t = idx / PRX;
    int py = (int)(t % PD); t /= PD;
    int pz = (int)(t % PD);
    if (px == 0 || px >= PD - 1 || py == 0 || py == PD - 1 || pz == 0 || pz == PD - 1)
        p[idx] = 0;
}

template <typename T>
__global__ __launch_bounds__(256) void zero_halo_t(T* __restrict__ p, int C, int PD)
{
    long total = (long)C * PD * PD * PD;
    long idx = (long)blockIdx.x * blockDim.x + threadIdx.x;
    if (idx >= total) return;
    int px = (int)(idx % PD); long t = idx / PD;
    int py = (int)(t % PD); t /= PD;
    int pz = (int)(t % PD);
    if (px == 0 || px == PD - 1 || py == 0 || py == PD - 1 || pz == 0 || pz == PD - 1)
        p[idx] = (T)0;
}

// ---------------------------------------------------------------------------
// Conv3d k4 s2 p1 as MFMA implicit GEMM, bf16 hi/lo pair inputs (enc1 only)
// ---------------------------------------------------------------------------
template <int CIN, int COUT, int DOUT, int PD, int PRX, int MTW, int OWT,
          int OWHALF, int KSPLIT, int OUTSPLIT>
__global__ __launch_bounds__(256)
void conv_s2_mfma(const unsigned short* __restrict__ xhi,
                  const unsigned short* __restrict__ xlo,
                  const short* __restrict__ Whi, const short* __restrict__ Wlo,
                  const float* __restrict__ bias,
                  unsigned short* __restrict__ yhi, unsigned short* __restrict__ ylo,
                  float* __restrict__ yf,
                  int OPD, int OPRX, int po, long sstride)
{
    constexpr int K = CIN * 64;
    constexpr int MWAVES = COUT / (16 * MTW);
    constexpr int RPB = 4 / MWAVES;
    constexpr int KN = (CIN * 2) / KSPLIT;

    int bx = blockIdx.x;
    const int ks = (KSPLIT > 1) ? (bx % KSPLIT) : 0;
    const int rowblk = (KSPLIT > 1) ? (bx / KSPLIT) : bx;
    const int lane = (int)threadIdx.x & 63, w = (int)threadIdx.x >> 6;
    const int mi = (MWAVES == 4) ? w : 0;
    const int ri = (MWAVES == 4) ? 0 : w;
    const int rowid = rowblk * RPB + ri;
    const int n16 = lane & 15, quad = lane >> 4;

    int b, od, oh, ow;
    if (OWHALF) {
        constexpr int NOH = DOUT / 2;
        const int ohb = rowid % NOH; int t = rowid / NOH;
        od = t % DOUT; b = t / DOUT;
        oh = ohb * 2 + (n16 >> 3);
        ow = n16 & 7;
    } else {
        const int owt = rowid % OWT; int t = rowid / OWT;
        oh = t % DOUT; t /= DOUT;
        od = t % DOUT; b = t / DOUT;
        ow = owt * 16 + n16;
    }

    const int co0 = mi * (MTW * 16);

    f32x4 acc[MTW];
    #pragma unroll
    for (int mt = 0; mt < MTW; ++mt)
        #pragma unroll
        for (int r = 0; r < 4; ++r) {
            int co = co0 + mt * 16 + quad * 4 + r;
            acc[mt][r] = (ks == 0) ? bias[co] : 0.0f;
        }

    const int sg0 = ks * KN;
    const long chs = (long)PD * PD * PRX;
    long off = ((long)(b * CIN + (sg0 >> 1)) * PD + (2 * od + (quad >> 1))) * PD * PRX
             + (long)(2 * oh + (quad & 1) * 2) * PRX + 2 * ow;
    const unsigned short* phi = xhi + off;
    const unsigned short* plo = xlo + off;
    const long incA = 2L * PD * PRX;
    const long incB = chs - 2L * PD * PRX;

    const short* a0h = Whi + (long)(co0 + n16) * K + sg0 * 32 + quad * 8;
    const short* a0l = Wlo + (long)(co0 + n16) * K + sg0 * 32 + quad * 8;

    #pragma unroll 2
    for (int s = 0; s < KN; ++s) {
        u16x4u h0 = *(const u16x4u*)phi;
        u16x4u h1 = *(const u16x4u*)(phi + PRX);
        u16x4u l0 = *(const u16x4u*)plo;
        u16x4u l1 = *(const u16x4u*)(plo + PRX);
        bf16x8 bhi = pack_b(h0, h1);
        bf16x8 blo = pack_b(l0, l1);
        #pragma unroll
        for (int mt = 0; mt < MTW; ++mt) {
            bf16x8 ah = *(const bf16x8*)(a0h + (long)mt * 16 * K + s * 32);
            bf16x8 al = *(const bf16x8*)(a0l + (long)mt * 16 * K + s * 32);
            acc[mt] = __builtin_amdgcn_mfma_f32_16x16x32_bf16(ah, bhi, acc[mt], 0, 0, 0);
            acc[mt] = __builtin_amdgcn_mfma_f32_16x16x32_bf16(ah, blo, acc[mt], 0, 0, 0);
            acc[mt] = __builtin_amdgcn_mfma_f32_16x16x32_bf16(al, bhi, acc[mt], 0, 0, 0);
        }
        long inc = (s & 1) ? incB : incA;
        phi += inc; plo += inc;
    }

    if (OUTSPLIT) {
        #pragma unroll
        for (int mt = 0; mt < MTW; ++mt)
            #pragma unroll
            for (int r = 0; r < 4; ++r) {
                int co = co0 + mt * 16 + quad * 4 + r;
                float v = fmaxf(acc[mt][r], 0.0f);
                unsigned short h, l;
                split_bf16(v, h, l);
                long o = (((long)(b * COUT + co) * OPD + od + po) * OPD + oh + po) * OPRX
                       + ow + po;
                yhi[o] = h; ylo[o] = l;
            }
    } else {
        #pragma unroll
        for (int mt = 0; mt < MTW; ++mt)
            #pragma unroll
            for (int r = 0; r < 4; ++r) {
                int co = co0 + mt * 16 + quad * 4 + r;
                long o = (long)ks * sstride
                       + (((long)(b * COUT + co) * OPD + od) * OPD + oh) * OPRX + ow;
                yf[o] = acc[mt][r];
            }
    }
}

// LDS-staged variant (enc2/enc3): fragment-major Whi/Wlo, per-step tile
// staged cooperatively into a double-buffered LDS pair. Same MFMA order.
template <int CIN, int COUT, int DOUT, int PD, int PRX, int MTW, int OWT,
          int OWHALF, int KSPLIT, int OUTSPLIT>
__global__ __launch_bounds__(256)
void conv_s2_mfma_lds(const unsigned short* __restrict__ xhi,
                      const unsigned short* __restrict__ xlo,
                      const short* __restrict__ Whi, const short* __restrict__ Wlo,
                      const float* __restrict__ bias,
                      unsigned short* __restrict__ yhi, unsigned short* __restrict__ ylo,
                      float* __restrict__ yf,
                      int OPD, int OPRX, int po, long sstride)
{
    constexpr int K = CIN * 64;
    constexpr int MWAVES = COUT / (16 * MTW);
    constexpr int RPB = 4 / MWAVES;
    constexpr int KN = (CIN * 2) / KSPLIT;
    constexpr int TILE = COUT * 32;                 // shorts per step tile
    constexpr int PASSES = TILE / (256 * 8);        // dwordx4 passes/thread
    static_assert(PASSES >= 1, "tile too small for 256-thread staging");

    int bx = blockIdx.x;
    const int ks = (KSPLIT > 1) ? (bx % KSPLIT) : 0;
    const int rowblk = (KSPLIT > 1) ? (bx / KSPLIT) : bx;
    const int tid = (int)threadIdx.x;
    const int lane = tid & 63, w = tid >> 6;
    const int mi = (MWAVES == 4) ? w : 0;
    const int ri = (MWAVES == 4) ? 0 : w;
    const int rowid = rowblk * RPB + ri;
    const int n16 = lane & 15, quad = lane >> 4;

    int b, od, oh, ow;
    if (OWHALF) {
        constexpr int NOH = DOUT / 2;
        const int ohb = rowid % NOH; int t = rowid / NOH;
        od = t % DOUT; b = t / DOUT;
        oh = ohb * 2 + (n16 >> 3);
        ow = n16 & 7;
    } else {
        const int owt = rowid % OWT; int t = rowid / OWT;
        oh = t % DOUT; t /= DOUT;
        od = t % DOUT; b = t / DOUT;
        ow = owt * 16 + n16;
    }

    const int co0 = mi * (MTW * 16);

    f32x4 acc[MTW];
    #pragma unroll
    for (int mt = 0; mt < MTW; ++mt)
        #pragma unroll
        for (int r = 0; r < 4; ++r) {
            int co = co0 + mt * 16 + quad * 4 + r;
            acc[mt][r] = (ks == 0) ? bias[co] : 0.0f;
        }

    const int sg0 = ks * KN;
    const long chs = (long)PD * PD * PRX;
    long off = ((long)(b * CIN + (sg0 >> 1)) * PD + (2 * od + (quad >> 1))) * PD * PRX
             + (long)(2 * oh + (quad & 1) * 2) * PRX + 2 * ow;
    const unsigned short* phi = xhi + off;
    const unsigned short* plo = xlo + off;
    const long incA = 2L * PD * PRX;
    const long incB = chs - 2L * PD * PRX;

    __shared__ short AhiB[2][TILE];
    __shared__ short AloB[2][TILE];

    // prologue: stage step 0
    {
        const long tb = (long)sg0 * TILE;
        #pragma unroll
        for (int j = 0; j < PASSES; ++j) {
            const int o = tid * 8 + j * 2048;
            *(bf16x8*)(&AhiB[0][o]) = *(const bf16x8*)(Whi + tb + o);
            *(bf16x8*)(&AloB[0][o]) = *(const bf16x8*)(Wlo + tb + o);
        }
    }
    __syncthreads();

    #pragma unroll 1
    for (int s = 0; s < KN; ++s) {
        const int cur = s & 1;
        const bool more = (s + 1 < KN);
        bf16x8 nh[PASSES], nl[PASSES];
        if (more) {
            const long tb = (long)(sg0 + s + 1) * TILE;
            #pragma unroll
            for (int j = 0; j < PASSES; ++j) {
                const int o = tid * 8 + j * 2048;
                nh[j] = *(const bf16x8*)(Whi + tb + o);
                nl[j] = *(const bf16x8*)(Wlo + tb + o);
            }
        }

        u16x4u h0 = *(const u16x4u*)phi;
        u16x4u h1 = *(const u16x4u*)(phi + PRX);
        u16x4u l0 = *(const u16x4u*)plo;
        u16x4u l1 = *(const u16x4u*)(plo + PRX);
        bf16x8 bhi = pack_b(h0, h1);
        bf16x8 blo = pack_b(l0, l1);

        #pragma unroll
        for (int mt = 0; mt < MTW; ++mt) {
            const int m = mi * MTW + mt;
            bf16x8 ah = *(const bf16x8*)(&AhiB[cur][(m * 64 + lane) * 8]);
            bf16x8 al = *(const bf16x8*)(&AloB[cur][(m * 64 + lane) * 8]);
            acc[mt] = __builtin_amdgcn_mfma_f32_16x16x32_bf16(ah, bhi, acc[mt], 0, 0, 0);
            acc[mt] = __builtin_amdgcn_mfma_f32_16x16x32_bf16(ah, blo, acc[mt], 0, 0, 0);
            acc[mt] = __builtin_amdgcn_mfma_f32_16x16x32_bf16(al, bhi, acc[mt], 0, 0, 0);
        }

        long inc = (s & 1) ? incB : incA;
        phi += inc; plo += inc;

        if (more) {
            #pragma unroll
            for (int j = 0; j < PASSES; ++j) {
                const int o = tid * 8 + j * 2048;
                *(bf16x8*)(&AhiB[cur ^ 1][o]) = nh[j];
                *(bf16x8*)(&AloB[cur ^ 1][o]) = nl[j];
            }
        }
        __syncthreads();
    }

    if (OUTSPLIT) {
        #pragma unroll
        for (int mt = 0; mt < MTW; ++mt)
            #pragma unroll
            for (int r = 0; r < 4; ++r) {
                int co = co0 + mt * 16 + quad * 4 + r;
                float v = fmaxf(acc[mt][r], 0.0f);
                unsigned short h, l;
                split_bf16(v, h, l);
                long o = (((long)(b * COUT + co) * OPD + od + po) * OPD + oh + po) * OPRX
                       + ow + po;
                yhi[o] = h; ylo[o] = l;
            }
    } else {
        #pragma unroll
        for (int mt = 0; mt < MTW; ++mt)
            #pragma unroll
            for (int r = 0; r < 4; ++r) {
                int co = co0 + mt * 16 + quad * 4 + r;
                long o = (long)ks * sstride
                       + (((long)(b * COUT + co) * OPD + od) * OPD + oh) * OPRX + ow;
                yf[o] = acc[mt][r];
            }
    }
}

__global__ __launch_bounds__(256)
void combine4_relu(const float* __restrict__ p, float* __restrict__ y, long N, long ss)
{
    long idx = (long)blockIdx.x * blockDim.x + threadIdx.x;
    if (idx >= N) return;
    float v = p[idx] + p[idx + ss] + p[idx + 2 * ss] + p[idx + 3 * ss];
    y[idx] = fmaxf(v, 0.0f);
}

// ---------------- 1x1 conv (fp32 exact) ----------------
__global__ __launch_bounds__(128)
void conv1x1_b(const float* __restrict__ x, const float* __restrict__ w,
               const float* __restrict__ bias, float* __restrict__ y)
{
    const int co = blockIdx.x & 255, b = blockIdx.x >> 8;
    const int s4 = (int)threadIdx.x * 4;
    const float* xb = x + (long)b * 256 * 512 + s4;
    const float* wr = w + (long)co * 256;      // uniform -> s_load
    float bv = bias[co];
    float4 acc = {bv, bv, bv, bv};
    for (int ci = 0; ci < 256; ++ci) {
        float wv = wr[ci];
        float4 xv = *(const float4*)(xb + (long)ci * 512);
        acc.x = fmaf(xv.x, wv, acc.x); acc.y = fmaf(xv.y, wv, acc.y);
        acc.z = fmaf(xv.z, wv, acc.z); acc.w = fmaf(xv.w, wv, acc.w);
    }
    *(float4*)(y + (long)(b * 256 + co) * 512 + s4) = acc;
}

// ---------------- VQ (fp32 exact; unchanged) ----------------
__global__ void codenorm_kernel(const float* __restrict__ cb, float* __restrict__ norms)
{
    int k = blockIdx.x;
    int lane = threadIdx.x;
    float s = 0.0f;
    const float* row = cb + (long)k * 256;
    for (int d = lane; d < 256; d += 64) { float v = row[d]; s = fmaf(v, v, s); }
    for (int off = 32; off > 0; off >>= 1) s += __shfl_down(s, off);
    if (lane == 0) norms[k] = s;
}

__global__ __launch_bounds__(256)
void vq_kernel(const float* __restrict__ lat, const float* __restrict__ cb,
               const float* __restrict__ norms, unsigned short* __restrict__ q,
               float* __restrict__ idx_out)
{
    __shared__ __align__(16) float row[256];
    __shared__ float s_best[256];
    __shared__ int   s_bidx[256];
    int r = blockIdx.x;
    int t = threadIdx.x;
    row[t] = lat[(long)r * 256 + t];
    __syncthreads();

    const float4* rowv = (const float4*)row;
    float latn = 0.0f;
    #pragma unroll 4
    for (int d = 0; d < 64; ++d) {
        float4 rv = rowv[d];
        latn = fmaf(rv.x, rv.x, latn); latn = fmaf(rv.y, rv.y, latn);
        latn = fmaf(rv.z, rv.z, latn); latn = fmaf(rv.w, rv.w, latn);
    }

    float best = FLT_MAX;
    int bidx = 0x7fffffff;
    for (int j = 0; j < 4; ++j) {
        int k = t + 256 * j;
        const float4* cr = (const float4*)(cb + (long)k * 256);
        float dot = 0.0f;
        #pragma unroll 4
        for (int d = 0; d < 64; ++d) {
            float4 c = cr[d]; float4 rv = rowv[d];
            dot = fmaf(rv.x, c.x, dot); dot = fmaf(rv.y, c.y, dot);
            dot = fmaf(rv.z, c.z, dot); dot = fmaf(rv.w, c.w, dot);
        }
        float sc = latn - 2.0f * dot + norms[k];
        if (sc < best || (sc == best && k < bidx)) { best = sc; bidx = k; }
    }
    s_best[t] = best; s_bidx[t] = bidx;
    __syncthreads();
    for (int off = 128; off > 0; off >>= 1) {
        if (t < off) {
            float o = s_best[t + off]; int oi = s_bidx[t + off];
            if (o < s_best[t] || (o == s_best[t] && oi < s_bidx[t])) {
                s_best[t] = o; s_bidx[t] = oi;
            }
        }
        __syncthreads();
    }
    int bk = s_bidx[0];
    int b = r >> 9, n = r & 511;
    int zz = n >> 6, yy = (n >> 3) & 7, xx = n & 7;
    q[(long)(b * 256 + t) * 1000 + ((long)(zz + 1) * 10 + (yy + 1)) * 10 + (xx + 1)]
        = f32_to_bf16(cb[(long)bk * 256 + t]);
    if (t == 0) idx_out[r] = (float)bk;
}

// ---------------- decoder: MFMA implicit-GEMM ConvTranspose ----------------
// xflip=0: B slot a <-> x offset (1-ax), kw=(1-px)+2*ax (old cube kernel).
// xflip=1: B slot a <-> x offset ax,     kw=(1-px)+2*(1-ax) (dword-pair kernel).
__global__ __launch_bounds__(256)
void prep_convt_w(const float* __restrict__ w, short* __restrict__ Ap,
                  int Cin, int Cout, int xflip)
{
    const int K = Cin * 8;
    long total = 8L * Cout * K;
    long idx = (long)blockIdx.x * blockDim.x + threadIdx.x;
    if (idx >= total) return;
    int k = (int)(idx % K);
    int co = (int)((idx / K) % Cout);
    int p = (int)(idx / ((long)K * Cout));
    int ci = k >> 3, a = k & 7;
    int az = (a >> 2) & 1, ay = (a >> 1) & 1, ax = a & 1;
    int pz = p >> 2, py = (p >> 1) & 1, px = p & 1;
    int axw = xflip ? (1 - ax) : ax;
    int kd = (1 - pz) + 2 * az, kh = (1 - py) + 2 * ay, kw = (1 - px) + 2 * axw;
    float v = w[((long)ci * Cout + co) * 64 + kd * 16 + kh * 4 + kw];
    Ap[idx] = (short)f32_to_bf16(v);
}

// Fragment-major layout for the LDS-staged v2 kernel:
//   ApN[((p*MG + mg)*nsteps + s)*2048 + cb*512 + l*8 + kk]
// where l = quad*16 + n16, korig = s*32 + quad*8 + kk, co = mg*64 + cb*16 + n16.
// Each (p,mg,s) tile is one contiguous 4KB block.
__global__ __launch_bounds__(256)
void prep_convt_w_frag(const float* __restrict__ w, short* __restrict__ Ap,
                       int Cin, int Cout, int xflip)
{
    const int MG = Cout >> 6;
    const int nsteps = Cin >> 2;             // (Cin*8)/32
    long total = 8L * MG * nsteps * 2048;
    long idx = (long)blockIdx.x * blockDim.x + threadIdx.x;
    if (idx >= total) return;
    int kk = (int)(idx & 7); long r = idx >> 3;
    int l  = (int)(r & 63);  r >>= 6;
    int cb = (int)(r & 3);   r >>= 2;
    int s  = (int)(r % nsteps); r /= nsteps;
    int mg = (int)(r % MG);
    int p  = (int)(r / MG);

    int n16 = l & 15, quad = l >> 4;
    int korig = s * 32 + quad * 8 + kk;
    int co = mg * 64 + cb * 16 + n16;
    int ci = korig >> 3, a = korig & 7;
    int az = (a >> 2) & 1, ay = (a >> 1) & 1, ax = a & 1;
    int pz = p >> 2, py = (p >> 1) & 1, px = p & 1;
    int axw = xflip ? (1 - ax) : ax;
    int kd = (1 - pz) + 2 * az, kh = (1 - py) + 2 * ay, kw = (1 - px) + 2 * axw;
    float v = w[((long)ci * Cout + co) * 64 + kd * 16 + kh * 4 + kw];
    Ap[idx] = (short)f32_to_bf16(v);
}

// Old cube-N layout (kept for dec1, DIN=8): round-0 body.
template <int CIN, int COUT, int DIN, int OPAD, typename OutT>
__global__ __launch_bounds__(256)
void convt_mfma(const unsigned short* __restrict__ Xp, const short* __restrict__ Ap,
                const float* __restrict__ bias, OutT* __restrict__ Y)
{
    constexpr int PD = DIN + 2;
    constexpr int PD3 = PD * PD * PD;
    constexpr int T = DIN >> 2;
    constexpr int NT = T * T * T;
    constexpr int SLAB = NT / 8;
    constexpr int OPD = 2 * DIN + 2 * OPAD;
    constexpr int K = CIN * 8;
    constexpr int MG = COUT >> 6;
    constexpr int nsteps = K >> 5;

    int bx = blockIdx.x;
    const int xcd = bx & 7;
    int local = bx >> 3;
    const int px = local & 1; local >>= 1;
    const int mg = local % MG; local /= MG;
    const int ntin = local % SLAB;
    const int pzy = local / SLAB;            // 0..3
    const int pz = pzy >> 1, py = pzy & 1;
    const int p = pz * 4 + py * 2 + px;
    const int nt = xcd * SLAB + ntin;

    const int lane = threadIdx.x & 63, wave = threadIdx.x >> 6;
    const int n16 = lane & 15, quad = lane >> 4;

    const int tx = nt % T, ty = (nt / T) % T, tz = nt / (T * T);
    const int mz = tz * 4 + wave, my = ty * 4 + (n16 >> 2), mx = tx * 4 + (n16 & 3);
    const int sp = ((mz + pz) * PD + (my + py)) * PD + (mx + px);

    const unsigned short* xq = Xp + (long)quad * PD3 + sp;

    const int cobase = mg * 64;
    const short* ap0 = Ap + ((long)p * COUT + cobase + n16) * K + quad * 8;

    f32x4 acc[4];
    #pragma unroll
    for (int cb = 0; cb < 4; ++cb) {
        const float* bp = bias + cobase + cb * 16 + quad * 4;
        acc[cb][0] = bp[0]; acc[cb][1] = bp[1]; acc[cb][2] = bp[2]; acc[cb][3] = bp[3];
    }

    #pragma unroll 4
    for (int s = 0; s < nsteps; ++s) {
        const unsigned short* xs = xq + (long)s * 4 * PD3;
        bf16x8 bf;
        bf[0] = (short)xs[(PD + 1) * PD + 1];
        bf[1] = (short)xs[(PD + 1) * PD];
        bf[2] = (short)xs[PD * PD + 1];
        bf[3] = (short)xs[PD * PD];
        bf[4] = (short)xs[PD + 1];
        bf[5] = (short)xs[PD];
        bf[6] = (short)xs[1];
        bf[7] = (short)xs[0];
        #pragma unroll
        for (int cb = 0; cb < 4; ++cb) {
            bf16x8 af = *(const bf16x8*)(ap0 + (long)cb * 16 * K + s * 32);
            acc[cb] = __builtin_amdgcn_mfma_f32_16x16x32_bf16(af, bf, acc[cb], 0, 0, 0);
        }
    }

    const int opz = 2 * mz + pz + OPAD, opy = 2 * my + py + OPAD, opx = 2 * mx + px + OPAD;
    const long spo = ((long)opz * OPD + opy) * OPD + opx;
    #pragma unroll
    for (int cb = 0; cb < 4; ++cb) {
        #pragma unroll
        for (int r = 0; r < 4; ++r) {
            int co = cobase + cb * 16 + quad * 4 + r;
            float v = fmaxf(acc[cb][r], 0.0f);
            store_act(Y + (long)co * OPD * OPD * OPD + spo, v);
        }
    }
}

// Dword-pair B-gather (dec2/dec3), R20: A staged through LDS (unchanged).
template <int CIN, int COUT, int DIN, int OPAD, int MXP, int MYP, typename OutT>
__global__ __launch_bounds__(256)
void convt_mfma_v2(const unsigned short* __restrict__ Xp, const short* __restrict__ Ap,
                   const float* __restrict__ bias, OutT* __restrict__ Y)
{
    constexpr int PD = DIN + 2;
    constexpr int PD3 = PD * PD * PD;
    constexpr int OPD = 2 * DIN + 2 * OPAD;
    constexpr int K = CIN * 8;
    constexpr int MG = COUT >> 6;
    constexpr int nsteps = K >> 5;
    static_assert(nsteps >= 2, "need at least 2 K-steps");
    constexpr int MXT = DIN / (16 * MXP);
    constexpr int MYT = DIN / (4 * MYP);
    constexpr int MZS = DIN / 8;             // mz per XCD slab
    constexpr int TPE = MXP * MYP;           // tiles per wave (one of MXP/MYP is 1)

    int bx = blockIdx.x;
    const int xcd = bx & 7;
    int local = bx >> 3;
    const int px = local & 1; local >>= 1;
    const int py = local & 1; local >>= 1;
    const int mg = local % MG; local /= MG;
    const int mxt = local % MXT; local /= MXT;
    const int myt = local % MYT; local /= MYT;
    const int pz = local & 1; local >>= 1;
    const int mzin = local;                  // 0..MZS-1
    const int mz = xcd * MZS + mzin;
    const int p = pz * 4 + py * 2 + px;

    const int lane = threadIdx.x & 63, wave = threadIdx.x >> 6;
    const int n16 = lane & 15, quad = lane >> 4;

    const int mx0 = mxt * (16 * MXP) + n16;
    const int my0 = myt * (4 * MYP) + wave * MYP;
    const int baseX = mx0 & ~1;
    const int sh = 16 * ((n16 & 1) + px);    // 0, 16, or 32
    const long sp = ((long)(mz + pz) * PD + (my0 + py)) * PD + baseX;

    const unsigned short* xq = Xp + (long)quad * PD3 + sp;

    // fragment-major weight tiles: 2048 shorts (4KB) per (p,mg,s)
    const short* ApT = Ap + (((long)p * MG + mg) * nsteps) * 2048;

    __shared__ short Abuf[2][2048];          // 8KB double buffer

    f32x4 acc[TPE][4];
    #pragma unroll
    for (int t = 0; t < TPE; ++t)
        #pragma unroll
        for (int cb = 0; cb < 4; ++cb) {
            const float* bp = bias + (mg * 64) + cb * 16 + quad * 4;
            acc[t][cb][0] = bp[0]; acc[t][cb][1] = bp[1];
            acc[t][cb][2] = bp[2]; acc[t][cb][3] = bp[3];
        }

    constexpr int rowoff[4] = { (PD + 1) * PD, PD * PD, PD, 0 };
    union Frag { unsigned u[4]; bf16x8 b; };

    const int chunkoff = wave * 512 + lane * 8;   // this thread's 16B of the 4KB tile

    // prologue: stage step 0
    {
        bf16x8 a0 = *(const bf16x8*)(ApT + chunkoff);
        *(bf16x8*)(&Abuf[0][chunkoff]) = a0;
    }
    __syncthreads();

    #pragma unroll 1
    for (int s = 0; s < nsteps; ++s) {
        const int cur = s & 1;
        bf16x8 anext;
        const bool more = (s + 1 < nsteps);
        if (more)
            anext = *(const bf16x8*)(ApT + (long)(s + 1) * 2048 + chunkoff);

        // X loads (plain C, raw staging)
        const unsigned short* xs = xq + (long)s * 4 * PD3;
        unsigned long long xr[TPE][4];
        #pragma unroll
        for (int t = 0; t < TPE; ++t) {
            const int toff = (MXP > 1) ? t * 16 : t * PD;
            #pragma unroll
            for (int j = 0; j < 4; ++j) {
                union { u16x4u v; unsigned long long u; } ld;
                ld.v = *(const u16x4u*)(xs + toff + rowoff[j]);
                xr[t][j] = ld.u;
            }
        }

        // A fragments from LDS (l = quad*16 + n16 == lane)
        bf16x8 af[4];
        #pragma unroll
        for (int cb = 0; cb < 4; ++cb)
            af[cb] = *(const bf16x8*)(&Abuf[cur][cb * 512 + lane * 8]);

        #pragma unroll
        for (int t = 0; t < TPE; ++t) {
            Frag fr;
            #pragma unroll
            for (int j = 0; j < 4; ++j)
                fr.u[j] = (unsigned)(xr[t][j] >> sh);
            #pragma unroll
            for (int cb = 0; cb < 4; ++cb)
                acc[t][cb] = __builtin_amdgcn_mfma_f32_16x16x32_bf16(af[cb], fr.b,
                                                                     acc[t][cb], 0, 0, 0);
        }

        if (more)
            *(bf16x8*)(&Abuf[cur ^ 1][chunkoff]) = anext;
        __syncthreads();
    }

    const int opz = 2 * mz + pz + OPAD;
    #pragma unroll
    for (int t = 0; t < TPE; ++t) {
        const int opx = 2 * (mx0 + ((MXP > 1) ? t * 16 : 0)) + px + OPAD;
        const int opy = 2 * (my0 + ((MYP > 1) ? t : 0)) + py + OPAD;
        const long spo = ((long)opz * OPD + opy) * OPD + opx;
        #pragma unroll
        for (int cb = 0; cb < 4; ++cb) {
            #pragma unroll
            for (int r = 0; r < 4; ++r) {
                int co = (mg * 64) + cb * 16 + quad * 4 + r;
                float v = fmaxf(acc[t][cb][r], 0.0f);
                store_act(Y + (long)co * OPD * OPD * OPD + spo, v);
            }
        }
    }
}

// ---------------- dec4 as MFMA GEMM, R23: LDS-staged X + frag-major A -------
// Fragment-major: Aw[(s*64 + lane)*8 + kk] = RNE(w[m*4096 + k]) with
// m = lane&15 (zero-padded beyond co=3), k = s*32 + (lane>>4)*8 + kk.
// Per-step A tile = contiguous 1KB.
__global__ __launch_bounds__(256)
void prep_dec4A_frag(const float* __restrict__ w, short* __restrict__ Aw)
{
    int idx = blockIdx.x * 256 + (int)threadIdx.x;    // 0..65535
    int kk = idx & 7;
    int l  = (idx >> 3) & 63;
    int s  = idx >> 9;                                // 0..127
    int n16 = l & 15, quad = l >> 4;
    int k = s * 32 + quad * 8 + kk;
    float v = (n16 < 3) ? w[n16 * 4096 + k] : 0.0f;
    Aw[idx] = (short)f32_to_bf16(v);
}

// All 4 waves of a block need the SAME 14 X-rows (2 z x 7 y) per step ->
// stage them once into a double-buffered LDS tile (224 threads x 1 dwordx4,
// 56 sequential lines/step vs ~160 scattered). Truncation-pack expressions
// and MFMA order unchanged; d3 stays fp32 => bit-identical output.
__global__ __launch_bounds__(256)
void conv_dec4_mfma(const float* __restrict__ d3, const short* __restrict__ Aw,
                    const float* __restrict__ bias, float* __restrict__ y)
{
    constexpr int D = 64, Dout = 61;
    int bx = blockIdx.x;
    const int slab = bx & 7;
    const int i = bx >> 3;                 // 0..127
    const int od = slab * 8 + (i >> 4);
    const int oh0 = (i & 15) * 4;          // covers oh0..oh0+3 (guard < 61)
    if (od >= Dout) return;                // uniform per block -> barriers safe
    const int tid = (int)threadIdx.x;
    const int lane = tid & 63, wave = tid >> 6;
    const int n16 = lane & 15, quad = lane >> 4;
    const int ow = wave * 16 + n16;

    // [dbuf][z'][y'][x] fp32; row 68 so ow+3 <= 66 stays in-bounds (pad
    // floats 64..67 uninitialized -- consumed only by discarded ow>=61 cols)
    __shared__ float Xs[2][2][7][68];

    f32x4 acc[4];
    #pragma unroll
    for (int j = 0; j < 4; ++j)
        #pragma unroll
        for (int r = 0; r < 4; ++r) {
            int co = quad * 4 + r;
            acc[j][r] = (co < 3) ? bias[co] : 0.0f;
        }

    const int kd0 = quad >> 1;
    const int kh0 = (quad & 1) * 2;

    // staging role: 224 threads, each owns (z', y', 16-float segment)
    const int srow = tid >> 4;             // 0..15 (14 used)
    const int sseg = tid & 15;
    const int szi = srow / 7, syi = srow % 7;
    const bool sact = (srow < 14);
    const long sbase = (((long)(od + szi) * D) + min(oh0 + syi, D - 1)) * D + sseg * 4;
    auto saddr = [&](int s) {
        return d3 + sbase + ((long)((s >> 1) * D + (s & 1) * 2)) * D * D;
    };

    // prologue: stage step 0
    if (sact)
        *(f32x4u*)(&Xs[0][szi][syi][sseg * 4]) = *(const f32x4u*)saddr(0);
    __syncthreads();

    #pragma unroll 1
    for (int s = 0; s < 128; ++s) {
        const int cur = s & 1;
        const bool more = (s + 1 < 128);
        f32x4u nv;
        if (more && sact)
            nv = *(const f32x4u*)saddr(s + 1);

        bf16x8 af = *(const bf16x8*)(Aw + ((long)s * 64 + lane) * 8);

        unsigned p0[5], p1[5];
        #pragma unroll
        for (int r = 0; r < 5; ++r) {
            f32x4u v = *(const f32x4u*)(&Xs[cur][kd0][kh0 + r][ow]);
            p0[r] = (__float_as_uint(v[0]) >> 16) | (__float_as_uint(v[1]) & 0xffff0000u);
            p1[r] = (__float_as_uint(v[2]) >> 16) | (__float_as_uint(v[3]) & 0xffff0000u);
        }
        #pragma unroll
        for (int j = 0; j < 4; ++j) {
            union { unsigned u[4]; bf16x8 b; } fr;
            fr.u[0] = p0[j];     fr.u[1] = p1[j];
            fr.u[2] = p0[j + 1]; fr.u[3] = p1[j + 1];
            acc[j] = __builtin_amdgcn_mfma_f32_16x16x32_bf16(af, fr.b, acc[j], 0, 0, 0);
        }

        if (more && sact)
            *(f32x4u*)(&Xs[cur ^ 1][szi][syi][sseg * 4]) = nv;
        __syncthreads();
    }

    if (ow < Dout && quad == 0) {
        #pragma unroll
        for (int j = 0; j < 4; ++j) {
            const int oh = oh0 + j;
            if (oh >= Dout) continue;
            #pragma unroll
            for (int r = 0; r < 3; ++r)
                y[((long)(r * Dout + od) * Dout + oh) * Dout + ow] = tanhf(acc[j][r]);
        }
    }
}

extern "C" void kernel_launch(void* const* d_in, const int* in_sizes, int n_in,
                              void* d_out, int out_size, void* d_ws, size_t ws_size,
                              hipStream_t stream)
{
    const float* x        = (const float*)d_in[0];
    const float* enc_w1   = (const float*)d_in[1];
    const float* enc_b1   = (const float*)d_in[2];
    const float* enc_w2   = (const float*)d_in[3];
    const float* enc_b2   = (const float*)d_in[4];
    const float* enc_w3   = (const float*)d_in[5];
    const float* enc_b3   = (const float*)d_in[6];
    const float* enc_w4   = (const float*)d_in[7];
    const float* enc_b4   = (const float*)d_in[8];
    const float* codebook = (const float*)d_in[9];
    const float* dec_w1   = (const float*)d_in[10];
    const float* dec_b1   = (const float*)d_in[11];
    const float* dec_w2   = (const float*)d_in[12];
    const float* dec_b2   = (const float*)d_in[13];
    const float* dec_w3   = (const float*)d_in[14];
    const float* dec_b3   = (const float*)d_in[15];
    const float* dec_w4   = (const float*)d_in[16];
    const float* dec_b4   = (const float*)d_in[17];

    float* out = (float*)d_out;
    float* idx_out = out + 2L * 3 * 61 * 61 * 61;

    // ---- workspace (byte offsets) ----
    char* wsb = (char*)d_ws;
    float*          cn   = (float*)wsb;                        //      4,096
    unsigned short* qp   = (unsigned short*)(wsb + 4096);      //  1,024,000
    short*          Ap1  = (short*)(wsb + 1028096);            //  8,388,608
    short*          Ap2  = (short*)(wsb + 9416704);            //  4,194,304
    short*          Ap3  = (short*)(wsb + 13611008);           //  1,048,576
    short*          Aw4  = (short*)(wsb + 14659584);           //    131,072
    short*          W1hi = (short*)(wsb + 14790656);           //     24,576
    short*          W1lo = (short*)(wsb + 14815232);           //     24,576
    short*          W2hi = (short*)(wsb + 14839808);           //  1,048,576
    short*          W2lo = (short*)(wsb + 15888384);           //  1,048,576
    short*          W3hi = (short*)(wsb + 16936960);           //  4,194,304
    short*          W3lo = (short*)(wsb + 21131264);           //  4,194,304
    char* arena = wsb + 25325568;
    // encoder phase:
    unsigned short* xphi = (unsigned short*)arena;                    // (2,3,66,66,68)
    unsigned short* xplo = (unsigned short*)(arena + 3554496);
    unsigned short* h1hi = (unsigned short*)(arena + 7108992);        // (2,64,34,34,36)
    unsigned short* h1lo = (unsigned short*)(arena + 17762688);
    unsigned short* h2hi = (unsigned short*)(arena + 28416384);       // (2,128,18,18,20)
    unsigned short* h2lo = (unsigned short*)(arena + 31734144);
    float*          pp3  = (float*)(arena + 35051904);                // 4x(2,256,8^3)
    float*          h3   = (float*)(arena + 39246208);                // (2,256,512)
    float*          lat  = (float*)(arena + 40294784);                // (2,256,512)
    // decoder phase (after VQ; overlaps encoder buffers):
    unsigned short* d1 = (unsigned short*)arena;                      // (256,18^3) bf16
    unsigned short* d2 = (unsigned short*)(arena + 2985984);          // (128,34^3) bf16
    float*          d3 = (float*)(arena + 13047808);                  // (64,64^3) fp32
    // arena peak 80.2 MB; total 105.5 MB (< 112.2 MB proven in R0)

    dim3 blk(256);
    auto nblk = [](long n) { return dim3((unsigned)((n + 255) / 256)); };

    // ---- weight prep ----
    prep_convt_w<<<nblk(8L * 256 * 2048), blk, 0, stream>>>(dec_w1, Ap1, 256, 256, 0);
    prep_convt_w_frag<<<nblk(8L * 128 * 2048), blk, 0, stream>>>(dec_w2, Ap2, 256, 128, 1);
    prep_convt_w_frag<<<nblk(8L * 64 * 1024), blk, 0, stream>>>(dec_w3, Ap3, 128, 64, 1);
    prep_dec4A_frag<<<dim3(256), blk, 0, stream>>>(dec_w4, Aw4);
    prep_split_w<<<nblk(12288), blk, 0, stream>>>(enc_w1, W1hi, W1lo, 12288);
    prep_split_w_frag<<<nblk(524288), blk, 0, stream>>>(enc_w2, W2hi, W2lo, 64, 128);
    prep_split_w_frag<<<nblk(2097152), blk, 0, stream>>>(enc_w3, W3hi, W3lo, 128, 256);

    // ---- encoder (MFMA, bf16-pair) ----
    pad_input_split<<<nblk(6L * 66 * 66 * 68), blk, 0, stream>>>(x, xphi, xplo);
    zero_halo_ps<<<nblk(128L * 34 * 34 * 36), blk, 0, stream>>>(h1hi, 128, 34, 36);
    zero_halo_ps<<<nblk(128L * 34 * 34 * 36), blk, 0, stream>>>(h1lo, 128, 34, 36);
    conv_s2_mfma<3, 64, 32, 66, 68, 4, 2, 0, 1, 1><<<dim3(1024), blk, 0, stream>>>(
        xphi, xplo, W1hi, W1lo, enc_b1, h1hi, h1lo, nullptr, 34, 36, 1, 0);
    zero_halo_ps<<<nblk(256L * 18 * 18 * 20), blk, 0, stream>>>(h2hi, 256, 18, 20);
    zero_halo_ps<<<nblk(256L * 18 * 18 * 20), blk, 0, stream>>>(h2lo, 256, 18, 20);
    conv_s2_mfma_lds<64, 128, 16, 34, 36, 2, 1, 0, 1, 1><<<dim3(512), blk, 0, stream>>>(
        h1hi, h1lo, W2hi, W2lo, enc_b2, h2hi, h2lo, nullptr, 18, 20, 1, 0);
    conv_s2_mfma_lds<128, 256, 8, 18, 20, 4, 1, 1, 4, 0><<<dim3(256), blk, 0, stream>>>(
        h2hi, h2lo, W3hi, W3lo, enc_b3, nullptr, nullptr, pp3, 8, 8, 0, 262144);
    combine4_relu<<<nblk(262144), blk, 0, stream>>>(pp3, h3, 262144, 262144);
    conv1x1_b<<<dim3(512), dim3(128), 0, stream>>>(h3, enc_w4, enc_b4, lat);

    // ---- VQ (fp32 exact) ----
    codenorm_kernel<<<dim3(1024), dim3(64), 0, stream>>>(codebook, cn);
    zero_halo_t<unsigned short><<<nblk(512L * 10 * 10 * 10), blk, 0, stream>>>(qp, 512, 10);
    vq_kernel<<<dim3(1024), blk, 0, stream>>>(lat, codebook, cn, qp, idx_out);

    // ---- decoder halos ----
    zero_halo_t<unsigned short><<<nblk(256L * 18 * 18 * 18), blk, 0, stream>>>(d1, 256, 18);
    zero_halo_t<unsigned short><<<nblk(128L * 34 * 34 * 34), blk, 0, stream>>>(d2, 128, 34);

    // ---- decoder (MFMA) per batch ----
    for (int b = 0; b < 2; ++b) {
        const unsigned short* qb = qp + (long)b * 256 * 1000;
        float* outb = out + (long)b * 3 * 226981;
        // dec1 (DIN=8, old layout): grid = 8*2*4*1*4 = 256
        convt_mfma<256, 256, 8, 1, unsigned short><<<dim3(256), blk, 0, stream>>>(
            qb, Ap1, dec_b1, d1);
        // dec2 (v2, MXP=1 MYP=2): grid = 8 * (2*2*2*1*2*2*2) = 512
        convt_mfma_v2<256, 128, 16, 1, 1, 2, unsigned short><<<dim3(512), blk, 0, stream>>>(
            d1, Ap2, dec_b2, d2);
        // dec3 (v2, MXP=2 MYP=1): grid = 8 * (2*2*1*1*8*2*4) = 2048
        convt_mfma_v2<128, 64, 32, 0, 2, 1, float><<<dim3(2048), blk, 0, stream>>>(
            d2, Ap3, dec_b3, d3);
        conv_dec4_mfma<<<dim3(8 * 8 * 16), blk, 0, stream>>>(d3, Aw4, dec_b4, outb);
    }
}

// Round 7
// 985.734 us; speedup vs baseline: 1.4795x; 1.0778x over previous
//
#include <hip/hip_runtime.h>
#include <cfloat>
#include <cmath>

// ---------------------------------------------------------------------------
// Round 24: coalesce + de-duplicate the VQ distance kernel.
// R23 post-mortem: dec4 LDS staging confirmed (1125 -> 1062us). New top-5:
// vq_kernel at 128us steady-state (the 31.8ms _ord-7 entry is a rocprof
// replay artifact -- graph total is 1062us). VALUBusy 8%, HBM 1%: per-lane
// code-major codebook reads are 64-scattered-lines-per-instruction, and
// each of 1024 blocks re-reads the whole 1MB codebook (1GB L2 traffic).
// Fix: (a) prep-transpose codebook to cbT[d][k] so thread t's float4 load
// of codes 4t..4t+3 is perfectly coalesced; (b) 4 rows per block (grid 256)
// with rows in LDS -- each cbT element read once per block feeds 16 FMAs,
// L2 traffic 1GB -> 256MB. dot/latn fmaf chains keep the original
// sequential d-order and argmin is (min score, min idx) (scan-order-
// independent) => bit-identical output. Everything else unchanged from R23.
// ---------------------------------------------------------------------------

using f32x4  = __attribute__((ext_vector_type(4))) float;
using bf16x8 = __attribute__((ext_vector_type(8))) short;
typedef float f32x4u __attribute__((ext_vector_type(4), aligned(4)));
typedef unsigned short u16x4u __attribute__((ext_vector_type(4), aligned(4)));

__device__ __forceinline__ unsigned short f32_to_bf16(float f) {
    unsigned int u = __float_as_uint(f);
    u += 0x7fffu + ((u >> 16) & 1u);          // round-to-nearest-even
    return (unsigned short)(u >> 16);
}
__device__ __forceinline__ void split_bf16(float v, unsigned short& h, unsigned short& l) {
    h = f32_to_bf16(v);
    float hf = __uint_as_float((unsigned)h << 16);
    l = f32_to_bf16(v - hf);
}
__device__ __forceinline__ void store_act(float* p, float v) { *p = v; }
__device__ __forceinline__ void store_act(unsigned short* p, float v) { *p = f32_to_bf16(v); }

template <typename V>
__device__ __forceinline__ bf16x8 pack_b(V r0, V r1) {
    bf16x8 b;
    b[0] = (short)r0[0]; b[1] = (short)r0[1]; b[2] = (short)r0[2]; b[3] = (short)r0[3];
    b[4] = (short)r1[0]; b[5] = (short)r1[1]; b[6] = (short)r1[2]; b[7] = (short)r1[3];
    return b;
}

// ---------------- prep: weight hi/lo split (linear; enc1) ----------------
__global__ __launch_bounds__(256)
void prep_split_w(const float* __restrict__ w, short* __restrict__ whi,
                  short* __restrict__ wlo, long total)
{
    long idx = (long)blockIdx.x * blockDim.x + threadIdx.x;
    if (idx >= total) return;
    unsigned short h, l;
    split_bf16(w[idx], h, l);
    whi[idx] = (short)h; wlo[idx] = (short)l;
}

// Fragment-major hi/lo split for the LDS-staged conv_s2 (enc2/enc3):
//   whi[((s*MT + m)*64 + l)*8 + kk] = hi(w[co*K + korig])
// with MT = COUT/16, co = m*16 + (l&15), korig = s*32 + (l>>4)*8 + kk.
// Each step tile (COUT*32 shorts) is contiguous.
__global__ __launch_bounds__(256)
void prep_split_w_frag(const float* __restrict__ w, short* __restrict__ whi,
                       short* __restrict__ wlo, int CIN, int COUT)
{
    const int K = CIN * 64;
    const int MT = COUT >> 4;
    long total = (long)COUT * K;
    long idx = (long)blockIdx.x * blockDim.x + threadIdx.x;
    if (idx >= total) return;
    int kk = (int)(idx & 7); long r = idx >> 3;
    int l  = (int)(r & 63);  r >>= 6;
    int m  = (int)(r % MT);
    int s  = (int)(r / MT);
    int n16 = l & 15, quad = l >> 4;
    int co = m * 16 + n16;
    int korig = s * 32 + quad * 8 + kk;
    unsigned short h, lo16;
    split_bf16(w[(long)co * K + korig], h, lo16);
    whi[idx] = (short)h; wlo[idx] = (short)lo16;
}

// ---------------- pad input -> hi/lo bf16 pitched planes --------------------
__global__ __launch_bounds__(256)
void pad_input_split(const float* __restrict__ x, unsigned short* __restrict__ xhi,
                     unsigned short* __restrict__ xlo)
{
    const int D = 64, PD = 66, PRX = 68, BC = 6;
    long total = (long)BC * PD * PD * PRX;
    long idx = (long)blockIdx.x * blockDim.x + threadIdx.x;
    if (idx >= total) return;
    int px = (int)(idx % PRX); long t = idx / PRX;
    int py = (int)(t % PD); t /= PD;
    int pz = (int)(t % PD); int c = (int)(t / PD);
    int ix = px - 1, iy = py - 1, iz = pz - 1;
    float v = 0.0f;
    if ((unsigned)ix < (unsigned)D && (unsigned)iy < (unsigned)D && (unsigned)iz < (unsigned)D)
        v = x[(((long)c * D + iz) * D + iy) * D + ix];
    unsigned short h, l;
    split_bf16(v, h, l);
    xhi[idx] = h; xlo[idx] = l;
}

__global__ __launch_bounds__(256)
void zero_halo_ps(unsigned short* __restrict__ p, int C, int PD, int PRX)
{
    long total = (long)C * PD * PD * PRX;
    long idx = (long)blockIdx.x * blockDim.x + threadIdx.x;
    if (idx >= total) return;
    int px = (int)(idx % PRX); long t = idx / PRX;
    int py = (int)(t % PD); t /= PD;
    int pz = (int)(t % PD);
    if (px == 0 || px >= PD - 1 || py == 0 || py == PD - 1 || pz == 0 || pz == PD - 1)
        p[idx] = 0;
}

template <typename T>
__global__ __launch_bounds__(256) void zero_halo_t(T* __restrict__ p, int C, int PD)
{
    long total = (long)C * PD * PD * PD;
    long idx = (long)blockIdx.x * blockDim.x + threadIdx.x;
    if (idx >= total) return;
    int px = (int)(idx % PD); long t = idx / PD;
    int py = (int)(t % PD); t /= PD;
    int pz = (int)(t % PD);
    if (px == 0 || px == PD - 1 || py == 0 || py == PD - 1 || pz == 0 || pz == PD - 1)
        p[idx] = (T)0;
}

// ---------------------------------------------------------------------------
// Conv3d k4 s2 p1 as MFMA implicit GEMM, bf16 hi/lo pair inputs (enc1 only)
// ---------------------------------------------------------------------------
template <int CIN, int COUT, int DOUT, int PD, int PRX, int MTW, int OWT,
          int OWHALF, int KSPLIT, int OUTSPLIT>
__global__ __launch_bounds__(256)
void conv_s2_mfma(const unsigned short* __restrict__ xhi,
                  const unsigned short* __restrict__ xlo,
                  const short* __restrict__ Whi, const short* __restrict__ Wlo,
                  const float* __restrict__ bias,
                  unsigned short* __restrict__ yhi, unsigned short* __restrict__ ylo,
                  float* __restrict__ yf,
                  int OPD, int OPRX, int po, long sstride)
{
    constexpr int K = CIN * 64;
    constexpr int MWAVES = COUT / (16 * MTW);
    constexpr int RPB = 4 / MWAVES;
    constexpr int KN = (CIN * 2) / KSPLIT;

    int bx = blockIdx.x;
    const int ks = (KSPLIT > 1) ? (bx % KSPLIT) : 0;
    const int rowblk = (KSPLIT > 1) ? (bx / KSPLIT) : bx;
    const int lane = (int)threadIdx.x & 63, w = (int)threadIdx.x >> 6;
    const int mi = (MWAVES == 4) ? w : 0;
    const int ri = (MWAVES == 4) ? 0 : w;
    const int rowid = rowblk * RPB + ri;
    const int n16 = lane & 15, quad = lane >> 4;

    int b, od, oh, ow;
    if (OWHALF) {
        constexpr int NOH = DOUT / 2;
        const int ohb = rowid % NOH; int t = rowid / NOH;
        od = t % DOUT; b = t / DOUT;
        oh = ohb * 2 + (n16 >> 3);
        ow = n16 & 7;
    } else {
        const int owt = rowid % OWT; int t = rowid / OWT;
        oh = t % DOUT; t /= DOUT;
        od = t % DOUT; b = t / DOUT;
        ow = owt * 16 + n16;
    }

    const int co0 = mi * (MTW * 16);

    f32x4 acc[MTW];
    #pragma unroll
    for (int mt = 0; mt < MTW; ++mt)
        #pragma unroll
        for (int r = 0; r < 4; ++r) {
            int co = co0 + mt * 16 + quad * 4 + r;
            acc[mt][r] = (ks == 0) ? bias[co] : 0.0f;
        }

    const int sg0 = ks * KN;
    const long chs = (long)PD * PD * PRX;
    long off = ((long)(b * CIN + (sg0 >> 1)) * PD + (2 * od + (quad >> 1))) * PD * PRX
             + (long)(2 * oh + (quad & 1) * 2) * PRX + 2 * ow;
    const unsigned short* phi = xhi + off;
    const unsigned short* plo = xlo + off;
    const long incA = 2L * PD * PRX;
    const long incB = chs - 2L * PD * PRX;

    const short* a0h = Whi + (long)(co0 + n16) * K + sg0 * 32 + quad * 8;
    const short* a0l = Wlo + (long)(co0 + n16) * K + sg0 * 32 + quad * 8;

    #pragma unroll 2
    for (int s = 0; s < KN; ++s) {
        u16x4u h0 = *(const u16x4u*)phi;
        u16x4u h1 = *(const u16x4u*)(phi + PRX);
        u16x4u l0 = *(const u16x4u*)plo;
        u16x4u l1 = *(const u16x4u*)(plo + PRX);
        bf16x8 bhi = pack_b(h0, h1);
        bf16x8 blo = pack_b(l0, l1);
        #pragma unroll
        for (int mt = 0; mt < MTW; ++mt) {
            bf16x8 ah = *(const bf16x8*)(a0h + (long)mt * 16 * K + s * 32);
            bf16x8 al = *(const bf16x8*)(a0l + (long)mt * 16 * K + s * 32);
            acc[mt] = __builtin_amdgcn_mfma_f32_16x16x32_bf16(ah, bhi, acc[mt], 0, 0, 0);
            acc[mt] = __builtin_amdgcn_mfma_f32_16x16x32_bf16(ah, blo, acc[mt], 0, 0, 0);
            acc[mt] = __builtin_amdgcn_mfma_f32_16x16x32_bf16(al, bhi, acc[mt], 0, 0, 0);
        }
        long inc = (s & 1) ? incB : incA;
        phi += inc; plo += inc;
    }

    if (OUTSPLIT) {
        #pragma unroll
        for (int mt = 0; mt < MTW; ++mt)
            #pragma unroll
            for (int r = 0; r < 4; ++r) {
                int co = co0 + mt * 16 + quad * 4 + r;
                float v = fmaxf(acc[mt][r], 0.0f);
                unsigned short h, l;
                split_bf16(v, h, l);
                long o = (((long)(b * COUT + co) * OPD + od + po) * OPD + oh + po) * OPRX
                       + ow + po;
                yhi[o] = h; ylo[o] = l;
            }
    } else {
        #pragma unroll
        for (int mt = 0; mt < MTW; ++mt)
            #pragma unroll
            for (int r = 0; r < 4; ++r) {
                int co = co0 + mt * 16 + quad * 4 + r;
                long o = (long)ks * sstride
                       + (((long)(b * COUT + co) * OPD + od) * OPD + oh) * OPRX + ow;
                yf[o] = acc[mt][r];
            }
    }
}

// LDS-staged variant (enc2/enc3): fragment-major Whi/Wlo, per-step tile
// staged cooperatively into a double-buffered LDS pair. Same MFMA order.
template <int CIN, int COUT, int DOUT, int PD, int PRX, int MTW, int OWT,
          int OWHALF, int KSPLIT, int OUTSPLIT>
__global__ __launch_bounds__(256)
void conv_s2_mfma_lds(const unsigned short* __restrict__ xhi,
                      const unsigned short* __restrict__ xlo,
                      const short* __restrict__ Whi, const short* __restrict__ Wlo,
                      const float* __restrict__ bias,
                      unsigned short* __restrict__ yhi, unsigned short* __restrict__ ylo,
                      float* __restrict__ yf,
                      int OPD, int OPRX, int po, long sstride)
{
    constexpr int K = CIN * 64;
    constexpr int MWAVES = COUT / (16 * MTW);
    constexpr int RPB = 4 / MWAVES;
    constexpr int KN = (CIN * 2) / KSPLIT;
    constexpr int TILE = COUT * 32;                 // shorts per step tile
    constexpr int PASSES = TILE / (256 * 8);        // dwordx4 passes/thread
    static_assert(PASSES >= 1, "tile too small for 256-thread staging");

    int bx = blockIdx.x;
    const int ks = (KSPLIT > 1) ? (bx % KSPLIT) : 0;
    const int rowblk = (KSPLIT > 1) ? (bx / KSPLIT) : bx;
    const int tid = (int)threadIdx.x;
    const int lane = tid & 63, w = tid >> 6;
    const int mi = (MWAVES == 4) ? w : 0;
    const int ri = (MWAVES == 4) ? 0 : w;
    const int rowid = rowblk * RPB + ri;
    const int n16 = lane & 15, quad = lane >> 4;

    int b, od, oh, ow;
    if (OWHALF) {
        constexpr int NOH = DOUT / 2;
        const int ohb = rowid % NOH; int t = rowid / NOH;
        od = t % DOUT; b = t / DOUT;
        oh = ohb * 2 + (n16 >> 3);
        ow = n16 & 7;
    } else {
        const int owt = rowid % OWT; int t = rowid / OWT;
        oh = t % DOUT; t /= DOUT;
        od = t % DOUT; b = t / DOUT;
        ow = owt * 16 + n16;
    }

    const int co0 = mi * (MTW * 16);

    f32x4 acc[MTW];
    #pragma unroll
    for (int mt = 0; mt < MTW; ++mt)
        #pragma unroll
        for (int r = 0; r < 4; ++r) {
            int co = co0 + mt * 16 + quad * 4 + r;
            acc[mt][r] = (ks == 0) ? bias[co] : 0.0f;
        }

    const int sg0 = ks * KN;
    const long chs = (long)PD * PD * PRX;
    long off = ((long)(b * CIN + (sg0 >> 1)) * PD + (2 * od + (quad >> 1))) * PD * PRX
             + (long)(2 * oh + (quad & 1) * 2) * PRX + 2 * ow;
    const unsigned short* phi = xhi + off;
    const unsigned short* plo = xlo + off;
    const long incA = 2L * PD * PRX;
    const long incB = chs - 2L * PD * PRX;

    __shared__ short AhiB[2][TILE];
    __shared__ short AloB[2][TILE];

    // prologue: stage step 0
    {
        const long tb = (long)sg0 * TILE;
        #pragma unroll
        for (int j = 0; j < PASSES; ++j) {
            const int o = tid * 8 + j * 2048;
            *(bf16x8*)(&AhiB[0][o]) = *(const bf16x8*)(Whi + tb + o);
            *(bf16x8*)(&AloB[0][o]) = *(const bf16x8*)(Wlo + tb + o);
        }
    }
    __syncthreads();

    #pragma unroll 1
    for (int s = 0; s < KN; ++s) {
        const int cur = s & 1;
        const bool more = (s + 1 < KN);
        bf16x8 nh[PASSES], nl[PASSES];
        if (more) {
            const long tb = (long)(sg0 + s + 1) * TILE;
            #pragma unroll
            for (int j = 0; j < PASSES; ++j) {
                const int o = tid * 8 + j * 2048;
                nh[j] = *(const bf16x8*)(Whi + tb + o);
                nl[j] = *(const bf16x8*)(Wlo + tb + o);
            }
        }

        u16x4u h0 = *(const u16x4u*)phi;
        u16x4u h1 = *(const u16x4u*)(phi + PRX);
        u16x4u l0 = *(const u16x4u*)plo;
        u16x4u l1 = *(const u16x4u*)(plo + PRX);
        bf16x8 bhi = pack_b(h0, h1);
        bf16x8 blo = pack_b(l0, l1);

        #pragma unroll
        for (int mt = 0; mt < MTW; ++mt) {
            const int m = mi * MTW + mt;
            bf16x8 ah = *(const bf16x8*)(&AhiB[cur][(m * 64 + lane) * 8]);
            bf16x8 al = *(const bf16x8*)(&AloB[cur][(m * 64 + lane) * 8]);
            acc[mt] = __builtin_amdgcn_mfma_f32_16x16x32_bf16(ah, bhi, acc[mt], 0, 0, 0);
            acc[mt] = __builtin_amdgcn_mfma_f32_16x16x32_bf16(ah, blo, acc[mt], 0, 0, 0);
            acc[mt] = __builtin_amdgcn_mfma_f32_16x16x32_bf16(al, bhi, acc[mt], 0, 0, 0);
        }

        long inc = (s & 1) ? incB : incA;
        phi += inc; plo += inc;

        if (more) {
            #pragma unroll
            for (int j = 0; j < PASSES; ++j) {
                const int o = tid * 8 + j * 2048;
                *(bf16x8*)(&AhiB[cur ^ 1][o]) = nh[j];
                *(bf16x8*)(&AloB[cur ^ 1][o]) = nl[j];
            }
        }
        __syncthreads();
    }

    if (OUTSPLIT) {
        #pragma unroll
        for (int mt = 0; mt < MTW; ++mt)
            #pragma unroll
            for (int r = 0; r < 4; ++r) {
                int co = co0 + mt * 16 + quad * 4 + r;
                float v = fmaxf(acc[mt][r], 0.0f);
                unsigned short h, l;
                split_bf16(v, h, l);
                long o = (((long)(b * COUT + co) * OPD + od + po) * OPD + oh + po) * OPRX
                       + ow + po;
                yhi[o] = h; ylo[o] = l;
            }
    } else {
        #pragma unroll
        for (int mt = 0; mt < MTW; ++mt)
            #pragma unroll
            for (int r = 0; r < 4; ++r) {
                int co = co0 + mt * 16 + quad * 4 + r;
                long o = (long)ks * sstride
                       + (((long)(b * COUT + co) * OPD + od) * OPD + oh) * OPRX + ow;
                yf[o] = acc[mt][r];
            }
    }
}

__global__ __launch_bounds__(256)
void combine4_relu(const float* __restrict__ p, float* __restrict__ y, long N, long ss)
{
    long idx = (long)blockIdx.x * blockDim.x + threadIdx.x;
    if (idx >= N) return;
    float v = p[idx] + p[idx + ss] + p[idx + 2 * ss] + p[idx + 3 * ss];
    y[idx] = fmaxf(v, 0.0f);
}

// ---------------- 1x1 conv (fp32 exact) ----------------
__global__ __launch_bounds__(128)
void conv1x1_b(const float* __restrict__ x, const float* __restrict__ w,
               const float* __restrict__ bias, float* __restrict__ y)
{
    const int co = blockIdx.x & 255, b = blockIdx.x >> 8;
    const int s4 = (int)threadIdx.x * 4;
    const float* xb = x + (long)b * 256 * 512 + s4;
    const float* wr = w + (long)co * 256;      // uniform -> s_load
    float bv = bias[co];
    float4 acc = {bv, bv, bv, bv};
    for (int ci = 0; ci < 256; ++ci) {
        float wv = wr[ci];
        float4 xv = *(const float4*)(xb + (long)ci * 512);
        acc.x = fmaf(xv.x, wv, acc.x); acc.y = fmaf(xv.y, wv, acc.y);
        acc.z = fmaf(xv.z, wv, acc.z); acc.w = fmaf(xv.w, wv, acc.w);
    }
    *(float4*)(y + (long)(b * 256 + co) * 512 + s4) = acc;
}

// ---------------- VQ (fp32 exact) ----------------
__global__ void codenorm_kernel(const float* __restrict__ cb, float* __restrict__ norms)
{
    int k = blockIdx.x;
    int lane = threadIdx.x;
    float s = 0.0f;
    const float* row = cb + (long)k * 256;
    for (int d = lane; d < 256; d += 64) { float v = row[d]; s = fmaf(v, v, s); }
    for (int off = 32; off > 0; off >>= 1) s += __shfl_down(s, off);
    if (lane == 0) norms[k] = s;
}

// cbT[d*1024 + k] = cb[k*256 + d]  (fp32 copy -> values unchanged)
__global__ __launch_bounds__(256)
void transpose_cb(const float* __restrict__ cb, float* __restrict__ cbT)
{
    int idx = blockIdx.x * 256 + (int)threadIdx.x;    // 0..262143
    int d = idx & 255, k = idx >> 8;
    cbT[(long)d * 1024 + k] = cb[(long)k * 256 + d];
}

// R24: 4 rows/block (grid 256), coalesced cbT float4 loads (codes 4t..4t+3),
// rows staged in LDS. dot/latn fmaf chains keep the original sequential
// d-order; argmin = (min score, min idx), scan-order-independent
// => bit-identical to the original per-row kernel.
__global__ __launch_bounds__(256)
void vq_kernel4(const float* __restrict__ lat, const float* __restrict__ cb,
                const float* __restrict__ cbT, const float* __restrict__ norms,
                unsigned short* __restrict__ q, float* __restrict__ idx_out)
{
    __shared__ __align__(16) float rows[4][256];
    __shared__ float s_best[4][256];
    __shared__ int   s_bidx[4][256];
    const int r0 = blockIdx.x * 4;
    const int t = (int)threadIdx.x;

    #pragma unroll
    for (int j = 0; j < 4; ++j)
        rows[j][t] = lat[(long)(r0 + j) * 256 + t];
    __syncthreads();

    // latn per row -- identical float4 fmaf chain to the original
    float latn[4];
    #pragma unroll
    for (int j = 0; j < 4; ++j) {
        const float4* rowv = (const float4*)rows[j];
        float a = 0.0f;
        #pragma unroll 4
        for (int d = 0; d < 64; ++d) {
            float4 rv = rowv[d];
            a = fmaf(rv.x, rv.x, a); a = fmaf(rv.y, rv.y, a);
            a = fmaf(rv.z, rv.z, a); a = fmaf(rv.w, rv.w, a);
        }
        latn[j] = a;
    }

    // codes 4t..4t+3; dot[j][c] accumulates d = 0..255 sequentially (same
    // chain as the original scalar loop)
    float dot[4][4] = {};
    const float* ct = cbT + t * 4;
    #pragma unroll 4
    for (int d = 0; d < 256; ++d) {
        float4 c4 = *(const float4*)(ct + (long)d * 1024);
        #pragma unroll
        for (int j = 0; j < 4; ++j) {
            float rv = rows[j][d];
            dot[j][0] = fmaf(rv, c4.x, dot[j][0]);
            dot[j][1] = fmaf(rv, c4.y, dot[j][1]);
            dot[j][2] = fmaf(rv, c4.z, dot[j][2]);
            dot[j][3] = fmaf(rv, c4.w, dot[j][3]);
        }
    }

    float4 nv = *(const float4*)(norms + t * 4);
    float nr[4] = {nv.x, nv.y, nv.z, nv.w};

    #pragma unroll
    for (int j = 0; j < 4; ++j) {
        float best = FLT_MAX;
        int bidx = 0x7fffffff;
        #pragma unroll
        for (int c = 0; c < 4; ++c) {
            float sc = latn[j] - 2.0f * dot[j][c] + nr[c];
            int k = t * 4 + c;
            if (sc < best || (sc == best && k < bidx)) { best = sc; bidx = k; }
        }
        s_best[j][t] = best; s_bidx[j][t] = bidx;
    }
    __syncthreads();
    for (int off = 128; off > 0; off >>= 1) {
        if (t < off) {
            #pragma unroll
            for (int j = 0; j < 4; ++j) {
                float o = s_best[j][t + off]; int oi = s_bidx[j][t + off];
                if (o < s_best[j][t] || (o == s_best[j][t] && oi < s_bidx[j][t])) {
                    s_best[j][t] = o; s_bidx[j][t] = oi;
                }
            }
        }
        __syncthreads();
    }

    #pragma unroll
    for (int j = 0; j < 4; ++j) {
        const int bk = s_bidx[j][0];
        const int r = r0 + j;
        const int b = r >> 9, n = r & 511;
        const int zz = n >> 6, yy = (n >> 3) & 7, xx = n & 7;
        q[(long)(b * 256 + t) * 1000 + ((long)(zz + 1) * 10 + (yy + 1)) * 10 + (xx + 1)]
            = f32_to_bf16(cb[(long)bk * 256 + t]);
    }
    if (t == 0) {
        #pragma unroll
        for (int j = 0; j < 4; ++j)
            idx_out[r0 + j] = (float)s_bidx[j][0];
    }
}

// ---------------- decoder: MFMA implicit-GEMM ConvTranspose ----------------
// xflip=0: B slot a <-> x offset (1-ax), kw=(1-px)+2*ax (old cube kernel).
// xflip=1: B slot a <-> x offset ax,     kw=(1-px)+2*(1-ax) (dword-pair kernel).
__global__ __launch_bounds__(256)
void prep_convt_w(const float* __restrict__ w, short* __restrict__ Ap,
                  int Cin, int Cout, int xflip)
{
    const int K = Cin * 8;
    long total = 8L * Cout * K;
    long idx = (long)blockIdx.x * blockDim.x + threadIdx.x;
    if (idx >= total) return;
    int k = (int)(idx % K);
    int co = (int)((idx / K) % Cout);
    int p = (int)(idx / ((long)K * Cout));
    int ci = k >> 3, a = k & 7;
    int az = (a >> 2) & 1, ay = (a >> 1) & 1, ax = a & 1;
    int pz = p >> 2, py = (p >> 1) & 1, px = p & 1;
    int axw = xflip ? (1 - ax) : ax;
    int kd = (1 - pz) + 2 * az, kh = (1 - py) + 2 * ay, kw = (1 - px) + 2 * axw;
    float v = w[((long)ci * Cout + co) * 64 + kd * 16 + kh * 4 + kw];
    Ap[idx] = (short)f32_to_bf16(v);
}

// Fragment-major layout for the LDS-staged v2 kernel:
//   ApN[((p*MG + mg)*nsteps + s)*2048 + cb*512 + l*8 + kk]
// where l = quad*16 + n16, korig = s*32 + quad*8 + kk, co = mg*64 + cb*16 + n16.
// Each (p,mg,s) tile is one contiguous 4KB block.
__global__ __launch_bounds__(256)
void prep_convt_w_frag(const float* __restrict__ w, short* __restrict__ Ap,
                       int Cin, int Cout, int xflip)
{
    const int MG = Cout >> 6;
    const int nsteps = Cin >> 2;             // (Cin*8)/32
    long total = 8L * MG * nsteps * 2048;
    long idx = (long)blockIdx.x * blockDim.x + threadIdx.x;
    if (idx >= total) return;
    int kk = (int)(idx & 7); long r = idx >> 3;
    int l  = (int)(r & 63);  r >>= 6;
    int cb = (int)(r & 3);   r >>= 2;
    int s  = (int)(r % nsteps); r /= nsteps;
    int mg = (int)(r % MG);
    int p  = (int)(r / MG);

    int n16 = l & 15, quad = l >> 4;
    int korig = s * 32 + quad * 8 + kk;
    int co = mg * 64 + cb * 16 + n16;
    int ci = korig >> 3, a = korig & 7;
    int az = (a >> 2) & 1, ay = (a >> 1) & 1, ax = a & 1;
    int pz = p >> 2, py = (p >> 1) & 1, px = p & 1;
    int axw = xflip ? (1 - ax) : ax;
    int kd = (1 - pz) + 2 * az, kh = (1 - py) + 2 * ay, kw = (1 - px) + 2 * axw;
    float v = w[((long)ci * Cout + co) * 64 + kd * 16 + kh * 4 + kw];
    Ap[idx] = (short)f32_to_bf16(v);
}

// Old cube-N layout (kept for dec1, DIN=8): round-0 body.
template <int CIN, int COUT, int DIN, int OPAD, typename OutT>
__global__ __launch_bounds__(256)
void convt_mfma(const unsigned short* __restrict__ Xp, const short* __restrict__ Ap,
                const float* __restrict__ bias, OutT* __restrict__ Y)
{
    constexpr int PD = DIN + 2;
    constexpr int PD3 = PD * PD * PD;
    constexpr int T = DIN >> 2;
    constexpr int NT = T * T * T;
    constexpr int SLAB = NT / 8;
    constexpr int OPD = 2 * DIN + 2 * OPAD;
    constexpr int K = CIN * 8;
    constexpr int MG = COUT >> 6;
    constexpr int nsteps = K >> 5;

    int bx = blockIdx.x;
    const int xcd = bx & 7;
    int local = bx >> 3;
    const int px = local & 1; local >>= 1;
    const int mg = local % MG; local /= MG;
    const int ntin = local % SLAB;
    const int pzy = local / SLAB;            // 0..3
    const int pz = pzy >> 1, py = pzy & 1;
    const int p = pz * 4 + py * 2 + px;
    const int nt = xcd * SLAB + ntin;

    const int lane = threadIdx.x & 63, wave = threadIdx.x >> 6;
    const int n16 = lane & 15, quad = lane >> 4;

    const int tx = nt % T, ty = (nt / T) % T, tz = nt / (T * T);
    const int mz = tz * 4 + wave, my = ty * 4 + (n16 >> 2), mx = tx * 4 + (n16 & 3);
    const int sp = ((mz + pz) * PD + (my + py)) * PD + (mx + px);

    const unsigned short* xq = Xp + (long)quad * PD3 + sp;

    const int cobase = mg * 64;
    const short* ap0 = Ap + ((long)p * COUT + cobase + n16) * K + quad * 8;

    f32x4 acc[4];
    #pragma unroll
    for (int cb = 0; cb < 4; ++cb) {
        const float* bp = bias + cobase + cb * 16 + quad * 4;
        acc[cb][0] = bp[0]; acc[cb][1] = bp[1]; acc[cb][2] = bp[2]; acc[cb][3] = bp[3];
    }

    #pragma unroll 4
    for (int s = 0; s < nsteps; ++s) {
        const unsigned short* xs = xq + (long)s * 4 * PD3;
        bf16x8 bf;
        bf[0] = (short)xs[(PD + 1) * PD + 1];
        bf[1] = (short)xs[(PD + 1) * PD];
        bf[2] = (short)xs[PD * PD + 1];
        bf[3] = (short)xs[PD * PD];
        bf[4] = (short)xs[PD + 1];
        bf[5] = (short)xs[PD];
        bf[6] = (short)xs[1];
        bf[7] = (short)xs[0];
        #pragma unroll
        for (int cb = 0; cb < 4; ++cb) {
            bf16x8 af = *(const bf16x8*)(ap0 + (long)cb * 16 * K + s * 32);
            acc[cb] = __builtin_amdgcn_mfma_f32_16x16x32_bf16(af, bf, acc[cb], 0, 0, 0);
        }
    }

    const int opz = 2 * mz + pz + OPAD, opy = 2 * my + py + OPAD, opx = 2 * mx + px + OPAD;
    const long spo = ((long)opz * OPD + opy) * OPD + opx;
    #pragma unroll
    for (int cb = 0; cb < 4; ++cb) {
        #pragma unroll
        for (int r = 0; r < 4; ++r) {
            int co = cobase + cb * 16 + quad * 4 + r;
            float v = fmaxf(acc[cb][r], 0.0f);
            store_act(Y + (long)co * OPD * OPD * OPD + spo, v);
        }
    }
}

// Dword-pair B-gather (dec2/dec3), R20: A staged through LDS (unchanged).
template <int CIN, int COUT, int DIN, int OPAD, int MXP, int MYP, typename OutT>
__global__ __launch_bounds__(256)
void convt_mfma_v2(const unsigned short* __restrict__ Xp, const short* __restrict__ Ap,
                   const float* __restrict__ bias, OutT* __restrict__ Y)
{
    constexpr int PD = DIN + 2;
    constexpr int PD3 = PD * PD * PD;
    constexpr int OPD = 2 * DIN + 2 * OPAD;
    constexpr int K = CIN * 8;
    constexpr int MG = COUT >> 6;
    constexpr int nsteps = K >> 5;
    static_assert(nsteps >= 2, "need at least 2 K-steps");
    constexpr int MXT = DIN / (16 * MXP);
    constexpr int MYT = DIN / (4 * MYP);
    constexpr int MZS = DIN / 8;             // mz per XCD slab
    constexpr int TPE = MXP * MYP;           // tiles per wave (one of MXP/MYP is 1)

    int bx = blockIdx.x;
    const int xcd = bx & 7;
    int local = bx >> 3;
    const int px = local & 1; local >>= 1;
    const int py = local & 1; local >>= 1;
    const int mg = local % MG; local /= MG;
    const int mxt = local % MXT; local /= MXT;
    const int myt = local % MYT; local /= MYT;
    const int pz = local & 1; local >>= 1;
    const int mzin = local;                  // 0..MZS-1
    const int mz = xcd * MZS + mzin;
    const int p = pz * 4 + py * 2 + px;

    const int lane = threadIdx.x & 63, wave = threadIdx.x >> 6;
    const int n16 = lane & 15, quad = lane >> 4;

    const int mx0 = mxt * (16 * MXP) + n16;
    const int my0 = myt * (4 * MYP) + wave * MYP;
    const int baseX = mx0 & ~1;
    const int sh = 16 * ((n16 & 1) + px);    // 0, 16, or 32
    const long sp = ((long)(mz + pz) * PD + (my0 + py)) * PD + baseX;

    const unsigned short* xq = Xp + (long)quad * PD3 + sp;

    // fragment-major weight tiles: 2048 shorts (4KB) per (p,mg,s)
    const short* ApT = Ap + (((long)p * MG + mg) * nsteps) * 2048;

    __shared__ short Abuf[2][2048];          // 8KB double buffer

    f32x4 acc[TPE][4];
    #pragma unroll
    for (int t = 0; t < TPE; ++t)
        #pragma unroll
        for (int cb = 0; cb < 4; ++cb) {
            const float* bp = bias + (mg * 64) + cb * 16 + quad * 4;
            acc[t][cb][0] = bp[0]; acc[t][cb][1] = bp[1];
            acc[t][cb][2] = bp[2]; acc[t][cb][3] = bp[3];
        }

    constexpr int rowoff[4] = { (PD + 1) * PD, PD * PD, PD, 0 };
    union Frag { unsigned u[4]; bf16x8 b; };

    const int chunkoff = wave * 512 + lane * 8;   // this thread's 16B of the 4KB tile

    // prologue: stage step 0
    {
        bf16x8 a0 = *(const bf16x8*)(ApT + chunkoff);
        *(bf16x8*)(&Abuf[0][chunkoff]) = a0;
    }
    __syncthreads();

    #pragma unroll 1
    for (int s = 0; s < nsteps; ++s) {
        const int cur = s & 1;
        bf16x8 anext;
        const bool more = (s + 1 < nsteps);
        if (more)
            anext = *(const bf16x8*)(ApT + (long)(s + 1) * 2048 + chunkoff);

        // X loads (plain C, raw staging)
        const unsigned short* xs = xq + (long)s * 4 * PD3;
        unsigned long long xr[TPE][4];
        #pragma unroll
        for (int t = 0; t < TPE; ++t) {
            const int toff = (MXP > 1) ? t * 16 : t * PD;
            #pragma unroll
            for (int j = 0; j < 4; ++j) {
                union { u16x4u v; unsigned long long u; } ld;
                ld.v = *(const u16x4u*)(xs + toff + rowoff[j]);
                xr[t][j] = ld.u;
            }
        }

        // A fragments from LDS (l = quad*16 + n16 == lane)
        bf16x8 af[4];
        #pragma unroll
        for (int cb = 0; cb < 4; ++cb)
            af[cb] = *(const bf16x8*)(&Abuf[cur][cb * 512 + lane * 8]);

        #pragma unroll
        for (int t = 0; t < TPE; ++t) {
            Frag fr;
            #pragma unroll
            for (int j = 0; j < 4; ++j)
                fr.u[j] = (unsigned)(xr[t][j] >> sh);
            #pragma unroll
            for (int cb = 0; cb < 4; ++cb)
                acc[t][cb] = __builtin_amdgcn_mfma_f32_16x16x32_bf16(af[cb], fr.b,
                                                                     acc[t][cb], 0, 0, 0);
        }

        if (more)
            *(bf16x8*)(&Abuf[cur ^ 1][chunkoff]) = anext;
        __syncthreads();
    }

    const int opz = 2 * mz + pz + OPAD;
    #pragma unroll
    for (int t = 0; t < TPE; ++t) {
        const int opx = 2 * (mx0 + ((MXP > 1) ? t * 16 : 0)) + px + OPAD;
        const int opy = 2 * (my0 + ((MYP > 1) ? t : 0)) + py + OPAD;
        const long spo = ((long)opz * OPD + opy) * OPD + opx;
        #pragma unroll
        for (int cb = 0; cb < 4; ++cb) {
            #pragma unroll
            for (int r = 0; r < 4; ++r) {
                int co = (mg * 64) + cb * 16 + quad * 4 + r;
                float v = fmaxf(acc[t][cb][r], 0.0f);
                store_act(Y + (long)co * OPD * OPD * OPD + spo, v);
            }
        }
    }
}

// ---------------- dec4 as MFMA GEMM, R23: LDS-staged X + frag-major A -------
// Fragment-major: Aw[(s*64 + lane)*8 + kk] = RNE(w[m*4096 + k]) with
// m = lane&15 (zero-padded beyond co=3), k = s*32 + (lane>>4)*8 + kk.
// Per-step A tile = contiguous 1KB.
__global__ __launch_bounds__(256)
void prep_dec4A_frag(const float* __restrict__ w, short* __restrict__ Aw)
{
    int idx = blockIdx.x * 256 + (int)threadIdx.x;    // 0..65535
    int kk = idx & 7;
    int l  = (idx >> 3) & 63;
    int s  = idx >> 9;                                // 0..127
    int n16 = l & 15, quad = l >> 4;
    int k = s * 32 + quad * 8 + kk;
    float v = (n16 < 3) ? w[n16 * 4096 + k] : 0.0f;
    Aw[idx] = (short)f32_to_bf16(v);
}

// All 4 waves of a block need the SAME 14 X-rows (2 z x 7 y) per step ->
// stage them once into a double-buffered LDS tile (224 threads x 1 dwordx4,
// 56 sequential lines/step vs ~160 scattered). Truncation-pack expressions
// and MFMA order unchanged; d3 stays fp32 => bit-identical output.
__global__ __launch_bounds__(256)
void conv_dec4_mfma(const float* __restrict__ d3, const short* __restrict__ Aw,
                    const float* __restrict__ bias, float* __restrict__ y)
{
    constexpr int D = 64, Dout = 61;
    int bx = blockIdx.x;
    const int slab = bx & 7;
    const int i = bx >> 3;                 // 0..127
    const int od = slab * 8 + (i >> 4);
    const int oh0 = (i & 15) * 4;          // covers oh0..oh0+3 (guard < 61)
    if (od >= Dout) return;                // uniform per block -> barriers safe
    const int tid = (int)threadIdx.x;
    const int lane = tid & 63, wave = tid >> 6;
    const int n16 = lane & 15, quad = lane >> 4;
    const int ow = wave * 16 + n16;

    // [dbuf][z'][y'][x] fp32; row 68 so ow+3 <= 66 stays in-bounds (pad
    // floats 64..67 uninitialized -- consumed only by discarded ow>=61 cols)
    __shared__ float Xs[2][2][7][68];

    f32x4 acc[4];
    #pragma unroll
    for (int j = 0; j < 4; ++j)
        #pragma unroll
        for (int r = 0; r < 4; ++r) {
            int co = quad * 4 + r;
            acc[j][r] = (co < 3) ? bias[co] : 0.0f;
        }

    const int kd0 = quad >> 1;
    const int kh0 = (quad & 1) * 2;

    // staging role: 224 threads, each owns (z', y', 16-float segment)
    const int srow = tid >> 4;             // 0..15 (14 used)
    const int sseg = tid & 15;
    const int szi = srow / 7, syi = srow % 7;
    const bool sact = (srow < 14);
    const long sbase = (((long)(od + szi) * D) + min(oh0 + syi, D - 1)) * D + sseg * 4;
    auto saddr = [&](int s) {
        return d3 + sbase + ((long)((s >> 1) * D + (s & 1) * 2)) * D * D;
    };

    // prologue: stage step 0
    if (sact)
        *(f32x4u*)(&Xs[0][szi][syi][sseg * 4]) = *(const f32x4u*)saddr(0);
    __syncthreads();

    #pragma unroll 1
    for (int s = 0; s < 128; ++s) {
        const int cur = s & 1;
        const bool more = (s + 1 < 128);
        f32x4u nv;
        if (more && sact)
            nv = *(const f32x4u*)saddr(s + 1);

        bf16x8 af = *(const bf16x8*)(Aw + ((long)s * 64 + lane) * 8);

        unsigned p0[5], p1[5];
        #pragma unroll
        for (int r = 0; r < 5; ++r) {
            f32x4u v = *(const f32x4u*)(&Xs[cur][kd0][kh0 + r][ow]);
            p0[r] = (__float_as_uint(v[0]) >> 16) | (__float_as_uint(v[1]) & 0xffff0000u);
            p1[r] = (__float_as_uint(v[2]) >> 16) | (__float_as_uint(v[3]) & 0xffff0000u);
        }
        #pragma unroll
        for (int j = 0; j < 4; ++j) {
            union { unsigned u[4]; bf16x8 b; } fr;
            fr.u[0] = p0[j];     fr.u[1] = p1[j];
            fr.u[2] = p0[j + 1]; fr.u[3] = p1[j + 1];
            acc[j] = __builtin_amdgcn_mfma_f32_16x16x32_bf16(af, fr.b, acc[j], 0, 0, 0);
        }

        if (more && sact)
            *(f32x4u*)(&Xs[cur ^ 1][szi][syi][sseg * 4]) = nv;
        __syncthreads();
    }

    if (ow < Dout && quad == 0) {
        #pragma unroll
        for (int j = 0; j < 4; ++j) {
            const int oh = oh0 + j;
            if (oh >= Dout) continue;
            #pragma unroll
            for (int r = 0; r < 3; ++r)
                y[((long)(r * Dout + od) * Dout + oh) * Dout + ow] = tanhf(acc[j][r]);
        }
    }
}

extern "C" void kernel_launch(void* const* d_in, const int* in_sizes, int n_in,
                              void* d_out, int out_size, void* d_ws, size_t ws_size,
                              hipStream_t stream)
{
    const float* x        = (const float*)d_in[0];
    const float* enc_w1   = (const float*)d_in[1];
    const float* enc_b1   = (const float*)d_in[2];
    const float* enc_w2   = (const float*)d_in[3];
    const float* enc_b2   = (const float*)d_in[4];
    const float* enc_w3   = (const float*)d_in[5];
    const float* enc_b3   = (const float*)d_in[6];
    const float* enc_w4   = (const float*)d_in[7];
    const float* enc_b4   = (const float*)d_in[8];
    const float* codebook = (const float*)d_in[9];
    const float* dec_w1   = (const float*)d_in[10];
    const float* dec_b1   = (const float*)d_in[11];
    const float* dec_w2   = (const float*)d_in[12];
    const float* dec_b2   = (const float*)d_in[13];
    const float* dec_w3   = (const float*)d_in[14];
    const float* dec_b3   = (const float*)d_in[15];
    const float* dec_w4   = (const float*)d_in[16];
    const float* dec_b4   = (const float*)d_in[17];

    float* out = (float*)d_out;
    float* idx_out = out + 2L * 3 * 61 * 61 * 61;

    // ---- workspace (byte offsets) ----
    char* wsb = (char*)d_ws;
    float*          cn   = (float*)wsb;                        //      4,096
    unsigned short* qp   = (unsigned short*)(wsb + 4096);      //  1,024,000
    short*          Ap1  = (short*)(wsb + 1028096);            //  8,388,608
    short*          Ap2  = (short*)(wsb + 9416704);            //  4,194,304
    short*          Ap3  = (short*)(wsb + 13611008);           //  1,048,576
    short*          Aw4  = (short*)(wsb + 14659584);           //    131,072
    short*          W1hi = (short*)(wsb + 14790656);           //     24,576
    short*          W1lo = (short*)(wsb + 14815232);           //     24,576
    short*          W2hi = (short*)(wsb + 14839808);           //  1,048,576
    short*          W2lo = (short*)(wsb + 15888384);           //  1,048,576
    short*          W3hi = (short*)(wsb + 16936960);           //  4,194,304
    short*          W3lo = (short*)(wsb + 21131264);           //  4,194,304
    char* arena = wsb + 25325568;
    // encoder phase:
    unsigned short* xphi = (unsigned short*)arena;                    // (2,3,66,66,68)
    unsigned short* xplo = (unsigned short*)(arena + 3554496);
    unsigned short* h1hi = (unsigned short*)(arena + 7108992);        // (2,64,34,34,36)
    unsigned short* h1lo = (unsigned short*)(arena + 17762688);
    unsigned short* h2hi = (unsigned short*)(arena + 28416384);       // (2,128,18,18,20)
    unsigned short* h2lo = (unsigned short*)(arena + 31734144);
    float*          pp3  = (float*)(arena + 35051904);                // 4x(2,256,8^3)
    float*          h3   = (float*)(arena + 39246208);                // (2,256,512)
    float*          lat  = (float*)(arena + 40294784);                // (2,256,512)
    // decoder phase (after VQ; overlaps encoder buffers):
    unsigned short* d1 = (unsigned short*)arena;                      // (256,18^3) bf16
    unsigned short* d2 = (unsigned short*)(arena + 2985984);          // (128,34^3) bf16
    float*          d3 = (float*)(arena + 13047808);                  // (64,64^3) fp32
    // arena peak 80.2 MB -> ws used 105.5 MB; cbT appended below:
    float*          cbT = (float*)(wsb + 105482240);                  // 1,048,576
    // total 106.5 MB (< 112.2 MB proven in R0)

    dim3 blk(256);
    auto nblk = [](long n) { return dim3((unsigned)((n + 255) / 256)); };

    // ---- weight prep ----
    prep_convt_w<<<nblk(8L * 256 * 2048), blk, 0, stream>>>(dec_w1, Ap1, 256, 256, 0);
    prep_convt_w_frag<<<nblk(8L * 128 * 2048), blk, 0, stream>>>(dec_w2, Ap2, 256, 128, 1);
    prep_convt_w_frag<<<nblk(8L * 64 * 1024), blk, 0, stream>>>(dec_w3, Ap3, 128, 64, 1);
    prep_dec4A_frag<<<dim3(256), blk, 0, stream>>>(dec_w4, Aw4);
    prep_split_w<<<nblk(12288), blk, 0, stream>>>(enc_w1, W1hi, W1lo, 12288);
    prep_split_w_frag<<<nblk(524288), blk, 0, stream>>>(enc_w2, W2hi, W2lo, 64, 128);
    prep_split_w_frag<<<nblk(2097152), blk, 0, stream>>>(enc_w3, W3hi, W3lo, 128, 256);
    transpose_cb<<<dim3(1024), blk, 0, stream>>>(codebook, cbT);

    // ---- encoder (MFMA, bf16-pair) ----
    pad_input_split<<<nblk(6L * 66 * 66 * 68), blk, 0, stream>>>(x, xphi, xplo);
    zero_halo_ps<<<nblk(128L * 34 * 34 * 36), blk, 0, stream>>>(h1hi, 128, 34, 36);
    zero_halo_ps<<<nblk(128L * 34 * 34 * 36), blk, 0, stream>>>(h1lo, 128, 34, 36);
    conv_s2_mfma<3, 64, 32, 66, 68, 4, 2, 0, 1, 1><<<dim3(1024), blk, 0, stream>>>(
        xphi, xplo, W1hi, W1lo, enc_b1, h1hi, h1lo, nullptr, 34, 36, 1, 0);
    zero_halo_ps<<<nblk(256L * 18 * 18 * 20), blk, 0, stream>>>(h2hi, 256, 18, 20);
    zero_halo_ps<<<nblk(256L * 18 * 18 * 20), blk, 0, stream>>>(h2lo, 256, 18, 20);
    conv_s2_mfma_lds<64, 128, 16, 34, 36, 2, 1, 0, 1, 1><<<dim3(512), blk, 0, stream>>>(
        h1hi, h1lo, W2hi, W2lo, enc_b2, h2hi, h2lo, nullptr, 18, 20, 1, 0);
    conv_s2_mfma_lds<128, 256, 8, 18, 20, 4, 1, 1, 4, 0><<<dim3(256), blk, 0, stream>>>(
        h2hi, h2lo, W3hi, W3lo, enc_b3, nullptr, nullptr, pp3, 8, 8, 0, 262144);
    combine4_relu<<<nblk(262144), blk, 0, stream>>>(pp3, h3, 262144, 262144);
    conv1x1_b<<<dim3(512), dim3(128), 0, stream>>>(h3, enc_w4, enc_b4, lat);

    // ---- VQ (fp32 exact) ----
    codenorm_kernel<<<dim3(1024), dim3(64), 0, stream>>>(codebook, cn);
    zero_halo_t<unsigned short><<<nblk(512L * 10 * 10 * 10), blk, 0, stream>>>(qp, 512, 10);
    vq_kernel4<<<dim3(256), blk, 0, stream>>>(lat, codebook, cbT, cn, qp, idx_out);

    // ---- decoder halos ----
    zero_halo_t<unsigned short><<<nblk(256L * 18 * 18 * 18), blk, 0, stream>>>(d1, 256, 18);
    zero_halo_t<unsigned short><<<nblk(128L * 34 * 34 * 34), blk, 0, stream>>>(d2, 128, 34);

    // ---- decoder (MFMA) per batch ----
    for (int b = 0; b < 2; ++b) {
        const unsigned short* qb = qp + (long)b * 256 * 1000;
        float* outb = out + (long)b * 3 * 226981;
        // dec1 (DIN=8, old layout): grid = 8*2*4*1*4 = 256
        convt_mfma<256, 256, 8, 1, unsigned short><<<dim3(256), blk, 0, stream>>>(
            qb, Ap1, dec_b1, d1);
        // dec2 (v2, MXP=1 MYP=2): grid = 8 * (2*2*2*1*2*2*2) = 512
        convt_mfma_v2<256, 128, 16, 1, 1, 2, unsigned short><<<dim3(512), blk, 0, stream>>>(
            d1, Ap2, dec_b2, d2);
        // dec3 (v2, MXP=2 MYP=1): grid = 8 * (2*2*1*1*8*2*4) = 2048
        convt_mfma_v2<128, 64, 32, 0, 2, 1, float><<<dim3(2048), blk, 0, stream>>>(
            d2, Ap3, dec_b3, d3);
        conv_dec4_mfma<<<dim3(8 * 8 * 16), blk, 0, stream>>>(d3, Aw4, dec_b4, outb);
    }
}

// Round 9
// 955.122 us; speedup vs baseline: 1.5269x; 1.0321x over previous
//
#include <hip/hip_runtime.h>
#include <cfloat>
#include <cmath>

// ---------------------------------------------------------------------------
// Round 26 (= R25 resubmit; R25 bench was an infra failure -- container died
// with no compile/pytest/counter verdict; source audit found no hang/fault
// candidate: 8KB LDS, uniform barriers, all indices in-bounds. Same failure
// mode as R21 which passed on identical resubmission.)
//
// R25 theory (unchanged): kill dec4's LDS bank conflicts.
// R24 counters: conv_dec4_mfma 106us x2 with SQ_LDS_BANK_CONFLICT = 2.0e7
// (~31% of kernel cycles). Bank math (stride 68 = 4 mod 32): read windows
// start {0,8,28,4} -> up to 4-way; b128 write chunks all start = 0 mod 4 ->
// 8-way. Fix: (a) row stride 72 (= 8 mod 32): read windows {0,16,24,8} tile
// all 32 banks at exactly 2/bank (free); (b) strided staging -- thread t
// owns words g = t + 224j of the 896-word tile (4 scalar loads + 4
// ds_write_b32): wave-pass writes 64 consecutive words = 2/bank free;
// global loads stay coalesced. Same values, same truncation-pack, same MFMA
// order => bit-identical. Everything else unchanged from R24.
// ---------------------------------------------------------------------------

using f32x4  = __attribute__((ext_vector_type(4))) float;
using bf16x8 = __attribute__((ext_vector_type(8))) short;
typedef float f32x4u __attribute__((ext_vector_type(4), aligned(4)));
typedef unsigned short u16x4u __attribute__((ext_vector_type(4), aligned(4)));

__device__ __forceinline__ unsigned short f32_to_bf16(float f) {
    unsigned int u = __float_as_uint(f);
    u += 0x7fffu + ((u >> 16) & 1u);          // round-to-nearest-even
    return (unsigned short)(u >> 16);
}
__device__ __forceinline__ void split_bf16(float v, unsigned short& h, unsigned short& l) {
    h = f32_to_bf16(v);
    float hf = __uint_as_float((unsigned)h << 16);
    l = f32_to_bf16(v - hf);
}
__device__ __forceinline__ void store_act(float* p, float v) { *p = v; }
__device__ __forceinline__ void store_act(unsigned short* p, float v) { *p = f32_to_bf16(v); }

template <typename V>
__device__ __forceinline__ bf16x8 pack_b(V r0, V r1) {
    bf16x8 b;
    b[0] = (short)r0[0]; b[1] = (short)r0[1]; b[2] = (short)r0[2]; b[3] = (short)r0[3];
    b[4] = (short)r1[0]; b[5] = (short)r1[1]; b[6] = (short)r1[2]; b[7] = (short)r1[3];
    return b;
}

// ---------------- prep: weight hi/lo split (linear; enc1) ----------------
__global__ __launch_bounds__(256)
void prep_split_w(const float* __restrict__ w, short* __restrict__ whi,
                  short* __restrict__ wlo, long total)
{
    long idx = (long)blockIdx.x * blockDim.x + threadIdx.x;
    if (idx >= total) return;
    unsigned short h, l;
    split_bf16(w[idx], h, l);
    whi[idx] = (short)h; wlo[idx] = (short)l;
}

// Fragment-major hi/lo split for the LDS-staged conv_s2 (enc2/enc3):
//   whi[((s*MT + m)*64 + l)*8 + kk] = hi(w[co*K + korig])
// with MT = COUT/16, co = m*16 + (l&15), korig = s*32 + (l>>4)*8 + kk.
// Each step tile (COUT*32 shorts) is contiguous.
__global__ __launch_bounds__(256)
void prep_split_w_frag(const float* __restrict__ w, short* __restrict__ whi,
                       short* __restrict__ wlo, int CIN, int COUT)
{
    const int K = CIN * 64;
    const int MT = COUT >> 4;
    long total = (long)COUT * K;
    long idx = (long)blockIdx.x * blockDim.x + threadIdx.x;
    if (idx >= total) return;
    int kk = (int)(idx & 7); long r = idx >> 3;
    int l  = (int)(r & 63);  r >>= 6;
    int m  = (int)(r % MT);
    int s  = (int)(r / MT);
    int n16 = l & 15, quad = l >> 4;
    int co = m * 16 + n16;
    int korig = s * 32 + quad * 8 + kk;
    unsigned short h, lo16;
    split_bf16(w[(long)co * K + korig], h, lo16);
    whi[idx] = (short)h; wlo[idx] = (short)lo16;
}

// ---------------- pad input -> hi/lo bf16 pitched planes --------------------
__global__ __launch_bounds__(256)
void pad_input_split(const float* __restrict__ x, unsigned short* __restrict__ xhi,
                     unsigned short* __restrict__ xlo)
{
    const int D = 64, PD = 66, PRX = 68, BC = 6;
    long total = (long)BC * PD * PD * PRX;
    long idx = (long)blockIdx.x * blockDim.x + threadIdx.x;
    if (idx >= total) return;
    int px = (int)(idx % PRX); long t = idx / PRX;
    int py = (int)(t % PD); t /= PD;
    int pz = (int)(t % PD); int c = (int)(t / PD);
    int ix = px - 1, iy = py - 1, iz = pz - 1;
    float v = 0.0f;
    if ((unsigned)ix < (unsigned)D && (unsigned)iy < (unsigned)D && (unsigned)iz < (unsigned)D)
        v = x[(((long)c * D + iz) * D + iy) * D + ix];
    unsigned short h, l;
    split_bf16(v, h, l);
    xhi[idx] = h; xlo[idx] = l;
}

__global__ __launch_bounds__(256)
void zero_halo_ps(unsigned short* __restrict__ p, int C, int PD, int PRX)
{
    long total = (long)C * PD * PD * PRX;
    long idx = (long)blockIdx.x * blockDim.x + threadIdx.x;
    if (idx >= total) return;
    int px = (int)(idx % PRX); long t = idx / PRX;
    int py = (int)(t % PD); t /= PD;
    int pz = (int)(t % PD);
    if (px == 0 || px >= PD - 1 || py == 0 || py == PD - 1 || pz == 0 || pz == PD - 1)
        p[idx] = 0;
}

template <typename T>
__global__ __launch_bounds__(256) void zero_halo_t(T* __restrict__ p, int C, int PD)
{
    long total = (long)C * PD * PD * PD;
    long idx = (long)blockIdx.x * blockDim.x + threadIdx.x;
    if (idx >= total) return;
    int px = (int)(idx % PD); long t = idx / PD;
    int py = (int)(t % PD); t /= PD;
    int pz = (int)(t % PD);
    if (px == 0 || px == PD - 1 || py == 0 || py == PD - 1 || pz == 0 || pz == PD - 1)
        p[idx] = (T)0;
}

// ---------------------------------------------------------------------------
// Conv3d k4 s2 p1 as MFMA implicit GEMM, bf16 hi/lo pair inputs (enc1 only)
// ---------------------------------------------------------------------------
template <int CIN, int COUT, int DOUT, int PD, int PRX, int MTW, int OWT,
          int OWHALF, int KSPLIT, int OUTSPLIT>
__global__ __launch_bounds__(256)
void conv_s2_mfma(const unsigned short* __restrict__ xhi,
                  const unsigned short* __restrict__ xlo,
                  const short* __restrict__ Whi, const short* __restrict__ Wlo,
                  const float* __restrict__ bias,
                  unsigned short* __restrict__ yhi, unsigned short* __restrict__ ylo,
                  float* __restrict__ yf,
                  int OPD, int OPRX, int po, long sstride)
{
    constexpr int K = CIN * 64;
    constexpr int MWAVES = COUT / (16 * MTW);
    constexpr int RPB = 4 / MWAVES;
    constexpr int KN = (CIN * 2) / KSPLIT;

    int bx = blockIdx.x;
    const int ks = (KSPLIT > 1) ? (bx % KSPLIT) : 0;
    const int rowblk = (KSPLIT > 1) ? (bx / KSPLIT) : bx;
    const int lane = (int)threadIdx.x & 63, w = (int)threadIdx.x >> 6;
    const int mi = (MWAVES == 4) ? w : 0;
    const int ri = (MWAVES == 4) ? 0 : w;
    const int rowid = rowblk * RPB + ri;
    const int n16 = lane & 15, quad = lane >> 4;

    int b, od, oh, ow;
    if (OWHALF) {
        constexpr int NOH = DOUT / 2;
        const int ohb = rowid % NOH; int t = rowid / NOH;
        od = t % DOUT; b = t / DOUT;
        oh = ohb * 2 + (n16 >> 3);
        ow = n16 & 7;
    } else {
        const int owt = rowid % OWT; int t = rowid / OWT;
        oh = t % DOUT; t /= DOUT;
        od = t % DOUT; b = t / DOUT;
        ow = owt * 16 + n16;
    }

    const int co0 = mi * (MTW * 16);

    f32x4 acc[MTW];
    #pragma unroll
    for (int mt = 0; mt < MTW; ++mt)
        #pragma unroll
        for (int r = 0; r < 4; ++r) {
            int co = co0 + mt * 16 + quad * 4 + r;
            acc[mt][r] = (ks == 0) ? bias[co] : 0.0f;
        }

    const int sg0 = ks * KN;
    const long chs = (long)PD * PD * PRX;
    long off = ((long)(b * CIN + (sg0 >> 1)) * PD + (2 * od + (quad >> 1))) * PD * PRX
             + (long)(2 * oh + (quad & 1) * 2) * PRX + 2 * ow;
    const unsigned short* phi = xhi + off;
    const unsigned short* plo = xlo + off;
    const long incA = 2L * PD * PRX;
    const long incB = chs - 2L * PD * PRX;

    const short* a0h = Whi + (long)(co0 + n16) * K + sg0 * 32 + quad * 8;
    const short* a0l = Wlo + (long)(co0 + n16) * K + sg0 * 32 + quad * 8;

    #pragma unroll 2
    for (int s = 0; s < KN; ++s) {
        u16x4u h0 = *(const u16x4u*)phi;
        u16x4u h1 = *(const u16x4u*)(phi + PRX);
        u16x4u l0 = *(const u16x4u*)plo;
        u16x4u l1 = *(const u16x4u*)(plo + PRX);
        bf16x8 bhi = pack_b(h0, h1);
        bf16x8 blo = pack_b(l0, l1);
        #pragma unroll
        for (int mt = 0; mt < MTW; ++mt) {
            bf16x8 ah = *(const bf16x8*)(a0h + (long)mt * 16 * K + s * 32);
            bf16x8 al = *(const bf16x8*)(a0l + (long)mt * 16 * K + s * 32);
            acc[mt] = __builtin_amdgcn_mfma_f32_16x16x32_bf16(ah, bhi, acc[mt], 0, 0, 0);
            acc[mt] = __builtin_amdgcn_mfma_f32_16x16x32_bf16(ah, blo, acc[mt], 0, 0, 0);
            acc[mt] = __builtin_amdgcn_mfma_f32_16x16x32_bf16(al, bhi, acc[mt], 0, 0, 0);
        }
        long inc = (s & 1) ? incB : incA;
        phi += inc; plo += inc;
    }

    if (OUTSPLIT) {
        #pragma unroll
        for (int mt = 0; mt < MTW; ++mt)
            #pragma unroll
            for (int r = 0; r < 4; ++r) {
                int co = co0 + mt * 16 + quad * 4 + r;
                float v = fmaxf(acc[mt][r], 0.0f);
                unsigned short h, l;
                split_bf16(v, h, l);
                long o = (((long)(b * COUT + co) * OPD + od + po) * OPD + oh + po) * OPRX
                       + ow + po;
                yhi[o] = h; ylo[o] = l;
            }
    } else {
        #pragma unroll
        for (int mt = 0; mt < MTW; ++mt)
            #pragma unroll
            for (int r = 0; r < 4; ++r) {
                int co = co0 + mt * 16 + quad * 4 + r;
                long o = (long)ks * sstride
                       + (((long)(b * COUT + co) * OPD + od) * OPD + oh) * OPRX + ow;
                yf[o] = acc[mt][r];
            }
    }
}

// LDS-staged variant (enc2/enc3): fragment-major Whi/Wlo, per-step tile
// staged cooperatively into a double-buffered LDS pair. Same MFMA order.
template <int CIN, int COUT, int DOUT, int PD, int PRX, int MTW, int OWT,
          int OWHALF, int KSPLIT, int OUTSPLIT>
__global__ __launch_bounds__(256)
void conv_s2_mfma_lds(const unsigned short* __restrict__ xhi,
                      const unsigned short* __restrict__ xlo,
                      const short* __restrict__ Whi, const short* __restrict__ Wlo,
                      const float* __restrict__ bias,
                      unsigned short* __restrict__ yhi, unsigned short* __restrict__ ylo,
                      float* __restrict__ yf,
                      int OPD, int OPRX, int po, long sstride)
{
    constexpr int K = CIN * 64;
    constexpr int MWAVES = COUT / (16 * MTW);
    constexpr int RPB = 4 / MWAVES;
    constexpr int KN = (CIN * 2) / KSPLIT;
    constexpr int TILE = COUT * 32;                 // shorts per step tile
    constexpr int PASSES = TILE / (256 * 8);        // dwordx4 passes/thread
    static_assert(PASSES >= 1, "tile too small for 256-thread staging");

    int bx = blockIdx.x;
    const int ks = (KSPLIT > 1) ? (bx % KSPLIT) : 0;
    const int rowblk = (KSPLIT > 1) ? (bx / KSPLIT) : bx;
    const int tid = (int)threadIdx.x;
    const int lane = tid & 63, w = tid >> 6;
    const int mi = (MWAVES == 4) ? w : 0;
    const int ri = (MWAVES == 4) ? 0 : w;
    const int rowid = rowblk * RPB + ri;
    const int n16 = lane & 15, quad = lane >> 4;

    int b, od, oh, ow;
    if (OWHALF) {
        constexpr int NOH = DOUT / 2;
        const int ohb = rowid % NOH; int t = rowid / NOH;
        od = t % DOUT; b = t / DOUT;
        oh = ohb * 2 + (n16 >> 3);
        ow = n16 & 7;
    } else {
        const int owt = rowid % OWT; int t = rowid / OWT;
        oh = t % DOUT; t /= DOUT;
        od = t % DOUT; b = t / DOUT;
        ow = owt * 16 + n16;
    }

    const int co0 = mi * (MTW * 16);

    f32x4 acc[MTW];
    #pragma unroll
    for (int mt = 0; mt < MTW; ++mt)
        #pragma unroll
        for (int r = 0; r < 4; ++r) {
            int co = co0 + mt * 16 + quad * 4 + r;
            acc[mt][r] = (ks == 0) ? bias[co] : 0.0f;
        }

    const int sg0 = ks * KN;
    const long chs = (long)PD * PD * PRX;
    long off = ((long)(b * CIN + (sg0 >> 1)) * PD + (2 * od + (quad >> 1))) * PD * PRX
             + (long)(2 * oh + (quad & 1) * 2) * PRX + 2 * ow;
    const unsigned short* phi = xhi + off;
    const unsigned short* plo = xlo + off;
    const long incA = 2L * PD * PRX;
    const long incB = chs - 2L * PD * PRX;

    __shared__ short AhiB[2][TILE];
    __shared__ short AloB[2][TILE];

    // prologue: stage step 0
    {
        const long tb = (long)sg0 * TILE;
        #pragma unroll
        for (int j = 0; j < PASSES; ++j) {
            const int o = tid * 8 + j * 2048;
            *(bf16x8*)(&AhiB[0][o]) = *(const bf16x8*)(Whi + tb + o);
            *(bf16x8*)(&AloB[0][o]) = *(const bf16x8*)(Wlo + tb + o);
        }
    }
    __syncthreads();

    #pragma unroll 1
    for (int s = 0; s < KN; ++s) {
        const int cur = s & 1;
        const bool more = (s + 1 < KN);
        bf16x8 nh[PASSES], nl[PASSES];
        if (more) {
            const long tb = (long)(sg0 + s + 1) * TILE;
            #pragma unroll
            for (int j = 0; j < PASSES; ++j) {
                const int o = tid * 8 + j * 2048;
                nh[j] = *(const bf16x8*)(Whi + tb + o);
                nl[j] = *(const bf16x8*)(Wlo + tb + o);
            }
        }

        u16x4u h0 = *(const u16x4u*)phi;
        u16x4u h1 = *(const u16x4u*)(phi + PRX);
        u16x4u l0 = *(const u16x4u*)plo;
        u16x4u l1 = *(const u16x4u*)(plo + PRX);
        bf16x8 bhi = pack_b(h0, h1);
        bf16x8 blo = pack_b(l0, l1);

        #pragma unroll
        for (int mt = 0; mt < MTW; ++mt) {
            const int m = mi * MTW + mt;
            bf16x8 ah = *(const bf16x8*)(&AhiB[cur][(m * 64 + lane) * 8]);
            bf16x8 al = *(const bf16x8*)(&AloB[cur][(m * 64 + lane) * 8]);
            acc[mt] = __builtin_amdgcn_mfma_f32_16x16x32_bf16(ah, bhi, acc[mt], 0, 0, 0);
            acc[mt] = __builtin_amdgcn_mfma_f32_16x16x32_bf16(ah, blo, acc[mt], 0, 0, 0);
            acc[mt] = __builtin_amdgcn_mfma_f32_16x16x32_bf16(al, bhi, acc[mt], 0, 0, 0);
        }

        long inc = (s & 1) ? incB : incA;
        phi += inc; plo += inc;

        if (more) {
            #pragma unroll
            for (int j = 0; j < PASSES; ++j) {
                const int o = tid * 8 + j * 2048;
                *(bf16x8*)(&AhiB[cur ^ 1][o]) = nh[j];
                *(bf16x8*)(&AloB[cur ^ 1][o]) = nl[j];
            }
        }
        __syncthreads();
    }

    if (OUTSPLIT) {
        #pragma unroll
        for (int mt = 0; mt < MTW; ++mt)
            #pragma unroll
            for (int r = 0; r < 4; ++r) {
                int co = co0 + mt * 16 + quad * 4 + r;
                float v = fmaxf(acc[mt][r], 0.0f);
                unsigned short h, l;
                split_bf16(v, h, l);
                long o = (((long)(b * COUT + co) * OPD + od + po) * OPD + oh + po) * OPRX
                       + ow + po;
                yhi[o] = h; ylo[o] = l;
            }
    } else {
        #pragma unroll
        for (int mt = 0; mt < MTW; ++mt)
            #pragma unroll
            for (int r = 0; r < 4; ++r) {
                int co = co0 + mt * 16 + quad * 4 + r;
                long o = (long)ks * sstride
                       + (((long)(b * COUT + co) * OPD + od) * OPD + oh) * OPRX + ow;
                yf[o] = acc[mt][r];
            }
    }
}

__global__ __launch_bounds__(256)
void combine4_relu(const float* __restrict__ p, float* __restrict__ y, long N, long ss)
{
    long idx = (long)blockIdx.x * blockDim.x + threadIdx.x;
    if (idx >= N) return;
    float v = p[idx] + p[idx + ss] + p[idx + 2 * ss] + p[idx + 3 * ss];
    y[idx] = fmaxf(v, 0.0f);
}

// ---------------- 1x1 conv (fp32 exact) ----------------
__global__ __launch_bounds__(128)
void conv1x1_b(const float* __restrict__ x, const float* __restrict__ w,
               const float* __restrict__ bias, float* __restrict__ y)
{
    const int co = blockIdx.x & 255, b = blockIdx.x >> 8;
    const int s4 = (int)threadIdx.x * 4;
    const float* xb = x + (long)b * 256 * 512 + s4;
    const float* wr = w + (long)co * 256;      // uniform -> s_load
    float bv = bias[co];
    float4 acc = {bv, bv, bv, bv};
    for (int ci = 0; ci < 256; ++ci) {
        float wv = wr[ci];
        float4 xv = *(const float4*)(xb + (long)ci * 512);
        acc.x = fmaf(xv.x, wv, acc.x); acc.y = fmaf(xv.y, wv, acc.y);
        acc.z = fmaf(xv.z, wv, acc.z); acc.w = fmaf(xv.w, wv, acc.w);
    }
    *(float4*)(y + (long)(b * 256 + co) * 512 + s4) = acc;
}

// ---------------- VQ (fp32 exact) ----------------
__global__ void codenorm_kernel(const float* __restrict__ cb, float* __restrict__ norms)
{
    int k = blockIdx.x;
    int lane = threadIdx.x;
    float s = 0.0f;
    const float* row = cb + (long)k * 256;
    for (int d = lane; d < 256; d += 64) { float v = row[d]; s = fmaf(v, v, s); }
    for (int off = 32; off > 0; off >>= 1) s += __shfl_down(s, off);
    if (lane == 0) norms[k] = s;
}

// cbT[d*1024 + k] = cb[k*256 + d]  (fp32 copy -> values unchanged)
__global__ __launch_bounds__(256)
void transpose_cb(const float* __restrict__ cb, float* __restrict__ cbT)
{
    int idx = blockIdx.x * 256 + (int)threadIdx.x;    // 0..262143
    int d = idx & 255, k = idx >> 8;
    cbT[(long)d * 1024 + k] = cb[(long)k * 256 + d];
}

// R24: 4 rows/block (grid 256), coalesced cbT float4 loads (codes 4t..4t+3),
// rows staged in LDS. Bit-identical to the original per-row kernel.
__global__ __launch_bounds__(256)
void vq_kernel4(const float* __restrict__ lat, const float* __restrict__ cb,
                const float* __restrict__ cbT, const float* __restrict__ norms,
                unsigned short* __restrict__ q, float* __restrict__ idx_out)
{
    __shared__ __align__(16) float rows[4][256];
    __shared__ float s_best[4][256];
    __shared__ int   s_bidx[4][256];
    const int r0 = blockIdx.x * 4;
    const int t = (int)threadIdx.x;

    #pragma unroll
    for (int j = 0; j < 4; ++j)
        rows[j][t] = lat[(long)(r0 + j) * 256 + t];
    __syncthreads();

    // latn per row -- identical float4 fmaf chain to the original
    float latn[4];
    #pragma unroll
    for (int j = 0; j < 4; ++j) {
        const float4* rowv = (const float4*)rows[j];
        float a = 0.0f;
        #pragma unroll 4
        for (int d = 0; d < 64; ++d) {
            float4 rv = rowv[d];
            a = fmaf(rv.x, rv.x, a); a = fmaf(rv.y, rv.y, a);
            a = fmaf(rv.z, rv.z, a); a = fmaf(rv.w, rv.w, a);
        }
        latn[j] = a;
    }

    // codes 4t..4t+3; dot[j][c] accumulates d = 0..255 sequentially (same
    // chain as the original scalar loop)
    float dot[4][4] = {};
    const float* ct = cbT + t * 4;
    #pragma unroll 4
    for (int d = 0; d < 256; ++d) {
        float4 c4 = *(const float4*)(ct + (long)d * 1024);
        #pragma unroll
        for (int j = 0; j < 4; ++j) {
            float rv = rows[j][d];
            dot[j][0] = fmaf(rv, c4.x, dot[j][0]);
            dot[j][1] = fmaf(rv, c4.y, dot[j][1]);
            dot[j][2] = fmaf(rv, c4.z, dot[j][2]);
            dot[j][3] = fmaf(rv, c4.w, dot[j][3]);
        }
    }

    float4 nv = *(const float4*)(norms + t * 4);
    float nr[4] = {nv.x, nv.y, nv.z, nv.w};

    #pragma unroll
    for (int j = 0; j < 4; ++j) {
        float best = FLT_MAX;
        int bidx = 0x7fffffff;
        #pragma unroll
        for (int c = 0; c < 4; ++c) {
            float sc = latn[j] - 2.0f * dot[j][c] + nr[c];
            int k = t * 4 + c;
            if (sc < best || (sc == best && k < bidx)) { best = sc; bidx = k; }
        }
        s_best[j][t] = best; s_bidx[j][t] = bidx;
    }
    __syncthreads();
    for (int off = 128; off > 0; off >>= 1) {
        if (t < off) {
            #pragma unroll
            for (int j = 0; j < 4; ++j) {
                float o = s_best[j][t + off]; int oi = s_bidx[j][t + off];
                if (o < s_best[j][t] || (o == s_best[j][t] && oi < s_bidx[j][t])) {
                    s_best[j][t] = o; s_bidx[j][t] = oi;
                }
            }
        }
        __syncthreads();
    }

    #pragma unroll
    for (int j = 0; j < 4; ++j) {
        const int bk = s_bidx[j][0];
        const int r = r0 + j;
        const int b = r >> 9, n = r & 511;
        const int zz = n >> 6, yy = (n >> 3) & 7, xx = n & 7;
        q[(long)(b * 256 + t) * 1000 + ((long)(zz + 1) * 10 + (yy + 1)) * 10 + (xx + 1)]
            = f32_to_bf16(cb[(long)bk * 256 + t]);
    }
    if (t == 0) {
        #pragma unroll
        for (int j = 0; j < 4; ++j)
            idx_out[r0 + j] = (float)s_bidx[j][0];
    }
}

// ---------------- decoder: MFMA implicit-GEMM ConvTranspose ----------------
// xflip=0: B slot a <-> x offset (1-ax), kw=(1-px)+2*ax (old cube kernel).
// xflip=1: B slot a <-> x offset ax,     kw=(1-px)+2*(1-ax) (dword-pair kernel).
__global__ __launch_bounds__(256)
void prep_convt_w(const float* __restrict__ w, short* __restrict__ Ap,
                  int Cin, int Cout, int xflip)
{
    const int K = Cin * 8;
    long total = 8L * Cout * K;
    long idx = (long)blockIdx.x * blockDim.x + threadIdx.x;
    if (idx >= total) return;
    int k = (int)(idx % K);
    int co = (int)((idx / K) % Cout);
    int p = (int)(idx / ((long)K * Cout));
    int ci = k >> 3, a = k & 7;
    int az = (a >> 2) & 1, ay = (a >> 1) & 1, ax = a & 1;
    int pz = p >> 2, py = (p >> 1) & 1, px = p & 1;
    int axw = xflip ? (1 - ax) : ax;
    int kd = (1 - pz) + 2 * az, kh = (1 - py) + 2 * ay, kw = (1 - px) + 2 * axw;
    float v = w[((long)ci * Cout + co) * 64 + kd * 16 + kh * 4 + kw];
    Ap[idx] = (short)f32_to_bf16(v);
}

// Fragment-major layout for the LDS-staged v2 kernel:
//   ApN[((p*MG + mg)*nsteps + s)*2048 + cb*512 + l*8 + kk]
// where l = quad*16 + n16, korig = s*32 + quad*8 + kk, co = mg*64 + cb*16 + n16.
// Each (p,mg,s) tile is one contiguous 4KB block.
__global__ __launch_bounds__(256)
void prep_convt_w_frag(const float* __restrict__ w, short* __restrict__ Ap,
                       int Cin, int Cout, int xflip)
{
    const int MG = Cout >> 6;
    const int nsteps = Cin >> 2;             // (Cin*8)/32
    long total = 8L * MG * nsteps * 2048;
    long idx = (long)blockIdx.x * blockDim.x + threadIdx.x;
    if (idx >= total) return;
    int kk = (int)(idx & 7); long r = idx >> 3;
    int l  = (int)(r & 63);  r >>= 6;
    int cb = (int)(r & 3);   r >>= 2;
    int s  = (int)(r % nsteps); r /= nsteps;
    int mg = (int)(r % MG);
    int p  = (int)(r / MG);

    int n16 = l & 15, quad = l >> 4;
    int korig = s * 32 + quad * 8 + kk;
    int co = mg * 64 + cb * 16 + n16;
    int ci = korig >> 3, a = korig & 7;
    int az = (a >> 2) & 1, ay = (a >> 1) & 1, ax = a & 1;
    int pz = p >> 2, py = (p >> 1) & 1, px = p & 1;
    int axw = xflip ? (1 - ax) : ax;
    int kd = (1 - pz) + 2 * az, kh = (1 - py) + 2 * ay, kw = (1 - px) + 2 * axw;
    float v = w[((long)ci * Cout + co) * 64 + kd * 16 + kh * 4 + kw];
    Ap[idx] = (short)f32_to_bf16(v);
}

// Old cube-N layout (kept for dec1, DIN=8): round-0 body.
template <int CIN, int COUT, int DIN, int OPAD, typename OutT>
__global__ __launch_bounds__(256)
void convt_mfma(const unsigned short* __restrict__ Xp, const short* __restrict__ Ap,
                const float* __restrict__ bias, OutT* __restrict__ Y)
{
    constexpr int PD = DIN + 2;
    constexpr int PD3 = PD * PD * PD;
    constexpr int T = DIN >> 2;
    constexpr int NT = T * T * T;
    constexpr int SLAB = NT / 8;
    constexpr int OPD = 2 * DIN + 2 * OPAD;
    constexpr int K = CIN * 8;
    constexpr int MG = COUT >> 6;
    constexpr int nsteps = K >> 5;

    int bx = blockIdx.x;
    const int xcd = bx & 7;
    int local = bx >> 3;
    const int px = local & 1; local >>= 1;
    const int mg = local % MG; local /= MG;
    const int ntin = local % SLAB;
    const int pzy = local / SLAB;            // 0..3
    const int pz = pzy >> 1, py = pzy & 1;
    const int p = pz * 4 + py * 2 + px;
    const int nt = xcd * SLAB + ntin;

    const int lane = threadIdx.x & 63, wave = threadIdx.x >> 6;
    const int n16 = lane & 15, quad = lane >> 4;

    const int tx = nt % T, ty = (nt / T) % T, tz = nt / (T * T);
    const int mz = tz * 4 + wave, my = ty * 4 + (n16 >> 2), mx = tx * 4 + (n16 & 3);
    const int sp = ((mz + pz) * PD + (my + py)) * PD + (mx + px);

    const unsigned short* xq = Xp + (long)quad * PD3 + sp;

    const int cobase = mg * 64;
    const short* ap0 = Ap + ((long)p * COUT + cobase + n16) * K + quad * 8;

    f32x4 acc[4];
    #pragma unroll
    for (int cb = 0; cb < 4; ++cb) {
        const float* bp = bias + cobase + cb * 16 + quad * 4;
        acc[cb][0] = bp[0]; acc[cb][1] = bp[1]; acc[cb][2] = bp[2]; acc[cb][3] = bp[3];
    }

    #pragma unroll 4
    for (int s = 0; s < nsteps; ++s) {
        const unsigned short* xs = xq + (long)s * 4 * PD3;
        bf16x8 bf;
        bf[0] = (short)xs[(PD + 1) * PD + 1];
        bf[1] = (short)xs[(PD + 1) * PD];
        bf[2] = (short)xs[PD * PD + 1];
        bf[3] = (short)xs[PD * PD];
        bf[4] = (short)xs[PD + 1];
        bf[5] = (short)xs[PD];
        bf[6] = (short)xs[1];
        bf[7] = (short)xs[0];
        #pragma unroll
        for (int cb = 0; cb < 4; ++cb) {
            bf16x8 af = *(const bf16x8*)(ap0 + (long)cb * 16 * K + s * 32);
            acc[cb] = __builtin_amdgcn_mfma_f32_16x16x32_bf16(af, bf, acc[cb], 0, 0, 0);
        }
    }

    const int opz = 2 * mz + pz + OPAD, opy = 2 * my + py + OPAD, opx = 2 * mx + px + OPAD;
    const long spo = ((long)opz * OPD + opy) * OPD + opx;
    #pragma unroll
    for (int cb = 0; cb < 4; ++cb) {
        #pragma unroll
        for (int r = 0; r < 4; ++r) {
            int co = cobase + cb * 16 + quad * 4 + r;
            float v = fmaxf(acc[cb][r], 0.0f);
            store_act(Y + (long)co * OPD * OPD * OPD + spo, v);
        }
    }
}

// Dword-pair B-gather (dec2/dec3), R20: A staged through LDS (unchanged).
template <int CIN, int COUT, int DIN, int OPAD, int MXP, int MYP, typename OutT>
__global__ __launch_bounds__(256)
void convt_mfma_v2(const unsigned short* __restrict__ Xp, const short* __restrict__ Ap,
                   const float* __restrict__ bias, OutT* __restrict__ Y)
{
    constexpr int PD = DIN + 2;
    constexpr int PD3 = PD * PD * PD;
    constexpr int OPD = 2 * DIN + 2 * OPAD;
    constexpr int K = CIN * 8;
    constexpr int MG = COUT >> 6;
    constexpr int nsteps = K >> 5;
    static_assert(nsteps >= 2, "need at least 2 K-steps");
    constexpr int MXT = DIN / (16 * MXP);
    constexpr int MYT = DIN / (4 * MYP);
    constexpr int MZS = DIN / 8;             // mz per XCD slab
    constexpr int TPE = MXP * MYP;           // tiles per wave (one of MXP/MYP is 1)

    int bx = blockIdx.x;
    const int xcd = bx & 7;
    int local = bx >> 3;
    const int px = local & 1; local >>= 1;
    const int py = local & 1; local >>= 1;
    const int mg = local % MG; local /= MG;
    const int mxt = local % MXT; local /= MXT;
    const int myt = local % MYT; local /= MYT;
    const int pz = local & 1; local >>= 1;
    const int mzin = local;                  // 0..MZS-1
    const int mz = xcd * MZS + mzin;
    const int p = pz * 4 + py * 2 + px;

    const int lane = threadIdx.x & 63, wave = threadIdx.x >> 6;
    const int n16 = lane & 15, quad = lane >> 4;

    const int mx0 = mxt * (16 * MXP) + n16;
    const int my0 = myt * (4 * MYP) + wave * MYP;
    const int baseX = mx0 & ~1;
    const int sh = 16 * ((n16 & 1) + px);    // 0, 16, or 32
    const long sp = ((long)(mz + pz) * PD + (my0 + py)) * PD + baseX;

    const unsigned short* xq = Xp + (long)quad * PD3 + sp;

    // fragment-major weight tiles: 2048 shorts (4KB) per (p,mg,s)
    const short* ApT = Ap + (((long)p * MG + mg) * nsteps) * 2048;

    __shared__ short Abuf[2][2048];          // 8KB double buffer

    f32x4 acc[TPE][4];
    #pragma unroll
    for (int t = 0; t < TPE; ++t)
        #pragma unroll
        for (int cb = 0; cb < 4; ++cb) {
            const float* bp = bias + (mg * 64) + cb * 16 + quad * 4;
            acc[t][cb][0] = bp[0]; acc[t][cb][1] = bp[1];
            acc[t][cb][2] = bp[2]; acc[t][cb][3] = bp[3];
        }

    constexpr int rowoff[4] = { (PD + 1) * PD, PD * PD, PD, 0 };
    union Frag { unsigned u[4]; bf16x8 b; };

    const int chunkoff = wave * 512 + lane * 8;   // this thread's 16B of the 4KB tile

    // prologue: stage step 0
    {
        bf16x8 a0 = *(const bf16x8*)(ApT + chunkoff);
        *(bf16x8*)(&Abuf[0][chunkoff]) = a0;
    }
    __syncthreads();

    #pragma unroll 1
    for (int s = 0; s < nsteps; ++s) {
        const int cur = s & 1;
        bf16x8 anext;
        const bool more = (s + 1 < nsteps);
        if (more)
            anext = *(const bf16x8*)(ApT + (long)(s + 1) * 2048 + chunkoff);

        // X loads (plain C, raw staging)
        const unsigned short* xs = xq + (long)s * 4 * PD3;
        unsigned long long xr[TPE][4];
        #pragma unroll
        for (int t = 0; t < TPE; ++t) {
            const int toff = (MXP > 1) ? t * 16 : t * PD;
            #pragma unroll
            for (int j = 0; j < 4; ++j) {
                union { u16x4u v; unsigned long long u; } ld;
                ld.v = *(const u16x4u*)(xs + toff + rowoff[j]);
                xr[t][j] = ld.u;
            }
        }

        // A fragments from LDS (l = quad*16 + n16 == lane)
        bf16x8 af[4];
        #pragma unroll
        for (int cb = 0; cb < 4; ++cb)
            af[cb] = *(const bf16x8*)(&Abuf[cur][cb * 512 + lane * 8]);

        #pragma unroll
        for (int t = 0; t < TPE; ++t) {
            Frag fr;
            #pragma unroll
            for (int j = 0; j < 4; ++j)
                fr.u[j] = (unsigned)(xr[t][j] >> sh);
            #pragma unroll
            for (int cb = 0; cb < 4; ++cb)
                acc[t][cb] = __builtin_amdgcn_mfma_f32_16x16x32_bf16(af[cb], fr.b,
                                                                     acc[t][cb], 0, 0, 0);
        }

        if (more)
            *(bf16x8*)(&Abuf[cur ^ 1][chunkoff]) = anext;
        __syncthreads();
    }

    const int opz = 2 * mz + pz + OPAD;
    #pragma unroll
    for (int t = 0; t < TPE; ++t) {
        const int opx = 2 * (mx0 + ((MXP > 1) ? t * 16 : 0)) + px + OPAD;
        const int opy = 2 * (my0 + ((MYP > 1) ? t : 0)) + py + OPAD;
        const long spo = ((long)opz * OPD + opy) * OPD + opx;
        #pragma unroll
        for (int cb = 0; cb < 4; ++cb) {
            #pragma unroll
            for (int r = 0; r < 4; ++r) {
                int co = (mg * 64) + cb * 16 + quad * 4 + r;
                float v = fmaxf(acc[t][cb][r], 0.0f);
                store_act(Y + (long)co * OPD * OPD * OPD + spo, v);
            }
        }
    }
}

// ---------------- dec4 as MFMA GEMM, R25: conflict-free LDS ---------------
// Fragment-major: Aw[(s*64 + lane)*8 + kk] (unchanged from R23).
__global__ __launch_bounds__(256)
void prep_dec4A_frag(const float* __restrict__ w, short* __restrict__ Aw)
{
    int idx = blockIdx.x * 256 + (int)threadIdx.x;    // 0..65535
    int kk = idx & 7;
    int l  = (idx >> 3) & 63;
    int s  = idx >> 9;                                // 0..127
    int n16 = l & 15, quad = l >> 4;
    int k = s * 32 + quad * 8 + kk;
    float v = (n16 < 3) ? w[n16 * 4096 + k] : 0.0f;
    Aw[idx] = (short)f32_to_bf16(v);
}

// R25 layout: Xs row stride 72 words (72 = 8 mod 32 -> the 4 quad read
// windows start at banks {0,16,24,8}: exact 2/bank, free). Staging is
// STRIDED: thread t owns words g = t + 224*j of the 896-word (14x64) step
// tile (4 scalar loads + 4 ds_write_b32): every wave-pass writes 64
// consecutive words = 2/bank free; global loads stay 4-lines/wave-pass.
// Same values, same truncation-pack, same MFMA order => bit-identical.
__global__ __launch_bounds__(256)
void conv_dec4_mfma(const float* __restrict__ d3, const short* __restrict__ Aw,
                    const float* __restrict__ bias, float* __restrict__ y)
{
    constexpr int D = 64, Dout = 61;
    constexpr int RS = 72;                 // row stride (words)
    int bx = blockIdx.x;
    const int slab = bx & 7;
    const int i = bx >> 3;                 // 0..127
    const int od = slab * 8 + (i >> 4);
    const int oh0 = (i & 15) * 4;          // covers oh0..oh0+3 (guard < 61)
    if (od >= Dout) return;                // uniform per block -> barriers safe
    const int tid = (int)threadIdx.x;
    const int lane = tid & 63, wave = tid >> 6;
    const int n16 = lane & 15, quad = lane >> 4;
    const int ow = wave * 16 + n16;

    // [dbuf][row 0..13][x 0..71]; words 64..71 per row uninitialized (only
    // consumed by discarded ow>=61 columns; reads reach word ow+3 <= 66)
    __shared__ float Xs[2][14][RS];

    f32x4 acc[4];
    #pragma unroll
    for (int j = 0; j < 4; ++j)
        #pragma unroll
        for (int r = 0; r < 4; ++r) {
            int co = quad * 4 + r;
            acc[j][r] = (co < 3) ? bias[co] : 0.0f;
        }

    const int kd0 = quad >> 1;
    const int kh0 = (quad & 1) * 2;

    // strided staging: thread t (t<224) owns words g = t + 224*j, j=0..3;
    // word g -> (row = g/64, x = g%64); row -> (z' = row/7, y' = row%7)
    const bool sact = (tid < 224);
    const float* gsrc[4];
    float* ldst[4][2];
    #pragma unroll
    for (int j = 0; j < 4; ++j) {
        const int g = tid + 224 * j;
        const int row = g >> 6, xx = g & 63;
        const int szi = row / 7, syi = row % 7;
        gsrc[j] = d3 + (((long)(od + szi) * D) + min(oh0 + syi, D - 1)) * D + xx;
        ldst[j][0] = &Xs[0][row][xx];
        ldst[j][1] = &Xs[1][row][xx];
    }
    auto choff = [&](int s) { return (long)((s >> 1) * D + (s & 1) * 2) * D * D; };

    // prologue: stage step 0
    if (sact) {
        const long c0 = choff(0);
        #pragma unroll
        for (int j = 0; j < 4; ++j)
            *ldst[j][0] = gsrc[j][c0];
    }
    __syncthreads();

    #pragma unroll 1
    for (int s = 0; s < 128; ++s) {
        const int cur = s & 1;
        const bool more = (s + 1 < 128);
        float nv[4];
        if (more && sact) {
            const long cn = choff(s + 1);
            #pragma unroll
            for (int j = 0; j < 4; ++j)
                nv[j] = gsrc[j][cn];
        }

        bf16x8 af = *(const bf16x8*)(Aw + ((long)s * 64 + lane) * 8);

        unsigned p0[5], p1[5];
        #pragma unroll
        for (int r = 0; r < 5; ++r) {
            f32x4u v = *(const f32x4u*)(&Xs[cur][kd0 * 7 + kh0 + r][ow]);
            p0[r] = (__float_as_uint(v[0]) >> 16) | (__float_as_uint(v[1]) & 0xffff0000u);
            p1[r] = (__float_as_uint(v[2]) >> 16) | (__float_as_uint(v[3]) & 0xffff0000u);
        }
        #pragma unroll
        for (int j = 0; j < 4; ++j) {
            union { unsigned u[4]; bf16x8 b; } fr;
            fr.u[0] = p0[j];     fr.u[1] = p1[j];
            fr.u[2] = p0[j + 1]; fr.u[3] = p1[j + 1];
            acc[j] = __builtin_amdgcn_mfma_f32_16x16x32_bf16(af, fr.b, acc[j], 0, 0, 0);
        }

        if (more && sact) {
            #pragma unroll
            for (int j = 0; j < 4; ++j)
                *ldst[j][cur ^ 1] = nv[j];
        }
        __syncthreads();
    }

    if (ow < Dout && quad == 0) {
        #pragma unroll
        for (int j = 0; j < 4; ++j) {
            const int oh = oh0 + j;
            if (oh >= Dout) continue;
            #pragma unroll
            for (int r = 0; r < 3; ++r)
                y[((long)(r * Dout + od) * Dout + oh) * Dout + ow] = tanhf(acc[j][r]);
        }
    }
}

extern "C" void kernel_launch(void* const* d_in, const int* in_sizes, int n_in,
                              void* d_out, int out_size, void* d_ws, size_t ws_size,
                              hipStream_t stream)
{
    const float* x        = (const float*)d_in[0];
    const float* enc_w1   = (const float*)d_in[1];
    const float* enc_b1   = (const float*)d_in[2];
    const float* enc_w2   = (const float*)d_in[3];
    const float* enc_b2   = (const float*)d_in[4];
    const float* enc_w3   = (const float*)d_in[5];
    const float* enc_b3   = (const float*)d_in[6];
    const float* enc_w4   = (const float*)d_in[7];
    const float* enc_b4   = (const float*)d_in[8];
    const float* codebook = (const float*)d_in[9];
    const float* dec_w1   = (const float*)d_in[10];
    const float* dec_b1   = (const float*)d_in[11];
    const float* dec_w2   = (const float*)d_in[12];
    const float* dec_b2   = (const float*)d_in[13];
    const float* dec_w3   = (const float*)d_in[14];
    const float* dec_b3   = (const float*)d_in[15];
    const float* dec_w4   = (const float*)d_in[16];
    const float* dec_b4   = (const float*)d_in[17];

    float* out = (float*)d_out;
    float* idx_out = out + 2L * 3 * 61 * 61 * 61;

    // ---- workspace (byte offsets) ----
    char* wsb = (char*)d_ws;
    float*          cn   = (float*)wsb;                        //      4,096
    unsigned short* qp   = (unsigned short*)(wsb + 4096);      //  1,024,000
    short*          Ap1  = (short*)(wsb + 1028096);            //  8,388,608
    short*          Ap2  = (short*)(wsb + 9416704);            //  4,194,304
    short*          Ap3  = (short*)(wsb + 13611008);           //  1,048,576
    short*          Aw4  = (short*)(wsb + 14659584);           //    131,072
    short*          W1hi = (short*)(wsb + 14790656);           //     24,576
    short*          W1lo = (short*)(wsb + 14815232);           //     24,576
    short*          W2hi = (short*)(wsb + 14839808);           //  1,048,576
    short*          W2lo = (short*)(wsb + 15888384);           //  1,048,576
    short*          W3hi = (short*)(wsb + 16936960);           //  4,194,304
    short*          W3lo = (short*)(wsb + 21131264);           //  4,194,304
    char* arena = wsb + 25325568;
    // encoder phase:
    unsigned short* xphi = (unsigned short*)arena;                    // (2,3,66,66,68)
    unsigned short* xplo = (unsigned short*)(arena + 3554496);
    unsigned short* h1hi = (unsigned short*)(arena + 7108992);        // (2,64,34,34,36)
    unsigned short* h1lo = (unsigned short*)(arena + 17762688);
    unsigned short* h2hi = (unsigned short*)(arena + 28416384);       // (2,128,18,18,20)
    unsigned short* h2lo = (unsigned short*)(arena + 31734144);
    float*          pp3  = (float*)(arena + 35051904);                // 4x(2,256,8^3)
    float*          h3   = (float*)(arena + 39246208);                // (2,256,512)
    float*          lat  = (float*)(arena + 40294784);                // (2,256,512)
    // decoder phase (after VQ; overlaps encoder buffers):
    unsigned short* d1 = (unsigned short*)arena;                      // (256,18^3) bf16
    unsigned short* d2 = (unsigned short*)(arena + 2985984);          // (128,34^3) bf16
    float*          d3 = (float*)(arena + 13047808);                  // (64,64^3) fp32
    // arena peak 80.2 MB -> ws used 105.5 MB; cbT appended below:
    float*          cbT = (float*)(wsb + 105482240);                  // 1,048,576
    // total 106.5 MB (< 112.2 MB proven in R0)

    dim3 blk(256);
    auto nblk = [](long n) { return dim3((unsigned)((n + 255) / 256)); };

    // ---- weight prep ----
    prep_convt_w<<<nblk(8L * 256 * 2048), blk, 0, stream>>>(dec_w1, Ap1, 256, 256, 0);
    prep_convt_w_frag<<<nblk(8L * 128 * 2048), blk, 0, stream>>>(dec_w2, Ap2, 256, 128, 1);
    prep_convt_w_frag<<<nblk(8L * 64 * 1024), blk, 0, stream>>>(dec_w3, Ap3, 128, 64, 1);
    prep_dec4A_frag<<<dim3(256), blk, 0, stream>>>(dec_w4, Aw4);
    prep_split_w<<<nblk(12288), blk, 0, stream>>>(enc_w1, W1hi, W1lo, 12288);
    prep_split_w_frag<<<nblk(524288), blk, 0, stream>>>(enc_w2, W2hi, W2lo, 64, 128);
    prep_split_w_frag<<<nblk(2097152), blk, 0, stream>>>(enc_w3, W3hi, W3lo, 128, 256);
    transpose_cb<<<dim3(1024), blk, 0, stream>>>(codebook, cbT);

    // ---- encoder (MFMA, bf16-pair) ----
    pad_input_split<<<nblk(6L * 66 * 66 * 68), blk, 0, stream>>>(x, xphi, xplo);
    zero_halo_ps<<<nblk(128L * 34 * 34 * 36), blk, 0, stream>>>(h1hi, 128, 34, 36);
    zero_halo_ps<<<nblk(128L * 34 * 34 * 36), blk, 0, stream>>>(h1lo, 128, 34, 36);
    conv_s2_mfma<3, 64, 32, 66, 68, 4, 2, 0, 1, 1><<<dim3(1024), blk, 0, stream>>>(
        xphi, xplo, W1hi, W1lo, enc_b1, h1hi, h1lo, nullptr, 34, 36, 1, 0);
    zero_halo_ps<<<nblk(256L * 18 * 18 * 20), blk, 0, stream>>>(h2hi, 256, 18, 20);
    zero_halo_ps<<<nblk(256L * 18 * 18 * 20), blk, 0, stream>>>(h2lo, 256, 18, 20);
    conv_s2_mfma_lds<64, 128, 16, 34, 36, 2, 1, 0, 1, 1><<<dim3(512), blk, 0, stream>>>(
        h1hi, h1lo, W2hi, W2lo, enc_b2, h2hi, h2lo, nullptr, 18, 20, 1, 0);
    conv_s2_mfma_lds<128, 256, 8, 18, 20, 4, 1, 1, 4, 0><<<dim3(256), blk, 0, stream>>>(
        h2hi, h2lo, W3hi, W3lo, enc_b3, nullptr, nullptr, pp3, 8, 8, 0, 262144);
    combine4_relu<<<nblk(262144), blk, 0, stream>>>(pp3, h3, 262144, 262144);
    conv1x1_b<<<dim3(512), dim3(128), 0, stream>>>(h3, enc_w4, enc_b4, lat);

    // ---- VQ (fp32 exact) ----
    codenorm_kernel<<<dim3(1024), dim3(64), 0, stream>>>(codebook, cn);
    zero_halo_t<unsigned short><<<nblk(512L * 10 * 10 * 10), blk, 0, stream>>>(qp, 512, 10);
    vq_kernel4<<<dim3(256), blk, 0, stream>>>(lat, codebook, cbT, cn, qp, idx_out);

    // ---- decoder halos ----
    zero_halo_t<unsigned short><<<nblk(256L * 18 * 18 * 18), blk, 0, stream>>>(d1, 256, 18);
    zero_halo_t<unsigned short><<<nblk(128L * 34 * 34 * 34), blk, 0, stream>>>(d2, 128, 34);

    // ---- decoder (MFMA) per batch ----
    for (int b = 0; b < 2; ++b) {
        const unsigned short* qb = qp + (long)b * 256 * 1000;
        float* outb = out + (long)b * 3 * 226981;
        // dec1 (DIN=8, old layout): grid = 8*2*4*1*4 = 256
        convt_mfma<256, 256, 8, 1, unsigned short><<<dim3(256), blk, 0, stream>>>(
            qb, Ap1, dec_b1, d1);
        // dec2 (v2, MXP=1 MYP=2): grid = 8 * (2*2*2*1*2*2*2) = 512
        convt_mfma_v2<256, 128, 16, 1, 1, 2, unsigned short><<<dim3(512), blk, 0, stream>>>(
            d1, Ap2, dec_b2, d2);
        // dec3 (v2, MXP=2 MYP=1): grid = 8 * (2*2*1*1*8*2*4) = 2048
        convt_mfma_v2<128, 64, 32, 0, 2, 1, float><<<dim3(2048), blk, 0, stream>>>(
            d2, Ap3, dec_b3, d3);
        conv_dec4_mfma<<<dim3(8 * 8 * 16), blk, 0, stream>>>(d3, Aw4, dec_b4, outb);
    }
}

// Round 10
// 942.445 us; speedup vs baseline: 1.5475x; 1.0135x over previous
//
#include <hip/hip_runtime.h>
#include <cfloat>
#include <cmath>

// ---------------------------------------------------------------------------
// Round 27: drop the per-step barrier in enc2/enc3 -- direct fragment loads.
// R26 post-mortem: dec4 bank-conflict fix confirmed (986 -> 955us). Top-5:
// conv_s2_mfma_lds (enc2) 100us, MfmaUtil 10%, occupancy 21.5% (grid-capped
// 2 blocks/CU), 0 bank conflicts. 1875 cy/step vs ~240 cy MFMA: the cost is
// the per-step __syncthreads (lowered to s_waitcnt vmcnt(0) + s_barrier --
// all waves drain and convoy 128 times).
// Realization: in enc2/enc3 each wave consumes DISJOINT m-fragments
// (MWAVES=4, wave mi reads only its own m) -- the LDS staging shares
// nothing. R21's win was the fragment-major contiguity, not LDS. So load
// fragments directly: per (s,m) a coalesced 1KB dwordx4 block per wave.
// Same global traffic (256 lines/block-step), zero LDS, zero barriers;
// 8 waves/CU of TLP hide L2 latency freely. Same fragment values, same
// MFMA order => bit-identical. prep kernels + everything else unchanged.
// ---------------------------------------------------------------------------

using f32x4  = __attribute__((ext_vector_type(4))) float;
using bf16x8 = __attribute__((ext_vector_type(8))) short;
typedef float f32x4u __attribute__((ext_vector_type(4), aligned(4)));
typedef unsigned short u16x4u __attribute__((ext_vector_type(4), aligned(4)));

__device__ __forceinline__ unsigned short f32_to_bf16(float f) {
    unsigned int u = __float_as_uint(f);
    u += 0x7fffu + ((u >> 16) & 1u);          // round-to-nearest-even
    return (unsigned short)(u >> 16);
}
__device__ __forceinline__ void split_bf16(float v, unsigned short& h, unsigned short& l) {
    h = f32_to_bf16(v);
    float hf = __uint_as_float((unsigned)h << 16);
    l = f32_to_bf16(v - hf);
}
__device__ __forceinline__ void store_act(float* p, float v) { *p = v; }
__device__ __forceinline__ void store_act(unsigned short* p, float v) { *p = f32_to_bf16(v); }

template <typename V>
__device__ __forceinline__ bf16x8 pack_b(V r0, V r1) {
    bf16x8 b;
    b[0] = (short)r0[0]; b[1] = (short)r0[1]; b[2] = (short)r0[2]; b[3] = (short)r0[3];
    b[4] = (short)r1[0]; b[5] = (short)r1[1]; b[6] = (short)r1[2]; b[7] = (short)r1[3];
    return b;
}

// ---------------- prep: weight hi/lo split (linear; enc1) ----------------
__global__ __launch_bounds__(256)
void prep_split_w(const float* __restrict__ w, short* __restrict__ whi,
                  short* __restrict__ wlo, long total)
{
    long idx = (long)blockIdx.x * blockDim.x + threadIdx.x;
    if (idx >= total) return;
    unsigned short h, l;
    split_bf16(w[idx], h, l);
    whi[idx] = (short)h; wlo[idx] = (short)l;
}

// Fragment-major hi/lo split for enc2/enc3:
//   whi[((s*MT + m)*64 + l)*8 + kk] = hi(w[co*K + korig])
// with MT = COUT/16, co = m*16 + (l&15), korig = s*32 + (l>>4)*8 + kk.
// Each (s,m) fragment block (512 shorts = 1KB) is contiguous.
__global__ __launch_bounds__(256)
void prep_split_w_frag(const float* __restrict__ w, short* __restrict__ whi,
                       short* __restrict__ wlo, int CIN, int COUT)
{
    const int K = CIN * 64;
    const int MT = COUT >> 4;
    long total = (long)COUT * K;
    long idx = (long)blockIdx.x * blockDim.x + threadIdx.x;
    if (idx >= total) return;
    int kk = (int)(idx & 7); long r = idx >> 3;
    int l  = (int)(r & 63);  r >>= 6;
    int m  = (int)(r % MT);
    int s  = (int)(r / MT);
    int n16 = l & 15, quad = l >> 4;
    int co = m * 16 + n16;
    int korig = s * 32 + quad * 8 + kk;
    unsigned short h, lo16;
    split_bf16(w[(long)co * K + korig], h, lo16);
    whi[idx] = (short)h; wlo[idx] = (short)lo16;
}

// ---------------- pad input -> hi/lo bf16 pitched planes --------------------
__global__ __launch_bounds__(256)
void pad_input_split(const float* __restrict__ x, unsigned short* __restrict__ xhi,
                     unsigned short* __restrict__ xlo)
{
    const int D = 64, PD = 66, PRX = 68, BC = 6;
    long total = (long)BC * PD * PD * PRX;
    long idx = (long)blockIdx.x * blockDim.x + threadIdx.x;
    if (idx >= total) return;
    int px = (int)(idx % PRX); long t = idx / PRX;
    int py = (int)(t % PD); t /= PD;
    int pz = (int)(t % PD); int c = (int)(t / PD);
    int ix = px - 1, iy = py - 1, iz = pz - 1;
    float v = 0.0f;
    if ((unsigned)ix < (unsigned)D && (unsigned)iy < (unsigned)D && (unsigned)iz < (unsigned)D)
        v = x[(((long)c * D + iz) * D + iy) * D + ix];
    unsigned short h, l;
    split_bf16(v, h, l);
    xhi[idx] = h; xlo[idx] = l;
}

__global__ __launch_bounds__(256)
void zero_halo_ps(unsigned short* __restrict__ p, int C, int PD, int PRX)
{
    long total = (long)C * PD * PD * PRX;
    long idx = (long)blockIdx.x * blockDim.x + threadIdx.x;
    if (idx >= total) return;
    int px = (int)(idx % PRX); long t = idx / PRX;
    int py = (int)(t % PD); t /= PD;
    int pz = (int)(t % PD);
    if (px == 0 || px >= PD - 1 || py == 0 || py == PD - 1 || pz == 0 || pz == PD - 1)
        p[idx] = 0;
}

template <typename T>
__global__ __launch_bounds__(256) void zero_halo_t(T* __restrict__ p, int C, int PD)
{
    long total = (long)C * PD * PD * PD;
    long idx = (long)blockIdx.x * blockDim.x + threadIdx.x;
    if (idx >= total) return;
    int px = (int)(idx % PD); long t = idx / PD;
    int py = (int)(t % PD); t /= PD;
    int pz = (int)(t % PD);
    if (px == 0 || px == PD - 1 || py == 0 || py == PD - 1 || pz == 0 || pz == PD - 1)
        p[idx] = (T)0;
}

// ---------------------------------------------------------------------------
// Conv3d k4 s2 p1 as MFMA implicit GEMM, bf16 hi/lo pair inputs (enc1 only)
// ---------------------------------------------------------------------------
template <int CIN, int COUT, int DOUT, int PD, int PRX, int MTW, int OWT,
          int OWHALF, int KSPLIT, int OUTSPLIT>
__global__ __launch_bounds__(256)
void conv_s2_mfma(const unsigned short* __restrict__ xhi,
                  const unsigned short* __restrict__ xlo,
                  const short* __restrict__ Whi, const short* __restrict__ Wlo,
                  const float* __restrict__ bias,
                  unsigned short* __restrict__ yhi, unsigned short* __restrict__ ylo,
                  float* __restrict__ yf,
                  int OPD, int OPRX, int po, long sstride)
{
    constexpr int K = CIN * 64;
    constexpr int MWAVES = COUT / (16 * MTW);
    constexpr int RPB = 4 / MWAVES;
    constexpr int KN = (CIN * 2) / KSPLIT;

    int bx = blockIdx.x;
    const int ks = (KSPLIT > 1) ? (bx % KSPLIT) : 0;
    const int rowblk = (KSPLIT > 1) ? (bx / KSPLIT) : bx;
    const int lane = (int)threadIdx.x & 63, w = (int)threadIdx.x >> 6;
    const int mi = (MWAVES == 4) ? w : 0;
    const int ri = (MWAVES == 4) ? 0 : w;
    const int rowid = rowblk * RPB + ri;
    const int n16 = lane & 15, quad = lane >> 4;

    int b, od, oh, ow;
    if (OWHALF) {
        constexpr int NOH = DOUT / 2;
        const int ohb = rowid % NOH; int t = rowid / NOH;
        od = t % DOUT; b = t / DOUT;
        oh = ohb * 2 + (n16 >> 3);
        ow = n16 & 7;
    } else {
        const int owt = rowid % OWT; int t = rowid / OWT;
        oh = t % DOUT; t /= DOUT;
        od = t % DOUT; b = t / DOUT;
        ow = owt * 16 + n16;
    }

    const int co0 = mi * (MTW * 16);

    f32x4 acc[MTW];
    #pragma unroll
    for (int mt = 0; mt < MTW; ++mt)
        #pragma unroll
        for (int r = 0; r < 4; ++r) {
            int co = co0 + mt * 16 + quad * 4 + r;
            acc[mt][r] = (ks == 0) ? bias[co] : 0.0f;
        }

    const int sg0 = ks * KN;
    const long chs = (long)PD * PD * PRX;
    long off = ((long)(b * CIN + (sg0 >> 1)) * PD + (2 * od + (quad >> 1))) * PD * PRX
             + (long)(2 * oh + (quad & 1) * 2) * PRX + 2 * ow;
    const unsigned short* phi = xhi + off;
    const unsigned short* plo = xlo + off;
    const long incA = 2L * PD * PRX;
    const long incB = chs - 2L * PD * PRX;

    const short* a0h = Whi + (long)(co0 + n16) * K + sg0 * 32 + quad * 8;
    const short* a0l = Wlo + (long)(co0 + n16) * K + sg0 * 32 + quad * 8;

    #pragma unroll 2
    for (int s = 0; s < KN; ++s) {
        u16x4u h0 = *(const u16x4u*)phi;
        u16x4u h1 = *(const u16x4u*)(phi + PRX);
        u16x4u l0 = *(const u16x4u*)plo;
        u16x4u l1 = *(const u16x4u*)(plo + PRX);
        bf16x8 bhi = pack_b(h0, h1);
        bf16x8 blo = pack_b(l0, l1);
        #pragma unroll
        for (int mt = 0; mt < MTW; ++mt) {
            bf16x8 ah = *(const bf16x8*)(a0h + (long)mt * 16 * K + s * 32);
            bf16x8 al = *(const bf16x8*)(a0l + (long)mt * 16 * K + s * 32);
            acc[mt] = __builtin_amdgcn_mfma_f32_16x16x32_bf16(ah, bhi, acc[mt], 0, 0, 0);
            acc[mt] = __builtin_amdgcn_mfma_f32_16x16x32_bf16(ah, blo, acc[mt], 0, 0, 0);
            acc[mt] = __builtin_amdgcn_mfma_f32_16x16x32_bf16(al, bhi, acc[mt], 0, 0, 0);
        }
        long inc = (s & 1) ? incB : incA;
        phi += inc; plo += inc;
    }

    if (OUTSPLIT) {
        #pragma unroll
        for (int mt = 0; mt < MTW; ++mt)
            #pragma unroll
            for (int r = 0; r < 4; ++r) {
                int co = co0 + mt * 16 + quad * 4 + r;
                float v = fmaxf(acc[mt][r], 0.0f);
                unsigned short h, l;
                split_bf16(v, h, l);
                long o = (((long)(b * COUT + co) * OPD + od + po) * OPD + oh + po) * OPRX
                       + ow + po;
                yhi[o] = h; ylo[o] = l;
            }
    } else {
        #pragma unroll
        for (int mt = 0; mt < MTW; ++mt)
            #pragma unroll
            for (int r = 0; r < 4; ++r) {
                int co = co0 + mt * 16 + quad * 4 + r;
                long o = (long)ks * sstride
                       + (((long)(b * COUT + co) * OPD + od) * OPD + oh) * OPRX + ow;
                yf[o] = acc[mt][r];
            }
    }
}

// Fragment-direct variant (enc2/enc3): fragment-major Whi/Wlo, each wave
// loads its OWN disjoint (s,m) fragment blocks (coalesced 1KB dwordx4) --
// no LDS, no barriers. Same fragment values + MFMA order as the LDS path
// => bit-identical.
template <int CIN, int COUT, int DOUT, int PD, int PRX, int MTW, int OWT,
          int OWHALF, int KSPLIT, int OUTSPLIT>
__global__ __launch_bounds__(256)
void conv_s2_mfma_fd(const unsigned short* __restrict__ xhi,
                     const unsigned short* __restrict__ xlo,
                     const short* __restrict__ Whi, const short* __restrict__ Wlo,
                     const float* __restrict__ bias,
                     unsigned short* __restrict__ yhi, unsigned short* __restrict__ ylo,
                     float* __restrict__ yf,
                     int OPD, int OPRX, int po, long sstride)
{
    constexpr int MWAVES = COUT / (16 * MTW);
    constexpr int RPB = 4 / MWAVES;
    constexpr int KN = (CIN * 2) / KSPLIT;
    constexpr int MT = COUT >> 4;            // fragment-major m count
    constexpr int SSTEP = MT * 512;          // shorts per s-step in frag layout

    int bx = blockIdx.x;
    const int ks = (KSPLIT > 1) ? (bx % KSPLIT) : 0;
    const int rowblk = (KSPLIT > 1) ? (bx / KSPLIT) : bx;
    const int lane = (int)threadIdx.x & 63, w = (int)threadIdx.x >> 6;
    const int mi = (MWAVES == 4) ? w : 0;
    const int ri = (MWAVES == 4) ? 0 : w;
    const int rowid = rowblk * RPB + ri;
    const int n16 = lane & 15, quad = lane >> 4;

    int b, od, oh, ow;
    if (OWHALF) {
        constexpr int NOH = DOUT / 2;
        const int ohb = rowid % NOH; int t = rowid / NOH;
        od = t % DOUT; b = t / DOUT;
        oh = ohb * 2 + (n16 >> 3);
        ow = n16 & 7;
    } else {
        const int owt = rowid % OWT; int t = rowid / OWT;
        oh = t % DOUT; t /= DOUT;
        od = t % DOUT; b = t / DOUT;
        ow = owt * 16 + n16;
    }

    const int co0 = mi * (MTW * 16);

    f32x4 acc[MTW];
    #pragma unroll
    for (int mt = 0; mt < MTW; ++mt)
        #pragma unroll
        for (int r = 0; r < 4; ++r) {
            int co = co0 + mt * 16 + quad * 4 + r;
            acc[mt][r] = (ks == 0) ? bias[co] : 0.0f;
        }

    const int sg0 = ks * KN;
    const long chs = (long)PD * PD * PRX;
    long off = ((long)(b * CIN + (sg0 >> 1)) * PD + (2 * od + (quad >> 1))) * PD * PRX
             + (long)(2 * oh + (quad & 1) * 2) * PRX + 2 * ow;
    const unsigned short* phi = xhi + off;
    const unsigned short* plo = xlo + off;
    const long incA = 2L * PD * PRX;
    const long incB = chs - 2L * PD * PRX;

    // fragment-major: (s, m) block at ((s*MT + m)*64 + lane)*8
    const short* ph = Whi + (((long)sg0 * MT + mi * MTW) * 64 + lane) * 8;
    const short* pl = Wlo + (((long)sg0 * MT + mi * MTW) * 64 + lane) * 8;

    #pragma unroll 2
    for (int s = 0; s < KN; ++s) {
        u16x4u h0 = *(const u16x4u*)phi;
        u16x4u h1 = *(const u16x4u*)(phi + PRX);
        u16x4u l0 = *(const u16x4u*)plo;
        u16x4u l1 = *(const u16x4u*)(plo + PRX);
        bf16x8 bhi = pack_b(h0, h1);
        bf16x8 blo = pack_b(l0, l1);
        #pragma unroll
        for (int mt = 0; mt < MTW; ++mt) {
            bf16x8 ah = *(const bf16x8*)(ph + mt * 512);
            bf16x8 al = *(const bf16x8*)(pl + mt * 512);
            acc[mt] = __builtin_amdgcn_mfma_f32_16x16x32_bf16(ah, bhi, acc[mt], 0, 0, 0);
            acc[mt] = __builtin_amdgcn_mfma_f32_16x16x32_bf16(ah, blo, acc[mt], 0, 0, 0);
            acc[mt] = __builtin_amdgcn_mfma_f32_16x16x32_bf16(al, bhi, acc[mt], 0, 0, 0);
        }
        long inc = (s & 1) ? incB : incA;
        phi += inc; plo += inc;
        ph += SSTEP; pl += SSTEP;
    }

    if (OUTSPLIT) {
        #pragma unroll
        for (int mt = 0; mt < MTW; ++mt)
            #pragma unroll
            for (int r = 0; r < 4; ++r) {
                int co = co0 + mt * 16 + quad * 4 + r;
                float v = fmaxf(acc[mt][r], 0.0f);
                unsigned short h, l;
                split_bf16(v, h, l);
                long o = (((long)(b * COUT + co) * OPD + od + po) * OPD + oh + po) * OPRX
                       + ow + po;
                yhi[o] = h; ylo[o] = l;
            }
    } else {
        #pragma unroll
        for (int mt = 0; mt < MTW; ++mt)
            #pragma unroll
            for (int r = 0; r < 4; ++r) {
                int co = co0 + mt * 16 + quad * 4 + r;
                long o = (long)ks * sstride
                       + (((long)(b * COUT + co) * OPD + od) * OPD + oh) * OPRX + ow;
                yf[o] = acc[mt][r];
            }
    }
}

__global__ __launch_bounds__(256)
void combine4_relu(const float* __restrict__ p, float* __restrict__ y, long N, long ss)
{
    long idx = (long)blockIdx.x * blockDim.x + threadIdx.x;
    if (idx >= N) return;
    float v = p[idx] + p[idx + ss] + p[idx + 2 * ss] + p[idx + 3 * ss];
    y[idx] = fmaxf(v, 0.0f);
}

// ---------------- 1x1 conv (fp32 exact) ----------------
__global__ __launch_bounds__(128)
void conv1x1_b(const float* __restrict__ x, const float* __restrict__ w,
               const float* __restrict__ bias, float* __restrict__ y)
{
    const int co = blockIdx.x & 255, b = blockIdx.x >> 8;
    const int s4 = (int)threadIdx.x * 4;
    const float* xb = x + (long)b * 256 * 512 + s4;
    const float* wr = w + (long)co * 256;      // uniform -> s_load
    float bv = bias[co];
    float4 acc = {bv, bv, bv, bv};
    for (int ci = 0; ci < 256; ++ci) {
        float wv = wr[ci];
        float4 xv = *(const float4*)(xb + (long)ci * 512);
        acc.x = fmaf(xv.x, wv, acc.x); acc.y = fmaf(xv.y, wv, acc.y);
        acc.z = fmaf(xv.z, wv, acc.z); acc.w = fmaf(xv.w, wv, acc.w);
    }
    *(float4*)(y + (long)(b * 256 + co) * 512 + s4) = acc;
}

// ---------------- VQ (fp32 exact) ----------------
__global__ void codenorm_kernel(const float* __restrict__ cb, float* __restrict__ norms)
{
    int k = blockIdx.x;
    int lane = threadIdx.x;
    float s = 0.0f;
    const float* row = cb + (long)k * 256;
    for (int d = lane; d < 256; d += 64) { float v = row[d]; s = fmaf(v, v, s); }
    for (int off = 32; off > 0; off >>= 1) s += __shfl_down(s, off);
    if (lane == 0) norms[k] = s;
}

// cbT[d*1024 + k] = cb[k*256 + d]  (fp32 copy -> values unchanged)
__global__ __launch_bounds__(256)
void transpose_cb(const float* __restrict__ cb, float* __restrict__ cbT)
{
    int idx = blockIdx.x * 256 + (int)threadIdx.x;    // 0..262143
    int d = idx & 255, k = idx >> 8;
    cbT[(long)d * 1024 + k] = cb[(long)k * 256 + d];
}

// R24: 4 rows/block (grid 256), coalesced cbT float4 loads (codes 4t..4t+3),
// rows staged in LDS. Bit-identical to the original per-row kernel.
__global__ __launch_bounds__(256)
void vq_kernel4(const float* __restrict__ lat, const float* __restrict__ cb,
                const float* __restrict__ cbT, const float* __restrict__ norms,
                unsigned short* __restrict__ q, float* __restrict__ idx_out)
{
    __shared__ __align__(16) float rows[4][256];
    __shared__ float s_best[4][256];
    __shared__ int   s_bidx[4][256];
    const int r0 = blockIdx.x * 4;
    const int t = (int)threadIdx.x;

    #pragma unroll
    for (int j = 0; j < 4; ++j)
        rows[j][t] = lat[(long)(r0 + j) * 256 + t];
    __syncthreads();

    // latn per row -- identical float4 fmaf chain to the original
    float latn[4];
    #pragma unroll
    for (int j = 0; j < 4; ++j) {
        const float4* rowv = (const float4*)rows[j];
        float a = 0.0f;
        #pragma unroll 4
        for (int d = 0; d < 64; ++d) {
            float4 rv = rowv[d];
            a = fmaf(rv.x, rv.x, a); a = fmaf(rv.y, rv.y, a);
            a = fmaf(rv.z, rv.z, a); a = fmaf(rv.w, rv.w, a);
        }
        latn[j] = a;
    }

    // codes 4t..4t+3; dot[j][c] accumulates d = 0..255 sequentially (same
    // chain as the original scalar loop)
    float dot[4][4] = {};
    const float* ct = cbT + t * 4;
    #pragma unroll 4
    for (int d = 0; d < 256; ++d) {
        float4 c4 = *(const float4*)(ct + (long)d * 1024);
        #pragma unroll
        for (int j = 0; j < 4; ++j) {
            float rv = rows[j][d];
            dot[j][0] = fmaf(rv, c4.x, dot[j][0]);
            dot[j][1] = fmaf(rv, c4.y, dot[j][1]);
            dot[j][2] = fmaf(rv, c4.z, dot[j][2]);
            dot[j][3] = fmaf(rv, c4.w, dot[j][3]);
        }
    }

    float4 nv = *(const float4*)(norms + t * 4);
    float nr[4] = {nv.x, nv.y, nv.z, nv.w};

    #pragma unroll
    for (int j = 0; j < 4; ++j) {
        float best = FLT_MAX;
        int bidx = 0x7fffffff;
        #pragma unroll
        for (int c = 0; c < 4; ++c) {
            float sc = latn[j] - 2.0f * dot[j][c] + nr[c];
            int k = t * 4 + c;
            if (sc < best || (sc == best && k < bidx)) { best = sc; bidx = k; }
        }
        s_best[j][t] = best; s_bidx[j][t] = bidx;
    }
    __syncthreads();
    for (int off = 128; off > 0; off >>= 1) {
        if (t < off) {
            #pragma unroll
            for (int j = 0; j < 4; ++j) {
                float o = s_best[j][t + off]; int oi = s_bidx[j][t + off];
                if (o < s_best[j][t] || (o == s_best[j][t] && oi < s_bidx[j][t])) {
                    s_best[j][t] = o; s_bidx[j][t] = oi;
                }
            }
        }
        __syncthreads();
    }

    #pragma unroll
    for (int j = 0; j < 4; ++j) {
        const int bk = s_bidx[j][0];
        const int r = r0 + j;
        const int b = r >> 9, n = r & 511;
        const int zz = n >> 6, yy = (n >> 3) & 7, xx = n & 7;
        q[(long)(b * 256 + t) * 1000 + ((long)(zz + 1) * 10 + (yy + 1)) * 10 + (xx + 1)]
            = f32_to_bf16(cb[(long)bk * 256 + t]);
    }
    if (t == 0) {
        #pragma unroll
        for (int j = 0; j < 4; ++j)
            idx_out[r0 + j] = (float)s_bidx[j][0];
    }
}

// ---------------- decoder: MFMA implicit-GEMM ConvTranspose ----------------
// xflip=0: B slot a <-> x offset (1-ax), kw=(1-px)+2*ax (old cube kernel).
// xflip=1: B slot a <-> x offset ax,     kw=(1-px)+2*(1-ax) (dword-pair kernel).
__global__ __launch_bounds__(256)
void prep_convt_w(const float* __restrict__ w, short* __restrict__ Ap,
                  int Cin, int Cout, int xflip)
{
    const int K = Cin * 8;
    long total = 8L * Cout * K;
    long idx = (long)blockIdx.x * blockDim.x + threadIdx.x;
    if (idx >= total) return;
    int k = (int)(idx % K);
    int co = (int)((idx / K) % Cout);
    int p = (int)(idx / ((long)K * Cout));
    int ci = k >> 3, a = k & 7;
    int az = (a >> 2) & 1, ay = (a >> 1) & 1, ax = a & 1;
    int pz = p >> 2, py = (p >> 1) & 1, px = p & 1;
    int axw = xflip ? (1 - ax) : ax;
    int kd = (1 - pz) + 2 * az, kh = (1 - py) + 2 * ay, kw = (1 - px) + 2 * axw;
    float v = w[((long)ci * Cout + co) * 64 + kd * 16 + kh * 4 + kw];
    Ap[idx] = (short)f32_to_bf16(v);
}

// Fragment-major layout for the LDS-staged v2 kernel:
//   ApN[((p*MG + mg)*nsteps + s)*2048 + cb*512 + l*8 + kk]
// where l = quad*16 + n16, korig = s*32 + quad*8 + kk, co = mg*64 + cb*16 + n16.
// Each (p,mg,s) tile is one contiguous 4KB block.
__global__ __launch_bounds__(256)
void prep_convt_w_frag(const float* __restrict__ w, short* __restrict__ Ap,
                       int Cin, int Cout, int xflip)
{
    const int MG = Cout >> 6;
    const int nsteps = Cin >> 2;             // (Cin*8)/32
    long total = 8L * MG * nsteps * 2048;
    long idx = (long)blockIdx.x * blockDim.x + threadIdx.x;
    if (idx >= total) return;
    int kk = (int)(idx & 7); long r = idx >> 3;
    int l  = (int)(r & 63);  r >>= 6;
    int cb = (int)(r & 3);   r >>= 2;
    int s  = (int)(r % nsteps); r /= nsteps;
    int mg = (int)(r % MG);
    int p  = (int)(r / MG);

    int n16 = l & 15, quad = l >> 4;
    int korig = s * 32 + quad * 8 + kk;
    int co = mg * 64 + cb * 16 + n16;
    int ci = korig >> 3, a = korig & 7;
    int az = (a >> 2) & 1, ay = (a >> 1) & 1, ax = a & 1;
    int pz = p >> 2, py = (p >> 1) & 1, px = p & 1;
    int axw = xflip ? (1 - ax) : ax;
    int kd = (1 - pz) + 2 * az, kh = (1 - py) + 2 * ay, kw = (1 - px) + 2 * axw;
    float v = w[((long)ci * Cout + co) * 64 + kd * 16 + kh * 4 + kw];
    Ap[idx] = (short)f32_to_bf16(v);
}

// Old cube-N layout (kept for dec1, DIN=8): round-0 body.
template <int CIN, int COUT, int DIN, int OPAD, typename OutT>
__global__ __launch_bounds__(256)
void convt_mfma(const unsigned short* __restrict__ Xp, const short* __restrict__ Ap,
                const float* __restrict__ bias, OutT* __restrict__ Y)
{
    constexpr int PD = DIN + 2;
    constexpr int PD3 = PD * PD * PD;
    constexpr int T = DIN >> 2;
    constexpr int NT = T * T * T;
    constexpr int SLAB = NT / 8;
    constexpr int OPD = 2 * DIN + 2 * OPAD;
    constexpr int K = CIN * 8;
    constexpr int MG = COUT >> 6;
    constexpr int nsteps = K >> 5;

    int bx = blockIdx.x;
    const int xcd = bx & 7;
    int local = bx >> 3;
    const int px = local & 1; local >>= 1;
    const int mg = local % MG; local /= MG;
    const int ntin = local % SLAB;
    const int pzy = local / SLAB;            // 0..3
    const int pz = pzy >> 1, py = pzy & 1;
    const int p = pz * 4 + py * 2 + px;
    const int nt = xcd * SLAB + ntin;

    const int lane = threadIdx.x & 63, wave = threadIdx.x >> 6;
    const int n16 = lane & 15, quad = lane >> 4;

    const int tx = nt % T, ty = (nt / T) % T, tz = nt / (T * T);
    const int mz = tz * 4 + wave, my = ty * 4 + (n16 >> 2), mx = tx * 4 + (n16 & 3);
    const int sp = ((mz + pz) * PD + (my + py)) * PD + (mx + px);

    const unsigned short* xq = Xp + (long)quad * PD3 + sp;

    const int cobase = mg * 64;
    const short* ap0 = Ap + ((long)p * COUT + cobase + n16) * K + quad * 8;

    f32x4 acc[4];
    #pragma unroll
    for (int cb = 0; cb < 4; ++cb) {
        const float* bp = bias + cobase + cb * 16 + quad * 4;
        acc[cb][0] = bp[0]; acc[cb][1] = bp[1]; acc[cb][2] = bp[2]; acc[cb][3] = bp[3];
    }

    #pragma unroll 4
    for (int s = 0; s < nsteps; ++s) {
        const unsigned short* xs = xq + (long)s * 4 * PD3;
        bf16x8 bf;
        bf[0] = (short)xs[(PD + 1) * PD + 1];
        bf[1] = (short)xs[(PD + 1) * PD];
        bf[2] = (short)xs[PD * PD + 1];
        bf[3] = (short)xs[PD * PD];
        bf[4] = (short)xs[PD + 1];
        bf[5] = (short)xs[PD];
        bf[6] = (short)xs[1];
        bf[7] = (short)xs[0];
        #pragma unroll
        for (int cb = 0; cb < 4; ++cb) {
            bf16x8 af = *(const bf16x8*)(ap0 + (long)cb * 16 * K + s * 32);
            acc[cb] = __builtin_amdgcn_mfma_f32_16x16x32_bf16(af, bf, acc[cb], 0, 0, 0);
        }
    }

    const int opz = 2 * mz + pz + OPAD, opy = 2 * my + py + OPAD, opx = 2 * mx + px + OPAD;
    const long spo = ((long)opz * OPD + opy) * OPD + opx;
    #pragma unroll
    for (int cb = 0; cb < 4; ++cb) {
        #pragma unroll
        for (int r = 0; r < 4; ++r) {
            int co = cobase + cb * 16 + quad * 4 + r;
            float v = fmaxf(acc[cb][r], 0.0f);
            store_act(Y + (long)co * OPD * OPD * OPD + spo, v);
        }
    }
}

// Dword-pair B-gather (dec2/dec3), R20: A staged through LDS (unchanged).
template <int CIN, int COUT, int DIN, int OPAD, int MXP, int MYP, typename OutT>
__global__ __launch_bounds__(256)
void convt_mfma_v2(const unsigned short* __restrict__ Xp, const short* __restrict__ Ap,
                   const float* __restrict__ bias, OutT* __restrict__ Y)
{
    constexpr int PD = DIN + 2;
    constexpr int PD3 = PD * PD * PD;
    constexpr int OPD = 2 * DIN + 2 * OPAD;
    constexpr int K = CIN * 8;
    constexpr int MG = COUT >> 6;
    constexpr int nsteps = K >> 5;
    static_assert(nsteps >= 2, "need at least 2 K-steps");
    constexpr int MXT = DIN / (16 * MXP);
    constexpr int MYT = DIN / (4 * MYP);
    constexpr int MZS = DIN / 8;             // mz per XCD slab
    constexpr int TPE = MXP * MYP;           // tiles per wave (one of MXP/MYP is 1)

    int bx = blockIdx.x;
    const int xcd = bx & 7;
    int local = bx >> 3;
    const int px = local & 1; local >>= 1;
    const int py = local & 1; local >>= 1;
    const int mg = local % MG; local /= MG;
    const int mxt = local % MXT; local /= MXT;
    const int myt = local % MYT; local /= MYT;
    const int pz = local & 1; local >>= 1;
    const int mzin = local;                  // 0..MZS-1
    const int mz = xcd * MZS + mzin;
    const int p = pz * 4 + py * 2 + px;

    const int lane = threadIdx.x & 63, wave = threadIdx.x >> 6;
    const int n16 = lane & 15, quad = lane >> 4;

    const int mx0 = mxt * (16 * MXP) + n16;
    const int my0 = myt * (4 * MYP) + wave * MYP;
    const int baseX = mx0 & ~1;
    const int sh = 16 * ((n16 & 1) + px);    // 0, 16, or 32
    const long sp = ((long)(mz + pz) * PD + (my0 + py)) * PD + baseX;

    const unsigned short* xq = Xp + (long)quad * PD3 + sp;

    // fragment-major weight tiles: 2048 shorts (4KB) per (p,mg,s)
    const short* ApT = Ap + (((long)p * MG + mg) * nsteps) * 2048;

    __shared__ short Abuf[2][2048];          // 8KB double buffer

    f32x4 acc[TPE][4];
    #pragma unroll
    for (int t = 0; t < TPE; ++t)
        #pragma unroll
        for (int cb = 0; cb < 4; ++cb) {
            const float* bp = bias + (mg * 64) + cb * 16 + quad * 4;
            acc[t][cb][0] = bp[0]; acc[t][cb][1] = bp[1];
            acc[t][cb][2] = bp[2]; acc[t][cb][3] = bp[3];
        }

    constexpr int rowoff[4] = { (PD + 1) * PD, PD * PD, PD, 0 };
    union Frag { unsigned u[4]; bf16x8 b; };

    const int chunkoff = wave * 512 + lane * 8;   // this thread's 16B of the 4KB tile

    // prologue: stage step 0
    {
        bf16x8 a0 = *(const bf16x8*)(ApT + chunkoff);
        *(bf16x8*)(&Abuf[0][chunkoff]) = a0;
    }
    __syncthreads();

    #pragma unroll 1
    for (int s = 0; s < nsteps; ++s) {
        const int cur = s & 1;
        bf16x8 anext;
        const bool more = (s + 1 < nsteps);
        if (more)
            anext = *(const bf16x8*)(ApT + (long)(s + 1) * 2048 + chunkoff);

        // X loads (plain C, raw staging)
        const unsigned short* xs = xq + (long)s * 4 * PD3;
        unsigned long long xr[TPE][4];
        #pragma unroll
        for (int t = 0; t < TPE; ++t) {
            const int toff = (MXP > 1) ? t * 16 : t * PD;
            #pragma unroll
            for (int j = 0; j < 4; ++j) {
                union { u16x4u v; unsigned long long u; } ld;
                ld.v = *(const u16x4u*)(xs + toff + rowoff[j]);
                xr[t][j] = ld.u;
            }
        }

        // A fragments from LDS (l = quad*16 + n16 == lane)
        bf16x8 af[4];
        #pragma unroll
        for (int cb = 0; cb < 4; ++cb)
            af[cb] = *(const bf16x8*)(&Abuf[cur][cb * 512 + lane * 8]);

        #pragma unroll
        for (int t = 0; t < TPE; ++t) {
            Frag fr;
            #pragma unroll
            for (int j = 0; j < 4; ++j)
                fr.u[j] = (unsigned)(xr[t][j] >> sh);
            #pragma unroll
            for (int cb = 0; cb < 4; ++cb)
                acc[t][cb] = __builtin_amdgcn_mfma_f32_16x16x32_bf16(af[cb], fr.b,
                                                                     acc[t][cb], 0, 0, 0);
        }

        if (more)
            *(bf16x8*)(&Abuf[cur ^ 1][chunkoff]) = anext;
        __syncthreads();
    }

    const int opz = 2 * mz + pz + OPAD;
    #pragma unroll
    for (int t = 0; t < TPE; ++t) {
        const int opx = 2 * (mx0 + ((MXP > 1) ? t * 16 : 0)) + px + OPAD;
        const int opy = 2 * (my0 + ((MYP > 1) ? t : 0)) + py + OPAD;
        const long spo = ((long)opz * OPD + opy) * OPD + opx;
        #pragma unroll
        for (int cb = 0; cb < 4; ++cb) {
            #pragma unroll
            for (int r = 0; r < 4; ++r) {
                int co = (mg * 64) + cb * 16 + quad * 4 + r;
                float v = fmaxf(acc[t][cb][r], 0.0f);
                store_act(Y + (long)co * OPD * OPD * OPD + spo, v);
            }
        }
    }
}

// ---------------- dec4 as MFMA GEMM, R25: conflict-free LDS ---------------
// Fragment-major: Aw[(s*64 + lane)*8 + kk] (unchanged from R23).
__global__ __launch_bounds__(256)
void prep_dec4A_frag(const float* __restrict__ w, short* __restrict__ Aw)
{
    int idx = blockIdx.x * 256 + (int)threadIdx.x;    // 0..65535
    int kk = idx & 7;
    int l  = (idx >> 3) & 63;
    int s  = idx >> 9;                                // 0..127
    int n16 = l & 15, quad = l >> 4;
    int k = s * 32 + quad * 8 + kk;
    float v = (n16 < 3) ? w[n16 * 4096 + k] : 0.0f;
    Aw[idx] = (short)f32_to_bf16(v);
}

// R25 layout: Xs row stride 72 words; strided staging (thread t owns words
// g = t + 224*j). Conflict-free reads ({0,16,24,8} bank windows, 2/bank)
// and writes (64 consecutive words/wave-pass). Bit-identical.
__global__ __launch_bounds__(256)
void conv_dec4_mfma(const float* __restrict__ d3, const short* __restrict__ Aw,
                    const float* __restrict__ bias, float* __restrict__ y)
{
    constexpr int D = 64, Dout = 61;
    constexpr int RS = 72;                 // row stride (words)
    int bx = blockIdx.x;
    const int slab = bx & 7;
    const int i = bx >> 3;                 // 0..127
    const int od = slab * 8 + (i >> 4);
    const int oh0 = (i & 15) * 4;          // covers oh0..oh0+3 (guard < 61)
    if (od >= Dout) return;                // uniform per block -> barriers safe
    const int tid = (int)threadIdx.x;
    const int lane = tid & 63, wave = tid >> 6;
    const int n16 = lane & 15, quad = lane >> 4;
    const int ow = wave * 16 + n16;

    // [dbuf][row 0..13][x 0..71]; words 64..71 per row uninitialized (only
    // consumed by discarded ow>=61 columns; reads reach word ow+3 <= 66)
    __shared__ float Xs[2][14][RS];

    f32x4 acc[4];
    #pragma unroll
    for (int j = 0; j < 4; ++j)
        #pragma unroll
        for (int r = 0; r < 4; ++r) {
            int co = quad * 4 + r;
            acc[j][r] = (co < 3) ? bias[co] : 0.0f;
        }

    const int kd0 = quad >> 1;
    const int kh0 = (quad & 1) * 2;

    // strided staging: thread t (t<224) owns words g = t + 224*j, j=0..3;
    // word g -> (row = g/64, x = g%64); row -> (z' = row/7, y' = row%7)
    const bool sact = (tid < 224);
    const float* gsrc[4];
    float* ldst[4][2];
    #pragma unroll
    for (int j = 0; j < 4; ++j) {
        const int g = tid + 224 * j;
        const int row = g >> 6, xx = g & 63;
        const int szi = row / 7, syi = row % 7;
        gsrc[j] = d3 + (((long)(od + szi) * D) + min(oh0 + syi, D - 1)) * D + xx;
        ldst[j][0] = &Xs[0][row][xx];
        ldst[j][1] = &Xs[1][row][xx];
    }
    auto choff = [&](int s) { return (long)((s >> 1) * D + (s & 1) * 2) * D * D; };

    // prologue: stage step 0
    if (sact) {
        const long c0 = choff(0);
        #pragma unroll
        for (int j = 0; j < 4; ++j)
            *ldst[j][0] = gsrc[j][c0];
    }
    __syncthreads();

    #pragma unroll 1
    for (int s = 0; s < 128; ++s) {
        const int cur = s & 1;
        const bool more = (s + 1 < 128);
        float nv[4];
        if (more && sact) {
            const long cn = choff(s + 1);
            #pragma unroll
            for (int j = 0; j < 4; ++j)
                nv[j] = gsrc[j][cn];
        }

        bf16x8 af = *(const bf16x8*)(Aw + ((long)s * 64 + lane) * 8);

        unsigned p0[5], p1[5];
        #pragma unroll
        for (int r = 0; r < 5; ++r) {
            f32x4u v = *(const f32x4u*)(&Xs[cur][kd0 * 7 + kh0 + r][ow]);
            p0[r] = (__float_as_uint(v[0]) >> 16) | (__float_as_uint(v[1]) & 0xffff0000u);
            p1[r] = (__float_as_uint(v[2]) >> 16) | (__float_as_uint(v[3]) & 0xffff0000u);
        }
        #pragma unroll
        for (int j = 0; j < 4; ++j) {
            union { unsigned u[4]; bf16x8 b; } fr;
            fr.u[0] = p0[j];     fr.u[1] = p1[j];
            fr.u[2] = p0[j + 1]; fr.u[3] = p1[j + 1];
            acc[j] = __builtin_amdgcn_mfma_f32_16x16x32_bf16(af, fr.b, acc[j], 0, 0, 0);
        }

        if (more && sact) {
            #pragma unroll
            for (int j = 0; j < 4; ++j)
                *ldst[j][cur ^ 1] = nv[j];
        }
        __syncthreads();
    }

    if (ow < Dout && quad == 0) {
        #pragma unroll
        for (int j = 0; j < 4; ++j) {
            const int oh = oh0 + j;
            if (oh >= Dout) continue;
            #pragma unroll
            for (int r = 0; r < 3; ++r)
                y[((long)(r * Dout + od) * Dout + oh) * Dout + ow] = tanhf(acc[j][r]);
        }
    }
}

extern "C" void kernel_launch(void* const* d_in, const int* in_sizes, int n_in,
                              void* d_out, int out_size, void* d_ws, size_t ws_size,
                              hipStream_t stream)
{
    const float* x        = (const float*)d_in[0];
    const float* enc_w1   = (const float*)d_in[1];
    const float* enc_b1   = (const float*)d_in[2];
    const float* enc_w2   = (const float*)d_in[3];
    const float* enc_b2   = (const float*)d_in[4];
    const float* enc_w3   = (const float*)d_in[5];
    const float* enc_b3   = (const float*)d_in[6];
    const float* enc_w4   = (const float*)d_in[7];
    const float* enc_b4   = (const float*)d_in[8];
    const float* codebook = (const float*)d_in[9];
    const float* dec_w1   = (const float*)d_in[10];
    const float* dec_b1   = (const float*)d_in[11];
    const float* dec_w2   = (const float*)d_in[12];
    const float* dec_b2   = (const float*)d_in[13];
    const float* dec_w3   = (const float*)d_in[14];
    const float* dec_b3   = (const float*)d_in[15];
    const float* dec_w4   = (const float*)d_in[16];
    const float* dec_b4   = (const float*)d_in[17];

    float* out = (float*)d_out;
    float* idx_out = out + 2L * 3 * 61 * 61 * 61;

    // ---- workspace (byte offsets) ----
    char* wsb = (char*)d_ws;
    float*          cn   = (float*)wsb;                        //      4,096
    unsigned short* qp   = (unsigned short*)(wsb + 4096);      //  1,024,000
    short*          Ap1  = (short*)(wsb + 1028096);            //  8,388,608
    short*          Ap2  = (short*)(wsb + 9416704);            //  4,194,304
    short*          Ap3  = (short*)(wsb + 13611008);           //  1,048,576
    short*          Aw4  = (short*)(wsb + 14659584);           //    131,072
    short*          W1hi = (short*)(wsb + 14790656);           //     24,576
    short*          W1lo = (short*)(wsb + 14815232);           //     24,576
    short*          W2hi = (short*)(wsb + 14839808);           //  1,048,576
    short*          W2lo = (short*)(wsb + 15888384);           //  1,048,576
    short*          W3hi = (short*)(wsb + 16936960);           //  4,194,304
    short*          W3lo = (short*)(wsb + 21131264);           //  4,194,304
    char* arena = wsb + 25325568;
    // encoder phase:
    unsigned short* xphi = (unsigned short*)arena;                    // (2,3,66,66,68)
    unsigned short* xplo = (unsigned short*)(arena + 3554496);
    unsigned short* h1hi = (unsigned short*)(arena + 7108992);        // (2,64,34,34,36)
    unsigned short* h1lo = (unsigned short*)(arena + 17762688);
    unsigned short* h2hi = (unsigned short*)(arena + 28416384);       // (2,128,18,18,20)
    unsigned short* h2lo = (unsigned short*)(arena + 31734144);
    float*          pp3  = (float*)(arena + 35051904);                // 4x(2,256,8^3)
    float*          h3   = (float*)(arena + 39246208);                // (2,256,512)
    float*          lat  = (float*)(arena + 40294784);                // (2,256,512)
    // decoder phase (after VQ; overlaps encoder buffers):
    unsigned short* d1 = (unsigned short*)arena;                      // (256,18^3) bf16
    unsigned short* d2 = (unsigned short*)(arena + 2985984);          // (128,34^3) bf16
    float*          d3 = (float*)(arena + 13047808);                  // (64,64^3) fp32
    // arena peak 80.2 MB -> ws used 105.5 MB; cbT appended below:
    float*          cbT = (float*)(wsb + 105482240);                  // 1,048,576
    // total 106.5 MB (< 112.2 MB proven in R0)

    dim3 blk(256);
    auto nblk = [](long n) { return dim3((unsigned)((n + 255) / 256)); };

    // ---- weight prep ----
    prep_convt_w<<<nblk(8L * 256 * 2048), blk, 0, stream>>>(dec_w1, Ap1, 256, 256, 0);
    prep_convt_w_frag<<<nblk(8L * 128 * 2048), blk, 0, stream>>>(dec_w2, Ap2, 256, 128, 1);
    prep_convt_w_frag<<<nblk(8L * 64 * 1024), blk, 0, stream>>>(dec_w3, Ap3, 128, 64, 1);
    prep_dec4A_frag<<<dim3(256), blk, 0, stream>>>(dec_w4, Aw4);
    prep_split_w<<<nblk(12288), blk, 0, stream>>>(enc_w1, W1hi, W1lo, 12288);
    prep_split_w_frag<<<nblk(524288), blk, 0, stream>>>(enc_w2, W2hi, W2lo, 64, 128);
    prep_split_w_frag<<<nblk(2097152), blk, 0, stream>>>(enc_w3, W3hi, W3lo, 128, 256);
    transpose_cb<<<dim3(1024), blk, 0, stream>>>(codebook, cbT);

    // ---- encoder (MFMA, bf16-pair) ----
    pad_input_split<<<nblk(6L * 66 * 66 * 68), blk, 0, stream>>>(x, xphi, xplo);
    zero_halo_ps<<<nblk(128L * 34 * 34 * 36), blk, 0, stream>>>(h1hi, 128, 34, 36);
    zero_halo_ps<<<nblk(128L * 34 * 34 * 36), blk, 0, stream>>>(h1lo, 128, 34, 36);
    conv_s2_mfma<3, 64, 32, 66, 68, 4, 2, 0, 1, 1><<<dim3(1024), blk, 0, stream>>>(
        xphi, xplo, W1hi, W1lo, enc_b1, h1hi, h1lo, nullptr, 34, 36, 1, 0);
    zero_halo_ps<<<nblk(256L * 18 * 18 * 20), blk, 0, stream>>>(h2hi, 256, 18, 20);
    zero_halo_ps<<<nblk(256L * 18 * 18 * 20), blk, 0, stream>>>(h2lo, 256, 18, 20);
    conv_s2_mfma_fd<64, 128, 16, 34, 36, 2, 1, 0, 1, 1><<<dim3(512), blk, 0, stream>>>(
        h1hi, h1lo, W2hi, W2lo, enc_b2, h2hi, h2lo, nullptr, 18, 20, 1, 0);
    conv_s2_mfma_fd<128, 256, 8, 18, 20, 4, 1, 1, 4, 0><<<dim3(256), blk, 0, stream>>>(
        h2hi, h2lo, W3hi, W3lo, enc_b3, nullptr, nullptr, pp3, 8, 8, 0, 262144);
    combine4_relu<<<nblk(262144), blk, 0, stream>>>(pp3, h3, 262144, 262144);
    conv1x1_b<<<dim3(512), dim3(128), 0, stream>>>(h3, enc_w4, enc_b4, lat);

    // ---- VQ (fp32 exact) ----
    codenorm_kernel<<<dim3(1024), dim3(64), 0, stream>>>(codebook, cn);
    zero_halo_t<unsigned short><<<nblk(512L * 10 * 10 * 10), blk, 0, stream>>>(qp, 512, 10);
    vq_kernel4<<<dim3(256), blk, 0, stream>>>(lat, codebook, cbT, cn, qp, idx_out);

    // ---- decoder halos ----
    zero_halo_t<unsigned short><<<nblk(256L * 18 * 18 * 18), blk, 0, stream>>>(d1, 256, 18);
    zero_halo_t<unsigned short><<<nblk(128L * 34 * 34 * 34), blk, 0, stream>>>(d2, 128, 34);

    // ---- decoder (MFMA) per batch ----
    for (int b = 0; b < 2; ++b) {
        const unsigned short* qb = qp + (long)b * 256 * 1000;
        float* outb = out + (long)b * 3 * 226981;
        // dec1 (DIN=8, old layout): grid = 8*2*4*1*4 = 256
        convt_mfma<256, 256, 8, 1, unsigned short><<<dim3(256), blk, 0, stream>>>(
            qb, Ap1, dec_b1, d1);
        // dec2 (v2, MXP=1 MYP=2): grid = 8 * (2*2*2*1*2*2*2) = 512
        convt_mfma_v2<256, 128, 16, 1, 1, 2, unsigned short><<<dim3(512), blk, 0, stream>>>(
            d1, Ap2, dec_b2, d2);
        // dec3 (v2, MXP=2 MYP=1): grid = 8 * (2*2*1*1*8*2*4) = 2048
        convt_mfma_v2<128, 64, 32, 0, 2, 1, float><<<dim3(2048), blk, 0, stream>>>(
            d2, Ap3, dec_b3, d3);
        conv_dec4_mfma<<<dim3(8 * 8 * 16), blk, 0, stream>>>(d3, Aw4, dec_b4, outb);
    }
}

// Round 11
// 921.359 us; speedup vs baseline: 1.5829x; 1.0229x over previous
//
#include <hip/hip_runtime.h>
#include <cfloat>
#include <cmath>

// ---------------------------------------------------------------------------
// Round 28: halve dec4's barrier/latency chain -- merge 2 ci-halves per step.
// R27 post-mortem: enc fragment-direct confirmed (955 -> 942us). Top-5:
// conv_dec4_mfma 94us x2, VALUBusy 37.7%, MfmaUtil 13.4%, conflicts 0,
// occupancy grid-capped (4 blocks/CU). ~50% of cycles are neither VALU nor
// MFMA: the 128-step {stage-load -> pack+MFMA -> __syncthreads(vmcnt(0)
// drain)} chain serializes on d3 load latency every step.
// Fix: one step per ci (64 steps): stage 28 rows (4z x 7y), run both
// z-half MFMA groups (af(2S) then af(2S+1)) per step. Latency rounds
// halve; per-work VALU/LDS/MFMA unchanged. Bank structure preserved:
// stride 72 -> read windows {0,16,24,8} (+uniform 14h shift) 2/bank free;
// writes 64-consecutive-word wave-passes free; staging 4 lines/wave-pass.
// MFMA sequence = old s=2S then s=2S+1 exactly => bit-identical.
// Everything else unchanged from R27.
// ---------------------------------------------------------------------------

using f32x4  = __attribute__((ext_vector_type(4))) float;
using bf16x8 = __attribute__((ext_vector_type(8))) short;
typedef float f32x4u __attribute__((ext_vector_type(4), aligned(4)));
typedef unsigned short u16x4u __attribute__((ext_vector_type(4), aligned(4)));

__device__ __forceinline__ unsigned short f32_to_bf16(float f) {
    unsigned int u = __float_as_uint(f);
    u += 0x7fffu + ((u >> 16) & 1u);          // round-to-nearest-even
    return (unsigned short)(u >> 16);
}
__device__ __forceinline__ void split_bf16(float v, unsigned short& h, unsigned short& l) {
    h = f32_to_bf16(v);
    float hf = __uint_as_float((unsigned)h << 16);
    l = f32_to_bf16(v - hf);
}
__device__ __forceinline__ void store_act(float* p, float v) { *p = v; }
__device__ __forceinline__ void store_act(unsigned short* p, float v) { *p = f32_to_bf16(v); }

template <typename V>
__device__ __forceinline__ bf16x8 pack_b(V r0, V r1) {
    bf16x8 b;
    b[0] = (short)r0[0]; b[1] = (short)r0[1]; b[2] = (short)r0[2]; b[3] = (short)r0[3];
    b[4] = (short)r1[0]; b[5] = (short)r1[1]; b[6] = (short)r1[2]; b[7] = (short)r1[3];
    return b;
}

// ---------------- prep: weight hi/lo split (linear; enc1) ----------------
__global__ __launch_bounds__(256)
void prep_split_w(const float* __restrict__ w, short* __restrict__ whi,
                  short* __restrict__ wlo, long total)
{
    long idx = (long)blockIdx.x * blockDim.x + threadIdx.x;
    if (idx >= total) return;
    unsigned short h, l;
    split_bf16(w[idx], h, l);
    whi[idx] = (short)h; wlo[idx] = (short)l;
}

// Fragment-major hi/lo split for enc2/enc3:
//   whi[((s*MT + m)*64 + l)*8 + kk] = hi(w[co*K + korig])
// with MT = COUT/16, co = m*16 + (l&15), korig = s*32 + (l>>4)*8 + kk.
// Each (s,m) fragment block (512 shorts = 1KB) is contiguous.
__global__ __launch_bounds__(256)
void prep_split_w_frag(const float* __restrict__ w, short* __restrict__ whi,
                       short* __restrict__ wlo, int CIN, int COUT)
{
    const int K = CIN * 64;
    const int MT = COUT >> 4;
    long total = (long)COUT * K;
    long idx = (long)blockIdx.x * blockDim.x + threadIdx.x;
    if (idx >= total) return;
    int kk = (int)(idx & 7); long r = idx >> 3;
    int l  = (int)(r & 63);  r >>= 6;
    int m  = (int)(r % MT);
    int s  = (int)(r / MT);
    int n16 = l & 15, quad = l >> 4;
    int co = m * 16 + n16;
    int korig = s * 32 + quad * 8 + kk;
    unsigned short h, lo16;
    split_bf16(w[(long)co * K + korig], h, lo16);
    whi[idx] = (short)h; wlo[idx] = (short)lo16;
}

// ---------------- pad input -> hi/lo bf16 pitched planes --------------------
__global__ __launch_bounds__(256)
void pad_input_split(const float* __restrict__ x, unsigned short* __restrict__ xhi,
                     unsigned short* __restrict__ xlo)
{
    const int D = 64, PD = 66, PRX = 68, BC = 6;
    long total = (long)BC * PD * PD * PRX;
    long idx = (long)blockIdx.x * blockDim.x + threadIdx.x;
    if (idx >= total) return;
    int px = (int)(idx % PRX); long t = idx / PRX;
    int py = (int)(t % PD); t /= PD;
    int pz = (int)(t % PD); int c = (int)(t / PD);
    int ix = px - 1, iy = py - 1, iz = pz - 1;
    float v = 0.0f;
    if ((unsigned)ix < (unsigned)D && (unsigned)iy < (unsigned)D && (unsigned)iz < (unsigned)D)
        v = x[(((long)c * D + iz) * D + iy) * D + ix];
    unsigned short h, l;
    split_bf16(v, h, l);
    xhi[idx] = h; xlo[idx] = l;
}

__global__ __launch_bounds__(256)
void zero_halo_ps(unsigned short* __restrict__ p, int C, int PD, int PRX)
{
    long total = (long)C * PD * PD * PRX;
    long idx = (long)blockIdx.x * blockDim.x + threadIdx.x;
    if (idx >= total) return;
    int px = (int)(idx % PRX); long t = idx / PRX;
    int py = (int)(t % PD); t /= PD;
    int pz = (int)(t % PD);
    if (px == 0 || px >= PD - 1 || py == 0 || py == PD - 1 || pz == 0 || pz == PD - 1)
        p[idx] = 0;
}

template <typename T>
__global__ __launch_bounds__(256) void zero_halo_t(T* __restrict__ p, int C, int PD)
{
    long total = (long)C * PD * PD * PD;
    long idx = (long)blockIdx.x * blockDim.x + threadIdx.x;
    if (idx >= total) return;
    int px = (int)(idx % PD); long t = idx / PD;
    int py = (int)(t % PD); t /= PD;
    int pz = (int)(t % PD);
    if (px == 0 || px == PD - 1 || py == 0 || py == PD - 1 || pz == 0 || pz == PD - 1)
        p[idx] = (T)0;
}

// ---------------------------------------------------------------------------
// Conv3d k4 s2 p1 as MFMA implicit GEMM, bf16 hi/lo pair inputs (enc1 only)
// ---------------------------------------------------------------------------
template <int CIN, int COUT, int DOUT, int PD, int PRX, int MTW, int OWT,
          int OWHALF, int KSPLIT, int OUTSPLIT>
__global__ __launch_bounds__(256)
void conv_s2_mfma(const unsigned short* __restrict__ xhi,
                  const unsigned short* __restrict__ xlo,
                  const short* __restrict__ Whi, const short* __restrict__ Wlo,
                  const float* __restrict__ bias,
                  unsigned short* __restrict__ yhi, unsigned short* __restrict__ ylo,
                  float* __restrict__ yf,
                  int OPD, int OPRX, int po, long sstride)
{
    constexpr int K = CIN * 64;
    constexpr int MWAVES = COUT / (16 * MTW);
    constexpr int RPB = 4 / MWAVES;
    constexpr int KN = (CIN * 2) / KSPLIT;

    int bx = blockIdx.x;
    const int ks = (KSPLIT > 1) ? (bx % KSPLIT) : 0;
    const int rowblk = (KSPLIT > 1) ? (bx / KSPLIT) : bx;
    const int lane = (int)threadIdx.x & 63, w = (int)threadIdx.x >> 6;
    const int mi = (MWAVES == 4) ? w : 0;
    const int ri = (MWAVES == 4) ? 0 : w;
    const int rowid = rowblk * RPB + ri;
    const int n16 = lane & 15, quad = lane >> 4;

    int b, od, oh, ow;
    if (OWHALF) {
        constexpr int NOH = DOUT / 2;
        const int ohb = rowid % NOH; int t = rowid / NOH;
        od = t % DOUT; b = t / DOUT;
        oh = ohb * 2 + (n16 >> 3);
        ow = n16 & 7;
    } else {
        const int owt = rowid % OWT; int t = rowid / OWT;
        oh = t % DOUT; t /= DOUT;
        od = t % DOUT; b = t / DOUT;
        ow = owt * 16 + n16;
    }

    const int co0 = mi * (MTW * 16);

    f32x4 acc[MTW];
    #pragma unroll
    for (int mt = 0; mt < MTW; ++mt)
        #pragma unroll
        for (int r = 0; r < 4; ++r) {
            int co = co0 + mt * 16 + quad * 4 + r;
            acc[mt][r] = (ks == 0) ? bias[co] : 0.0f;
        }

    const int sg0 = ks * KN;
    const long chs = (long)PD * PD * PRX;
    long off = ((long)(b * CIN + (sg0 >> 1)) * PD + (2 * od + (quad >> 1))) * PD * PRX
             + (long)(2 * oh + (quad & 1) * 2) * PRX + 2 * ow;
    const unsigned short* phi = xhi + off;
    const unsigned short* plo = xlo + off;
    const long incA = 2L * PD * PRX;
    const long incB = chs - 2L * PD * PRX;

    const short* a0h = Whi + (long)(co0 + n16) * K + sg0 * 32 + quad * 8;
    const short* a0l = Wlo + (long)(co0 + n16) * K + sg0 * 32 + quad * 8;

    #pragma unroll 2
    for (int s = 0; s < KN; ++s) {
        u16x4u h0 = *(const u16x4u*)phi;
        u16x4u h1 = *(const u16x4u*)(phi + PRX);
        u16x4u l0 = *(const u16x4u*)plo;
        u16x4u l1 = *(const u16x4u*)(plo + PRX);
        bf16x8 bhi = pack_b(h0, h1);
        bf16x8 blo = pack_b(l0, l1);
        #pragma unroll
        for (int mt = 0; mt < MTW; ++mt) {
            bf16x8 ah = *(const bf16x8*)(a0h + (long)mt * 16 * K + s * 32);
            bf16x8 al = *(const bf16x8*)(a0l + (long)mt * 16 * K + s * 32);
            acc[mt] = __builtin_amdgcn_mfma_f32_16x16x32_bf16(ah, bhi, acc[mt], 0, 0, 0);
            acc[mt] = __builtin_amdgcn_mfma_f32_16x16x32_bf16(ah, blo, acc[mt], 0, 0, 0);
            acc[mt] = __builtin_amdgcn_mfma_f32_16x16x32_bf16(al, bhi, acc[mt], 0, 0, 0);
        }
        long inc = (s & 1) ? incB : incA;
        phi += inc; plo += inc;
    }

    if (OUTSPLIT) {
        #pragma unroll
        for (int mt = 0; mt < MTW; ++mt)
            #pragma unroll
            for (int r = 0; r < 4; ++r) {
                int co = co0 + mt * 16 + quad * 4 + r;
                float v = fmaxf(acc[mt][r], 0.0f);
                unsigned short h, l;
                split_bf16(v, h, l);
                long o = (((long)(b * COUT + co) * OPD + od + po) * OPD + oh + po) * OPRX
                       + ow + po;
                yhi[o] = h; ylo[o] = l;
            }
    } else {
        #pragma unroll
        for (int mt = 0; mt < MTW; ++mt)
            #pragma unroll
            for (int r = 0; r < 4; ++r) {
                int co = co0 + mt * 16 + quad * 4 + r;
                long o = (long)ks * sstride
                       + (((long)(b * COUT + co) * OPD + od) * OPD + oh) * OPRX + ow;
                yf[o] = acc[mt][r];
            }
    }
}

// Fragment-direct variant (enc2/enc3): fragment-major Whi/Wlo, each wave
// loads its OWN disjoint (s,m) fragment blocks (coalesced 1KB dwordx4) --
// no LDS, no barriers. Bit-identical to the LDS path.
template <int CIN, int COUT, int DOUT, int PD, int PRX, int MTW, int OWT,
          int OWHALF, int KSPLIT, int OUTSPLIT>
__global__ __launch_bounds__(256)
void conv_s2_mfma_fd(const unsigned short* __restrict__ xhi,
                     const unsigned short* __restrict__ xlo,
                     const short* __restrict__ Whi, const short* __restrict__ Wlo,
                     const float* __restrict__ bias,
                     unsigned short* __restrict__ yhi, unsigned short* __restrict__ ylo,
                     float* __restrict__ yf,
                     int OPD, int OPRX, int po, long sstride)
{
    constexpr int MWAVES = COUT / (16 * MTW);
    constexpr int RPB = 4 / MWAVES;
    constexpr int KN = (CIN * 2) / KSPLIT;
    constexpr int MT = COUT >> 4;            // fragment-major m count
    constexpr int SSTEP = MT * 512;          // shorts per s-step in frag layout

    int bx = blockIdx.x;
    const int ks = (KSPLIT > 1) ? (bx % KSPLIT) : 0;
    const int rowblk = (KSPLIT > 1) ? (bx / KSPLIT) : bx;
    const int lane = (int)threadIdx.x & 63, w = (int)threadIdx.x >> 6;
    const int mi = (MWAVES == 4) ? w : 0;
    const int ri = (MWAVES == 4) ? 0 : w;
    const int rowid = rowblk * RPB + ri;
    const int n16 = lane & 15, quad = lane >> 4;

    int b, od, oh, ow;
    if (OWHALF) {
        constexpr int NOH = DOUT / 2;
        const int ohb = rowid % NOH; int t = rowid / NOH;
        od = t % DOUT; b = t / DOUT;
        oh = ohb * 2 + (n16 >> 3);
        ow = n16 & 7;
    } else {
        const int owt = rowid % OWT; int t = rowid / OWT;
        oh = t % DOUT; t /= DOUT;
        od = t % DOUT; b = t / DOUT;
        ow = owt * 16 + n16;
    }

    const int co0 = mi * (MTW * 16);

    f32x4 acc[MTW];
    #pragma unroll
    for (int mt = 0; mt < MTW; ++mt)
        #pragma unroll
        for (int r = 0; r < 4; ++r) {
            int co = co0 + mt * 16 + quad * 4 + r;
            acc[mt][r] = (ks == 0) ? bias[co] : 0.0f;
        }

    const int sg0 = ks * KN;
    const long chs = (long)PD * PD * PRX;
    long off = ((long)(b * CIN + (sg0 >> 1)) * PD + (2 * od + (quad >> 1))) * PD * PRX
             + (long)(2 * oh + (quad & 1) * 2) * PRX + 2 * ow;
    const unsigned short* phi = xhi + off;
    const unsigned short* plo = xlo + off;
    const long incA = 2L * PD * PRX;
    const long incB = chs - 2L * PD * PRX;

    // fragment-major: (s, m) block at ((s*MT + m)*64 + lane)*8
    const short* ph = Whi + (((long)sg0 * MT + mi * MTW) * 64 + lane) * 8;
    const short* pl = Wlo + (((long)sg0 * MT + mi * MTW) * 64 + lane) * 8;

    #pragma unroll 2
    for (int s = 0; s < KN; ++s) {
        u16x4u h0 = *(const u16x4u*)phi;
        u16x4u h1 = *(const u16x4u*)(phi + PRX);
        u16x4u l0 = *(const u16x4u*)plo;
        u16x4u l1 = *(const u16x4u*)(plo + PRX);
        bf16x8 bhi = pack_b(h0, h1);
        bf16x8 blo = pack_b(l0, l1);
        #pragma unroll
        for (int mt = 0; mt < MTW; ++mt) {
            bf16x8 ah = *(const bf16x8*)(ph + mt * 512);
            bf16x8 al = *(const bf16x8*)(pl + mt * 512);
            acc[mt] = __builtin_amdgcn_mfma_f32_16x16x32_bf16(ah, bhi, acc[mt], 0, 0, 0);
            acc[mt] = __builtin_amdgcn_mfma_f32_16x16x32_bf16(ah, blo, acc[mt], 0, 0, 0);
            acc[mt] = __builtin_amdgcn_mfma_f32_16x16x32_bf16(al, bhi, acc[mt], 0, 0, 0);
        }
        long inc = (s & 1) ? incB : incA;
        phi += inc; plo += inc;
        ph += SSTEP; pl += SSTEP;
    }

    if (OUTSPLIT) {
        #pragma unroll
        for (int mt = 0; mt < MTW; ++mt)
            #pragma unroll
            for (int r = 0; r < 4; ++r) {
                int co = co0 + mt * 16 + quad * 4 + r;
                float v = fmaxf(acc[mt][r], 0.0f);
                unsigned short h, l;
                split_bf16(v, h, l);
                long o = (((long)(b * COUT + co) * OPD + od + po) * OPD + oh + po) * OPRX
                       + ow + po;
                yhi[o] = h; ylo[o] = l;
            }
    } else {
        #pragma unroll
        for (int mt = 0; mt < MTW; ++mt)
            #pragma unroll
            for (int r = 0; r < 4; ++r) {
                int co = co0 + mt * 16 + quad * 4 + r;
                long o = (long)ks * sstride
                       + (((long)(b * COUT + co) * OPD + od) * OPD + oh) * OPRX + ow;
                yf[o] = acc[mt][r];
            }
    }
}

__global__ __launch_bounds__(256)
void combine4_relu(const float* __restrict__ p, float* __restrict__ y, long N, long ss)
{
    long idx = (long)blockIdx.x * blockDim.x + threadIdx.x;
    if (idx >= N) return;
    float v = p[idx] + p[idx + ss] + p[idx + 2 * ss] + p[idx + 3 * ss];
    y[idx] = fmaxf(v, 0.0f);
}

// ---------------- 1x1 conv (fp32 exact) ----------------
__global__ __launch_bounds__(128)
void conv1x1_b(const float* __restrict__ x, const float* __restrict__ w,
               const float* __restrict__ bias, float* __restrict__ y)
{
    const int co = blockIdx.x & 255, b = blockIdx.x >> 8;
    const int s4 = (int)threadIdx.x * 4;
    const float* xb = x + (long)b * 256 * 512 + s4;
    const float* wr = w + (long)co * 256;      // uniform -> s_load
    float bv = bias[co];
    float4 acc = {bv, bv, bv, bv};
    for (int ci = 0; ci < 256; ++ci) {
        float wv = wr[ci];
        float4 xv = *(const float4*)(xb + (long)ci * 512);
        acc.x = fmaf(xv.x, wv, acc.x); acc.y = fmaf(xv.y, wv, acc.y);
        acc.z = fmaf(xv.z, wv, acc.z); acc.w = fmaf(xv.w, wv, acc.w);
    }
    *(float4*)(y + (long)(b * 256 + co) * 512 + s4) = acc;
}

// ---------------- VQ (fp32 exact) ----------------
__global__ void codenorm_kernel(const float* __restrict__ cb, float* __restrict__ norms)
{
    int k = blockIdx.x;
    int lane = threadIdx.x;
    float s = 0.0f;
    const float* row = cb + (long)k * 256;
    for (int d = lane; d < 256; d += 64) { float v = row[d]; s = fmaf(v, v, s); }
    for (int off = 32; off > 0; off >>= 1) s += __shfl_down(s, off);
    if (lane == 0) norms[k] = s;
}

// cbT[d*1024 + k] = cb[k*256 + d]  (fp32 copy -> values unchanged)
__global__ __launch_bounds__(256)
void transpose_cb(const float* __restrict__ cb, float* __restrict__ cbT)
{
    int idx = blockIdx.x * 256 + (int)threadIdx.x;    // 0..262143
    int d = idx & 255, k = idx >> 8;
    cbT[(long)d * 1024 + k] = cb[(long)k * 256 + d];
}

// R24: 4 rows/block (grid 256), coalesced cbT float4 loads (codes 4t..4t+3),
// rows staged in LDS. Bit-identical to the original per-row kernel.
__global__ __launch_bounds__(256)
void vq_kernel4(const float* __restrict__ lat, const float* __restrict__ cb,
                const float* __restrict__ cbT, const float* __restrict__ norms,
                unsigned short* __restrict__ q, float* __restrict__ idx_out)
{
    __shared__ __align__(16) float rows[4][256];
    __shared__ float s_best[4][256];
    __shared__ int   s_bidx[4][256];
    const int r0 = blockIdx.x * 4;
    const int t = (int)threadIdx.x;

    #pragma unroll
    for (int j = 0; j < 4; ++j)
        rows[j][t] = lat[(long)(r0 + j) * 256 + t];
    __syncthreads();

    // latn per row -- identical float4 fmaf chain to the original
    float latn[4];
    #pragma unroll
    for (int j = 0; j < 4; ++j) {
        const float4* rowv = (const float4*)rows[j];
        float a = 0.0f;
        #pragma unroll 4
        for (int d = 0; d < 64; ++d) {
            float4 rv = rowv[d];
            a = fmaf(rv.x, rv.x, a); a = fmaf(rv.y, rv.y, a);
            a = fmaf(rv.z, rv.z, a); a = fmaf(rv.w, rv.w, a);
        }
        latn[j] = a;
    }

    // codes 4t..4t+3; dot[j][c] accumulates d = 0..255 sequentially (same
    // chain as the original scalar loop)
    float dot[4][4] = {};
    const float* ct = cbT + t * 4;
    #pragma unroll 4
    for (int d = 0; d < 256; ++d) {
        float4 c4 = *(const float4*)(ct + (long)d * 1024);
        #pragma unroll
        for (int j = 0; j < 4; ++j) {
            float rv = rows[j][d];
            dot[j][0] = fmaf(rv, c4.x, dot[j][0]);
            dot[j][1] = fmaf(rv, c4.y, dot[j][1]);
            dot[j][2] = fmaf(rv, c4.z, dot[j][2]);
            dot[j][3] = fmaf(rv, c4.w, dot[j][3]);
        }
    }

    float4 nv = *(const float4*)(norms + t * 4);
    float nr[4] = {nv.x, nv.y, nv.z, nv.w};

    #pragma unroll
    for (int j = 0; j < 4; ++j) {
        float best = FLT_MAX;
        int bidx = 0x7fffffff;
        #pragma unroll
        for (int c = 0; c < 4; ++c) {
            float sc = latn[j] - 2.0f * dot[j][c] + nr[c];
            int k = t * 4 + c;
            if (sc < best || (sc == best && k < bidx)) { best = sc; bidx = k; }
        }
        s_best[j][t] = best; s_bidx[j][t] = bidx;
    }
    __syncthreads();
    for (int off = 128; off > 0; off >>= 1) {
        if (t < off) {
            #pragma unroll
            for (int j = 0; j < 4; ++j) {
                float o = s_best[j][t + off]; int oi = s_bidx[j][t + off];
                if (o < s_best[j][t] || (o == s_best[j][t] && oi < s_bidx[j][t])) {
                    s_best[j][t] = o; s_bidx[j][t] = oi;
                }
            }
        }
        __syncthreads();
    }

    #pragma unroll
    for (int j = 0; j < 4; ++j) {
        const int bk = s_bidx[j][0];
        const int r = r0 + j;
        const int b = r >> 9, n = r & 511;
        const int zz = n >> 6, yy = (n >> 3) & 7, xx = n & 7;
        q[(long)(b * 256 + t) * 1000 + ((long)(zz + 1) * 10 + (yy + 1)) * 10 + (xx + 1)]
            = f32_to_bf16(cb[(long)bk * 256 + t]);
    }
    if (t == 0) {
        #pragma unroll
        for (int j = 0; j < 4; ++j)
            idx_out[r0 + j] = (float)s_bidx[j][0];
    }
}

// ---------------- decoder: MFMA implicit-GEMM ConvTranspose ----------------
// xflip=0: B slot a <-> x offset (1-ax), kw=(1-px)+2*ax (old cube kernel).
// xflip=1: B slot a <-> x offset ax,     kw=(1-px)+2*(1-ax) (dword-pair kernel).
__global__ __launch_bounds__(256)
void prep_convt_w(const float* __restrict__ w, short* __restrict__ Ap,
                  int Cin, int Cout, int xflip)
{
    const int K = Cin * 8;
    long total = 8L * Cout * K;
    long idx = (long)blockIdx.x * blockDim.x + threadIdx.x;
    if (idx >= total) return;
    int k = (int)(idx % K);
    int co = (int)((idx / K) % Cout);
    int p = (int)(idx / ((long)K * Cout));
    int ci = k >> 3, a = k & 7;
    int az = (a >> 2) & 1, ay = (a >> 1) & 1, ax = a & 1;
    int pz = p >> 2, py = (p >> 1) & 1, px = p & 1;
    int axw = xflip ? (1 - ax) : ax;
    int kd = (1 - pz) + 2 * az, kh = (1 - py) + 2 * ay, kw = (1 - px) + 2 * axw;
    float v = w[((long)ci * Cout + co) * 64 + kd * 16 + kh * 4 + kw];
    Ap[idx] = (short)f32_to_bf16(v);
}

// Fragment-major layout for the LDS-staged v2 kernel:
//   ApN[((p*MG + mg)*nsteps + s)*2048 + cb*512 + l*8 + kk]
__global__ __launch_bounds__(256)
void prep_convt_w_frag(const float* __restrict__ w, short* __restrict__ Ap,
                       int Cin, int Cout, int xflip)
{
    const int MG = Cout >> 6;
    const int nsteps = Cin >> 2;             // (Cin*8)/32
    long total = 8L * MG * nsteps * 2048;
    long idx = (long)blockIdx.x * blockDim.x + threadIdx.x;
    if (idx >= total) return;
    int kk = (int)(idx & 7); long r = idx >> 3;
    int l  = (int)(r & 63);  r >>= 6;
    int cb = (int)(r & 3);   r >>= 2;
    int s  = (int)(r % nsteps); r /= nsteps;
    int mg = (int)(r % MG);
    int p  = (int)(r / MG);

    int n16 = l & 15, quad = l >> 4;
    int korig = s * 32 + quad * 8 + kk;
    int co = mg * 64 + cb * 16 + n16;
    int ci = korig >> 3, a = korig & 7;
    int az = (a >> 2) & 1, ay = (a >> 1) & 1, ax = a & 1;
    int pz = p >> 2, py = (p >> 1) & 1, px = p & 1;
    int axw = xflip ? (1 - ax) : ax;
    int kd = (1 - pz) + 2 * az, kh = (1 - py) + 2 * ay, kw = (1 - px) + 2 * axw;
    float v = w[((long)ci * Cout + co) * 64 + kd * 16 + kh * 4 + kw];
    Ap[idx] = (short)f32_to_bf16(v);
}

// Old cube-N layout (kept for dec1, DIN=8): round-0 body.
template <int CIN, int COUT, int DIN, int OPAD, typename OutT>
__global__ __launch_bounds__(256)
void convt_mfma(const unsigned short* __restrict__ Xp, const short* __restrict__ Ap,
                const float* __restrict__ bias, OutT* __restrict__ Y)
{
    constexpr int PD = DIN + 2;
    constexpr int PD3 = PD * PD * PD;
    constexpr int T = DIN >> 2;
    constexpr int NT = T * T * T;
    constexpr int SLAB = NT / 8;
    constexpr int OPD = 2 * DIN + 2 * OPAD;
    constexpr int K = CIN * 8;
    constexpr int MG = COUT >> 6;
    constexpr int nsteps = K >> 5;

    int bx = blockIdx.x;
    const int xcd = bx & 7;
    int local = bx >> 3;
    const int px = local & 1; local >>= 1;
    const int mg = local % MG; local /= MG;
    const int ntin = local % SLAB;
    const int pzy = local / SLAB;            // 0..3
    const int pz = pzy >> 1, py = pzy & 1;
    const int p = pz * 4 + py * 2 + px;
    const int nt = xcd * SLAB + ntin;

    const int lane = threadIdx.x & 63, wave = threadIdx.x >> 6;
    const int n16 = lane & 15, quad = lane >> 4;

    const int tx = nt % T, ty = (nt / T) % T, tz = nt / (T * T);
    const int mz = tz * 4 + wave, my = ty * 4 + (n16 >> 2), mx = tx * 4 + (n16 & 3);
    const int sp = ((mz + pz) * PD + (my + py)) * PD + (mx + px);

    const unsigned short* xq = Xp + (long)quad * PD3 + sp;

    const int cobase = mg * 64;
    const short* ap0 = Ap + ((long)p * COUT + cobase + n16) * K + quad * 8;

    f32x4 acc[4];
    #pragma unroll
    for (int cb = 0; cb < 4; ++cb) {
        const float* bp = bias + cobase + cb * 16 + quad * 4;
        acc[cb][0] = bp[0]; acc[cb][1] = bp[1]; acc[cb][2] = bp[2]; acc[cb][3] = bp[3];
    }

    #pragma unroll 4
    for (int s = 0; s < nsteps; ++s) {
        const unsigned short* xs = xq + (long)s * 4 * PD3;
        bf16x8 bf;
        bf[0] = (short)xs[(PD + 1) * PD + 1];
        bf[1] = (short)xs[(PD + 1) * PD];
        bf[2] = (short)xs[PD * PD + 1];
        bf[3] = (short)xs[PD * PD];
        bf[4] = (short)xs[PD + 1];
        bf[5] = (short)xs[PD];
        bf[6] = (short)xs[1];
        bf[7] = (short)xs[0];
        #pragma unroll
        for (int cb = 0; cb < 4; ++cb) {
            bf16x8 af = *(const bf16x8*)(ap0 + (long)cb * 16 * K + s * 32);
            acc[cb] = __builtin_amdgcn_mfma_f32_16x16x32_bf16(af, bf, acc[cb], 0, 0, 0);
        }
    }

    const int opz = 2 * mz + pz + OPAD, opy = 2 * my + py + OPAD, opx = 2 * mx + px + OPAD;
    const long spo = ((long)opz * OPD + opy) * OPD + opx;
    #pragma unroll
    for (int cb = 0; cb < 4; ++cb) {
        #pragma unroll
        for (int r = 0; r < 4; ++r) {
            int co = cobase + cb * 16 + quad * 4 + r;
            float v = fmaxf(acc[cb][r], 0.0f);
            store_act(Y + (long)co * OPD * OPD * OPD + spo, v);
        }
    }
}

// Dword-pair B-gather (dec2/dec3), R20: A staged through LDS (unchanged).
template <int CIN, int COUT, int DIN, int OPAD, int MXP, int MYP, typename OutT>
__global__ __launch_bounds__(256)
void convt_mfma_v2(const unsigned short* __restrict__ Xp, const short* __restrict__ Ap,
                   const float* __restrict__ bias, OutT* __restrict__ Y)
{
    constexpr int PD = DIN + 2;
    constexpr int PD3 = PD * PD * PD;
    constexpr int OPD = 2 * DIN + 2 * OPAD;
    constexpr int K = CIN * 8;
    constexpr int MG = COUT >> 6;
    constexpr int nsteps = K >> 5;
    static_assert(nsteps >= 2, "need at least 2 K-steps");
    constexpr int MXT = DIN / (16 * MXP);
    constexpr int MYT = DIN / (4 * MYP);
    constexpr int MZS = DIN / 8;             // mz per XCD slab
    constexpr int TPE = MXP * MYP;           // tiles per wave (one of MXP/MYP is 1)

    int bx = blockIdx.x;
    const int xcd = bx & 7;
    int local = bx >> 3;
    const int px = local & 1; local >>= 1;
    const int py = local & 1; local >>= 1;
    const int mg = local % MG; local /= MG;
    const int mxt = local % MXT; local /= MXT;
    const int myt = local % MYT; local /= MYT;
    const int pz = local & 1; local >>= 1;
    const int mzin = local;                  // 0..MZS-1
    const int mz = xcd * MZS + mzin;
    const int p = pz * 4 + py * 2 + px;

    const int lane = threadIdx.x & 63, wave = threadIdx.x >> 6;
    const int n16 = lane & 15, quad = lane >> 4;

    const int mx0 = mxt * (16 * MXP) + n16;
    const int my0 = myt * (4 * MYP) + wave * MYP;
    const int baseX = mx0 & ~1;
    const int sh = 16 * ((n16 & 1) + px);    // 0, 16, or 32
    const long sp = ((long)(mz + pz) * PD + (my0 + py)) * PD + baseX;

    const unsigned short* xq = Xp + (long)quad * PD3 + sp;

    // fragment-major weight tiles: 2048 shorts (4KB) per (p,mg,s)
    const short* ApT = Ap + (((long)p * MG + mg) * nsteps) * 2048;

    __shared__ short Abuf[2][2048];          // 8KB double buffer

    f32x4 acc[TPE][4];
    #pragma unroll
    for (int t = 0; t < TPE; ++t)
        #pragma unroll
        for (int cb = 0; cb < 4; ++cb) {
            const float* bp = bias + (mg * 64) + cb * 16 + quad * 4;
            acc[t][cb][0] = bp[0]; acc[t][cb][1] = bp[1];
            acc[t][cb][2] = bp[2]; acc[t][cb][3] = bp[3];
        }

    constexpr int rowoff[4] = { (PD + 1) * PD, PD * PD, PD, 0 };
    union Frag { unsigned u[4]; bf16x8 b; };

    const int chunkoff = wave * 512 + lane * 8;   // this thread's 16B of the 4KB tile

    // prologue: stage step 0
    {
        bf16x8 a0 = *(const bf16x8*)(ApT + chunkoff);
        *(bf16x8*)(&Abuf[0][chunkoff]) = a0;
    }
    __syncthreads();

    #pragma unroll 1
    for (int s = 0; s < nsteps; ++s) {
        const int cur = s & 1;
        bf16x8 anext;
        const bool more = (s + 1 < nsteps);
        if (more)
            anext = *(const bf16x8*)(ApT + (long)(s + 1) * 2048 + chunkoff);

        // X loads (plain C, raw staging)
        const unsigned short* xs = xq + (long)s * 4 * PD3;
        unsigned long long xr[TPE][4];
        #pragma unroll
        for (int t = 0; t < TPE; ++t) {
            const int toff = (MXP > 1) ? t * 16 : t * PD;
            #pragma unroll
            for (int j = 0; j < 4; ++j) {
                union { u16x4u v; unsigned long long u; } ld;
                ld.v = *(const u16x4u*)(xs + toff + rowoff[j]);
                xr[t][j] = ld.u;
            }
        }

        // A fragments from LDS (l = quad*16 + n16 == lane)
        bf16x8 af[4];
        #pragma unroll
        for (int cb = 0; cb < 4; ++cb)
            af[cb] = *(const bf16x8*)(&Abuf[cur][cb * 512 + lane * 8]);

        #pragma unroll
        for (int t = 0; t < TPE; ++t) {
            Frag fr;
            #pragma unroll
            for (int j = 0; j < 4; ++j)
                fr.u[j] = (unsigned)(xr[t][j] >> sh);
            #pragma unroll
            for (int cb = 0; cb < 4; ++cb)
                acc[t][cb] = __builtin_amdgcn_mfma_f32_16x16x32_bf16(af[cb], fr.b,
                                                                     acc[t][cb], 0, 0, 0);
        }

        if (more)
            *(bf16x8*)(&Abuf[cur ^ 1][chunkoff]) = anext;
        __syncthreads();
    }

    const int opz = 2 * mz + pz + OPAD;
    #pragma unroll
    for (int t = 0; t < TPE; ++t) {
        const int opx = 2 * (mx0 + ((MXP > 1) ? t * 16 : 0)) + px + OPAD;
        const int opy = 2 * (my0 + ((MYP > 1) ? t : 0)) + py + OPAD;
        const long spo = ((long)opz * OPD + opy) * OPD + opx;
        #pragma unroll
        for (int cb = 0; cb < 4; ++cb) {
            #pragma unroll
            for (int r = 0; r < 4; ++r) {
                int co = (mg * 64) + cb * 16 + quad * 4 + r;
                float v = fmaxf(acc[t][cb][r], 0.0f);
                store_act(Y + (long)co * OPD * OPD * OPD + spo, v);
            }
        }
    }
}

// ---------------- dec4 as MFMA GEMM, R28: merged ci-steps ----------------
// Fragment-major: Aw[(s*64 + lane)*8 + kk] (unchanged from R23).
__global__ __launch_bounds__(256)
void prep_dec4A_frag(const float* __restrict__ w, short* __restrict__ Aw)
{
    int idx = blockIdx.x * 256 + (int)threadIdx.x;    // 0..65535
    int kk = idx & 7;
    int l  = (idx >> 3) & 63;
    int s  = idx >> 9;                                // 0..127
    int n16 = l & 15, quad = l >> 4;
    int k = s * 32 + quad * 8 + kk;
    float v = (n16 < 3) ? w[n16 * 4096 + k] : 0.0f;
    Aw[idx] = (short)f32_to_bf16(v);
}

// R28: one step per ci (64 steps, half the barrier/drain rounds). Stage
// 28 rows (4z x 7y) per step; per step run both z-half MFMA groups
// (af(2S) with rows 0..13, then af(2S+1) with rows 14..27) -- exactly the
// old s=2S, s=2S+1 sequence => bit-identical. Stride 72: read windows for
// rows {base,+2,+7,+9} start at banks {0,16,24,8}+const (2/bank, free);
// staging wave-passes write 64 consecutive words (free) and load 4
// coalesced lines. Offsets kept as ints (no pointer arrays).
__global__ __launch_bounds__(256)
void conv_dec4_mfma(const float* __restrict__ d3, const short* __restrict__ Aw,
                    const float* __restrict__ bias, float* __restrict__ y)
{
    constexpr int D = 64, Dout = 61;
    constexpr int RS = 72;                 // row stride (words)
    int bx = blockIdx.x;
    const int slab = bx & 7;
    const int i = bx >> 3;                 // 0..127
    const int od = slab * 8 + (i >> 4);
    const int oh0 = (i & 15) * 4;          // covers oh0..oh0+3 (guard < 61)
    if (od >= Dout) return;                // uniform per block -> barriers safe
    const int tid = (int)threadIdx.x;
    const int lane = tid & 63, wave = tid >> 6;
    const int n16 = lane & 15, quad = lane >> 4;
    const int ow = wave * 16 + n16;

    // [dbuf][row 0..27][x 0..71]; words 64..71 per row uninitialized (only
    // consumed by discarded ow>=61 columns; reads reach word ow+3 <= 66)
    __shared__ float Xs[2][28][RS];
    float* xsb = &Xs[0][0][0];
    constexpr int BUFW = 28 * RS;          // words per buffer

    f32x4 acc[4];
    #pragma unroll
    for (int j = 0; j < 4; ++j)
        #pragma unroll
        for (int r = 0; r < 4; ++r) {
            int co = quad * 4 + r;
            acc[j][r] = (co < 3) ? bias[co] : 0.0f;
        }

    const int kd0 = quad >> 1;
    const int kh0 = (quad & 1) * 2;

    // strided staging: thread t (t<224) owns words g = t + 224*j, j=0..7 of
    // the 1792-word (28 rows x 64) tile. row = g/64 -> (szi = row/7 in 0..3,
    // syi = row%7); global z = od + szi, y = min(oh0+syi, 63), x = g%64.
    const bool sact = (tid < 224);
    int goff[8];                           // global word offset (ci-invariant)
    int loff[8];                           // LDS word offset within a buffer
    #pragma unroll
    for (int j = 0; j < 8; ++j) {
        const int g = tid + 224 * j;
        const int row = g >> 6, xx = g & 63;
        const int szi = row / 7, syi = row % 7;
        goff[j] = ((od + szi) * D + min(oh0 + syi, D - 1)) * D + xx;
        loff[j] = row * RS + xx;
    }
    // ci step offset: ci * 64 * 4096 words
    auto choff = [](int S) { return (long)S * D * D * D; };

    // prologue: stage step 0
    if (sact) {
        #pragma unroll
        for (int j = 0; j < 8; ++j)
            xsb[loff[j]] = d3[goff[j]];
    }
    __syncthreads();

    #pragma unroll 1
    for (int S = 0; S < 64; ++S) {
        const int cur = S & 1;
        const bool more = (S + 1 < 64);
        float nv[8];
        if (more && sact) {
            const float* src = d3 + choff(S + 1);
            #pragma unroll
            for (int j = 0; j < 8; ++j)
                nv[j] = src[goff[j]];
        }

        #pragma unroll
        for (int h = 0; h < 2; ++h) {
            bf16x8 af = *(const bf16x8*)(Aw + ((long)(2 * S + h) * 64 + lane) * 8);
            unsigned p0[5], p1[5];
            #pragma unroll
            for (int r = 0; r < 5; ++r) {
                const int row = 14 * h + kd0 * 7 + kh0 + r;
                f32x4u v = *(const f32x4u*)(xsb + cur * BUFW + row * RS + ow);
                p0[r] = (__float_as_uint(v[0]) >> 16) | (__float_as_uint(v[1]) & 0xffff0000u);
                p1[r] = (__float_as_uint(v[2]) >> 16) | (__float_as_uint(v[3]) & 0xffff0000u);
            }
            #pragma unroll
            for (int j = 0; j < 4; ++j) {
                union { unsigned u[4]; bf16x8 b; } fr;
                fr.u[0] = p0[j];     fr.u[1] = p1[j];
                fr.u[2] = p0[j + 1]; fr.u[3] = p1[j + 1];
                acc[j] = __builtin_amdgcn_mfma_f32_16x16x32_bf16(af, fr.b, acc[j], 0, 0, 0);
            }
        }

        if (more && sact) {
            float* dst = xsb + (cur ^ 1) * BUFW;
            #pragma unroll
            for (int j = 0; j < 8; ++j)
                dst[loff[j]] = nv[j];
        }
        __syncthreads();
    }

    if (ow < Dout && quad == 0) {
        #pragma unroll
        for (int j = 0; j < 4; ++j) {
            const int oh = oh0 + j;
            if (oh >= Dout) continue;
            #pragma unroll
            for (int r = 0; r < 3; ++r)
                y[((long)(r * Dout + od) * Dout + oh) * Dout + ow] = tanhf(acc[j][r]);
        }
    }
}

extern "C" void kernel_launch(void* const* d_in, const int* in_sizes, int n_in,
                              void* d_out, int out_size, void* d_ws, size_t ws_size,
                              hipStream_t stream)
{
    const float* x        = (const float*)d_in[0];
    const float* enc_w1   = (const float*)d_in[1];
    const float* enc_b1   = (const float*)d_in[2];
    const float* enc_w2   = (const float*)d_in[3];
    const float* enc_b2   = (const float*)d_in[4];
    const float* enc_w3   = (const float*)d_in[5];
    const float* enc_b3   = (const float*)d_in[6];
    const float* enc_w4   = (const float*)d_in[7];
    const float* enc_b4   = (const float*)d_in[8];
    const float* codebook = (const float*)d_in[9];
    const float* dec_w1   = (const float*)d_in[10];
    const float* dec_b1   = (const float*)d_in[11];
    const float* dec_w2   = (const float*)d_in[12];
    const float* dec_b2   = (const float*)d_in[13];
    const float* dec_w3   = (const float*)d_in[14];
    const float* dec_b3   = (const float*)d_in[15];
    const float* dec_w4   = (const float*)d_in[16];
    const float* dec_b4   = (const float*)d_in[17];

    float* out = (float*)d_out;
    float* idx_out = out + 2L * 3 * 61 * 61 * 61;

    // ---- workspace (byte offsets) ----
    char* wsb = (char*)d_ws;
    float*          cn   = (float*)wsb;                        //      4,096
    unsigned short* qp   = (unsigned short*)(wsb + 4096);      //  1,024,000
    short*          Ap1  = (short*)(wsb + 1028096);            //  8,388,608
    short*          Ap2  = (short*)(wsb + 9416704);            //  4,194,304
    short*          Ap3  = (short*)(wsb + 13611008);           //  1,048,576
    short*          Aw4  = (short*)(wsb + 14659584);           //    131,072
    short*          W1hi = (short*)(wsb + 14790656);           //     24,576
    short*          W1lo = (short*)(wsb + 14815232);           //     24,576
    short*          W2hi = (short*)(wsb + 14839808);           //  1,048,576
    short*          W2lo = (short*)(wsb + 15888384);           //  1,048,576
    short*          W3hi = (short*)(wsb + 16936960);           //  4,194,304
    short*          W3lo = (short*)(wsb + 21131264);           //  4,194,304
    char* arena = wsb + 25325568;
    // encoder phase:
    unsigned short* xphi = (unsigned short*)arena;                    // (2,3,66,66,68)
    unsigned short* xplo = (unsigned short*)(arena + 3554496);
    unsigned short* h1hi = (unsigned short*)(arena + 7108992);        // (2,64,34,34,36)
    unsigned short* h1lo = (unsigned short*)(arena + 17762688);
    unsigned short* h2hi = (unsigned short*)(arena + 28416384);       // (2,128,18,18,20)
    unsigned short* h2lo = (unsigned short*)(arena + 31734144);
    float*          pp3  = (float*)(arena + 35051904);                // 4x(2,256,8^3)
    float*          h3   = (float*)(arena + 39246208);                // (2,256,512)
    float*          lat  = (float*)(arena + 40294784);                // (2,256,512)
    // decoder phase (after VQ; overlaps encoder buffers):
    unsigned short* d1 = (unsigned short*)arena;                      // (256,18^3) bf16
    unsigned short* d2 = (unsigned short*)(arena + 2985984);          // (128,34^3) bf16
    float*          d3 = (float*)(arena + 13047808);                  // (64,64^3) fp32
    // arena peak 80.2 MB -> ws used 105.5 MB; cbT appended below:
    float*          cbT = (float*)(wsb + 105482240);                  // 1,048,576
    // total 106.5 MB (< 112.2 MB proven in R0)

    dim3 blk(256);
    auto nblk = [](long n) { return dim3((unsigned)((n + 255) / 256)); };

    // ---- weight prep ----
    prep_convt_w<<<nblk(8L * 256 * 2048), blk, 0, stream>>>(dec_w1, Ap1, 256, 256, 0);
    prep_convt_w_frag<<<nblk(8L * 128 * 2048), blk, 0, stream>>>(dec_w2, Ap2, 256, 128, 1);
    prep_convt_w_frag<<<nblk(8L * 64 * 1024), blk, 0, stream>>>(dec_w3, Ap3, 128, 64, 1);
    prep_dec4A_frag<<<dim3(256), blk, 0, stream>>>(dec_w4, Aw4);
    prep_split_w<<<nblk(12288), blk, 0, stream>>>(enc_w1, W1hi, W1lo, 12288);
    prep_split_w_frag<<<nblk(524288), blk, 0, stream>>>(enc_w2, W2hi, W2lo, 64, 128);
    prep_split_w_frag<<<nblk(2097152), blk, 0, stream>>>(enc_w3, W3hi, W3lo, 128, 256);
    transpose_cb<<<dim3(1024), blk, 0, stream>>>(codebook, cbT);

    // ---- encoder (MFMA, bf16-pair) ----
    pad_input_split<<<nblk(6L * 66 * 66 * 68), blk, 0, stream>>>(x, xphi, xplo);
    zero_halo_ps<<<nblk(128L * 34 * 34 * 36), blk, 0, stream>>>(h1hi, 128, 34, 36);
    zero_halo_ps<<<nblk(128L * 34 * 34 * 36), blk, 0, stream>>>(h1lo, 128, 34, 36);
    conv_s2_mfma<3, 64, 32, 66, 68, 4, 2, 0, 1, 1><<<dim3(1024), blk, 0, stream>>>(
        xphi, xplo, W1hi, W1lo, enc_b1, h1hi, h1lo, nullptr, 34, 36, 1, 0);
    zero_halo_ps<<<nblk(256L * 18 * 18 * 20), blk, 0, stream>>>(h2hi, 256, 18, 20);
    zero_halo_ps<<<nblk(256L * 18 * 18 * 20), blk, 0, stream>>>(h2lo, 256, 18, 20);
    conv_s2_mfma_fd<64, 128, 16, 34, 36, 2, 1, 0, 1, 1><<<dim3(512), blk, 0, stream>>>(
        h1hi, h1lo, W2hi, W2lo, enc_b2, h2hi, h2lo, nullptr, 18, 20, 1, 0);
    conv_s2_mfma_fd<128, 256, 8, 18, 20, 4, 1, 1, 4, 0><<<dim3(256), blk, 0, stream>>>(
        h2hi, h2lo, W3hi, W3lo, enc_b3, nullptr, nullptr, pp3, 8, 8, 0, 262144);
    combine4_relu<<<nblk(262144), blk, 0, stream>>>(pp3, h3, 262144, 262144);
    conv1x1_b<<<dim3(512), dim3(128), 0, stream>>>(h3, enc_w4, enc_b4, lat);

    // ---- VQ (fp32 exact) ----
    codenorm_kernel<<<dim3(1024), dim3(64), 0, stream>>>(codebook, cn);
    zero_halo_t<unsigned short><<<nblk(512L * 10 * 10 * 10), blk, 0, stream>>>(qp, 512, 10);
    vq_kernel4<<<dim3(256), blk, 0, stream>>>(lat, codebook, cbT, cn, qp, idx_out);

    // ---- decoder halos ----
    zero_halo_t<unsigned short><<<nblk(256L * 18 * 18 * 18), blk, 0, stream>>>(d1, 256, 18);
    zero_halo_t<unsigned short><<<nblk(128L * 34 * 34 * 34), blk, 0, stream>>>(d2, 128, 34);

    // ---- decoder (MFMA) per batch ----
    for (int b = 0; b < 2; ++b) {
        const unsigned short* qb = qp + (long)b * 256 * 1000;
        float* outb = out + (long)b * 3 * 226981;
        // dec1 (DIN=8, old layout): grid = 8*2*4*1*4 = 256
        convt_mfma<256, 256, 8, 1, unsigned short><<<dim3(256), blk, 0, stream>>>(
            qb, Ap1, dec_b1, d1);
        // dec2 (v2, MXP=1 MYP=2): grid = 8 * (2*2*2*1*2*2*2) = 512
        convt_mfma_v2<256, 128, 16, 1, 1, 2, unsigned short><<<dim3(512), blk, 0, stream>>>(
            d1, Ap2, dec_b2, d2);
        // dec3 (v2, MXP=2 MYP=1): grid = 8 * (2*2*1*1*8*2*4) = 2048
        convt_mfma_v2<128, 64, 32, 0, 2, 1, float><<<dim3(2048), blk, 0, stream>>>(
            d2, Ap3, dec_b3, d3);
        conv_dec4_mfma<<<dim3(8 * 8 * 16), blk, 0, stream>>>(d3, Aw4, dec_b4, outb);
    }
}

// Round 12
// 897.048 us; speedup vs baseline: 1.6258x; 1.0271x over previous
//
#include <hip/hip_runtime.h>
#include <cfloat>
#include <cmath>

// ---------------------------------------------------------------------------
// Round 29: apply the R28 step-merge to convt_mfma_v2 (dec2/dec3).
// R28 post-mortem: dec4 merge confirmed (942 -> 921us). Top-5: convt_mfma_v2
// (dec3) 89us x2, MfmaUtil 15%, VALU 14%, HBM 12%, occupancy 41% -- ~70% of
// cycles in the 32-step {8 scattered X loads + LDS A read + 8 MFMA +
// __syncthreads(vmcnt(0) drain)} chain, same disease R28 fixed in dec4.
// Fix: 2 K-steps per barrier phase: Abuf[2][2][2048] (16KB), stage two 4KB
// step tiles per phase, issue both steps' X loads up front (2x MLP), MFMA
// step 2ph then 2ph+1, one barrier. Phases: dec3 32->16, dec2 64->32.
// Per-acc MFMA sequence identical to the old s-order => bit-identical.
// Everything else unchanged from R28.
// ---------------------------------------------------------------------------

using f32x4  = __attribute__((ext_vector_type(4))) float;
using bf16x8 = __attribute__((ext_vector_type(8))) short;
typedef float f32x4u __attribute__((ext_vector_type(4), aligned(4)));
typedef unsigned short u16x4u __attribute__((ext_vector_type(4), aligned(4)));

__device__ __forceinline__ unsigned short f32_to_bf16(float f) {
    unsigned int u = __float_as_uint(f);
    u += 0x7fffu + ((u >> 16) & 1u);          // round-to-nearest-even
    return (unsigned short)(u >> 16);
}
__device__ __forceinline__ void split_bf16(float v, unsigned short& h, unsigned short& l) {
    h = f32_to_bf16(v);
    float hf = __uint_as_float((unsigned)h << 16);
    l = f32_to_bf16(v - hf);
}
__device__ __forceinline__ void store_act(float* p, float v) { *p = v; }
__device__ __forceinline__ void store_act(unsigned short* p, float v) { *p = f32_to_bf16(v); }

template <typename V>
__device__ __forceinline__ bf16x8 pack_b(V r0, V r1) {
    bf16x8 b;
    b[0] = (short)r0[0]; b[1] = (short)r0[1]; b[2] = (short)r0[2]; b[3] = (short)r0[3];
    b[4] = (short)r1[0]; b[5] = (short)r1[1]; b[6] = (short)r1[2]; b[7] = (short)r1[3];
    return b;
}

// ---------------- prep: weight hi/lo split (linear; enc1) ----------------
__global__ __launch_bounds__(256)
void prep_split_w(const float* __restrict__ w, short* __restrict__ whi,
                  short* __restrict__ wlo, long total)
{
    long idx = (long)blockIdx.x * blockDim.x + threadIdx.x;
    if (idx >= total) return;
    unsigned short h, l;
    split_bf16(w[idx], h, l);
    whi[idx] = (short)h; wlo[idx] = (short)l;
}

// Fragment-major hi/lo split for enc2/enc3:
//   whi[((s*MT + m)*64 + l)*8 + kk] = hi(w[co*K + korig])
__global__ __launch_bounds__(256)
void prep_split_w_frag(const float* __restrict__ w, short* __restrict__ whi,
                       short* __restrict__ wlo, int CIN, int COUT)
{
    const int K = CIN * 64;
    const int MT = COUT >> 4;
    long total = (long)COUT * K;
    long idx = (long)blockIdx.x * blockDim.x + threadIdx.x;
    if (idx >= total) return;
    int kk = (int)(idx & 7); long r = idx >> 3;
    int l  = (int)(r & 63);  r >>= 6;
    int m  = (int)(r % MT);
    int s  = (int)(r / MT);
    int n16 = l & 15, quad = l >> 4;
    int co = m * 16 + n16;
    int korig = s * 32 + quad * 8 + kk;
    unsigned short h, lo16;
    split_bf16(w[(long)co * K + korig], h, lo16);
    whi[idx] = (short)h; wlo[idx] = (short)lo16;
}

// ---------------- pad input -> hi/lo bf16 pitched planes --------------------
__global__ __launch_bounds__(256)
void pad_input_split(const float* __restrict__ x, unsigned short* __restrict__ xhi,
                     unsigned short* __restrict__ xlo)
{
    const int D = 64, PD = 66, PRX = 68, BC = 6;
    long total = (long)BC * PD * PD * PRX;
    long idx = (long)blockIdx.x * blockDim.x + threadIdx.x;
    if (idx >= total) return;
    int px = (int)(idx % PRX); long t = idx / PRX;
    int py = (int)(t % PD); t /= PD;
    int pz = (int)(t % PD); int c = (int)(t / PD);
    int ix = px - 1, iy = py - 1, iz = pz - 1;
    float v = 0.0f;
    if ((unsigned)ix < (unsigned)D && (unsigned)iy < (unsigned)D && (unsigned)iz < (unsigned)D)
        v = x[(((long)c * D + iz) * D + iy) * D + ix];
    unsigned short h, l;
    split_bf16(v, h, l);
    xhi[idx] = h; xlo[idx] = l;
}

__global__ __launch_bounds__(256)
void zero_halo_ps(unsigned short* __restrict__ p, int C, int PD, int PRX)
{
    long total = (long)C * PD * PD * PRX;
    long idx = (long)blockIdx.x * blockDim.x + threadIdx.x;
    if (idx >= total) return;
    int px = (int)(idx % PRX); long t = idx / PRX;
    int py = (int)(t % PD); t /= PD;
    int pz = (int)(t % PD);
    if (px == 0 || px >= PD - 1 || py == 0 || py == PD - 1 || pz == 0 || pz == PD - 1)
        p[idx] = 0;
}

template <typename T>
__global__ __launch_bounds__(256) void zero_halo_t(T* __restrict__ p, int C, int PD)
{
    long total = (long)C * PD * PD * PD;
    long idx = (long)blockIdx.x * blockDim.x + threadIdx.x;
    if (idx >= total) return;
    int px = (int)(idx % PD); long t = idx / PD;
    int py = (int)(t % PD); t /= PD;
    int pz = (int)(t % PD);
    if (px == 0 || px == PD - 1 || py == 0 || py == PD - 1 || pz == 0 || pz == PD - 1)
        p[idx] = (T)0;
}

// ---------------------------------------------------------------------------
// Conv3d k4 s2 p1 as MFMA implicit GEMM, bf16 hi/lo pair inputs (enc1 only)
// ---------------------------------------------------------------------------
template <int CIN, int COUT, int DOUT, int PD, int PRX, int MTW, int OWT,
          int OWHALF, int KSPLIT, int OUTSPLIT>
__global__ __launch_bounds__(256)
void conv_s2_mfma(const unsigned short* __restrict__ xhi,
                  const unsigned short* __restrict__ xlo,
                  const short* __restrict__ Whi, const short* __restrict__ Wlo,
                  const float* __restrict__ bias,
                  unsigned short* __restrict__ yhi, unsigned short* __restrict__ ylo,
                  float* __restrict__ yf,
                  int OPD, int OPRX, int po, long sstride)
{
    constexpr int K = CIN * 64;
    constexpr int MWAVES = COUT / (16 * MTW);
    constexpr int RPB = 4 / MWAVES;
    constexpr int KN = (CIN * 2) / KSPLIT;

    int bx = blockIdx.x;
    const int ks = (KSPLIT > 1) ? (bx % KSPLIT) : 0;
    const int rowblk = (KSPLIT > 1) ? (bx / KSPLIT) : bx;
    const int lane = (int)threadIdx.x & 63, w = (int)threadIdx.x >> 6;
    const int mi = (MWAVES == 4) ? w : 0;
    const int ri = (MWAVES == 4) ? 0 : w;
    const int rowid = rowblk * RPB + ri;
    const int n16 = lane & 15, quad = lane >> 4;

    int b, od, oh, ow;
    if (OWHALF) {
        constexpr int NOH = DOUT / 2;
        const int ohb = rowid % NOH; int t = rowid / NOH;
        od = t % DOUT; b = t / DOUT;
        oh = ohb * 2 + (n16 >> 3);
        ow = n16 & 7;
    } else {
        const int owt = rowid % OWT; int t = rowid / OWT;
        oh = t % DOUT; t /= DOUT;
        od = t % DOUT; b = t / DOUT;
        ow = owt * 16 + n16;
    }

    const int co0 = mi * (MTW * 16);

    f32x4 acc[MTW];
    #pragma unroll
    for (int mt = 0; mt < MTW; ++mt)
        #pragma unroll
        for (int r = 0; r < 4; ++r) {
            int co = co0 + mt * 16 + quad * 4 + r;
            acc[mt][r] = (ks == 0) ? bias[co] : 0.0f;
        }

    const int sg0 = ks * KN;
    const long chs = (long)PD * PD * PRX;
    long off = ((long)(b * CIN + (sg0 >> 1)) * PD + (2 * od + (quad >> 1))) * PD * PRX
             + (long)(2 * oh + (quad & 1) * 2) * PRX + 2 * ow;
    const unsigned short* phi = xhi + off;
    const unsigned short* plo = xlo + off;
    const long incA = 2L * PD * PRX;
    const long incB = chs - 2L * PD * PRX;

    const short* a0h = Whi + (long)(co0 + n16) * K + sg0 * 32 + quad * 8;
    const short* a0l = Wlo + (long)(co0 + n16) * K + sg0 * 32 + quad * 8;

    #pragma unroll 2
    for (int s = 0; s < KN; ++s) {
        u16x4u h0 = *(const u16x4u*)phi;
        u16x4u h1 = *(const u16x4u*)(phi + PRX);
        u16x4u l0 = *(const u16x4u*)plo;
        u16x4u l1 = *(const u16x4u*)(plo + PRX);
        bf16x8 bhi = pack_b(h0, h1);
        bf16x8 blo = pack_b(l0, l1);
        #pragma unroll
        for (int mt = 0; mt < MTW; ++mt) {
            bf16x8 ah = *(const bf16x8*)(a0h + (long)mt * 16 * K + s * 32);
            bf16x8 al = *(const bf16x8*)(a0l + (long)mt * 16 * K + s * 32);
            acc[mt] = __builtin_amdgcn_mfma_f32_16x16x32_bf16(ah, bhi, acc[mt], 0, 0, 0);
            acc[mt] = __builtin_amdgcn_mfma_f32_16x16x32_bf16(ah, blo, acc[mt], 0, 0, 0);
            acc[mt] = __builtin_amdgcn_mfma_f32_16x16x32_bf16(al, bhi, acc[mt], 0, 0, 0);
        }
        long inc = (s & 1) ? incB : incA;
        phi += inc; plo += inc;
    }

    if (OUTSPLIT) {
        #pragma unroll
        for (int mt = 0; mt < MTW; ++mt)
            #pragma unroll
            for (int r = 0; r < 4; ++r) {
                int co = co0 + mt * 16 + quad * 4 + r;
                float v = fmaxf(acc[mt][r], 0.0f);
                unsigned short h, l;
                split_bf16(v, h, l);
                long o = (((long)(b * COUT + co) * OPD + od + po) * OPD + oh + po) * OPRX
                       + ow + po;
                yhi[o] = h; ylo[o] = l;
            }
    } else {
        #pragma unroll
        for (int mt = 0; mt < MTW; ++mt)
            #pragma unroll
            for (int r = 0; r < 4; ++r) {
                int co = co0 + mt * 16 + quad * 4 + r;
                long o = (long)ks * sstride
                       + (((long)(b * COUT + co) * OPD + od) * OPD + oh) * OPRX + ow;
                yf[o] = acc[mt][r];
            }
    }
}

// Fragment-direct variant (enc2/enc3): fragment-major Whi/Wlo, each wave
// loads its OWN disjoint (s,m) fragment blocks (coalesced 1KB dwordx4) --
// no LDS, no barriers. Bit-identical to the LDS path.
template <int CIN, int COUT, int DOUT, int PD, int PRX, int MTW, int OWT,
          int OWHALF, int KSPLIT, int OUTSPLIT>
__global__ __launch_bounds__(256)
void conv_s2_mfma_fd(const unsigned short* __restrict__ xhi,
                     const unsigned short* __restrict__ xlo,
                     const short* __restrict__ Whi, const short* __restrict__ Wlo,
                     const float* __restrict__ bias,
                     unsigned short* __restrict__ yhi, unsigned short* __restrict__ ylo,
                     float* __restrict__ yf,
                     int OPD, int OPRX, int po, long sstride)
{
    constexpr int MWAVES = COUT / (16 * MTW);
    constexpr int RPB = 4 / MWAVES;
    constexpr int KN = (CIN * 2) / KSPLIT;
    constexpr int MT = COUT >> 4;            // fragment-major m count
    constexpr int SSTEP = MT * 512;          // shorts per s-step in frag layout

    int bx = blockIdx.x;
    const int ks = (KSPLIT > 1) ? (bx % KSPLIT) : 0;
    const int rowblk = (KSPLIT > 1) ? (bx / KSPLIT) : bx;
    const int lane = (int)threadIdx.x & 63, w = (int)threadIdx.x >> 6;
    const int mi = (MWAVES == 4) ? w : 0;
    const int ri = (MWAVES == 4) ? 0 : w;
    const int rowid = rowblk * RPB + ri;
    const int n16 = lane & 15, quad = lane >> 4;

    int b, od, oh, ow;
    if (OWHALF) {
        constexpr int NOH = DOUT / 2;
        const int ohb = rowid % NOH; int t = rowid / NOH;
        od = t % DOUT; b = t / DOUT;
        oh = ohb * 2 + (n16 >> 3);
        ow = n16 & 7;
    } else {
        const int owt = rowid % OWT; int t = rowid / OWT;
        oh = t % DOUT; t /= DOUT;
        od = t % DOUT; b = t / DOUT;
        ow = owt * 16 + n16;
    }

    const int co0 = mi * (MTW * 16);

    f32x4 acc[MTW];
    #pragma unroll
    for (int mt = 0; mt < MTW; ++mt)
        #pragma unroll
        for (int r = 0; r < 4; ++r) {
            int co = co0 + mt * 16 + quad * 4 + r;
            acc[mt][r] = (ks == 0) ? bias[co] : 0.0f;
        }

    const int sg0 = ks * KN;
    const long chs = (long)PD * PD * PRX;
    long off = ((long)(b * CIN + (sg0 >> 1)) * PD + (2 * od + (quad >> 1))) * PD * PRX
             + (long)(2 * oh + (quad & 1) * 2) * PRX + 2 * ow;
    const unsigned short* phi = xhi + off;
    const unsigned short* plo = xlo + off;
    const long incA = 2L * PD * PRX;
    const long incB = chs - 2L * PD * PRX;

    // fragment-major: (s, m) block at ((s*MT + m)*64 + lane)*8
    const short* ph = Whi + (((long)sg0 * MT + mi * MTW) * 64 + lane) * 8;
    const short* pl = Wlo + (((long)sg0 * MT + mi * MTW) * 64 + lane) * 8;

    #pragma unroll 2
    for (int s = 0; s < KN; ++s) {
        u16x4u h0 = *(const u16x4u*)phi;
        u16x4u h1 = *(const u16x4u*)(phi + PRX);
        u16x4u l0 = *(const u16x4u*)plo;
        u16x4u l1 = *(const u16x4u*)(plo + PRX);
        bf16x8 bhi = pack_b(h0, h1);
        bf16x8 blo = pack_b(l0, l1);
        #pragma unroll
        for (int mt = 0; mt < MTW; ++mt) {
            bf16x8 ah = *(const bf16x8*)(ph + mt * 512);
            bf16x8 al = *(const bf16x8*)(pl + mt * 512);
            acc[mt] = __builtin_amdgcn_mfma_f32_16x16x32_bf16(ah, bhi, acc[mt], 0, 0, 0);
            acc[mt] = __builtin_amdgcn_mfma_f32_16x16x32_bf16(ah, blo, acc[mt], 0, 0, 0);
            acc[mt] = __builtin_amdgcn_mfma_f32_16x16x32_bf16(al, bhi, acc[mt], 0, 0, 0);
        }
        long inc = (s & 1) ? incB : incA;
        phi += inc; plo += inc;
        ph += SSTEP; pl += SSTEP;
    }

    if (OUTSPLIT) {
        #pragma unroll
        for (int mt = 0; mt < MTW; ++mt)
            #pragma unroll
            for (int r = 0; r < 4; ++r) {
                int co = co0 + mt * 16 + quad * 4 + r;
                float v = fmaxf(acc[mt][r], 0.0f);
                unsigned short h, l;
                split_bf16(v, h, l);
                long o = (((long)(b * COUT + co) * OPD + od + po) * OPD + oh + po) * OPRX
                       + ow + po;
                yhi[o] = h; ylo[o] = l;
            }
    } else {
        #pragma unroll
        for (int mt = 0; mt < MTW; ++mt)
            #pragma unroll
            for (int r = 0; r < 4; ++r) {
                int co = co0 + mt * 16 + quad * 4 + r;
                long o = (long)ks * sstride
                       + (((long)(b * COUT + co) * OPD + od) * OPD + oh) * OPRX + ow;
                yf[o] = acc[mt][r];
            }
    }
}

__global__ __launch_bounds__(256)
void combine4_relu(const float* __restrict__ p, float* __restrict__ y, long N, long ss)
{
    long idx = (long)blockIdx.x * blockDim.x + threadIdx.x;
    if (idx >= N) return;
    float v = p[idx] + p[idx + ss] + p[idx + 2 * ss] + p[idx + 3 * ss];
    y[idx] = fmaxf(v, 0.0f);
}

// ---------------- 1x1 conv (fp32 exact) ----------------
__global__ __launch_bounds__(128)
void conv1x1_b(const float* __restrict__ x, const float* __restrict__ w,
               const float* __restrict__ bias, float* __restrict__ y)
{
    const int co = blockIdx.x & 255, b = blockIdx.x >> 8;
    const int s4 = (int)threadIdx.x * 4;
    const float* xb = x + (long)b * 256 * 512 + s4;
    const float* wr = w + (long)co * 256;      // uniform -> s_load
    float bv = bias[co];
    float4 acc = {bv, bv, bv, bv};
    for (int ci = 0; ci < 256; ++ci) {
        float wv = wr[ci];
        float4 xv = *(const float4*)(xb + (long)ci * 512);
        acc.x = fmaf(xv.x, wv, acc.x); acc.y = fmaf(xv.y, wv, acc.y);
        acc.z = fmaf(xv.z, wv, acc.z); acc.w = fmaf(xv.w, wv, acc.w);
    }
    *(float4*)(y + (long)(b * 256 + co) * 512 + s4) = acc;
}

// ---------------- VQ (fp32 exact) ----------------
__global__ void codenorm_kernel(const float* __restrict__ cb, float* __restrict__ norms)
{
    int k = blockIdx.x;
    int lane = threadIdx.x;
    float s = 0.0f;
    const float* row = cb + (long)k * 256;
    for (int d = lane; d < 256; d += 64) { float v = row[d]; s = fmaf(v, v, s); }
    for (int off = 32; off > 0; off >>= 1) s += __shfl_down(s, off);
    if (lane == 0) norms[k] = s;
}

// cbT[d*1024 + k] = cb[k*256 + d]  (fp32 copy -> values unchanged)
__global__ __launch_bounds__(256)
void transpose_cb(const float* __restrict__ cb, float* __restrict__ cbT)
{
    int idx = blockIdx.x * 256 + (int)threadIdx.x;    // 0..262143
    int d = idx & 255, k = idx >> 8;
    cbT[(long)d * 1024 + k] = cb[(long)k * 256 + d];
}

// R24: 4 rows/block (grid 256), coalesced cbT float4 loads (codes 4t..4t+3),
// rows staged in LDS. Bit-identical to the original per-row kernel.
__global__ __launch_bounds__(256)
void vq_kernel4(const float* __restrict__ lat, const float* __restrict__ cb,
                const float* __restrict__ cbT, const float* __restrict__ norms,
                unsigned short* __restrict__ q, float* __restrict__ idx_out)
{
    __shared__ __align__(16) float rows[4][256];
    __shared__ float s_best[4][256];
    __shared__ int   s_bidx[4][256];
    const int r0 = blockIdx.x * 4;
    const int t = (int)threadIdx.x;

    #pragma unroll
    for (int j = 0; j < 4; ++j)
        rows[j][t] = lat[(long)(r0 + j) * 256 + t];
    __syncthreads();

    // latn per row -- identical float4 fmaf chain to the original
    float latn[4];
    #pragma unroll
    for (int j = 0; j < 4; ++j) {
        const float4* rowv = (const float4*)rows[j];
        float a = 0.0f;
        #pragma unroll 4
        for (int d = 0; d < 64; ++d) {
            float4 rv = rowv[d];
            a = fmaf(rv.x, rv.x, a); a = fmaf(rv.y, rv.y, a);
            a = fmaf(rv.z, rv.z, a); a = fmaf(rv.w, rv.w, a);
        }
        latn[j] = a;
    }

    // codes 4t..4t+3; dot[j][c] accumulates d = 0..255 sequentially (same
    // chain as the original scalar loop)
    float dot[4][4] = {};
    const float* ct = cbT + t * 4;
    #pragma unroll 4
    for (int d = 0; d < 256; ++d) {
        float4 c4 = *(const float4*)(ct + (long)d * 1024);
        #pragma unroll
        for (int j = 0; j < 4; ++j) {
            float rv = rows[j][d];
            dot[j][0] = fmaf(rv, c4.x, dot[j][0]);
            dot[j][1] = fmaf(rv, c4.y, dot[j][1]);
            dot[j][2] = fmaf(rv, c4.z, dot[j][2]);
            dot[j][3] = fmaf(rv, c4.w, dot[j][3]);
        }
    }

    float4 nv = *(const float4*)(norms + t * 4);
    float nr[4] = {nv.x, nv.y, nv.z, nv.w};

    #pragma unroll
    for (int j = 0; j < 4; ++j) {
        float best = FLT_MAX;
        int bidx = 0x7fffffff;
        #pragma unroll
        for (int c = 0; c < 4; ++c) {
            float sc = latn[j] - 2.0f * dot[j][c] + nr[c];
            int k = t * 4 + c;
            if (sc < best || (sc == best && k < bidx)) { best = sc; bidx = k; }
        }
        s_best[j][t] = best; s_bidx[j][t] = bidx;
    }
    __syncthreads();
    for (int off = 128; off > 0; off >>= 1) {
        if (t < off) {
            #pragma unroll
            for (int j = 0; j < 4; ++j) {
                float o = s_best[j][t + off]; int oi = s_bidx[j][t + off];
                if (o < s_best[j][t] || (o == s_best[j][t] && oi < s_bidx[j][t])) {
                    s_best[j][t] = o; s_bidx[j][t] = oi;
                }
            }
        }
        __syncthreads();
    }

    #pragma unroll
    for (int j = 0; j < 4; ++j) {
        const int bk = s_bidx[j][0];
        const int r = r0 + j;
        const int b = r >> 9, n = r & 511;
        const int zz = n >> 6, yy = (n >> 3) & 7, xx = n & 7;
        q[(long)(b * 256 + t) * 1000 + ((long)(zz + 1) * 10 + (yy + 1)) * 10 + (xx + 1)]
            = f32_to_bf16(cb[(long)bk * 256 + t]);
    }
    if (t == 0) {
        #pragma unroll
        for (int j = 0; j < 4; ++j)
            idx_out[r0 + j] = (float)s_bidx[j][0];
    }
}

// ---------------- decoder: MFMA implicit-GEMM ConvTranspose ----------------
// xflip=0: B slot a <-> x offset (1-ax), kw=(1-px)+2*ax (old cube kernel).
// xflip=1: B slot a <-> x offset ax,     kw=(1-px)+2*(1-ax) (dword-pair kernel).
__global__ __launch_bounds__(256)
void prep_convt_w(const float* __restrict__ w, short* __restrict__ Ap,
                  int Cin, int Cout, int xflip)
{
    const int K = Cin * 8;
    long total = 8L * Cout * K;
    long idx = (long)blockIdx.x * blockDim.x + threadIdx.x;
    if (idx >= total) return;
    int k = (int)(idx % K);
    int co = (int)((idx / K) % Cout);
    int p = (int)(idx / ((long)K * Cout));
    int ci = k >> 3, a = k & 7;
    int az = (a >> 2) & 1, ay = (a >> 1) & 1, ax = a & 1;
    int pz = p >> 2, py = (p >> 1) & 1, px = p & 1;
    int axw = xflip ? (1 - ax) : ax;
    int kd = (1 - pz) + 2 * az, kh = (1 - py) + 2 * ay, kw = (1 - px) + 2 * axw;
    float v = w[((long)ci * Cout + co) * 64 + kd * 16 + kh * 4 + kw];
    Ap[idx] = (short)f32_to_bf16(v);
}

// Fragment-major layout for the LDS-staged v2 kernel:
//   ApN[((p*MG + mg)*nsteps + s)*2048 + cb*512 + l*8 + kk]
__global__ __launch_bounds__(256)
void prep_convt_w_frag(const float* __restrict__ w, short* __restrict__ Ap,
                       int Cin, int Cout, int xflip)
{
    const int MG = Cout >> 6;
    const int nsteps = Cin >> 2;             // (Cin*8)/32
    long total = 8L * MG * nsteps * 2048;
    long idx = (long)blockIdx.x * blockDim.x + threadIdx.x;
    if (idx >= total) return;
    int kk = (int)(idx & 7); long r = idx >> 3;
    int l  = (int)(r & 63);  r >>= 6;
    int cb = (int)(r & 3);   r >>= 2;
    int s  = (int)(r % nsteps); r /= nsteps;
    int mg = (int)(r % MG);
    int p  = (int)(r / MG);

    int n16 = l & 15, quad = l >> 4;
    int korig = s * 32 + quad * 8 + kk;
    int co = mg * 64 + cb * 16 + n16;
    int ci = korig >> 3, a = korig & 7;
    int az = (a >> 2) & 1, ay = (a >> 1) & 1, ax = a & 1;
    int pz = p >> 2, py = (p >> 1) & 1, px = p & 1;
    int axw = xflip ? (1 - ax) : ax;
    int kd = (1 - pz) + 2 * az, kh = (1 - py) + 2 * ay, kw = (1 - px) + 2 * axw;
    float v = w[((long)ci * Cout + co) * 64 + kd * 16 + kh * 4 + kw];
    Ap[idx] = (short)f32_to_bf16(v);
}

// Old cube-N layout (kept for dec1, DIN=8): round-0 body.
template <int CIN, int COUT, int DIN, int OPAD, typename OutT>
__global__ __launch_bounds__(256)
void convt_mfma(const unsigned short* __restrict__ Xp, const short* __restrict__ Ap,
                const float* __restrict__ bias, OutT* __restrict__ Y)
{
    constexpr int PD = DIN + 2;
    constexpr int PD3 = PD * PD * PD;
    constexpr int T = DIN >> 2;
    constexpr int NT = T * T * T;
    constexpr int SLAB = NT / 8;
    constexpr int OPD = 2 * DIN + 2 * OPAD;
    constexpr int K = CIN * 8;
    constexpr int MG = COUT >> 6;
    constexpr int nsteps = K >> 5;

    int bx = blockIdx.x;
    const int xcd = bx & 7;
    int local = bx >> 3;
    const int px = local & 1; local >>= 1;
    const int mg = local % MG; local /= MG;
    const int ntin = local % SLAB;
    const int pzy = local / SLAB;            // 0..3
    const int pz = pzy >> 1, py = pzy & 1;
    const int p = pz * 4 + py * 2 + px;
    const int nt = xcd * SLAB + ntin;

    const int lane = threadIdx.x & 63, wave = threadIdx.x >> 6;
    const int n16 = lane & 15, quad = lane >> 4;

    const int tx = nt % T, ty = (nt / T) % T, tz = nt / (T * T);
    const int mz = tz * 4 + wave, my = ty * 4 + (n16 >> 2), mx = tx * 4 + (n16 & 3);
    const int sp = ((mz + pz) * PD + (my + py)) * PD + (mx + px);

    const unsigned short* xq = Xp + (long)quad * PD3 + sp;

    const int cobase = mg * 64;
    const short* ap0 = Ap + ((long)p * COUT + cobase + n16) * K + quad * 8;

    f32x4 acc[4];
    #pragma unroll
    for (int cb = 0; cb < 4; ++cb) {
        const float* bp = bias + cobase + cb * 16 + quad * 4;
        acc[cb][0] = bp[0]; acc[cb][1] = bp[1]; acc[cb][2] = bp[2]; acc[cb][3] = bp[3];
    }

    #pragma unroll 4
    for (int s = 0; s < nsteps; ++s) {
        const unsigned short* xs = xq + (long)s * 4 * PD3;
        bf16x8 bf;
        bf[0] = (short)xs[(PD + 1) * PD + 1];
        bf[1] = (short)xs[(PD + 1) * PD];
        bf[2] = (short)xs[PD * PD + 1];
        bf[3] = (short)xs[PD * PD];
        bf[4] = (short)xs[PD + 1];
        bf[5] = (short)xs[PD];
        bf[6] = (short)xs[1];
        bf[7] = (short)xs[0];
        #pragma unroll
        for (int cb = 0; cb < 4; ++cb) {
            bf16x8 af = *(const bf16x8*)(ap0 + (long)cb * 16 * K + s * 32);
            acc[cb] = __builtin_amdgcn_mfma_f32_16x16x32_bf16(af, bf, acc[cb], 0, 0, 0);
        }
    }

    const int opz = 2 * mz + pz + OPAD, opy = 2 * my + py + OPAD, opx = 2 * mx + px + OPAD;
    const long spo = ((long)opz * OPD + opy) * OPD + opx;
    #pragma unroll
    for (int cb = 0; cb < 4; ++cb) {
        #pragma unroll
        for (int r = 0; r < 4; ++r) {
            int co = cobase + cb * 16 + quad * 4 + r;
            float v = fmaxf(acc[cb][r], 0.0f);
            store_act(Y + (long)co * OPD * OPD * OPD + spo, v);
        }
    }
}

// Dword-pair B-gather (dec2/dec3), R29: 2 K-steps per barrier phase.
// Abuf[2][2][2048] (16KB): each phase stages two 4KB A step-tiles, issues
// both steps' X loads up front (2x MLP), runs MFMA step 2ph then 2ph+1,
// one barrier. Per-acc MFMA order = old sequential s => bit-identical.
template <int CIN, int COUT, int DIN, int OPAD, int MXP, int MYP, typename OutT>
__global__ __launch_bounds__(256)
void convt_mfma_v2(const unsigned short* __restrict__ Xp, const short* __restrict__ Ap,
                   const float* __restrict__ bias, OutT* __restrict__ Y)
{
    constexpr int PD = DIN + 2;
    constexpr int PD3 = PD * PD * PD;
    constexpr int OPD = 2 * DIN + 2 * OPAD;
    constexpr int K = CIN * 8;
    constexpr int MG = COUT >> 6;
    constexpr int nsteps = K >> 5;
    static_assert((nsteps & 1) == 0 && nsteps >= 4, "phase merge needs even nsteps");
    constexpr int NPH = nsteps / 2;
    constexpr int MXT = DIN / (16 * MXP);
    constexpr int MYT = DIN / (4 * MYP);
    constexpr int MZS = DIN / 8;             // mz per XCD slab
    constexpr int TPE = MXP * MYP;           // tiles per wave (one of MXP/MYP is 1)

    int bx = blockIdx.x;
    const int xcd = bx & 7;
    int local = bx >> 3;
    const int px = local & 1; local >>= 1;
    const int py = local & 1; local >>= 1;
    const int mg = local % MG; local /= MG;
    const int mxt = local % MXT; local /= MXT;
    const int myt = local % MYT; local /= MYT;
    const int pz = local & 1; local >>= 1;
    const int mzin = local;                  // 0..MZS-1
    const int mz = xcd * MZS + mzin;
    const int p = pz * 4 + py * 2 + px;

    const int lane = threadIdx.x & 63, wave = threadIdx.x >> 6;
    const int n16 = lane & 15, quad = lane >> 4;

    const int mx0 = mxt * (16 * MXP) + n16;
    const int my0 = myt * (4 * MYP) + wave * MYP;
    const int baseX = mx0 & ~1;
    const int sh = 16 * ((n16 & 1) + px);    // 0, 16, or 32
    const long sp = ((long)(mz + pz) * PD + (my0 + py)) * PD + baseX;

    const unsigned short* xq = Xp + (long)quad * PD3 + sp;

    // fragment-major weight tiles: 2048 shorts (4KB) per (p,mg,s)
    const short* ApT = Ap + (((long)p * MG + mg) * nsteps) * 2048;

    __shared__ short Abuf[2][2][2048];       // 16KB: dbuf x 2-steps x 4KB

    f32x4 acc[TPE][4];
    #pragma unroll
    for (int t = 0; t < TPE; ++t)
        #pragma unroll
        for (int cb = 0; cb < 4; ++cb) {
            const float* bp = bias + (mg * 64) + cb * 16 + quad * 4;
            acc[t][cb][0] = bp[0]; acc[t][cb][1] = bp[1];
            acc[t][cb][2] = bp[2]; acc[t][cb][3] = bp[3];
        }

    constexpr int rowoff[4] = { (PD + 1) * PD, PD * PD, PD, 0 };
    union Frag { unsigned u[4]; bf16x8 b; };

    const int chunkoff = wave * 512 + lane * 8;   // this thread's 16B of a 4KB tile

    // prologue: stage steps 0 and 1
    {
        *(bf16x8*)(&Abuf[0][0][chunkoff]) = *(const bf16x8*)(ApT + chunkoff);
        *(bf16x8*)(&Abuf[0][1][chunkoff]) = *(const bf16x8*)(ApT + 2048 + chunkoff);
    }
    __syncthreads();

    #pragma unroll 1
    for (int ph = 0; ph < NPH; ++ph) {
        const int cur = ph & 1;
        const bool more = (ph + 1 < NPH);
        bf16x8 an0, an1;
        if (more) {
            an0 = *(const bf16x8*)(ApT + (long)(2 * ph + 2) * 2048 + chunkoff);
            an1 = *(const bf16x8*)(ApT + (long)(2 * ph + 3) * 2048 + chunkoff);
        }

        // X loads for both steps (raw staging; 2x loads in flight)
        unsigned long long xr[2][TPE][4];
        #pragma unroll
        for (int u = 0; u < 2; ++u) {
            const unsigned short* xs = xq + (long)(2 * ph + u) * 4 * PD3;
            #pragma unroll
            for (int t = 0; t < TPE; ++t) {
                const int toff = (MXP > 1) ? t * 16 : t * PD;
                #pragma unroll
                for (int j = 0; j < 4; ++j) {
                    union { u16x4u v; unsigned long long u64; } ld;
                    ld.v = *(const u16x4u*)(xs + toff + rowoff[j]);
                    xr[u][t][j] = ld.u64;
                }
            }
        }

        // A fragments from LDS for both steps
        bf16x8 af[2][4];
        #pragma unroll
        for (int u = 0; u < 2; ++u)
            #pragma unroll
            for (int cb = 0; cb < 4; ++cb)
                af[u][cb] = *(const bf16x8*)(&Abuf[cur][u][cb * 512 + lane * 8]);

        // MFMA: step 2ph then 2ph+1 (old sequential order)
        #pragma unroll
        for (int u = 0; u < 2; ++u) {
            #pragma unroll
            for (int t = 0; t < TPE; ++t) {
                Frag fr;
                #pragma unroll
                for (int j = 0; j < 4; ++j)
                    fr.u[j] = (unsigned)(xr[u][t][j] >> sh);
                #pragma unroll
                for (int cb = 0; cb < 4; ++cb)
                    acc[t][cb] = __builtin_amdgcn_mfma_f32_16x16x32_bf16(af[u][cb], fr.b,
                                                                         acc[t][cb], 0, 0, 0);
            }
        }

        if (more) {
            *(bf16x8*)(&Abuf[cur ^ 1][0][chunkoff]) = an0;
            *(bf16x8*)(&Abuf[cur ^ 1][1][chunkoff]) = an1;
        }
        __syncthreads();
    }

    const int opz = 2 * mz + pz + OPAD;
    #pragma unroll
    for (int t = 0; t < TPE; ++t) {
        const int opx = 2 * (mx0 + ((MXP > 1) ? t * 16 : 0)) + px + OPAD;
        const int opy = 2 * (my0 + ((MYP > 1) ? t : 0)) + py + OPAD;
        const long spo = ((long)opz * OPD + opy) * OPD + opx;
        #pragma unroll
        for (int cb = 0; cb < 4; ++cb) {
            #pragma unroll
            for (int r = 0; r < 4; ++r) {
                int co = (mg * 64) + cb * 16 + quad * 4 + r;
                float v = fmaxf(acc[t][cb][r], 0.0f);
                store_act(Y + (long)co * OPD * OPD * OPD + spo, v);
            }
        }
    }
}

// ---------------- dec4 as MFMA GEMM, R28: merged ci-steps ----------------
// Fragment-major: Aw[(s*64 + lane)*8 + kk] (unchanged from R23).
__global__ __launch_bounds__(256)
void prep_dec4A_frag(const float* __restrict__ w, short* __restrict__ Aw)
{
    int idx = blockIdx.x * 256 + (int)threadIdx.x;    // 0..65535
    int kk = idx & 7;
    int l  = (idx >> 3) & 63;
    int s  = idx >> 9;                                // 0..127
    int n16 = l & 15, quad = l >> 4;
    int k = s * 32 + quad * 8 + kk;
    float v = (n16 < 3) ? w[n16 * 4096 + k] : 0.0f;
    Aw[idx] = (short)f32_to_bf16(v);
}

// R28: one step per ci (64 steps). Stage 28 rows (4z x 7y) per step; per
// step run both z-half MFMA groups -- exactly the old s=2S, s=2S+1 sequence
// => bit-identical. Stride 72 read windows {0,16,24,8}+const (2/bank free);
// staging wave-passes write 64 consecutive words (free), 4 coalesced lines.
__global__ __launch_bounds__(256)
void conv_dec4_mfma(const float* __restrict__ d3, const short* __restrict__ Aw,
                    const float* __restrict__ bias, float* __restrict__ y)
{
    constexpr int D = 64, Dout = 61;
    constexpr int RS = 72;                 // row stride (words)
    int bx = blockIdx.x;
    const int slab = bx & 7;
    const int i = bx >> 3;                 // 0..127
    const int od = slab * 8 + (i >> 4);
    const int oh0 = (i & 15) * 4;          // covers oh0..oh0+3 (guard < 61)
    if (od >= Dout) return;                // uniform per block -> barriers safe
    const int tid = (int)threadIdx.x;
    const int lane = tid & 63, wave = tid >> 6;
    const int n16 = lane & 15, quad = lane >> 4;
    const int ow = wave * 16 + n16;

    // [dbuf][row 0..27][x 0..71]; words 64..71 per row uninitialized (only
    // consumed by discarded ow>=61 columns; reads reach word ow+3 <= 66)
    __shared__ float Xs[2][28][RS];
    float* xsb = &Xs[0][0][0];
    constexpr int BUFW = 28 * RS;          // words per buffer

    f32x4 acc[4];
    #pragma unroll
    for (int j = 0; j < 4; ++j)
        #pragma unroll
        for (int r = 0; r < 4; ++r) {
            int co = quad * 4 + r;
            acc[j][r] = (co < 3) ? bias[co] : 0.0f;
        }

    const int kd0 = quad >> 1;
    const int kh0 = (quad & 1) * 2;

    // strided staging: thread t (t<224) owns words g = t + 224*j, j=0..7 of
    // the 1792-word (28 rows x 64) tile. row = g/64 -> (szi = row/7 in 0..3,
    // syi = row%7); global z = od + szi, y = min(oh0+syi, 63), x = g%64.
    const bool sact = (tid < 224);
    int goff[8];                           // global word offset (ci-invariant)
    int loff[8];                           // LDS word offset within a buffer
    #pragma unroll
    for (int j = 0; j < 8; ++j) {
        const int g = tid + 224 * j;
        const int row = g >> 6, xx = g & 63;
        const int szi = row / 7, syi = row % 7;
        goff[j] = ((od + szi) * D + min(oh0 + syi, D - 1)) * D + xx;
        loff[j] = row * RS + xx;
    }
    // ci step offset: ci * 64 * 4096 words
    auto choff = [](int S) { return (long)S * D * D * D; };

    // prologue: stage step 0
    if (sact) {
        #pragma unroll
        for (int j = 0; j < 8; ++j)
            xsb[loff[j]] = d3[goff[j]];
    }
    __syncthreads();

    #pragma unroll 1
    for (int S = 0; S < 64; ++S) {
        const int cur = S & 1;
        const bool more = (S + 1 < 64);
        float nv[8];
        if (more && sact) {
            const float* src = d3 + choff(S + 1);
            #pragma unroll
            for (int j = 0; j < 8; ++j)
                nv[j] = src[goff[j]];
        }

        #pragma unroll
        for (int h = 0; h < 2; ++h) {
            bf16x8 af = *(const bf16x8*)(Aw + ((long)(2 * S + h) * 64 + lane) * 8);
            unsigned p0[5], p1[5];
            #pragma unroll
            for (int r = 0; r < 5; ++r) {
                const int row = 14 * h + kd0 * 7 + kh0 + r;
                f32x4u v = *(const f32x4u*)(xsb + cur * BUFW + row * RS + ow);
                p0[r] = (__float_as_uint(v[0]) >> 16) | (__float_as_uint(v[1]) & 0xffff0000u);
                p1[r] = (__float_as_uint(v[2]) >> 16) | (__float_as_uint(v[3]) & 0xffff0000u);
            }
            #pragma unroll
            for (int j = 0; j < 4; ++j) {
                union { unsigned u[4]; bf16x8 b; } fr;
                fr.u[0] = p0[j];     fr.u[1] = p1[j];
                fr.u[2] = p0[j + 1]; fr.u[3] = p1[j + 1];
                acc[j] = __builtin_amdgcn_mfma_f32_16x16x32_bf16(af, fr.b, acc[j], 0, 0, 0);
            }
        }

        if (more && sact) {
            float* dst = xsb + (cur ^ 1) * BUFW;
            #pragma unroll
            for (int j = 0; j < 8; ++j)
                dst[loff[j]] = nv[j];
        }
        __syncthreads();
    }

    if (ow < Dout && quad == 0) {
        #pragma unroll
        for (int j = 0; j < 4; ++j) {
            const int oh = oh0 + j;
            if (oh >= Dout) continue;
            #pragma unroll
            for (int r = 0; r < 3; ++r)
                y[((long)(r * Dout + od) * Dout + oh) * Dout + ow] = tanhf(acc[j][r]);
        }
    }
}

extern "C" void kernel_launch(void* const* d_in, const int* in_sizes, int n_in,
                              void* d_out, int out_size, void* d_ws, size_t ws_size,
                              hipStream_t stream)
{
    const float* x        = (const float*)d_in[0];
    const float* enc_w1   = (const float*)d_in[1];
    const float* enc_b1   = (const float*)d_in[2];
    const float* enc_w2   = (const float*)d_in[3];
    const float* enc_b2   = (const float*)d_in[4];
    const float* enc_w3   = (const float*)d_in[5];
    const float* enc_b3   = (const float*)d_in[6];
    const float* enc_w4   = (const float*)d_in[7];
    const float* enc_b4   = (const float*)d_in[8];
    const float* codebook = (const float*)d_in[9];
    const float* dec_w1   = (const float*)d_in[10];
    const float* dec_b1   = (const float*)d_in[11];
    const float* dec_w2   = (const float*)d_in[12];
    const float* dec_b2   = (const float*)d_in[13];
    const float* dec_w3   = (const float*)d_in[14];
    const float* dec_b3   = (const float*)d_in[15];
    const float* dec_w4   = (const float*)d_in[16];
    const float* dec_b4   = (const float*)d_in[17];

    float* out = (float*)d_out;
    float* idx_out = out + 2L * 3 * 61 * 61 * 61;

    // ---- workspace (byte offsets) ----
    char* wsb = (char*)d_ws;
    float*          cn   = (float*)wsb;                        //      4,096
    unsigned short* qp   = (unsigned short*)(wsb + 4096);      //  1,024,000
    short*          Ap1  = (short*)(wsb + 1028096);            //  8,388,608
    short*          Ap2  = (short*)(wsb + 9416704);            //  4,194,304
    short*          Ap3  = (short*)(wsb + 13611008);           //  1,048,576
    short*          Aw4  = (short*)(wsb + 14659584);           //    131,072
    short*          W1hi = (short*)(wsb + 14790656);           //     24,576
    short*          W1lo = (short*)(wsb + 14815232);           //     24,576
    short*          W2hi = (short*)(wsb + 14839808);           //  1,048,576
    short*          W2lo = (short*)(wsb + 15888384);           //  1,048,576
    short*          W3hi = (short*)(wsb + 16936960);           //  4,194,304
    short*          W3lo = (short*)(wsb + 21131264);           //  4,194,304
    char* arena = wsb + 25325568;
    // encoder phase:
    unsigned short* xphi = (unsigned short*)arena;                    // (2,3,66,66,68)
    unsigned short* xplo = (unsigned short*)(arena + 3554496);
    unsigned short* h1hi = (unsigned short*)(arena + 7108992);        // (2,64,34,34,36)
    unsigned short* h1lo = (unsigned short*)(arena + 17762688);
    unsigned short* h2hi = (unsigned short*)(arena + 28416384);       // (2,128,18,18,20)
    unsigned short* h2lo = (unsigned short*)(arena + 31734144);
    float*          pp3  = (float*)(arena + 35051904);                // 4x(2,256,8^3)
    float*          h3   = (float*)(arena + 39246208);                // (2,256,512)
    float*          lat  = (float*)(arena + 40294784);                // (2,256,512)
    // decoder phase (after VQ; overlaps encoder buffers):
    unsigned short* d1 = (unsigned short*)arena;                      // (256,18^3) bf16
    unsigned short* d2 = (unsigned short*)(arena + 2985984);          // (128,34^3) bf16
    float*          d3 = (float*)(arena + 13047808);                  // (64,64^3) fp32
    // arena peak 80.2 MB -> ws used 105.5 MB; cbT appended below:
    float*          cbT = (float*)(wsb + 105482240);                  // 1,048,576
    // total 106.5 MB (< 112.2 MB proven in R0)

    dim3 blk(256);
    auto nblk = [](long n) { return dim3((unsigned)((n + 255) / 256)); };

    // ---- weight prep ----
    prep_convt_w<<<nblk(8L * 256 * 2048), blk, 0, stream>>>(dec_w1, Ap1, 256, 256, 0);
    prep_convt_w_frag<<<nblk(8L * 128 * 2048), blk, 0, stream>>>(dec_w2, Ap2, 256, 128, 1);
    prep_convt_w_frag<<<nblk(8L * 64 * 1024), blk, 0, stream>>>(dec_w3, Ap3, 128, 64, 1);
    prep_dec4A_frag<<<dim3(256), blk, 0, stream>>>(dec_w4, Aw4);
    prep_split_w<<<nblk(12288), blk, 0, stream>>>(enc_w1, W1hi, W1lo, 12288);
    prep_split_w_frag<<<nblk(524288), blk, 0, stream>>>(enc_w2, W2hi, W2lo, 64, 128);
    prep_split_w_frag<<<nblk(2097152), blk, 0, stream>>>(enc_w3, W3hi, W3lo, 128, 256);
    transpose_cb<<<dim3(1024), blk, 0, stream>>>(codebook, cbT);

    // ---- encoder (MFMA, bf16-pair) ----
    pad_input_split<<<nblk(6L * 66 * 66 * 68), blk, 0, stream>>>(x, xphi, xplo);
    zero_halo_ps<<<nblk(128L * 34 * 34 * 36), blk, 0, stream>>>(h1hi, 128, 34, 36);
    zero_halo_ps<<<nblk(128L * 34 * 34 * 36), blk, 0, stream>>>(h1lo, 128, 34, 36);
    conv_s2_mfma<3, 64, 32, 66, 68, 4, 2, 0, 1, 1><<<dim3(1024), blk, 0, stream>>>(
        xphi, xplo, W1hi, W1lo, enc_b1, h1hi, h1lo, nullptr, 34, 36, 1, 0);
    zero_halo_ps<<<nblk(256L * 18 * 18 * 20), blk, 0, stream>>>(h2hi, 256, 18, 20);
    zero_halo_ps<<<nblk(256L * 18 * 18 * 20), blk, 0, stream>>>(h2lo, 256, 18, 20);
    conv_s2_mfma_fd<64, 128, 16, 34, 36, 2, 1, 0, 1, 1><<<dim3(512), blk, 0, stream>>>(
        h1hi, h1lo, W2hi, W2lo, enc_b2, h2hi, h2lo, nullptr, 18, 20, 1, 0);
    conv_s2_mfma_fd<128, 256, 8, 18, 20, 4, 1, 1, 4, 0><<<dim3(256), blk, 0, stream>>>(
        h2hi, h2lo, W3hi, W3lo, enc_b3, nullptr, nullptr, pp3, 8, 8, 0, 262144);
    combine4_relu<<<nblk(262144), blk, 0, stream>>>(pp3, h3, 262144, 262144);
    conv1x1_b<<<dim3(512), dim3(128), 0, stream>>>(h3, enc_w4, enc_b4, lat);

    // ---- VQ (fp32 exact) ----
    codenorm_kernel<<<dim3(1024), dim3(64), 0, stream>>>(codebook, cn);
    zero_halo_t<unsigned short><<<nblk(512L * 10 * 10 * 10), blk, 0, stream>>>(qp, 512, 10);
    vq_kernel4<<<dim3(256), blk, 0, stream>>>(lat, codebook, cbT, cn, qp, idx_out);

    // ---- decoder halos ----
    zero_halo_t<unsigned short><<<nblk(256L * 18 * 18 * 18), blk, 0, stream>>>(d1, 256, 18);
    zero_halo_t<unsigned short><<<nblk(128L * 34 * 34 * 34), blk, 0, stream>>>(d2, 128, 34);

    // ---- decoder (MFMA) per batch ----
    for (int b = 0; b < 2; ++b) {
        const unsigned short* qb = qp + (long)b * 256 * 1000;
        float* outb = out + (long)b * 3 * 226981;
        // dec1 (DIN=8, old layout): grid = 8*2*4*1*4 = 256
        convt_mfma<256, 256, 8, 1, unsigned short><<<dim3(256), blk, 0, stream>>>(
            qb, Ap1, dec_b1, d1);
        // dec2 (v2, MXP=1 MYP=2): grid = 8 * (2*2*2*1*2*2*2) = 512
        convt_mfma_v2<256, 128, 16, 1, 1, 2, unsigned short><<<dim3(512), blk, 0, stream>>>(
            d1, Ap2, dec_b2, d2);
        // dec3 (v2, MXP=2 MYP=1): grid = 8 * (2*2*1*1*8*2*4) = 2048
        convt_mfma_v2<128, 64, 32, 0, 2, 1, float><<<dim3(2048), blk, 0, stream>>>(
            d2, Ap3, dec_b3, d3);
        conv_dec4_mfma<<<dim3(8 * 8 * 16), blk, 0, stream>>>(d3, Aw4, dec_b4, outb);
    }
}

// Round 13
// 883.367 us; speedup vs baseline: 1.6510x; 1.0155x over previous
//
#include <hip/hip_runtime.h>
#include <cfloat>
#include <cmath>

// ---------------------------------------------------------------------------
// Round 30: store d3 as truncated bf16 halves (bit-identical to fp32 path).
// R29 post-mortem: phase merge helped dec2 (total 921 -> 897us) but dec3 was
// UNCHANGED (89.6us) -- falsifier fired; dec3 is not barrier-bound. Counters:
// FETCH 13.7MB (d2 slab is L2-resident) but WRITE 66MB (full fp32 d3).
// Key fact: dec4 consumes ONLY the top 16 bits of d3 (its pack is a pure
// truncation (>>16 | &0xffff0000)). So d3 can be stored as the truncated
// hi-halves: dec3 stores ushort(bits>>16) (write 66->33MB, store lines
// halve); dec4 loads shorts and rebuilds identical p0/p1 via 64-bit shifts
// (FETCH 46->23MB, pack VALU gone). Xs becomes ushort[2][28][80]: RS=80 ->
// read windows at banks {0,16,24,8} (max 2-way, free); staging wave-pass =
// 64 consecutive shorts (free). All consumed bits identical => bit-identical
// output. Everything else unchanged from R29.
// ---------------------------------------------------------------------------

using f32x4  = __attribute__((ext_vector_type(4))) float;
using bf16x8 = __attribute__((ext_vector_type(8))) short;
typedef float f32x4u __attribute__((ext_vector_type(4), aligned(4)));
typedef unsigned short u16x4u __attribute__((ext_vector_type(4), aligned(4)));
typedef unsigned short u16x8a4 __attribute__((ext_vector_type(8), aligned(4)));

__device__ __forceinline__ unsigned short f32_to_bf16(float f) {
    unsigned int u = __float_as_uint(f);
    u += 0x7fffu + ((u >> 16) & 1u);          // round-to-nearest-even
    return (unsigned short)(u >> 16);
}
__device__ __forceinline__ void split_bf16(float v, unsigned short& h, unsigned short& l) {
    h = f32_to_bf16(v);
    float hf = __uint_as_float((unsigned)h << 16);
    l = f32_to_bf16(v - hf);
}
// truncating bf16 store type (top 16 bits of fp32; NOT RNE)
struct bf16t { unsigned short u; };
__device__ __forceinline__ void store_act(float* p, float v) { *p = v; }
__device__ __forceinline__ void store_act(unsigned short* p, float v) { *p = f32_to_bf16(v); }
__device__ __forceinline__ void store_act(bf16t* p, float v) {
    p->u = (unsigned short)(__float_as_uint(v) >> 16);
}

template <typename V>
__device__ __forceinline__ bf16x8 pack_b(V r0, V r1) {
    bf16x8 b;
    b[0] = (short)r0[0]; b[1] = (short)r0[1]; b[2] = (short)r0[2]; b[3] = (short)r0[3];
    b[4] = (short)r1[0]; b[5] = (short)r1[1]; b[6] = (short)r1[2]; b[7] = (short)r1[3];
    return b;
}

// ---------------- prep: weight hi/lo split (linear; enc1) ----------------
__global__ __launch_bounds__(256)
void prep_split_w(const float* __restrict__ w, short* __restrict__ whi,
                  short* __restrict__ wlo, long total)
{
    long idx = (long)blockIdx.x * blockDim.x + threadIdx.x;
    if (idx >= total) return;
    unsigned short h, l;
    split_bf16(w[idx], h, l);
    whi[idx] = (short)h; wlo[idx] = (short)l;
}

// Fragment-major hi/lo split for enc2/enc3:
//   whi[((s*MT + m)*64 + l)*8 + kk] = hi(w[co*K + korig])
__global__ __launch_bounds__(256)
void prep_split_w_frag(const float* __restrict__ w, short* __restrict__ whi,
                       short* __restrict__ wlo, int CIN, int COUT)
{
    const int K = CIN * 64;
    const int MT = COUT >> 4;
    long total = (long)COUT * K;
    long idx = (long)blockIdx.x * blockDim.x + threadIdx.x;
    if (idx >= total) return;
    int kk = (int)(idx & 7); long r = idx >> 3;
    int l  = (int)(r & 63);  r >>= 6;
    int m  = (int)(r % MT);
    int s  = (int)(r / MT);
    int n16 = l & 15, quad = l >> 4;
    int co = m * 16 + n16;
    int korig = s * 32 + quad * 8 + kk;
    unsigned short h, lo16;
    split_bf16(w[(long)co * K + korig], h, lo16);
    whi[idx] = (short)h; wlo[idx] = (short)lo16;
}

// ---------------- pad input -> hi/lo bf16 pitched planes --------------------
__global__ __launch_bounds__(256)
void pad_input_split(const float* __restrict__ x, unsigned short* __restrict__ xhi,
                     unsigned short* __restrict__ xlo)
{
    const int D = 64, PD = 66, PRX = 68, BC = 6;
    long total = (long)BC * PD * PD * PRX;
    long idx = (long)blockIdx.x * blockDim.x + threadIdx.x;
    if (idx >= total) return;
    int px = (int)(idx % PRX); long t = idx / PRX;
    int py = (int)(t % PD); t /= PD;
    int pz = (int)(t % PD); int c = (int)(t / PD);
    int ix = px - 1, iy = py - 1, iz = pz - 1;
    float v = 0.0f;
    if ((unsigned)ix < (unsigned)D && (unsigned)iy < (unsigned)D && (unsigned)iz < (unsigned)D)
        v = x[(((long)c * D + iz) * D + iy) * D + ix];
    unsigned short h, l;
    split_bf16(v, h, l);
    xhi[idx] = h; xlo[idx] = l;
}

__global__ __launch_bounds__(256)
void zero_halo_ps(unsigned short* __restrict__ p, int C, int PD, int PRX)
{
    long total = (long)C * PD * PD * PRX;
    long idx = (long)blockIdx.x * blockDim.x + threadIdx.x;
    if (idx >= total) return;
    int px = (int)(idx % PRX); long t = idx / PRX;
    int py = (int)(t % PD); t /= PD;
    int pz = (int)(t % PD);
    if (px == 0 || px >= PD - 1 || py == 0 || py == PD - 1 || pz == 0 || pz == PD - 1)
        p[idx] = 0;
}

template <typename T>
__global__ __launch_bounds__(256) void zero_halo_t(T* __restrict__ p, int C, int PD)
{
    long total = (long)C * PD * PD * PD;
    long idx = (long)blockIdx.x * blockDim.x + threadIdx.x;
    if (idx >= total) return;
    int px = (int)(idx % PD); long t = idx / PD;
    int py = (int)(t % PD); t /= PD;
    int pz = (int)(t % PD);
    if (px == 0 || px == PD - 1 || py == 0 || py == PD - 1 || pz == 0 || pz == PD - 1)
        p[idx] = (T)0;
}

// ---------------------------------------------------------------------------
// Conv3d k4 s2 p1 as MFMA implicit GEMM, bf16 hi/lo pair inputs (enc1 only)
// ---------------------------------------------------------------------------
template <int CIN, int COUT, int DOUT, int PD, int PRX, int MTW, int OWT,
          int OWHALF, int KSPLIT, int OUTSPLIT>
__global__ __launch_bounds__(256)
void conv_s2_mfma(const unsigned short* __restrict__ xhi,
                  const unsigned short* __restrict__ xlo,
                  const short* __restrict__ Whi, const short* __restrict__ Wlo,
                  const float* __restrict__ bias,
                  unsigned short* __restrict__ yhi, unsigned short* __restrict__ ylo,
                  float* __restrict__ yf,
                  int OPD, int OPRX, int po, long sstride)
{
    constexpr int K = CIN * 64;
    constexpr int MWAVES = COUT / (16 * MTW);
    constexpr int RPB = 4 / MWAVES;
    constexpr int KN = (CIN * 2) / KSPLIT;

    int bx = blockIdx.x;
    const int ks = (KSPLIT > 1) ? (bx % KSPLIT) : 0;
    const int rowblk = (KSPLIT > 1) ? (bx / KSPLIT) : bx;
    const int lane = (int)threadIdx.x & 63, w = (int)threadIdx.x >> 6;
    const int mi = (MWAVES == 4) ? w : 0;
    const int ri = (MWAVES == 4) ? 0 : w;
    const int rowid = rowblk * RPB + ri;
    const int n16 = lane & 15, quad = lane >> 4;

    int b, od, oh, ow;
    if (OWHALF) {
        constexpr int NOH = DOUT / 2;
        const int ohb = rowid % NOH; int t = rowid / NOH;
        od = t % DOUT; b = t / DOUT;
        oh = ohb * 2 + (n16 >> 3);
        ow = n16 & 7;
    } else {
        const int owt = rowid % OWT; int t = rowid / OWT;
        oh = t % DOUT; t /= DOUT;
        od = t % DOUT; b = t / DOUT;
        ow = owt * 16 + n16;
    }

    const int co0 = mi * (MTW * 16);

    f32x4 acc[MTW];
    #pragma unroll
    for (int mt = 0; mt < MTW; ++mt)
        #pragma unroll
        for (int r = 0; r < 4; ++r) {
            int co = co0 + mt * 16 + quad * 4 + r;
            acc[mt][r] = (ks == 0) ? bias[co] : 0.0f;
        }

    const int sg0 = ks * KN;
    const long chs = (long)PD * PD * PRX;
    long off = ((long)(b * CIN + (sg0 >> 1)) * PD + (2 * od + (quad >> 1))) * PD * PRX
             + (long)(2 * oh + (quad & 1) * 2) * PRX + 2 * ow;
    const unsigned short* phi = xhi + off;
    const unsigned short* plo = xlo + off;
    const long incA = 2L * PD * PRX;
    const long incB = chs - 2L * PD * PRX;

    const short* a0h = Whi + (long)(co0 + n16) * K + sg0 * 32 + quad * 8;
    const short* a0l = Wlo + (long)(co0 + n16) * K + sg0 * 32 + quad * 8;

    #pragma unroll 2
    for (int s = 0; s < KN; ++s) {
        u16x4u h0 = *(const u16x4u*)phi;
        u16x4u h1 = *(const u16x4u*)(phi + PRX);
        u16x4u l0 = *(const u16x4u*)plo;
        u16x4u l1 = *(const u16x4u*)(plo + PRX);
        bf16x8 bhi = pack_b(h0, h1);
        bf16x8 blo = pack_b(l0, l1);
        #pragma unroll
        for (int mt = 0; mt < MTW; ++mt) {
            bf16x8 ah = *(const bf16x8*)(a0h + (long)mt * 16 * K + s * 32);
            bf16x8 al = *(const bf16x8*)(a0l + (long)mt * 16 * K + s * 32);
            acc[mt] = __builtin_amdgcn_mfma_f32_16x16x32_bf16(ah, bhi, acc[mt], 0, 0, 0);
            acc[mt] = __builtin_amdgcn_mfma_f32_16x16x32_bf16(ah, blo, acc[mt], 0, 0, 0);
            acc[mt] = __builtin_amdgcn_mfma_f32_16x16x32_bf16(al, bhi, acc[mt], 0, 0, 0);
        }
        long inc = (s & 1) ? incB : incA;
        phi += inc; plo += inc;
    }

    if (OUTSPLIT) {
        #pragma unroll
        for (int mt = 0; mt < MTW; ++mt)
            #pragma unroll
            for (int r = 0; r < 4; ++r) {
                int co = co0 + mt * 16 + quad * 4 + r;
                float v = fmaxf(acc[mt][r], 0.0f);
                unsigned short h, l;
                split_bf16(v, h, l);
                long o = (((long)(b * COUT + co) * OPD + od + po) * OPD + oh + po) * OPRX
                       + ow + po;
                yhi[o] = h; ylo[o] = l;
            }
    } else {
        #pragma unroll
        for (int mt = 0; mt < MTW; ++mt)
            #pragma unroll
            for (int r = 0; r < 4; ++r) {
                int co = co0 + mt * 16 + quad * 4 + r;
                long o = (long)ks * sstride
                       + (((long)(b * COUT + co) * OPD + od) * OPD + oh) * OPRX + ow;
                yf[o] = acc[mt][r];
            }
    }
}

// Fragment-direct variant (enc2/enc3): fragment-major Whi/Wlo, each wave
// loads its OWN disjoint (s,m) fragment blocks (coalesced 1KB dwordx4) --
// no LDS, no barriers. Bit-identical to the LDS path.
template <int CIN, int COUT, int DOUT, int PD, int PRX, int MTW, int OWT,
          int OWHALF, int KSPLIT, int OUTSPLIT>
__global__ __launch_bounds__(256)
void conv_s2_mfma_fd(const unsigned short* __restrict__ xhi,
                     const unsigned short* __restrict__ xlo,
                     const short* __restrict__ Whi, const short* __restrict__ Wlo,
                     const float* __restrict__ bias,
                     unsigned short* __restrict__ yhi, unsigned short* __restrict__ ylo,
                     float* __restrict__ yf,
                     int OPD, int OPRX, int po, long sstride)
{
    constexpr int MWAVES = COUT / (16 * MTW);
    constexpr int RPB = 4 / MWAVES;
    constexpr int KN = (CIN * 2) / KSPLIT;
    constexpr int MT = COUT >> 4;            // fragment-major m count
    constexpr int SSTEP = MT * 512;          // shorts per s-step in frag layout

    int bx = blockIdx.x;
    const int ks = (KSPLIT > 1) ? (bx % KSPLIT) : 0;
    const int rowblk = (KSPLIT > 1) ? (bx / KSPLIT) : bx;
    const int lane = (int)threadIdx.x & 63, w = (int)threadIdx.x >> 6;
    const int mi = (MWAVES == 4) ? w : 0;
    const int ri = (MWAVES == 4) ? 0 : w;
    const int rowid = rowblk * RPB + ri;
    const int n16 = lane & 15, quad = lane >> 4;

    int b, od, oh, ow;
    if (OWHALF) {
        constexpr int NOH = DOUT / 2;
        const int ohb = rowid % NOH; int t = rowid / NOH;
        od = t % DOUT; b = t / DOUT;
        oh = ohb * 2 + (n16 >> 3);
        ow = n16 & 7;
    } else {
        const int owt = rowid % OWT; int t = rowid / OWT;
        oh = t % DOUT; t /= DOUT;
        od = t % DOUT; b = t / DOUT;
        ow = owt * 16 + n16;
    }

    const int co0 = mi * (MTW * 16);

    f32x4 acc[MTW];
    #pragma unroll
    for (int mt = 0; mt < MTW; ++mt)
        #pragma unroll
        for (int r = 0; r < 4; ++r) {
            int co = co0 + mt * 16 + quad * 4 + r;
            acc[mt][r] = (ks == 0) ? bias[co] : 0.0f;
        }

    const int sg0 = ks * KN;
    const long chs = (long)PD * PD * PRX;
    long off = ((long)(b * CIN + (sg0 >> 1)) * PD + (2 * od + (quad >> 1))) * PD * PRX
             + (long)(2 * oh + (quad & 1) * 2) * PRX + 2 * ow;
    const unsigned short* phi = xhi + off;
    const unsigned short* plo = xlo + off;
    const long incA = 2L * PD * PRX;
    const long incB = chs - 2L * PD * PRX;

    // fragment-major: (s, m) block at ((s*MT + m)*64 + lane)*8
    const short* ph = Whi + (((long)sg0 * MT + mi * MTW) * 64 + lane) * 8;
    const short* pl = Wlo + (((long)sg0 * MT + mi * MTW) * 64 + lane) * 8;

    #pragma unroll 2
    for (int s = 0; s < KN; ++s) {
        u16x4u h0 = *(const u16x4u*)phi;
        u16x4u h1 = *(const u16x4u*)(phi + PRX);
        u16x4u l0 = *(const u16x4u*)plo;
        u16x4u l1 = *(const u16x4u*)(plo + PRX);
        bf16x8 bhi = pack_b(h0, h1);
        bf16x8 blo = pack_b(l0, l1);
        #pragma unroll
        for (int mt = 0; mt < MTW; ++mt) {
            bf16x8 ah = *(const bf16x8*)(ph + mt * 512);
            bf16x8 al = *(const bf16x8*)(pl + mt * 512);
            acc[mt] = __builtin_amdgcn_mfma_f32_16x16x32_bf16(ah, bhi, acc[mt], 0, 0, 0);
            acc[mt] = __builtin_amdgcn_mfma_f32_16x16x32_bf16(ah, blo, acc[mt], 0, 0, 0);
            acc[mt] = __builtin_amdgcn_mfma_f32_16x16x32_bf16(al, bhi, acc[mt], 0, 0, 0);
        }
        long inc = (s & 1) ? incB : incA;
        phi += inc; plo += inc;
        ph += SSTEP; pl += SSTEP;
    }

    if (OUTSPLIT) {
        #pragma unroll
        for (int mt = 0; mt < MTW; ++mt)
            #pragma unroll
            for (int r = 0; r < 4; ++r) {
                int co = co0 + mt * 16 + quad * 4 + r;
                float v = fmaxf(acc[mt][r], 0.0f);
                unsigned short h, l;
                split_bf16(v, h, l);
                long o = (((long)(b * COUT + co) * OPD + od + po) * OPD + oh + po) * OPRX
                       + ow + po;
                yhi[o] = h; ylo[o] = l;
            }
    } else {
        #pragma unroll
        for (int mt = 0; mt < MTW; ++mt)
            #pragma unroll
            for (int r = 0; r < 4; ++r) {
                int co = co0 + mt * 16 + quad * 4 + r;
                long o = (long)ks * sstride
                       + (((long)(b * COUT + co) * OPD + od) * OPD + oh) * OPRX + ow;
                yf[o] = acc[mt][r];
            }
    }
}

__global__ __launch_bounds__(256)
void combine4_relu(const float* __restrict__ p, float* __restrict__ y, long N, long ss)
{
    long idx = (long)blockIdx.x * blockDim.x + threadIdx.x;
    if (idx >= N) return;
    float v = p[idx] + p[idx + ss] + p[idx + 2 * ss] + p[idx + 3 * ss];
    y[idx] = fmaxf(v, 0.0f);
}

// ---------------- 1x1 conv (fp32 exact) ----------------
__global__ __launch_bounds__(128)
void conv1x1_b(const float* __restrict__ x, const float* __restrict__ w,
               const float* __restrict__ bias, float* __restrict__ y)
{
    const int co = blockIdx.x & 255, b = blockIdx.x >> 8;
    const int s4 = (int)threadIdx.x * 4;
    const float* xb = x + (long)b * 256 * 512 + s4;
    const float* wr = w + (long)co * 256;      // uniform -> s_load
    float bv = bias[co];
    float4 acc = {bv, bv, bv, bv};
    for (int ci = 0; ci < 256; ++ci) {
        float wv = wr[ci];
        float4 xv = *(const float4*)(xb + (long)ci * 512);
        acc.x = fmaf(xv.x, wv, acc.x); acc.y = fmaf(xv.y, wv, acc.y);
        acc.z = fmaf(xv.z, wv, acc.z); acc.w = fmaf(xv.w, wv, acc.w);
    }
    *(float4*)(y + (long)(b * 256 + co) * 512 + s4) = acc;
}

// ---------------- VQ (fp32 exact) ----------------
__global__ void codenorm_kernel(const float* __restrict__ cb, float* __restrict__ norms)
{
    int k = blockIdx.x;
    int lane = threadIdx.x;
    float s = 0.0f;
    const float* row = cb + (long)k * 256;
    for (int d = lane; d < 256; d += 64) { float v = row[d]; s = fmaf(v, v, s); }
    for (int off = 32; off > 0; off >>= 1) s += __shfl_down(s, off);
    if (lane == 0) norms[k] = s;
}

// cbT[d*1024 + k] = cb[k*256 + d]  (fp32 copy -> values unchanged)
__global__ __launch_bounds__(256)
void transpose_cb(const float* __restrict__ cb, float* __restrict__ cbT)
{
    int idx = blockIdx.x * 256 + (int)threadIdx.x;    // 0..262143
    int d = idx & 255, k = idx >> 8;
    cbT[(long)d * 1024 + k] = cb[(long)k * 256 + d];
}

// R24: 4 rows/block (grid 256), coalesced cbT float4 loads (codes 4t..4t+3),
// rows staged in LDS. Bit-identical to the original per-row kernel.
__global__ __launch_bounds__(256)
void vq_kernel4(const float* __restrict__ lat, const float* __restrict__ cb,
                const float* __restrict__ cbT, const float* __restrict__ norms,
                unsigned short* __restrict__ q, float* __restrict__ idx_out)
{
    __shared__ __align__(16) float rows[4][256];
    __shared__ float s_best[4][256];
    __shared__ int   s_bidx[4][256];
    const int r0 = blockIdx.x * 4;
    const int t = (int)threadIdx.x;

    #pragma unroll
    for (int j = 0; j < 4; ++j)
        rows[j][t] = lat[(long)(r0 + j) * 256 + t];
    __syncthreads();

    // latn per row -- identical float4 fmaf chain to the original
    float latn[4];
    #pragma unroll
    for (int j = 0; j < 4; ++j) {
        const float4* rowv = (const float4*)rows[j];
        float a = 0.0f;
        #pragma unroll 4
        for (int d = 0; d < 64; ++d) {
            float4 rv = rowv[d];
            a = fmaf(rv.x, rv.x, a); a = fmaf(rv.y, rv.y, a);
            a = fmaf(rv.z, rv.z, a); a = fmaf(rv.w, rv.w, a);
        }
        latn[j] = a;
    }

    // codes 4t..4t+3; dot[j][c] accumulates d = 0..255 sequentially (same
    // chain as the original scalar loop)
    float dot[4][4] = {};
    const float* ct = cbT + t * 4;
    #pragma unroll 4
    for (int d = 0; d < 256; ++d) {
        float4 c4 = *(const float4*)(ct + (long)d * 1024);
        #pragma unroll
        for (int j = 0; j < 4; ++j) {
            float rv = rows[j][d];
            dot[j][0] = fmaf(rv, c4.x, dot[j][0]);
            dot[j][1] = fmaf(rv, c4.y, dot[j][1]);
            dot[j][2] = fmaf(rv, c4.z, dot[j][2]);
            dot[j][3] = fmaf(rv, c4.w, dot[j][3]);
        }
    }

    float4 nv = *(const float4*)(norms + t * 4);
    float nr[4] = {nv.x, nv.y, nv.z, nv.w};

    #pragma unroll
    for (int j = 0; j < 4; ++j) {
        float best = FLT_MAX;
        int bidx = 0x7fffffff;
        #pragma unroll
        for (int c = 0; c < 4; ++c) {
            float sc = latn[j] - 2.0f * dot[j][c] + nr[c];
            int k = t * 4 + c;
            if (sc < best || (sc == best && k < bidx)) { best = sc; bidx = k; }
        }
        s_best[j][t] = best; s_bidx[j][t] = bidx;
    }
    __syncthreads();
    for (int off = 128; off > 0; off >>= 1) {
        if (t < off) {
            #pragma unroll
            for (int j = 0; j < 4; ++j) {
                float o = s_best[j][t + off]; int oi = s_bidx[j][t + off];
                if (o < s_best[j][t] || (o == s_best[j][t] && oi < s_bidx[j][t])) {
                    s_best[j][t] = o; s_bidx[j][t] = oi;
                }
            }
        }
        __syncthreads();
    }

    #pragma unroll
    for (int j = 0; j < 4; ++j) {
        const int bk = s_bidx[j][0];
        const int r = r0 + j;
        const int b = r >> 9, n = r & 511;
        const int zz = n >> 6, yy = (n >> 3) & 7, xx = n & 7;
        q[(long)(b * 256 + t) * 1000 + ((long)(zz + 1) * 10 + (yy + 1)) * 10 + (xx + 1)]
            = f32_to_bf16(cb[(long)bk * 256 + t]);
    }
    if (t == 0) {
        #pragma unroll
        for (int j = 0; j < 4; ++j)
            idx_out[r0 + j] = (float)s_bidx[j][0];
    }
}

// ---------------- decoder: MFMA implicit-GEMM ConvTranspose ----------------
// xflip=0: B slot a <-> x offset (1-ax), kw=(1-px)+2*ax (old cube kernel).
// xflip=1: B slot a <-> x offset ax,     kw=(1-px)+2*(1-ax) (dword-pair kernel).
__global__ __launch_bounds__(256)
void prep_convt_w(const float* __restrict__ w, short* __restrict__ Ap,
                  int Cin, int Cout, int xflip)
{
    const int K = Cin * 8;
    long total = 8L * Cout * K;
    long idx = (long)blockIdx.x * blockDim.x + threadIdx.x;
    if (idx >= total) return;
    int k = (int)(idx % K);
    int co = (int)((idx / K) % Cout);
    int p = (int)(idx / ((long)K * Cout));
    int ci = k >> 3, a = k & 7;
    int az = (a >> 2) & 1, ay = (a >> 1) & 1, ax = a & 1;
    int pz = p >> 2, py = (p >> 1) & 1, px = p & 1;
    int axw = xflip ? (1 - ax) : ax;
    int kd = (1 - pz) + 2 * az, kh = (1 - py) + 2 * ay, kw = (1 - px) + 2 * axw;
    float v = w[((long)ci * Cout + co) * 64 + kd * 16 + kh * 4 + kw];
    Ap[idx] = (short)f32_to_bf16(v);
}

// Fragment-major layout for the LDS-staged v2 kernel:
//   ApN[((p*MG + mg)*nsteps + s)*2048 + cb*512 + l*8 + kk]
__global__ __launch_bounds__(256)
void prep_convt_w_frag(const float* __restrict__ w, short* __restrict__ Ap,
                       int Cin, int Cout, int xflip)
{
    const int MG = Cout >> 6;
    const int nsteps = Cin >> 2;             // (Cin*8)/32
    long total = 8L * MG * nsteps * 2048;
    long idx = (long)blockIdx.x * blockDim.x + threadIdx.x;
    if (idx >= total) return;
    int kk = (int)(idx & 7); long r = idx >> 3;
    int l  = (int)(r & 63);  r >>= 6;
    int cb = (int)(r & 3);   r >>= 2;
    int s  = (int)(r % nsteps); r /= nsteps;
    int mg = (int)(r % MG);
    int p  = (int)(r / MG);

    int n16 = l & 15, quad = l >> 4;
    int korig = s * 32 + quad * 8 + kk;
    int co = mg * 64 + cb * 16 + n16;
    int ci = korig >> 3, a = korig & 7;
    int az = (a >> 2) & 1, ay = (a >> 1) & 1, ax = a & 1;
    int pz = p >> 2, py = (p >> 1) & 1, px = p & 1;
    int axw = xflip ? (1 - ax) : ax;
    int kd = (1 - pz) + 2 * az, kh = (1 - py) + 2 * ay, kw = (1 - px) + 2 * axw;
    float v = w[((long)ci * Cout + co) * 64 + kd * 16 + kh * 4 + kw];
    Ap[idx] = (short)f32_to_bf16(v);
}

// Old cube-N layout (kept for dec1, DIN=8): round-0 body.
template <int CIN, int COUT, int DIN, int OPAD, typename OutT>
__global__ __launch_bounds__(256)
void convt_mfma(const unsigned short* __restrict__ Xp, const short* __restrict__ Ap,
                const float* __restrict__ bias, OutT* __restrict__ Y)
{
    constexpr int PD = DIN + 2;
    constexpr int PD3 = PD * PD * PD;
    constexpr int T = DIN >> 2;
    constexpr int NT = T * T * T;
    constexpr int SLAB = NT / 8;
    constexpr int OPD = 2 * DIN + 2 * OPAD;
    constexpr int K = CIN * 8;
    constexpr int MG = COUT >> 6;
    constexpr int nsteps = K >> 5;

    int bx = blockIdx.x;
    const int xcd = bx & 7;
    int local = bx >> 3;
    const int px = local & 1; local >>= 1;
    const int mg = local % MG; local /= MG;
    const int ntin = local % SLAB;
    const int pzy = local / SLAB;            // 0..3
    const int pz = pzy >> 1, py = pzy & 1;
    const int p = pz * 4 + py * 2 + px;
    const int nt = xcd * SLAB + ntin;

    const int lane = threadIdx.x & 63, wave = threadIdx.x >> 6;
    const int n16 = lane & 15, quad = lane >> 4;

    const int tx = nt % T, ty = (nt / T) % T, tz = nt / (T * T);
    const int mz = tz * 4 + wave, my = ty * 4 + (n16 >> 2), mx = tx * 4 + (n16 & 3);
    const int sp = ((mz + pz) * PD + (my + py)) * PD + (mx + px);

    const unsigned short* xq = Xp + (long)quad * PD3 + sp;

    const int cobase = mg * 64;
    const short* ap0 = Ap + ((long)p * COUT + cobase + n16) * K + quad * 8;

    f32x4 acc[4];
    #pragma unroll
    for (int cb = 0; cb < 4; ++cb) {
        const float* bp = bias + cobase + cb * 16 + quad * 4;
        acc[cb][0] = bp[0]; acc[cb][1] = bp[1]; acc[cb][2] = bp[2]; acc[cb][3] = bp[3];
    }

    #pragma unroll 4
    for (int s = 0; s < nsteps; ++s) {
        const unsigned short* xs = xq + (long)s * 4 * PD3;
        bf16x8 bf;
        bf[0] = (short)xs[(PD + 1) * PD + 1];
        bf[1] = (short)xs[(PD + 1) * PD];
        bf[2] = (short)xs[PD * PD + 1];
        bf[3] = (short)xs[PD * PD];
        bf[4] = (short)xs[PD + 1];
        bf[5] = (short)xs[PD];
        bf[6] = (short)xs[1];
        bf[7] = (short)xs[0];
        #pragma unroll
        for (int cb = 0; cb < 4; ++cb) {
            bf16x8 af = *(const bf16x8*)(ap0 + (long)cb * 16 * K + s * 32);
            acc[cb] = __builtin_amdgcn_mfma_f32_16x16x32_bf16(af, bf, acc[cb], 0, 0, 0);
        }
    }

    const int opz = 2 * mz + pz + OPAD, opy = 2 * my + py + OPAD, opx = 2 * mx + px + OPAD;
    const long spo = ((long)opz * OPD + opy) * OPD + opx;
    #pragma unroll
    for (int cb = 0; cb < 4; ++cb) {
        #pragma unroll
        for (int r = 0; r < 4; ++r) {
            int co = cobase + cb * 16 + quad * 4 + r;
            float v = fmaxf(acc[cb][r], 0.0f);
            store_act(Y + (long)co * OPD * OPD * OPD + spo, v);
        }
    }
}

// Dword-pair B-gather (dec2/dec3), R29: 2 K-steps per barrier phase.
// Per-acc MFMA order = old sequential s => bit-identical.
template <int CIN, int COUT, int DIN, int OPAD, int MXP, int MYP, typename OutT>
__global__ __launch_bounds__(256)
void convt_mfma_v2(const unsigned short* __restrict__ Xp, const short* __restrict__ Ap,
                   const float* __restrict__ bias, OutT* __restrict__ Y)
{
    constexpr int PD = DIN + 2;
    constexpr int PD3 = PD * PD * PD;
    constexpr int OPD = 2 * DIN + 2 * OPAD;
    constexpr int K = CIN * 8;
    constexpr int MG = COUT >> 6;
    constexpr int nsteps = K >> 5;
    static_assert((nsteps & 1) == 0 && nsteps >= 4, "phase merge needs even nsteps");
    constexpr int NPH = nsteps / 2;
    constexpr int MXT = DIN / (16 * MXP);
    constexpr int MYT = DIN / (4 * MYP);
    constexpr int MZS = DIN / 8;             // mz per XCD slab
    constexpr int TPE = MXP * MYP;           // tiles per wave (one of MXP/MYP is 1)

    int bx = blockIdx.x;
    const int xcd = bx & 7;
    int local = bx >> 3;
    const int px = local & 1; local >>= 1;
    const int py = local & 1; local >>= 1;
    const int mg = local % MG; local /= MG;
    const int mxt = local % MXT; local /= MXT;
    const int myt = local % MYT; local /= MYT;
    const int pz = local & 1; local >>= 1;
    const int mzin = local;                  // 0..MZS-1
    const int mz = xcd * MZS + mzin;
    const int p = pz * 4 + py * 2 + px;

    const int lane = threadIdx.x & 63, wave = threadIdx.x >> 6;
    const int n16 = lane & 15, quad = lane >> 4;

    const int mx0 = mxt * (16 * MXP) + n16;
    const int my0 = myt * (4 * MYP) + wave * MYP;
    const int baseX = mx0 & ~1;
    const int sh = 16 * ((n16 & 1) + px);    // 0, 16, or 32
    const long sp = ((long)(mz + pz) * PD + (my0 + py)) * PD + baseX;

    const unsigned short* xq = Xp + (long)quad * PD3 + sp;

    // fragment-major weight tiles: 2048 shorts (4KB) per (p,mg,s)
    const short* ApT = Ap + (((long)p * MG + mg) * nsteps) * 2048;

    __shared__ short Abuf[2][2][2048];       // 16KB: dbuf x 2-steps x 4KB

    f32x4 acc[TPE][4];
    #pragma unroll
    for (int t = 0; t < TPE; ++t)
        #pragma unroll
        for (int cb = 0; cb < 4; ++cb) {
            const float* bp = bias + (mg * 64) + cb * 16 + quad * 4;
            acc[t][cb][0] = bp[0]; acc[t][cb][1] = bp[1];
            acc[t][cb][2] = bp[2]; acc[t][cb][3] = bp[3];
        }

    constexpr int rowoff[4] = { (PD + 1) * PD, PD * PD, PD, 0 };
    union Frag { unsigned u[4]; bf16x8 b; };

    const int chunkoff = wave * 512 + lane * 8;   // this thread's 16B of a 4KB tile

    // prologue: stage steps 0 and 1
    {
        *(bf16x8*)(&Abuf[0][0][chunkoff]) = *(const bf16x8*)(ApT + chunkoff);
        *(bf16x8*)(&Abuf[0][1][chunkoff]) = *(const bf16x8*)(ApT + 2048 + chunkoff);
    }
    __syncthreads();

    #pragma unroll 1
    for (int ph = 0; ph < NPH; ++ph) {
        const int cur = ph & 1;
        const bool more = (ph + 1 < NPH);
        bf16x8 an0, an1;
        if (more) {
            an0 = *(const bf16x8*)(ApT + (long)(2 * ph + 2) * 2048 + chunkoff);
            an1 = *(const bf16x8*)(ApT + (long)(2 * ph + 3) * 2048 + chunkoff);
        }

        // X loads for both steps (raw staging; 2x loads in flight)
        unsigned long long xr[2][TPE][4];
        #pragma unroll
        for (int u = 0; u < 2; ++u) {
            const unsigned short* xs = xq + (long)(2 * ph + u) * 4 * PD3;
            #pragma unroll
            for (int t = 0; t < TPE; ++t) {
                const int toff = (MXP > 1) ? t * 16 : t * PD;
                #pragma unroll
                for (int j = 0; j < 4; ++j) {
                    union { u16x4u v; unsigned long long u64; } ld;
                    ld.v = *(const u16x4u*)(xs + toff + rowoff[j]);
                    xr[u][t][j] = ld.u64;
                }
            }
        }

        // A fragments from LDS for both steps
        bf16x8 af[2][4];
        #pragma unroll
        for (int u = 0; u < 2; ++u)
            #pragma unroll
            for (int cb = 0; cb < 4; ++cb)
                af[u][cb] = *(const bf16x8*)(&Abuf[cur][u][cb * 512 + lane * 8]);

        // MFMA: step 2ph then 2ph+1 (old sequential order)
        #pragma unroll
        for (int u = 0; u < 2; ++u) {
            #pragma unroll
            for (int t = 0; t < TPE; ++t) {
                Frag fr;
                #pragma unroll
                for (int j = 0; j < 4; ++j)
                    fr.u[j] = (unsigned)(xr[u][t][j] >> sh);
                #pragma unroll
                for (int cb = 0; cb < 4; ++cb)
                    acc[t][cb] = __builtin_amdgcn_mfma_f32_16x16x32_bf16(af[u][cb], fr.b,
                                                                         acc[t][cb], 0, 0, 0);
            }
        }

        if (more) {
            *(bf16x8*)(&Abuf[cur ^ 1][0][chunkoff]) = an0;
            *(bf16x8*)(&Abuf[cur ^ 1][1][chunkoff]) = an1;
        }
        __syncthreads();
    }

    const int opz = 2 * mz + pz + OPAD;
    #pragma unroll
    for (int t = 0; t < TPE; ++t) {
        const int opx = 2 * (mx0 + ((MXP > 1) ? t * 16 : 0)) + px + OPAD;
        const int opy = 2 * (my0 + ((MYP > 1) ? t : 0)) + py + OPAD;
        const long spo = ((long)opz * OPD + opy) * OPD + opx;
        #pragma unroll
        for (int cb = 0; cb < 4; ++cb) {
            #pragma unroll
            for (int r = 0; r < 4; ++r) {
                int co = (mg * 64) + cb * 16 + quad * 4 + r;
                float v = fmaxf(acc[t][cb][r], 0.0f);
                store_act(Y + (long)co * OPD * OPD * OPD + spo, v);
            }
        }
    }
}

// ---------------- dec4 as MFMA GEMM, R30: bf16 d3 input ----------------
// Fragment-major: Aw[(s*64 + lane)*8 + kk] (unchanged from R23).
__global__ __launch_bounds__(256)
void prep_dec4A_frag(const float* __restrict__ w, short* __restrict__ Aw)
{
    int idx = blockIdx.x * 256 + (int)threadIdx.x;    // 0..65535
    int kk = idx & 7;
    int l  = (idx >> 3) & 63;
    int s  = idx >> 9;                                // 0..127
    int n16 = l & 15, quad = l >> 4;
    int k = s * 32 + quad * 8 + kk;
    float v = (n16 < 3) ? w[n16 * 4096 + k] : 0.0f;
    Aw[idx] = (short)f32_to_bf16(v);
}

// R30: d3 is now truncated-bf16 (ushort). Xs rows are ushorts, RS=80:
// read windows (rows {base,+2,+7,+9}, 40*{0,2,7,9} mod 32 = {0,16,24,8})
// max 2-way = free; staging wave-pass writes 64 consecutive shorts = free.
// Fragment words p0/p1 rebuilt from shorts via 64-bit shifts: identical
// bits to the old fp32-truncation pack => bit-identical output.
__global__ __launch_bounds__(256)
void conv_dec4_mfma(const unsigned short* __restrict__ d3h, const short* __restrict__ Aw,
                    const float* __restrict__ bias, float* __restrict__ y)
{
    constexpr int D = 64, Dout = 61;
    constexpr int RS = 80;                 // row stride (shorts)
    int bx = blockIdx.x;
    const int slab = bx & 7;
    const int i = bx >> 3;                 // 0..127
    const int od = slab * 8 + (i >> 4);
    const int oh0 = (i & 15) * 4;          // covers oh0..oh0+3 (guard < 61)
    if (od >= Dout) return;                // uniform per block -> barriers safe
    const int tid = (int)threadIdx.x;
    const int lane = tid & 63, wave = tid >> 6;
    const int n16 = lane & 15, quad = lane >> 4;
    const int ow = wave * 16 + n16;

    // [dbuf][row 0..27][x 0..79] shorts; cols 64..79 uninitialized (only
    // consumed by discarded ow>=61 columns; reads reach short (ow&~1)+7 <= 69)
    __shared__ unsigned short Xs[2][28][RS];
    unsigned short* xsb = &Xs[0][0][0];
    constexpr int BUFW = 28 * RS;          // shorts per buffer

    f32x4 acc[4];
    #pragma unroll
    for (int j = 0; j < 4; ++j)
        #pragma unroll
        for (int r = 0; r < 4; ++r) {
            int co = quad * 4 + r;
            acc[j][r] = (co < 3) ? bias[co] : 0.0f;
        }

    const int kd0 = quad >> 1;
    const int kh0 = (quad & 1) * 2;
    const int sha = 16 * (ow & 1);
    const int owb = ow & ~1;

    // strided staging: thread t (t<224) owns shorts g = t + 224*j, j=0..7 of
    // the 1792-short (28 rows x 64) tile. row = g/64 -> (szi = row/7,
    // syi = row%7); global z = od + szi, y = min(oh0+syi, 63), x = g%64.
    const bool sact = (tid < 224);
    int goff[8];                           // global short offset (ci-invariant)
    int loff[8];                           // LDS short offset within a buffer
    #pragma unroll
    for (int j = 0; j < 8; ++j) {
        const int g = tid + 224 * j;
        const int row = g >> 6, xx = g & 63;
        const int szi = row / 7, syi = row % 7;
        goff[j] = ((od + szi) * D + min(oh0 + syi, D - 1)) * D + xx;
        loff[j] = row * RS + xx;
    }
    auto choff = [](int S) { return (long)S * D * D * D; };

    // prologue: stage step 0
    if (sact) {
        #pragma unroll
        for (int j = 0; j < 8; ++j)
            xsb[loff[j]] = d3h[goff[j]];
    }
    __syncthreads();

    #pragma unroll 1
    for (int S = 0; S < 64; ++S) {
        const int cur = S & 1;
        const bool more = (S + 1 < 64);
        unsigned short nv[8];
        if (more && sact) {
            const unsigned short* src = d3h + choff(S + 1);
            #pragma unroll
            for (int j = 0; j < 8; ++j)
                nv[j] = src[goff[j]];
        }

        #pragma unroll
        for (int h = 0; h < 2; ++h) {
            bf16x8 af = *(const bf16x8*)(Aw + ((long)(2 * S + h) * 64 + lane) * 8);
            unsigned p0[5], p1[5];
            #pragma unroll
            for (int r = 0; r < 5; ++r) {
                const int row = 14 * h + kd0 * 7 + kh0 + r;
                union { u16x8a4 v; unsigned long long q[2]; } ld;
                ld.v = *(const u16x8a4*)(xsb + cur * BUFW + row * RS + owb);
                // shorts owb..owb+7; need ow..ow+3:
                p0[r] = (unsigned)(ld.q[0] >> sha);
                p1[r] = (unsigned)(((ld.q[0] >> 32) | (ld.q[1] << 32)) >> sha);
            }
            #pragma unroll
            for (int j = 0; j < 4; ++j) {
                union { unsigned u[4]; bf16x8 b; } fr;
                fr.u[0] = p0[j];     fr.u[1] = p1[j];
                fr.u[2] = p0[j + 1]; fr.u[3] = p1[j + 1];
                acc[j] = __builtin_amdgcn_mfma_f32_16x16x32_bf16(af, fr.b, acc[j], 0, 0, 0);
            }
        }

        if (more && sact) {
            unsigned short* dst = xsb + (cur ^ 1) * BUFW;
            #pragma unroll
            for (int j = 0; j < 8; ++j)
                dst[loff[j]] = nv[j];
        }
        __syncthreads();
    }

    if (ow < Dout && quad == 0) {
        #pragma unroll
        for (int j = 0; j < 4; ++j) {
            const int oh = oh0 + j;
            if (oh >= Dout) continue;
            #pragma unroll
            for (int r = 0; r < 3; ++r)
                y[((long)(r * Dout + od) * Dout + oh) * Dout + ow] = tanhf(acc[j][r]);
        }
    }
}

extern "C" void kernel_launch(void* const* d_in, const int* in_sizes, int n_in,
                              void* d_out, int out_size, void* d_ws, size_t ws_size,
                              hipStream_t stream)
{
    const float* x        = (const float*)d_in[0];
    const float* enc_w1   = (const float*)d_in[1];
    const float* enc_b1   = (const float*)d_in[2];
    const float* enc_w2   = (const float*)d_in[3];
    const float* enc_b2   = (const float*)d_in[4];
    const float* enc_w3   = (const float*)d_in[5];
    const float* enc_b3   = (const float*)d_in[6];
    const float* enc_w4   = (const float*)d_in[7];
    const float* enc_b4   = (const float*)d_in[8];
    const float* codebook = (const float*)d_in[9];
    const float* dec_w1   = (const float*)d_in[10];
    const float* dec_b1   = (const float*)d_in[11];
    const float* dec_w2   = (const float*)d_in[12];
    const float* dec_b2   = (const float*)d_in[13];
    const float* dec_w3   = (const float*)d_in[14];
    const float* dec_b3   = (const float*)d_in[15];
    const float* dec_w4   = (const float*)d_in[16];
    const float* dec_b4   = (const float*)d_in[17];

    float* out = (float*)d_out;
    float* idx_out = out + 2L * 3 * 61 * 61 * 61;

    // ---- workspace (byte offsets) ----
    char* wsb = (char*)d_ws;
    float*          cn   = (float*)wsb;                        //      4,096
    unsigned short* qp   = (unsigned short*)(wsb + 4096);      //  1,024,000
    short*          Ap1  = (short*)(wsb + 1028096);            //  8,388,608
    short*          Ap2  = (short*)(wsb + 9416704);            //  4,194,304
    short*          Ap3  = (short*)(wsb + 13611008);           //  1,048,576
    short*          Aw4  = (short*)(wsb + 14659584);           //    131,072
    short*          W1hi = (short*)(wsb + 14790656);           //     24,576
    short*          W1lo = (short*)(wsb + 14815232);           //     24,576
    short*          W2hi = (short*)(wsb + 14839808);           //  1,048,576
    short*          W2lo = (short*)(wsb + 15888384);           //  1,048,576
    short*          W3hi = (short*)(wsb + 16936960);           //  4,194,304
    short*          W3lo = (short*)(wsb + 21131264);           //  4,194,304
    char* arena = wsb + 25325568;
    // encoder phase:
    unsigned short* xphi = (unsigned short*)arena;                    // (2,3,66,66,68)
    unsigned short* xplo = (unsigned short*)(arena + 3554496);
    unsigned short* h1hi = (unsigned short*)(arena + 7108992);        // (2,64,34,34,36)
    unsigned short* h1lo = (unsigned short*)(arena + 17762688);
    unsigned short* h2hi = (unsigned short*)(arena + 28416384);       // (2,128,18,18,20)
    unsigned short* h2lo = (unsigned short*)(arena + 31734144);
    float*          pp3  = (float*)(arena + 35051904);                // 4x(2,256,8^3)
    float*          h3   = (float*)(arena + 39246208);                // (2,256,512)
    float*          lat  = (float*)(arena + 40294784);                // (2,256,512)
    // decoder phase (after VQ; overlaps encoder buffers):
    unsigned short* d1 = (unsigned short*)arena;                      // (256,18^3) bf16
    unsigned short* d2 = (unsigned short*)(arena + 2985984);          // (128,34^3) bf16
    bf16t*          d3 = (bf16t*)(arena + 13047808);                  // (64,64^3) bf16-trunc
    // arena peak < 80.2 MB -> ws used 105.5 MB; cbT appended below:
    float*          cbT = (float*)(wsb + 105482240);                  // 1,048,576
    // total 106.5 MB (< 112.2 MB proven in R0)

    dim3 blk(256);
    auto nblk = [](long n) { return dim3((unsigned)((n + 255) / 256)); };

    // ---- weight prep ----
    prep_convt_w<<<nblk(8L * 256 * 2048), blk, 0, stream>>>(dec_w1, Ap1, 256, 256, 0);
    prep_convt_w_frag<<<nblk(8L * 128 * 2048), blk, 0, stream>>>(dec_w2, Ap2, 256, 128, 1);
    prep_convt_w_frag<<<nblk(8L * 64 * 1024), blk, 0, stream>>>(dec_w3, Ap3, 128, 64, 1);
    prep_dec4A_frag<<<dim3(256), blk, 0, stream>>>(dec_w4, Aw4);
    prep_split_w<<<nblk(12288), blk, 0, stream>>>(enc_w1, W1hi, W1lo, 12288);
    prep_split_w_frag<<<nblk(524288), blk, 0, stream>>>(enc_w2, W2hi, W2lo, 64, 128);
    prep_split_w_frag<<<nblk(2097152), blk, 0, stream>>>(enc_w3, W3hi, W3lo, 128, 256);
    transpose_cb<<<dim3(1024), blk, 0, stream>>>(codebook, cbT);

    // ---- encoder (MFMA, bf16-pair) ----
    pad_input_split<<<nblk(6L * 66 * 66 * 68), blk, 0, stream>>>(x, xphi, xplo);
    zero_halo_ps<<<nblk(128L * 34 * 34 * 36), blk, 0, stream>>>(h1hi, 128, 34, 36);
    zero_halo_ps<<<nblk(128L * 34 * 34 * 36), blk, 0, stream>>>(h1lo, 128, 34, 36);
    conv_s2_mfma<3, 64, 32, 66, 68, 4, 2, 0, 1, 1><<<dim3(1024), blk, 0, stream>>>(
        xphi, xplo, W1hi, W1lo, enc_b1, h1hi, h1lo, nullptr, 34, 36, 1, 0);
    zero_halo_ps<<<nblk(256L * 18 * 18 * 20), blk, 0, stream>>>(h2hi, 256, 18, 20);
    zero_halo_ps<<<nblk(256L * 18 * 18 * 20), blk, 0, stream>>>(h2lo, 256, 18, 20);
    conv_s2_mfma_fd<64, 128, 16, 34, 36, 2, 1, 0, 1, 1><<<dim3(512), blk, 0, stream>>>(
        h1hi, h1lo, W2hi, W2lo, enc_b2, h2hi, h2lo, nullptr, 18, 20, 1, 0);
    conv_s2_mfma_fd<128, 256, 8, 18, 20, 4, 1, 1, 4, 0><<<dim3(256), blk, 0, stream>>>(
        h2hi, h2lo, W3hi, W3lo, enc_b3, nullptr, nullptr, pp3, 8, 8, 0, 262144);
    combine4_relu<<<nblk(262144), blk, 0, stream>>>(pp3, h3, 262144, 262144);
    conv1x1_b<<<dim3(512), dim3(128), 0, stream>>>(h3, enc_w4, enc_b4, lat);

    // ---- VQ (fp32 exact) ----
    codenorm_kernel<<<dim3(1024), dim3(64), 0, stream>>>(codebook, cn);
    zero_halo_t<unsigned short><<<nblk(512L * 10 * 10 * 10), blk, 0, stream>>>(qp, 512, 10);
    vq_kernel4<<<dim3(256), blk, 0, stream>>>(lat, codebook, cbT, cn, qp, idx_out);

    // ---- decoder halos ----
    zero_halo_t<unsigned short><<<nblk(256L * 18 * 18 * 18), blk, 0, stream>>>(d1, 256, 18);
    zero_halo_t<unsigned short><<<nblk(128L * 34 * 34 * 34), blk, 0, stream>>>(d2, 128, 34);

    // ---- decoder (MFMA) per batch ----
    for (int b = 0; b < 2; ++b) {
        const unsigned short* qb = qp + (long)b * 256 * 1000;
        float* outb = out + (long)b * 3 * 226981;
        // dec1 (DIN=8, old layout): grid = 8*2*4*1*4 = 256
        convt_mfma<256, 256, 8, 1, unsigned short><<<dim3(256), blk, 0, stream>>>(
            qb, Ap1, dec_b1, d1);
        // dec2 (v2, MXP=1 MYP=2): grid = 8 * (2*2*2*1*2*2*2) = 512
        convt_mfma_v2<256, 128, 16, 1, 1, 2, unsigned short><<<dim3(512), blk, 0, stream>>>(
            d1, Ap2, dec_b2, d2);
        // dec3 (v2, MXP=2 MYP=1): grid = 8 * (2*2*1*1*8*2*4) = 2048, bf16t out
        convt_mfma_v2<128, 64, 32, 0, 2, 1, bf16t><<<dim3(2048), blk, 0, stream>>>(
            d2, Ap3, dec_b3, d3);
        conv_dec4_mfma<<<dim3(8 * 8 * 16), blk, 0, stream>>>(
            (const unsigned short*)d3, Aw4, dec_b4, outb);
    }
}